// Round 1
// baseline (1696.835 us; speedup 1.0000x reference)
//
#include <hip/hip_runtime.h>
#include <math.h>

#define KNN 75
#define NL 8
#define NB 1024
#define NT 50000
#define NT_PAD 50048  // NTB*TT rows allocated for bf16 banks (pad rows masked)
#define NCALI 10000
#define KC 32
#define QT 64
#define TT 128
#define NTB 391       // ceil(NT/TT)
#define CAP 6144      // candidate buffer per query
#define NSUB 2048     // sampled train points for threshold
#define SSTRIDE 24
#define SOFF 11       // 11 + 24*2047 = 49139 < 50000
#define RSEL 32       // sample rank -> expected |{k < T}| ~ 780 per query
#define CNTP 32       // cntq padding (uints) -> one counter per 128B line

typedef __attribute__((ext_vector_type(8))) short bf16x8;
typedef __attribute__((ext_vector_type(4))) float f32x4;

__device__ __forceinline__ int swz(int c){ return c + ((c>>5)<<2); }

__device__ __forceinline__ unsigned short f2bf_rn(float x){
  unsigned u = __float_as_uint(x);
  unsigned r = (u + 0x7FFFu + ((u>>16)&1u)) >> 16;
  return (unsigned short)r;
}
__device__ __forceinline__ float bf2f(unsigned short h){
  return __uint_as_float(((unsigned)h)<<16);
}
__device__ __forceinline__ bf16x8 ld8(const unsigned short* p){
  return *(const bf16x8*)p;
}
// async global->LDS, 16B per lane; LDS dest = wave-uniform base + lane*16
__device__ __forceinline__ void gl_lds16(const unsigned short* g, unsigned short* l){
  __builtin_amdgcn_global_load_lds(
      (const __attribute__((address_space(1))) void*)g,
      (__attribute__((address_space(3))) void*)l, 16, 0, 0);
}

// ---------------- pad copy (zero-fill pad cols every call: ws is poisoned) ----
__global__ void pad_copy_k(const float* __restrict__ in, float* __restrict__ out,
                           int M, int Din, int Dout){
  int idx = blockIdx.x*256 + threadIdx.x;
  if (idx >= M*Dout) return;
  int r = idx / Dout, c = idx - r*Dout;
  out[idx] = (c < Din) ? in[r*Din + c] : 0.f;
}

// ---------------- MLP GEMM: Out[M][128] = relu(A[M][lda] @ W[kreal][128] + b) --
__global__ __launch_bounds__(256) void mlp_gemm_k(
    const float* __restrict__ A, int lda, int kchunks,
    const float* __restrict__ W, int kreal,
    const float* __restrict__ bias,
    float* __restrict__ Out, int M)
{
  __shared__ float As[KC][132];
  __shared__ float Bs[KC][148];
  int tid = threadIdx.x;
  int r0 = (tid>>4)*8, c0 = (tid&15)*8;
  int rowBase = blockIdx.x*128;
  float acc[8][8];
  #pragma unroll
  for (int i=0;i<8;i++)
    #pragma unroll
    for (int j=0;j<8;j++) acc[i][j]=0.f;

  for (int kc=0;kc<kchunks;kc++){
    { int rr = tid>>3, k4=(tid&7)*4;
      #pragma unroll
      for (int i=0;i<4;i++){
        int row = rr + i*32, gr = rowBase + row;
        float4 v = make_float4(0.f,0.f,0.f,0.f);
        if (gr < M) v = *(const float4*)&A[(size_t)gr*lda + kc*KC + k4];
        As[k4+0][row]=v.x; As[k4+1][row]=v.y; As[k4+2][row]=v.z; As[k4+3][row]=v.w;
      }
    }
    { int kk=tid>>5, c4=(tid&31)*4;
      #pragma unroll
      for (int i=0;i<4;i++){
        int k = kk + i*8, gk = kc*KC + k;
        float4 v = make_float4(0.f,0.f,0.f,0.f);
        if (gk < kreal) v = *(const float4*)&W[(size_t)gk*128 + c4];
        *(float4*)&Bs[k][swz(c4)] = v;
      }
    }
    __syncthreads();
    #pragma unroll 4
    for (int k=0;k<KC;k++){
      float4 a0 = *(const float4*)&As[k][r0];
      float4 a1 = *(const float4*)&As[k][r0+4];
      float4 b0 = *(const float4*)&Bs[k][swz(c0)];
      float4 b1 = *(const float4*)&Bs[k][swz(c0+4)];
      float av[8] = {a0.x,a0.y,a0.z,a0.w,a1.x,a1.y,a1.z,a1.w};
      float bv[8] = {b0.x,b0.y,b0.z,b0.w,b1.x,b1.y,b1.z,b1.w};
      #pragma unroll
      for (int i=0;i<8;i++)
        #pragma unroll
        for (int j=0;j<8;j++) acc[i][j] += av[i]*bv[j];
    }
    __syncthreads();
  }
  float bb[8];
  #pragma unroll
  for (int j=0;j<8;j++) bb[j]=bias[c0+j];
  #pragma unroll
  for (int i=0;i<8;i++){
    int gr = rowBase + r0 + i;
    if (gr < M){
      float o[8];
      #pragma unroll
      for (int j=0;j<8;j++){ float v=acc[i][j]+bb[j]; o[j]=v>0.f?v:0.f; }
      *(float4*)&Out[(size_t)gr*128 + c0]   = make_float4(o[0],o[1],o[2],o[3]);
      *(float4*)&Out[(size_t)gr*128 + c0+4] = make_float4(o[4],o[5],o[6],o[7]);
    }
  }
}

// ---------------- last layer: logits[M][8] into stride-32 rows ----------------
__global__ void mlp8_k(const float* __restrict__ A, const float* __restrict__ W4,
                       const float* __restrict__ b4, float* __restrict__ Out, int M){
  __shared__ float Ws[128*8];
  int tid = threadIdx.x;
  for (int i=tid;i<1024;i+=256) Ws[i]=W4[i];
  __syncthreads();
  int r = blockIdx.x*32 + (tid>>3), c = tid&7;
  if (r >= M) return;
  const float* a = &A[(size_t)r*128];
  float acc = b4[c];
  #pragma unroll 16
  for (int k=0;k<128;k++) acc += a[k]*Ws[k*8+c];
  Out[(size_t)r*32 + c] = acc;
}

// ---------------- softmax over 8 logits, zero cols 8..31 ----------------------
__global__ void softmax_k(float* __restrict__ X, int M){
  int r = blockIdx.x*256 + threadIdx.x;
  if (r >= M) return;
  float* p = &X[(size_t)r*32];
  float v[8], m=-1e30f;
  #pragma unroll
  for (int j=0;j<8;j++){ v[j]=p[j]; m = v[j]>m ? v[j] : m; }
  float s=0.f;
  #pragma unroll
  for (int j=0;j<8;j++){ v[j]=__expf(v[j]-m); s+=v[j]; }
  float inv=1.f/s;
  #pragma unroll
  for (int j=0;j<8;j++) p[j]=v[j]*inv;
  #pragma unroll
  for (int j=8;j<32;j++) p[j]=0.f;
}

// ---------------- fp32 -> (hi,lo) bf16 split + row squared-norms --------------
__global__ void conv_norm_k(const float* __restrict__ X,
                            unsigned short* __restrict__ H,
                            unsigned short* __restrict__ L,
                            float* __restrict__ nrm, int M, int dp){
  int w = threadIdx.x>>6, lane = threadIdx.x&63;
  int row = blockIdx.x*4 + w;
  if (row >= M) return;
  const float* src = &X[(size_t)row*dp];
  unsigned short* dh = &H[(size_t)row*dp];
  unsigned short* dl = &L[(size_t)row*dp];
  float s=0.f;
  for (int c=lane;c<dp;c+=64){
    float v = src[c];
    s += v*v;
    unsigned short h = f2bf_rn(v);
    float rem = v - bf2f(h);
    dh[c] = h;
    dl[c] = f2bf_rn(rem);
  }
  #pragma unroll
  for (int off=32;off>0;off>>=1) s += __shfl_down(s, off, 64);
  if (lane==0) nrm[row]=s;
}

// ---------------- gather sampled subset bank + its norms ----------------------
__global__ void sub_gather_k(const float* __restrict__ Bank, const float* __restrict__ tnb,
                             float* __restrict__ Tsub, float* __restrict__ tnsub, int dp){
  int idx = blockIdx.x*256 + threadIdx.x;
  int total = NSUB*dp;
  if (idx < total){
    int s = idx/dp, c = idx - s*dp;
    Tsub[idx] = Bank[(size_t)(s*SSTRIDE+SOFF)*dp + c];
  } else if (idx < total + NSUB){
    int s = idx - total;
    tnsub[s] = tnb[s*SSTRIDE+SOFF];
  }
}

// ---------------- subset distance GEMM (fp32) -> packed keys ------------------
__global__ __launch_bounds__(256) void dist_key_k(
    const float* __restrict__ Qm, const float* __restrict__ Tm,
    const float* __restrict__ qn, const float* __restrict__ tn,
    const int* __restrict__ labels, unsigned* __restrict__ keys, int dp, int nt)
{
  __shared__ float qs[KC][68];
  __shared__ float ts[KC][148];
  int tid = threadIdx.x;
  int qbase = blockIdx.x*QT;
  int n0 = blockIdx.y*TT;
  int kchunks = dp >> 5;
  int r0 = (tid>>4)*4, c0=(tid&15)*8;
  float acc[4][8];
  #pragma unroll
  for (int i=0;i<4;i++)
    #pragma unroll
    for (int j=0;j<8;j++) acc[i][j]=0.f;

  for (int kc=0;kc<kchunks;kc++){
    { int qq0=tid>>3, k4=(tid&7)*4;
      #pragma unroll
      for (int i=0;i<2;i++){
        int qq=qq0+i*32;
        float4 v = *(const float4*)&Qm[(size_t)(qbase+qq)*dp + kc*KC + k4];
        qs[k4+0][qq]=v.x; qs[k4+1][qq]=v.y; qs[k4+2][qq]=v.z; qs[k4+3][qq]=v.w;
      }
    }
    { int tt0=tid>>3, k4=(tid&7)*4;
      #pragma unroll
      for (int i=0;i<4;i++){
        int ttI=tt0+i*32, g=n0+ttI;
        float4 v = make_float4(0.f,0.f,0.f,0.f);
        if (g < nt) v = *(const float4*)&Tm[(size_t)g*dp + kc*KC + k4];
        int o=swz(ttI);
        ts[k4+0][o]=v.x; ts[k4+1][o]=v.y; ts[k4+2][o]=v.z; ts[k4+3][o]=v.w;
      }
    }
    __syncthreads();
    #pragma unroll 8
    for (int k=0;k<KC;k++){
      float4 a  = *(const float4*)&qs[k][r0];
      float4 b0 = *(const float4*)&ts[k][swz(c0)];
      float4 b1 = *(const float4*)&ts[k][swz(c0+4)];
      float av[4]={a.x,a.y,a.z,a.w};
      float bv[8]={b0.x,b0.y,b0.z,b0.w,b1.x,b1.y,b1.z,b1.w};
      #pragma unroll
      for (int i=0;i<4;i++)
        #pragma unroll
        for (int j=0;j<8;j++) acc[i][j] += av[i]*bv[j];
    }
    __syncthreads();
  }
  int tl = nt - n0; if (tl > TT) tl = TT;
  if (c0 < tl){
    float qnr[4];
    #pragma unroll
    for (int i=0;i<4;i++) qnr[i]=qn[qbase+r0+i];
    float tnv[8]; unsigned labv[8];
    #pragma unroll
    for (int j=0;j<8;j++){ int g=n0+c0+j; tnv[j]=tn[g]; labv[j]=(unsigned)labels[g]; }
    #pragma unroll
    for (int i=0;i<4;i++){
      unsigned kk[8];
      #pragma unroll
      for (int j=0;j<8;j++){
        float d2 = fmaxf(qnr[i] - 2.f*acc[i][j] + tnv[j], 0.f);
        kk[j] = (__float_as_uint(d2)&0xFFFFFFF8u) | labv[j];
      }
      unsigned* dst = &keys[(size_t)(qbase+r0+i)*nt + n0+c0];
      *(uint4*)dst     = make_uint4(kk[0],kk[1],kk[2],kk[3]);
      *(uint4*)(dst+4) = make_uint4(kk[4],kk[5],kk[6],kk[7]);
    }
  }
}

// ---------------- scan helper: find bin containing rank Krem ------------------
__device__ __forceinline__ void find_bin(int* hist, int* part, int nb, int Krem,
                                         int tid, int* s_B, int* s_lob){
  int ch = nb>>8;
  int s=0;
  for (int b=tid*ch;b<tid*ch+ch;b++) s+=hist[b];
  part[tid]=s;
  __syncthreads();
  if (tid==0){
    int cum=0, B=nb-1, lob=0;
    for (int t=0;t<256;t++){
      if (cum+part[t] >= Krem){
        lob=cum;
        for (int b=t*ch;b<t*ch+ch;b++){
          if (lob+hist[b]>=Krem){ B=b; break; }
          lob+=hist[b];
        }
        break;
      }
      cum+=part[t];
    }
    *s_B=B; *s_lob=lob;
  }
  __syncthreads();
}

// ---------------- per-query threshold: exact RSEL-th smallest sample key ------
// Also zero-inits the per-query candidate counter for the following dist_mfma_k.
__global__ __launch_bounds__(256) void sel64_k(const unsigned* __restrict__ skeys,
                                               unsigned* __restrict__ Tthr,
                                               unsigned* __restrict__ cntq){
  __shared__ unsigned buf[NSUB];
  __shared__ int hist[2048];
  __shared__ int part[256];
  __shared__ int sB, sLob;
  int tid=threadIdx.x, q=blockIdx.x;
  if (tid==0) cntq[(size_t)q*CNTP]=0u;
  for (int i=tid;i<NSUB;i+=256) buf[i]=skeys[(size_t)q*NSUB+i];
  int Krem=RSEL;
  for (int i=tid;i<2048;i+=256) hist[i]=0;
  __syncthreads();
  for (int i=tid;i<NSUB;i+=256) atomicAdd(&hist[buf[i]>>21],1);
  __syncthreads();
  find_bin(hist,part,2048,Krem,tid,&sB,&sLob);
  unsigned pre=(unsigned)sB; Krem-=sLob;
  for (int i=tid;i<2048;i+=256) hist[i]=0;
  __syncthreads();
  for (int i=tid;i<NSUB;i+=256){ unsigned k=buf[i]; if ((k>>21)==pre) atomicAdd(&hist[(k>>10)&0x7FFu],1); }
  __syncthreads();
  find_bin(hist,part,2048,Krem,tid,&sB,&sLob);
  pre=(pre<<11)|(unsigned)sB; Krem-=sLob;
  for (int i=tid;i<1024;i+=256) hist[i]=0;
  __syncthreads();
  for (int i=tid;i<NSUB;i+=256){ unsigned k=buf[i]; if ((k>>10)==pre) atomicAdd(&hist[k&0x3FFu],1); }
  __syncthreads();
  find_bin(hist,part,1024,Krem,tid,&sB,&sLob);
  if (tid==0) Tthr[q]=(pre<<10)|(unsigned)sB;
}

// ---------------- MFMA split-bf16 distance GEMM, double-buffered staging ------
// 1D grid 8*8*49, XCD-swizzled (b&7 = stripe). Block = 128q x 128t.
// Epilogue: hits (key < per-query threshold) are compacted straight into a
// per-query global candidate list via atomicAdd on a line-padded counter.
// (The old [q][t_blk] 64B-slab writes were scattered partial-line RMW across
// XCDs -> the whole kernel was dp-independent at 87us; writes drop 25.6MB->~3MB.)
#define MFMA_SEC(CUR, A0H, A0L, A1H, A1L)                                        \
  _Pragma("unroll")                                                              \
  for (int tj=0;tj<8;tj++){                                                      \
    int rowB = tj*16 + col;                                                      \
    int sw = (((quad + (rowB>>1)) & 3) << 3);                                    \
    bf16x8 bh = *(const bf16x8*)&BH[CUR][rowB*32 + sw];                          \
    bf16x8 bl = *(const bf16x8*)&BL[CUR][rowB*32 + sw];                          \
    acc[0][tj] = __builtin_amdgcn_mfma_f32_16x16x32_bf16(A0H, bh, acc[0][tj], 0,0,0); \
    acc[0][tj] = __builtin_amdgcn_mfma_f32_16x16x32_bf16(A0H, bl, acc[0][tj], 0,0,0); \
    acc[0][tj] = __builtin_amdgcn_mfma_f32_16x16x32_bf16(A0L, bh, acc[0][tj], 0,0,0); \
    acc[1][tj] = __builtin_amdgcn_mfma_f32_16x16x32_bf16(A1H, bh, acc[1][tj], 0,0,0); \
    acc[1][tj] = __builtin_amdgcn_mfma_f32_16x16x32_bf16(A1H, bl, acc[1][tj], 0,0,0); \
    acc[1][tj] = __builtin_amdgcn_mfma_f32_16x16x32_bf16(A1L, bh, acc[1][tj], 0,0,0); \
  }

__global__ __launch_bounds__(256) void dist_mfma_k(
    const unsigned short* __restrict__ QH, const unsigned short* __restrict__ QL,
    const unsigned short* __restrict__ TH, const unsigned short* __restrict__ TL,
    const float* __restrict__ qn, const float* __restrict__ tn,
    const int* __restrict__ labels, const unsigned* __restrict__ Tthr,
    unsigned* __restrict__ cand, unsigned* __restrict__ cntq, int dp)
{
  __shared__ unsigned short BH[2][128*32];   // 16 KB
  __shared__ unsigned short BL[2][128*32];   // 16 KB  (32 KB total -> 4 blk/CU)
  int b = blockIdx.x;
  int xcd = b & 7, s = b >> 3;
  int qb = s & 7, tslot = s >> 3;
  int t_blk = xcd + 8*tslot;
  if (t_blk >= NTB) return;
  int tid = threadIdx.x, w = tid>>6, lane = tid&63;
  int quad = lane>>4, col = lane&15;
  int qbase = qb*128;
  int n0 = t_blk*TT;
  int kchunks = dp >> 5;

  size_t aoff = (size_t)(qbase + w*32 + col)*dp + quad*8;
  const unsigned short* pAH = QH + aoff;
  const unsigned short* pAL = QL + aoff;
  size_t qi_step = (size_t)16*dp;

  int i0 = tid,      row0 = i0>>2, sg0 = ((i0&3) - (row0>>1)) & 3;
  int i1 = tid+256,  row1 = i1>>2, sg1 = ((i1&3) - (row1>>1)) & 3;
  size_t g0 = (size_t)(n0+row0)*dp + (size_t)sg0*8;
  size_t g1 = (size_t)(n0+row1)*dp + (size_t)sg1*8;

  f32x4 acc[2][8];
  #pragma unroll
  for (int qi=0;qi<2;qi++)
    #pragma unroll
    for (int tj=0;tj<8;tj++){ f32x4 z={0.f,0.f,0.f,0.f}; acc[qi][tj]=z; }

  // prologue: stage chunk 0 into buf0, load A(0) into set X
  gl_lds16(TH + g0, &BH[0][i0*8]);
  gl_lds16(TH + g1, &BH[0][i1*8]);
  gl_lds16(TL + g0, &BL[0][i0*8]);
  gl_lds16(TL + g1, &BL[0][i1*8]);
  bf16x8 x0h = ld8(pAH), x0l = ld8(pAL);
  bf16x8 x1h = ld8(pAH + qi_step), x1l = ld8(pAL + qi_step);
  bf16x8 y0h = x0h, y0l = x0l, y1h = x1h, y1l = x1l;

  for (int kc=0; kc<kchunks; kc+=2){
    // even chunk: compute on buf0/setX, prefetch kc+1 -> buf1/setY
    __syncthreads();   // drains staging(kc)+A(kc); readers of buf1 (iter kc-1) done
    if (kc+1 < kchunks){
      size_t ko=(size_t)(kc+1)*32;
      gl_lds16(TH + g0 + ko, &BH[1][i0*8]);
      gl_lds16(TH + g1 + ko, &BH[1][i1*8]);
      gl_lds16(TL + g0 + ko, &BL[1][i0*8]);
      gl_lds16(TL + g1 + ko, &BL[1][i1*8]);
      y0h = ld8(pAH + ko);           y0l = ld8(pAL + ko);
      y1h = ld8(pAH + qi_step + ko); y1l = ld8(pAL + qi_step + ko);
    }
    MFMA_SEC(0, x0h, x0l, x1h, x1l);
    if (kc+1 < kchunks){
      // odd chunk: compute on buf1/setY, prefetch kc+2 -> buf0/setX
      __syncthreads();
      if (kc+2 < kchunks){
        size_t ko=(size_t)(kc+2)*32;
        gl_lds16(TH + g0 + ko, &BH[0][i0*8]);
        gl_lds16(TH + g1 + ko, &BH[0][i1*8]);
        gl_lds16(TL + g0 + ko, &BL[0][i0*8]);
        gl_lds16(TL + g1 + ko, &BL[0][i1*8]);
        x0h = ld8(pAH + ko);           x0l = ld8(pAL + ko);
        x1h = ld8(pAH + qi_step + ko); x1l = ld8(pAL + qi_step + ko);
      }
      MFMA_SEC(1, y0h, y0l, y1h, y1l);
    }
  }

  // epilogue: d2 from norms + acc, threshold compare, global compaction
  float qnr[2][4]; unsigned Tq[2][4];
  #pragma unroll
  for (int qi=0;qi<2;qi++)
    #pragma unroll
    for (int r=0;r<4;r++){
      int q = qbase + w*32 + qi*16 + quad*4 + r;
      qnr[qi][r] = qn[q];
      Tq[qi][r]  = Tthr[q];
    }
  #pragma unroll
  for (int tj=0;tj<8;tj++){
    int t = n0 + tj*16 + col;
    if (t < NT){
      float tnv = tn[t];
      unsigned lab = (unsigned)labels[t];
      #pragma unroll
      for (int qi=0;qi<2;qi++)
        #pragma unroll
        for (int r=0;r<4;r++){
          float d2 = fmaxf(qnr[qi][r] - 2.f*acc[qi][tj][r] + tnv, 0.f);
          unsigned key = (__float_as_uint(d2)&0xFFFFFFF8u) | lab;
          if (key < Tq[qi][r]){
            int q = qbase + w*32 + qi*16 + quad*4 + r;
            unsigned idx = atomicAdd(&cntq[(size_t)q*CNTP], 1u);
            if (idx < (unsigned)CAP) cand[(size_t)q*CAP + idx] = key;
          }
        }
    }
  }
}

// ---------------- per-query candidate list: exact radix select + class sums ---
__global__ __launch_bounds__(256) void final_k(
    const unsigned* __restrict__ cand, const unsigned* __restrict__ cntq,
    const float* __restrict__ Qm, const float* __restrict__ Tm,
    const float* __restrict__ qn, const float* __restrict__ tn,
    const int* __restrict__ labels,
    float* __restrict__ tot, int first, int dp)
{
  __shared__ int hist[2048];
  __shared__ int part[256];
  __shared__ unsigned buf[CAP];
  __shared__ unsigned lowbuf[96];
  __shared__ float qrow[128];
  __shared__ int sB,sLob,s_cnt,s_low;
  __shared__ float s_w[9];
  int tid=threadIdx.x, q=blockIdx.x;
  if (tid==0){ for (int j=0;j<9;j++) s_w[j]=0.f; s_cnt=0; s_low=0; }
  __syncthreads();

  int total = (int)cntq[(size_t)q*CNTP];

#define CONTRIB(kk) do{ float d2_=__uint_as_float((kk)&0xFFFFFFF8u); \
    if (d2_>0.f){ float w_=1.0f/sqrtf(d2_); \
      atomicAdd(&s_w[8],w_); atomicAdd(&s_w[(kk)&7u],w_); } }while(0)

  unsigned T; int Krem=KNN;
  if (total>=KNN && total<=CAP){
    // coalesced gather of this query's candidates (thread i owns buf[i],i+256,..)
    for (int i=tid;i<total;i+=256) buf[i]=cand[(size_t)q*CAP+i];
    for (int i=tid;i<2048;i+=256) hist[i]=0;
    __syncthreads();
    for (int i=tid;i<total;i+=256) atomicAdd(&hist[buf[i]>>21],1);
    __syncthreads();
    find_bin(hist,part,2048,Krem,tid,&sB,&sLob);
    unsigned pre=(unsigned)sB; Krem-=sLob;
    for (int i=tid;i<2048;i+=256) hist[i]=0;
    __syncthreads();
    for (int i=tid;i<total;i+=256){ unsigned k=buf[i]; if ((k>>21)==pre) atomicAdd(&hist[(k>>10)&0x7FFu],1); }
    __syncthreads();
    find_bin(hist,part,2048,Krem,tid,&sB,&sLob);
    pre=(pre<<11)|(unsigned)sB; Krem-=sLob;
    for (int i=tid;i<1024;i+=256) hist[i]=0;
    __syncthreads();
    for (int i=tid;i<total;i+=256){ unsigned k=buf[i]; if ((k>>10)==pre) atomicAdd(&hist[k&0x3FFu],1); }
    __syncthreads();
    find_bin(hist,part,1024,Krem,tid,&sB,&sLob);
    T=(pre<<10)|(unsigned)sB; Krem-=sLob;
    __syncthreads();
    for (int i=tid;i<total;i+=256){ unsigned k=buf[i]; if (k<T) CONTRIB(k); }
  } else {
    // fallback (P ~ 1e-10): exact fp32 full recompute select
    if (tid==0) s_cnt=0;
    for (int i=tid;i<dp;i+=256) qrow[i]=Qm[(size_t)q*dp+i];
    __syncthreads();
    float qq=qn[q];
    auto KEY=[&](int t)->unsigned{
      const float* br=&Tm[(size_t)t*dp];
      float dot=0.f;
      for (int k2=0;k2<dp;k2++) dot+=qrow[k2]*br[k2];
      float d2=fmaxf(qq-2.f*dot+tn[t],0.f);
      return (__float_as_uint(d2)&0xFFFFFFF8u)|(unsigned)labels[t];
    };
    for (int i=tid;i<2048;i+=256) hist[i]=0;
    __syncthreads();
    for (int t=tid;t<NT;t+=256) atomicAdd(&hist[KEY(t)>>21],1);
    __syncthreads();
    find_bin(hist,part,2048,Krem,tid,&sB,&sLob);
    int c=hist[sB]; Krem-=sLob;
    unsigned prefix=(unsigned)sB; int shift=21;
    if (c > CAP){
      __syncthreads();
      for (int i=tid;i<2048;i+=256) hist[i]=0;
      __syncthreads();
      for (int t=tid;t<NT;t+=256){ unsigned k=KEY(t); if ((k>>21)==prefix) atomicAdd(&hist[(k>>10)&0x7FFu],1); }
      __syncthreads();
      find_bin(hist,part,2048,Krem,tid,&sB,&sLob);
      c=hist[sB]; Krem-=sLob; prefix=(prefix<<11)|(unsigned)sB; shift=10;
    }
    if (c > CAP){
      __syncthreads();
      for (int i=tid;i<1024;i+=256) hist[i]=0;
      __syncthreads();
      for (int t=tid;t<NT;t+=256){ unsigned k=KEY(t); if ((k>>10)==prefix) atomicAdd(&hist[k&0x3FFu],1); }
      __syncthreads();
      find_bin(hist,part,1024,Krem,tid,&sB,&sLob);
      c=hist[sB]; Krem-=sLob; prefix=(prefix<<10)|(unsigned)sB; shift=0;
    }
    if (c <= CAP){
      for (int t=tid;t<NT;t+=256){
        unsigned k=KEY(t); unsigned pp=k>>shift;
        if (pp==prefix){ int j=atomicAdd(&s_cnt,1); if (j<CAP) buf[j]=k; }
        else if (pp<prefix){ int j=atomicAdd(&s_low,1); if (j<96) lowbuf[j]=k; }
      }
      __syncthreads();
      int sh=shift;
      while (sh>0){
        int nsh=(sh==21)?10:0;
        int nb=1<<(sh-nsh);
        __syncthreads();
        for (int i=tid;i<nb;i+=256) hist[i]=0;
        __syncthreads();
        int cc=s_cnt;
        for (int i=tid;i<cc;i+=256) atomicAdd(&hist[(buf[i]>>nsh)&(unsigned)(nb-1)],1);
        __syncthreads();
        find_bin(hist,part,nb,Krem,tid,&sB,&sLob);
        Krem-=sLob; prefix=(prefix<<(sh-nsh))|(unsigned)sB; sh=nsh;
      }
      T=prefix;
      __syncthreads();
      int lowc=s_low, cc=s_cnt;
      for (int i=tid;i<lowc;i+=256){ unsigned k=lowbuf[i]; CONTRIB(k); }
      for (int i=tid;i<cc;i+=256){ unsigned k=buf[i]; if (k<T) CONTRIB(k); }
    } else {
      T=prefix;
      for (int t=tid;t<NT;t+=256){ unsigned k=KEY(t); if (k<T) CONTRIB(k); }
    }
  }
  __syncthreads();
  if (tid==0){
    float d2=__uint_as_float(T&0xFFFFFFF8u);
    float w=(d2>0.f)?(1.0f/sqrtf(d2)):0.f;
    s_w[8] += (float)Krem*w;
    s_w[T&7u] += (float)Krem*w;
  }
  __syncthreads();
  if (tid<8){
    float contrib = s_w[8]-s_w[tid];
    size_t o=(size_t)q*NL+tid;
    tot[o] = first ? contrib : tot[o]+contrib;
  }
#undef CONTRIB
}

// ---------------- empirical p-values ------------------------------------------
__global__ void pvalue_k(const float* __restrict__ tot, const float* __restrict__ cali,
                         float* __restrict__ out){
  __shared__ float t8[NL];
  __shared__ int part[4][NL];
  int tid=threadIdx.x, q=blockIdx.x;
  if (tid<NL) t8[tid]=tot[(size_t)q*NL+tid];
  __syncthreads();
  float th[NL];
  #pragma unroll
  for (int c=0;c<NL;c++) th[c]=t8[c];
  int cnt[NL];
  #pragma unroll
  for (int c=0;c<NL;c++) cnt[c]=0;
  for (int i=tid;i<NCALI;i+=256){
    float v=cali[i];
    #pragma unroll
    for (int c=0;c<NL;c++) cnt[c] += (v>=th[c]) ? 1 : 0;
  }
  #pragma unroll
  for (int c=0;c<NL;c++){
    #pragma unroll
    for (int off=32;off>0;off>>=1) cnt[c]+=__shfl_down(cnt[c],off,64);
  }
  if ((tid&63)==0){
    #pragma unroll
    for (int c=0;c<NL;c++) part[tid>>6][c]=cnt[c];
  }
  __syncthreads();
  if (tid<NL){
    int s=part[0][tid]+part[1][tid]+part[2][tid]+part[3][tid];
    out[(size_t)q*NL+tid] = (float)s / 10000.f;
  }
}

extern "C" void kernel_launch(void* const* d_in, const int* in_sizes, int n_in,
                              void* d_out, int out_size, void* d_ws, size_t ws_size,
                              hipStream_t stream) {
  const float* x   = (const float*)d_in[0];
  const float* txr = (const float*)d_in[1];
  const int*   lbl = (const int*)  d_in[2];
  const float* cal = (const float*)d_in[3];
  const float* W1  = (const float*)d_in[4];
  const float* b1  = (const float*)d_in[5];
  const float* W2  = (const float*)d_in[6];
  const float* b2  = (const float*)d_in[7];
  const float* W3  = (const float*)d_in[8];
  const float* b3  = (const float*)d_in[9];
  const float* W4  = (const float*)d_in[10];
  const float* b4  = (const float*)d_in[11];
  float* out = (float*)d_out;
  float* ws  = (float*)d_ws;

  size_t off=0;
  float* xq0=ws+off; off+=(size_t)NB*96;
  float* xq1=ws+off; off+=(size_t)NB*128;
  float* xq2=ws+off; off+=(size_t)NB*128;
  float* xq3=ws+off; off+=(size_t)NB*128;
  float* xq4=ws+off; off+=(size_t)NB*32;
  float* tbA=ws+off; off+=(size_t)NT*128;
  float* tbB=ws+off; off+=(size_t)NT*128;
  float* tb4=ws+off; off+=(size_t)NT*32;
  float* qnb=ws+off; off+=(size_t)5*NB;
  float* tnb=ws+off; off+=(size_t)NT;
  float* Tsub=ws+off; off+=(size_t)NSUB*128;
  float* tnsub=ws+off; off+=(size_t)NSUB;
  float* tot=ws+off; off+=(size_t)NB*NL;
  unsigned* sT=(unsigned*)(ws+off); off+=NB;
  unsigned short* qH=(unsigned short*)(ws+off); off+=(size_t)NB*64;
  unsigned short* qL=(unsigned short*)(ws+off); off+=(size_t)NB*64;
  unsigned short* bankH=(unsigned short*)(ws+off); off+=(size_t)NT_PAD*64;
  unsigned short* bankL=(unsigned short*)(ws+off); off+=(size_t)NT_PAD*64;
  off=(off+3)&~(size_t)3;
  unsigned* cand=(unsigned*)(ws+off);   // NB*CAP  = 25.2 MB
  unsigned* skeys=(unsigned*)(ws+off);  // NB*NSUB =  8.4 MB (aliased; skeys dead
                                        // before dist_mfma_k writes cand)
  { size_t cand_sz=(size_t)NB*CAP, skey_sz=(size_t)NB*NSUB;
    off += (cand_sz > skey_sz ? cand_sz : skey_sz); }
  unsigned* cntq=(unsigned*)(ws+off); off+=(size_t)NB*CNTP;  // 128B-padded counters

  // query features; layer-0 features at stride 96
  pad_copy_k<<<(NB*96+255)/256,256,0,stream>>>(x, xq0, NB, 83, 96);
  pad_copy_k<<<((size_t)NT*96+255)/256,256,0,stream>>>(txr, tbA, NT, 83, 96);
  mlp_gemm_k<<<(NB+127)/128,256,0,stream>>>(xq0,96,3,W1,83,b1,xq1,NB);
  mlp_gemm_k<<<(NB+127)/128,256,0,stream>>>(xq1,128,4,W2,128,b2,xq2,NB);
  mlp_gemm_k<<<(NB+127)/128,256,0,stream>>>(xq2,128,4,W3,128,b3,xq3,NB);
  mlp8_k<<<(NB+31)/32,256,0,stream>>>(xq3,W4,b4,xq4,NB);
  softmax_k<<<(NB+255)/256,256,0,stream>>>(xq4,NB);

  auto knn_layer = [&](const float* Qm, const float* Bank, float* qnl,
                       int dp, int first){
    conv_norm_k<<<(NT+3)/4,256,0,stream>>>(Bank, bankH, bankL, tnb, NT, dp);
    conv_norm_k<<<(NB+3)/4,256,0,stream>>>(Qm, qH, qL, qnl, NB, dp);
    sub_gather_k<<<(NSUB*dp+NSUB+255)/256,256,0,stream>>>(Bank,tnb,Tsub,tnsub,dp);
    dist_key_k<<<dim3(NB/QT,NSUB/TT),256,0,stream>>>(Qm,Tsub,qnl,tnsub,lbl,skeys,dp,NSUB);
    sel64_k<<<NB,256,0,stream>>>(skeys,sT,cntq);
    dist_mfma_k<<<8*8*49,256,0,stream>>>(qH,qL,bankH,bankL,qnl,tnb,lbl,sT,cand,cntq,dp);
    final_k<<<NB,256,0,stream>>>(cand,cntq,Qm,Bank,qnl,tnb,lbl,tot,first,dp);
  };

  knn_layer(xq0, tbA, qnb+0*NB, 96, 1);
  mlp_gemm_k<<<(NT+127)/128,256,0,stream>>>(tbA,96,3,W1,83,b1,tbB,NT);
  knn_layer(xq1, tbB, qnb+1*NB, 128, 0);
  mlp_gemm_k<<<(NT+127)/128,256,0,stream>>>(tbB,128,4,W2,128,b2,tbA,NT);
  knn_layer(xq2, tbA, qnb+2*NB, 128, 0);
  mlp_gemm_k<<<(NT+127)/128,256,0,stream>>>(tbA,128,4,W3,128,b3,tbB,NT);
  knn_layer(xq3, tbB, qnb+3*NB, 128, 0);
  mlp8_k<<<(NT+31)/32,256,0,stream>>>(tbB,W4,b4,tb4,NT);
  softmax_k<<<(NT+255)/256,256,0,stream>>>(tb4,NT);
  knn_layer(xq4, tb4, qnb+4*NB, 32, 0);

  pvalue_k<<<NB,256,0,stream>>>(tot,cal,out);
}

// Round 2
// 1224.776 us; speedup vs baseline: 1.3854x; 1.3854x over previous
//
#include <hip/hip_runtime.h>
#include <math.h>

#define KNN 75
#define NL 8
#define NB 1024
#define NT 50000
#define NT_PAD 50048  // NTB*TT rows allocated for bf16 banks (pad rows masked)
#define NCALI 10000
#define KC 32
#define QT 64
#define TT 128
#define NTB 391       // ceil(NT/TT)
#define SLOTS 16      // per (t-block, q) slab: [count, up to 15 hit keys] = 64B
#define CAP 6144      // candidate buffer per query
#define NSUB 2048     // sampled train points for threshold
#define SSTRIDE 24
#define SOFF 11       // 11 + 24*2047 = 49139 < 50000
#define RSEL 32       // sample rank -> expected |{k < T}| ~ 780, lambda/slab ~ 2

typedef __attribute__((ext_vector_type(8))) short bf16x8;
typedef __attribute__((ext_vector_type(4))) float f32x4;

__device__ __forceinline__ int swz(int c){ return c + ((c>>5)<<2); }

__device__ __forceinline__ unsigned short f2bf_rn(float x){
  unsigned u = __float_as_uint(x);
  unsigned r = (u + 0x7FFFu + ((u>>16)&1u)) >> 16;
  return (unsigned short)r;
}
__device__ __forceinline__ float bf2f(unsigned short h){
  return __uint_as_float(((unsigned)h)<<16);
}
__device__ __forceinline__ bf16x8 ld8(const unsigned short* p){
  return *(const bf16x8*)p;
}
// async global->LDS, 16B per lane; LDS dest = wave-uniform base + lane*16
__device__ __forceinline__ void gl_lds16(const unsigned short* g, unsigned short* l){
  __builtin_amdgcn_global_load_lds(
      (const __attribute__((address_space(1))) void*)g,
      (__attribute__((address_space(3))) void*)l, 16, 0, 0);
}

// ---------------- pad copy (zero-fill pad cols every call: ws is poisoned) ----
__global__ void pad_copy_k(const float* __restrict__ in, float* __restrict__ out,
                           int M, int Din, int Dout){
  int idx = blockIdx.x*256 + threadIdx.x;
  if (idx >= M*Dout) return;
  int r = idx / Dout, c = idx - r*Dout;
  out[idx] = (c < Din) ? in[r*Din + c] : 0.f;
}

// ---------------- MLP GEMM: Out[M][128] = relu(A[M][lda] @ W[kreal][128] + b) --
__global__ __launch_bounds__(256) void mlp_gemm_k(
    const float* __restrict__ A, int lda, int kchunks,
    const float* __restrict__ W, int kreal,
    const float* __restrict__ bias,
    float* __restrict__ Out, int M)
{
  __shared__ float As[KC][132];
  __shared__ float Bs[KC][148];
  int tid = threadIdx.x;
  int r0 = (tid>>4)*8, c0 = (tid&15)*8;
  int rowBase = blockIdx.x*128;
  float acc[8][8];
  #pragma unroll
  for (int i=0;i<8;i++)
    #pragma unroll
    for (int j=0;j<8;j++) acc[i][j]=0.f;

  for (int kc=0;kc<kchunks;kc++){
    { int rr = tid>>3, k4=(tid&7)*4;
      #pragma unroll
      for (int i=0;i<4;i++){
        int row = rr + i*32, gr = rowBase + row;
        float4 v = make_float4(0.f,0.f,0.f,0.f);
        if (gr < M) v = *(const float4*)&A[(size_t)gr*lda + kc*KC + k4];
        As[k4+0][row]=v.x; As[k4+1][row]=v.y; As[k4+2][row]=v.z; As[k4+3][row]=v.w;
      }
    }
    { int kk=tid>>5, c4=(tid&31)*4;
      #pragma unroll
      for (int i=0;i<4;i++){
        int k = kk + i*8, gk = kc*KC + k;
        float4 v = make_float4(0.f,0.f,0.f,0.f);
        if (gk < kreal) v = *(const float4*)&W[(size_t)gk*128 + c4];
        *(float4*)&Bs[k][swz(c4)] = v;
      }
    }
    __syncthreads();
    #pragma unroll 4
    for (int k=0;k<KC;k++){
      float4 a0 = *(const float4*)&As[k][r0];
      float4 a1 = *(const float4*)&As[k][r0+4];
      float4 b0 = *(const float4*)&Bs[k][swz(c0)];
      float4 b1 = *(const float4*)&Bs[k][swz(c0+4)];
      float av[8] = {a0.x,a0.y,a0.z,a0.w,a1.x,a1.y,a1.z,a1.w};
      float bv[8] = {b0.x,b0.y,b0.z,b0.w,b1.x,b1.y,b1.z,b1.w};
      #pragma unroll
      for (int i=0;i<8;i++)
        #pragma unroll
        for (int j=0;j<8;j++) acc[i][j] += av[i]*bv[j];
    }
    __syncthreads();
  }
  float bb[8];
  #pragma unroll
  for (int j=0;j<8;j++) bb[j]=bias[c0+j];
  #pragma unroll
  for (int i=0;i<8;i++){
    int gr = rowBase + r0 + i;
    if (gr < M){
      float o[8];
      #pragma unroll
      for (int j=0;j<8;j++){ float v=acc[i][j]+bb[j]; o[j]=v>0.f?v:0.f; }
      *(float4*)&Out[(size_t)gr*128 + c0]   = make_float4(o[0],o[1],o[2],o[3]);
      *(float4*)&Out[(size_t)gr*128 + c0+4] = make_float4(o[4],o[5],o[6],o[7]);
    }
  }
}

// ---------------- last layer: logits[M][8] into stride-32 rows ----------------
__global__ void mlp8_k(const float* __restrict__ A, const float* __restrict__ W4,
                       const float* __restrict__ b4, float* __restrict__ Out, int M){
  __shared__ float Ws[128*8];
  int tid = threadIdx.x;
  for (int i=tid;i<1024;i+=256) Ws[i]=W4[i];
  __syncthreads();
  int r = blockIdx.x*32 + (tid>>3), c = tid&7;
  if (r >= M) return;
  const float* a = &A[(size_t)r*128];
  float acc = b4[c];
  #pragma unroll 16
  for (int k=0;k<128;k++) acc += a[k]*Ws[k*8+c];
  Out[(size_t)r*32 + c] = acc;
}

// ---------------- softmax over 8 logits, zero cols 8..31 ----------------------
__global__ void softmax_k(float* __restrict__ X, int M){
  int r = blockIdx.x*256 + threadIdx.x;
  if (r >= M) return;
  float* p = &X[(size_t)r*32];
  float v[8], m=-1e30f;
  #pragma unroll
  for (int j=0;j<8;j++){ v[j]=p[j]; m = v[j]>m ? v[j] : m; }
  float s=0.f;
  #pragma unroll
  for (int j=0;j<8;j++){ v[j]=__expf(v[j]-m); s+=v[j]; }
  float inv=1.f/s;
  #pragma unroll
  for (int j=0;j<8;j++) p[j]=v[j]*inv;
  #pragma unroll
  for (int j=8;j<32;j++) p[j]=0.f;
}

// ---------------- fp32 -> (hi,lo) bf16 split + row squared-norms --------------
__global__ void conv_norm_k(const float* __restrict__ X,
                            unsigned short* __restrict__ H,
                            unsigned short* __restrict__ L,
                            float* __restrict__ nrm, int M, int dp){
  int w = threadIdx.x>>6, lane = threadIdx.x&63;
  int row = blockIdx.x*4 + w;
  if (row >= M) return;
  const float* src = &X[(size_t)row*dp];
  unsigned short* dh = &H[(size_t)row*dp];
  unsigned short* dl = &L[(size_t)row*dp];
  float s=0.f;
  for (int c=lane;c<dp;c+=64){
    float v = src[c];
    s += v*v;
    unsigned short h = f2bf_rn(v);
    float rem = v - bf2f(h);
    dh[c] = h;
    dl[c] = f2bf_rn(rem);
  }
  #pragma unroll
  for (int off=32;off>0;off>>=1) s += __shfl_down(s, off, 64);
  if (lane==0) nrm[row]=s;
}

// ---------------- gather sampled subset bank + its norms ----------------------
__global__ void sub_gather_k(const float* __restrict__ Bank, const float* __restrict__ tnb,
                             float* __restrict__ Tsub, float* __restrict__ tnsub, int dp){
  int idx = blockIdx.x*256 + threadIdx.x;
  int total = NSUB*dp;
  if (idx < total){
    int s = idx/dp, c = idx - s*dp;
    Tsub[idx] = Bank[(size_t)(s*SSTRIDE+SOFF)*dp + c];
  } else if (idx < total + NSUB){
    int s = idx - total;
    tnsub[s] = tnb[s*SSTRIDE+SOFF];
  }
}

// ---------------- subset distance GEMM (fp32) -> packed keys ------------------
__global__ __launch_bounds__(256) void dist_key_k(
    const float* __restrict__ Qm, const float* __restrict__ Tm,
    const float* __restrict__ qn, const float* __restrict__ tn,
    const int* __restrict__ labels, unsigned* __restrict__ keys, int dp, int nt)
{
  __shared__ float qs[KC][68];
  __shared__ float ts[KC][148];
  int tid = threadIdx.x;
  int qbase = blockIdx.x*QT;
  int n0 = blockIdx.y*TT;
  int kchunks = dp >> 5;
  int r0 = (tid>>4)*4, c0=(tid&15)*8;
  float acc[4][8];
  #pragma unroll
  for (int i=0;i<4;i++)
    #pragma unroll
    for (int j=0;j<8;j++) acc[i][j]=0.f;

  for (int kc=0;kc<kchunks;kc++){
    { int qq0=tid>>3, k4=(tid&7)*4;
      #pragma unroll
      for (int i=0;i<2;i++){
        int qq=qq0+i*32;
        float4 v = *(const float4*)&Qm[(size_t)(qbase+qq)*dp + kc*KC + k4];
        qs[k4+0][qq]=v.x; qs[k4+1][qq]=v.y; qs[k4+2][qq]=v.z; qs[k4+3][qq]=v.w;
      }
    }
    { int tt0=tid>>3, k4=(tid&7)*4;
      #pragma unroll
      for (int i=0;i<4;i++){
        int ttI=tt0+i*32, g=n0+ttI;
        float4 v = make_float4(0.f,0.f,0.f,0.f);
        if (g < nt) v = *(const float4*)&Tm[(size_t)g*dp + kc*KC + k4];
        int o=swz(ttI);
        ts[k4+0][o]=v.x; ts[k4+1][o]=v.y; ts[k4+2][o]=v.z; ts[k4+3][o]=v.w;
      }
    }
    __syncthreads();
    #pragma unroll 8
    for (int k=0;k<KC;k++){
      float4 a  = *(const float4*)&qs[k][r0];
      float4 b0 = *(const float4*)&ts[k][swz(c0)];
      float4 b1 = *(const float4*)&ts[k][swz(c0+4)];
      float av[4]={a.x,a.y,a.z,a.w};
      float bv[8]={b0.x,b0.y,b0.z,b0.w,b1.x,b1.y,b1.z,b1.w};
      #pragma unroll
      for (int i=0;i<4;i++)
        #pragma unroll
        for (int j=0;j<8;j++) acc[i][j] += av[i]*bv[j];
    }
    __syncthreads();
  }
  int tl = nt - n0; if (tl > TT) tl = TT;
  if (c0 < tl){
    float qnr[4];
    #pragma unroll
    for (int i=0;i<4;i++) qnr[i]=qn[qbase+r0+i];
    float tnv[8]; unsigned labv[8];
    #pragma unroll
    for (int j=0;j<8;j++){ int g=n0+c0+j; tnv[j]=tn[g]; labv[j]=(unsigned)labels[g]; }
    #pragma unroll
    for (int i=0;i<4;i++){
      unsigned kk[8];
      #pragma unroll
      for (int j=0;j<8;j++){
        float d2 = fmaxf(qnr[i] - 2.f*acc[i][j] + tnv[j], 0.f);
        kk[j] = (__float_as_uint(d2)&0xFFFFFFF8u) | labv[j];
      }
      unsigned* dst = &keys[(size_t)(qbase+r0+i)*nt + n0+c0];
      *(uint4*)dst     = make_uint4(kk[0],kk[1],kk[2],kk[3]);
      *(uint4*)(dst+4) = make_uint4(kk[4],kk[5],kk[6],kk[7]);
    }
  }
}

// ---------------- scan helper: find bin containing rank Krem ------------------
__device__ __forceinline__ void find_bin(int* hist, int* part, int nb, int Krem,
                                         int tid, int* s_B, int* s_lob){
  int ch = nb>>8;
  int s=0;
  for (int b=tid*ch;b<tid*ch+ch;b++) s+=hist[b];
  part[tid]=s;
  __syncthreads();
  if (tid==0){
    int cum=0, B=nb-1, lob=0;
    for (int t=0;t<256;t++){
      if (cum+part[t] >= Krem){
        lob=cum;
        for (int b=t*ch;b<t*ch+ch;b++){
          if (lob+hist[b]>=Krem){ B=b; break; }
          lob+=hist[b];
        }
        break;
      }
      cum+=part[t];
    }
    *s_B=B; *s_lob=lob;
  }
  __syncthreads();
}

// ---------------- per-query threshold: exact RSEL-th smallest sample key ------
__global__ __launch_bounds__(256) void sel64_k(const unsigned* __restrict__ skeys,
                                               unsigned* __restrict__ Tthr){
  __shared__ unsigned buf[NSUB];
  __shared__ int hist[2048];
  __shared__ int part[256];
  __shared__ int sB, sLob;
  int tid=threadIdx.x, q=blockIdx.x;
  for (int i=tid;i<NSUB;i+=256) buf[i]=skeys[(size_t)q*NSUB+i];
  int Krem=RSEL;
  for (int i=tid;i<2048;i+=256) hist[i]=0;
  __syncthreads();
  for (int i=tid;i<NSUB;i+=256) atomicAdd(&hist[buf[i]>>21],1);
  __syncthreads();
  find_bin(hist,part,2048,Krem,tid,&sB,&sLob);
  unsigned pre=(unsigned)sB; Krem-=sLob;
  for (int i=tid;i<2048;i+=256) hist[i]=0;
  __syncthreads();
  for (int i=tid;i<NSUB;i+=256){ unsigned k=buf[i]; if ((k>>21)==pre) atomicAdd(&hist[(k>>10)&0x7FFu],1); }
  __syncthreads();
  find_bin(hist,part,2048,Krem,tid,&sB,&sLob);
  pre=(pre<<11)|(unsigned)sB; Krem-=sLob;
  for (int i=tid;i<1024;i+=256) hist[i]=0;
  __syncthreads();
  for (int i=tid;i<NSUB;i+=256){ unsigned k=buf[i]; if ((k>>10)==pre) atomicAdd(&hist[k&0x3FFu],1); }
  __syncthreads();
  find_bin(hist,part,1024,Krem,tid,&sB,&sLob);
  if (tid==0) Tthr[q]=(pre<<10)|(unsigned)sB;
}

// ---------------- MFMA split-bf16 distance GEMM, double-buffered staging ------
// 1D grid 8*8*49, XCD-swizzled (b&7 = stripe). Block = 128q x 128t.
// Epilogue: LDS hitbuf compaction, then slab written TRANSPOSED: slab[t_blk][q].
// A block (fixed t_blk, q = qbase..qbase+127) writes ONE contiguous 8 KB
// block-private region -> full-line streaming stores, no cross-XCD RMW.
// (Old slab[q][t_blk] put adjacent t_blk -- different XCDs by construction --
// in the same 128B line: read-for-ownership ping-pong made the kernel a
// dp-independent 87us. Round-1's global-atomic compaction was worse: 800K
// cross-XCD atomics + scattered dword stores -> 190us. Layout was the bug.)
#define MFMA_SEC(CUR, A0H, A0L, A1H, A1L)                                        \
  _Pragma("unroll")                                                              \
  for (int tj=0;tj<8;tj++){                                                      \
    int rowB = tj*16 + col;                                                      \
    int sw = (((quad + (rowB>>1)) & 3) << 3);                                    \
    bf16x8 bh = *(const bf16x8*)&BH[CUR][rowB*32 + sw];                          \
    bf16x8 bl = *(const bf16x8*)&BL[CUR][rowB*32 + sw];                          \
    acc[0][tj] = __builtin_amdgcn_mfma_f32_16x16x32_bf16(A0H, bh, acc[0][tj], 0,0,0); \
    acc[0][tj] = __builtin_amdgcn_mfma_f32_16x16x32_bf16(A0H, bl, acc[0][tj], 0,0,0); \
    acc[0][tj] = __builtin_amdgcn_mfma_f32_16x16x32_bf16(A0L, bh, acc[0][tj], 0,0,0); \
    acc[1][tj] = __builtin_amdgcn_mfma_f32_16x16x32_bf16(A1H, bh, acc[1][tj], 0,0,0); \
    acc[1][tj] = __builtin_amdgcn_mfma_f32_16x16x32_bf16(A1H, bl, acc[1][tj], 0,0,0); \
    acc[1][tj] = __builtin_amdgcn_mfma_f32_16x16x32_bf16(A1L, bh, acc[1][tj], 0,0,0); \
  }

__global__ __launch_bounds__(256) void dist_mfma_k(
    const unsigned short* __restrict__ QH, const unsigned short* __restrict__ QL,
    const unsigned short* __restrict__ TH, const unsigned short* __restrict__ TL,
    const float* __restrict__ qn, const float* __restrict__ tn,
    const int* __restrict__ labels, const unsigned* __restrict__ Tthr,
    unsigned* __restrict__ slab, int dp)
{
  __shared__ unsigned short BH[2][128*32];   // 16 KB
  __shared__ unsigned short BL[2][128*32];   // 16 KB
  __shared__ unsigned hitbuf[128][SLOTS];    // 8 KB
  __shared__ int hcnt[128];
  int b = blockIdx.x;
  int xcd = b & 7, s = b >> 3;
  int qb = s & 7, tslot = s >> 3;
  int t_blk = xcd + 8*tslot;
  if (t_blk >= NTB) return;
  int tid = threadIdx.x, w = tid>>6, lane = tid&63;
  int quad = lane>>4, col = lane&15;
  int qbase = qb*128;
  int n0 = t_blk*TT;
  int kchunks = dp >> 5;

  size_t aoff = (size_t)(qbase + w*32 + col)*dp + quad*8;
  const unsigned short* pAH = QH + aoff;
  const unsigned short* pAL = QL + aoff;
  size_t qi_step = (size_t)16*dp;

  int i0 = tid,      row0 = i0>>2, sg0 = ((i0&3) - (row0>>1)) & 3;
  int i1 = tid+256,  row1 = i1>>2, sg1 = ((i1&3) - (row1>>1)) & 3;
  size_t g0 = (size_t)(n0+row0)*dp + (size_t)sg0*8;
  size_t g1 = (size_t)(n0+row1)*dp + (size_t)sg1*8;

  f32x4 acc[2][8];
  #pragma unroll
  for (int qi=0;qi<2;qi++)
    #pragma unroll
    for (int tj=0;tj<8;tj++){ f32x4 z={0.f,0.f,0.f,0.f}; acc[qi][tj]=z; }

  // prologue: stage chunk 0 into buf0, load A(0) into set X
  gl_lds16(TH + g0, &BH[0][i0*8]);
  gl_lds16(TH + g1, &BH[0][i1*8]);
  gl_lds16(TL + g0, &BL[0][i0*8]);
  gl_lds16(TL + g1, &BL[0][i1*8]);
  bf16x8 x0h = ld8(pAH), x0l = ld8(pAL);
  bf16x8 x1h = ld8(pAH + qi_step), x1l = ld8(pAL + qi_step);
  bf16x8 y0h = x0h, y0l = x0l, y1h = x1h, y1l = x1l;

  for (int kc=0; kc<kchunks; kc+=2){
    // even chunk: compute on buf0/setX, prefetch kc+1 -> buf1/setY
    __syncthreads();   // drains staging(kc)+A(kc); readers of buf1 (iter kc-1) done
    if (kc+1 < kchunks){
      size_t ko=(size_t)(kc+1)*32;
      gl_lds16(TH + g0 + ko, &BH[1][i0*8]);
      gl_lds16(TH + g1 + ko, &BH[1][i1*8]);
      gl_lds16(TL + g0 + ko, &BL[1][i0*8]);
      gl_lds16(TL + g1 + ko, &BL[1][i1*8]);
      y0h = ld8(pAH + ko);           y0l = ld8(pAL + ko);
      y1h = ld8(pAH + qi_step + ko); y1l = ld8(pAL + qi_step + ko);
    }
    MFMA_SEC(0, x0h, x0l, x1h, x1l);
    if (kc+1 < kchunks){
      // odd chunk: compute on buf1/setY, prefetch kc+2 -> buf0/setX
      __syncthreads();
      if (kc+2 < kchunks){
        size_t ko=(size_t)(kc+2)*32;
        gl_lds16(TH + g0 + ko, &BH[0][i0*8]);
        gl_lds16(TH + g1 + ko, &BH[0][i1*8]);
        gl_lds16(TL + g0 + ko, &BL[0][i0*8]);
        gl_lds16(TL + g1 + ko, &BL[0][i1*8]);
        x0h = ld8(pAH + ko);           x0l = ld8(pAL + ko);
        x1h = ld8(pAH + qi_step + ko); x1l = ld8(pAL + qi_step + ko);
      }
      MFMA_SEC(1, y0h, y0l, y1h, y1l);
    }
  }

  // epilogue: d2 from norms + acc, threshold compare, LDS slab compaction
  if (tid<128) hcnt[tid]=0;
  __syncthreads();
  float qnr[2][4]; unsigned Tq[2][4];
  #pragma unroll
  for (int qi=0;qi<2;qi++)
    #pragma unroll
    for (int r=0;r<4;r++){
      int q = qbase + w*32 + qi*16 + quad*4 + r;
      qnr[qi][r] = qn[q];
      Tq[qi][r]  = Tthr[q];
    }
  #pragma unroll
  for (int tj=0;tj<8;tj++){
    int t = n0 + tj*16 + col;
    if (t < NT){
      float tnv = tn[t];
      unsigned lab = (unsigned)labels[t];
      #pragma unroll
      for (int qi=0;qi<2;qi++)
        #pragma unroll
        for (int r=0;r<4;r++){
          float d2 = fmaxf(qnr[qi][r] - 2.f*acc[qi][tj][r] + tnv, 0.f);
          unsigned key = (__float_as_uint(d2)&0xFFFFFFF8u) | lab;
          if (key < Tq[qi][r]){
            int ql = w*32 + qi*16 + quad*4 + r;
            int idx = atomicAdd(&hcnt[ql], 1);
            if (idx < SLOTS-1) hitbuf[ql][1+idx] = key;
          }
        }
    }
  }
  __syncthreads();
  if (tid<128) hitbuf[tid][0]=(unsigned)hcnt[tid];
  __syncthreads();
  // transposed slab write: contiguous 8 KB per block
  #pragma unroll
  for (int rep=0; rep<2; rep++){
    int idx = rep*256 + tid;
    int q = idx>>2, sub = (idx&3)*4;
    uint4 v = *(uint4*)&hitbuf[q][sub];
    *(uint4*)&slab[((size_t)t_blk*NB + (qbase+q))*SLOTS + sub] = v;
  }
}

// ---------------- gather slabs, exact radix select + class sums ---------------
__global__ __launch_bounds__(256) void final_k(
    const unsigned* __restrict__ slab,
    const float* __restrict__ Qm, const float* __restrict__ Tm,
    const float* __restrict__ qn, const float* __restrict__ tn,
    const int* __restrict__ labels,
    float* __restrict__ tot, int first, int dp)
{
  __shared__ int hist[2048];
  __shared__ int part[256];
  __shared__ unsigned buf[CAP];
  __shared__ unsigned lowbuf[96];
  __shared__ float qrow[128];
  __shared__ int sB,sLob,s_cnt,s_low,s_bad;
  __shared__ float s_w[9];
  int tid=threadIdx.x, q=blockIdx.x;
  if (tid==0){ for (int j=0;j<9;j++) s_w[j]=0.f; s_cnt=0; s_low=0; s_bad=0; }
  __syncthreads();

  // transposed layout: query q's slab for t-block sidx is at (sidx*NB + q)
  for (int sidx=tid; sidx<NTB; sidx+=256){
    const unsigned* s = slab + ((size_t)sidx*NB + q)*SLOTS;
    uint4 a = *(const uint4*)s;
    unsigned cnt = a.x;
    if (cnt > SLOTS-1){ s_bad=1; continue; }
    if (!cnt) continue;
    int base = atomicAdd(&s_cnt, (int)cnt);
    if (base + (int)cnt <= CAP){
      buf[base] = a.y;
      if (cnt>=2) buf[base+1] = a.z;
      if (cnt>=3) buf[base+2] = a.w;
      for (unsigned w=4; w<=cnt; w++) buf[base+w-1] = s[w];
    }
  }
  __syncthreads();
  int total = s_cnt;
  int bad = s_bad;

#define CONTRIB(kk) do{ float d2_=__uint_as_float((kk)&0xFFFFFFF8u); \
    if (d2_>0.f){ float w_=1.0f/sqrtf(d2_); \
      atomicAdd(&s_w[8],w_); atomicAdd(&s_w[(kk)&7u],w_); } }while(0)

  unsigned T; int Krem=KNN;
  if (!bad && total>=KNN && total<=CAP){
    for (int i=tid;i<2048;i+=256) hist[i]=0;
    __syncthreads();
    for (int i=tid;i<total;i+=256) atomicAdd(&hist[buf[i]>>21],1);
    __syncthreads();
    find_bin(hist,part,2048,Krem,tid,&sB,&sLob);
    unsigned pre=(unsigned)sB; Krem-=sLob;
    for (int i=tid;i<2048;i+=256) hist[i]=0;
    __syncthreads();
    for (int i=tid;i<total;i+=256){ unsigned k=buf[i]; if ((k>>21)==pre) atomicAdd(&hist[(k>>10)&0x7FFu],1); }
    __syncthreads();
    find_bin(hist,part,2048,Krem,tid,&sB,&sLob);
    pre=(pre<<11)|(unsigned)sB; Krem-=sLob;
    for (int i=tid;i<1024;i+=256) hist[i]=0;
    __syncthreads();
    for (int i=tid;i<total;i+=256){ unsigned k=buf[i]; if ((k>>10)==pre) atomicAdd(&hist[k&0x3FFu],1); }
    __syncthreads();
    find_bin(hist,part,1024,Krem,tid,&sB,&sLob);
    T=(pre<<10)|(unsigned)sB; Krem-=sLob;
    __syncthreads();
    for (int i=tid;i<total;i+=256){ unsigned k=buf[i]; if (k<T) CONTRIB(k); }
  } else {
    // fallback (P ~ 1e-10): exact fp32 full recompute select
    if (tid==0) s_cnt=0;
    for (int i=tid;i<dp;i+=256) qrow[i]=Qm[(size_t)q*dp+i];
    __syncthreads();
    float qq=qn[q];
    auto KEY=[&](int t)->unsigned{
      const float* br=&Tm[(size_t)t*dp];
      float dot=0.f;
      for (int k2=0;k2<dp;k2++) dot+=qrow[k2]*br[k2];
      float d2=fmaxf(qq-2.f*dot+tn[t],0.f);
      return (__float_as_uint(d2)&0xFFFFFFF8u)|(unsigned)labels[t];
    };
    for (int i=tid;i<2048;i+=256) hist[i]=0;
    __syncthreads();
    for (int t=tid;t<NT;t+=256) atomicAdd(&hist[KEY(t)>>21],1);
    __syncthreads();
    find_bin(hist,part,2048,Krem,tid,&sB,&sLob);
    int c=hist[sB]; Krem-=sLob;
    unsigned prefix=(unsigned)sB; int shift=21;
    if (c > CAP){
      __syncthreads();
      for (int i=tid;i<2048;i+=256) hist[i]=0;
      __syncthreads();
      for (int t=tid;t<NT;t+=256){ unsigned k=KEY(t); if ((k>>21)==prefix) atomicAdd(&hist[(k>>10)&0x7FFu],1); }
      __syncthreads();
      find_bin(hist,part,2048,Krem,tid,&sB,&sLob);
      c=hist[sB]; Krem-=sLob; prefix=(prefix<<11)|(unsigned)sB; shift=10;
    }
    if (c > CAP){
      __syncthreads();
      for (int i=tid;i<1024;i+=256) hist[i]=0;
      __syncthreads();
      for (int t=tid;t<NT;t+=256){ unsigned k=KEY(t); if ((k>>10)==prefix) atomicAdd(&hist[k&0x3FFu],1); }
      __syncthreads();
      find_bin(hist,part,1024,Krem,tid,&sB,&sLob);
      c=hist[sB]; Krem-=sLob; prefix=(prefix<<10)|(unsigned)sB; shift=0;
    }
    if (c <= CAP){
      for (int t=tid;t<NT;t+=256){
        unsigned k=KEY(t); unsigned pp=k>>shift;
        if (pp==prefix){ int j=atomicAdd(&s_cnt,1); if (j<CAP) buf[j]=k; }
        else if (pp<prefix){ int j=atomicAdd(&s_low,1); if (j<96) lowbuf[j]=k; }
      }
      __syncthreads();
      int sh=shift;
      while (sh>0){
        int nsh=(sh==21)?10:0;
        int nb=1<<(sh-nsh);
        __syncthreads();
        for (int i=tid;i<nb;i+=256) hist[i]=0;
        __syncthreads();
        int cc=s_cnt;
        for (int i=tid;i<cc;i+=256) atomicAdd(&hist[(buf[i]>>nsh)&(unsigned)(nb-1)],1);
        __syncthreads();
        find_bin(hist,part,nb,Krem,tid,&sB,&sLob);
        Krem-=sLob; prefix=(prefix<<(sh-nsh))|(unsigned)sB; sh=nsh;
      }
      T=prefix;
      __syncthreads();
      int lowc=s_low, cc=s_cnt;
      for (int i=tid;i<lowc;i+=256){ unsigned k=lowbuf[i]; CONTRIB(k); }
      for (int i=tid;i<cc;i+=256){ unsigned k=buf[i]; if (k<T) CONTRIB(k); }
    } else {
      T=prefix;
      for (int t=tid;t<NT;t+=256){ unsigned k=KEY(t); if (k<T) CONTRIB(k); }
    }
  }
  __syncthreads();
  if (tid==0){
    float d2=__uint_as_float(T&0xFFFFFFF8u);
    float w=(d2>0.f)?(1.0f/sqrtf(d2)):0.f;
    s_w[8] += (float)Krem*w;
    s_w[T&7u] += (float)Krem*w;
  }
  __syncthreads();
  if (tid<8){
    float contrib = s_w[8]-s_w[tid];
    size_t o=(size_t)q*NL+tid;
    tot[o] = first ? contrib : tot[o]+contrib;
  }
#undef CONTRIB
}

// ---------------- empirical p-values ------------------------------------------
__global__ void pvalue_k(const float* __restrict__ tot, const float* __restrict__ cali,
                         float* __restrict__ out){
  __shared__ float t8[NL];
  __shared__ int part[4][NL];
  int tid=threadIdx.x, q=blockIdx.x;
  if (tid<NL) t8[tid]=tot[(size_t)q*NL+tid];
  __syncthreads();
  float th[NL];
  #pragma unroll
  for (int c=0;c<NL;c++) th[c]=t8[c];
  int cnt[NL];
  #pragma unroll
  for (int c=0;c<NL;c++) cnt[c]=0;
  for (int i=tid;i<NCALI;i+=256){
    float v=cali[i];
    #pragma unroll
    for (int c=0;c<NL;c++) cnt[c] += (v>=th[c]) ? 1 : 0;
  }
  #pragma unroll
  for (int c=0;c<NL;c++){
    #pragma unroll
    for (int off=32;off>0;off>>=1) cnt[c]+=__shfl_down(cnt[c],off,64);
  }
  if ((tid&63)==0){
    #pragma unroll
    for (int c=0;c<NL;c++) part[tid>>6][c]=cnt[c];
  }
  __syncthreads();
  if (tid<NL){
    int s=part[0][tid]+part[1][tid]+part[2][tid]+part[3][tid];
    out[(size_t)q*NL+tid] = (float)s / 10000.f;
  }
}

extern "C" void kernel_launch(void* const* d_in, const int* in_sizes, int n_in,
                              void* d_out, int out_size, void* d_ws, size_t ws_size,
                              hipStream_t stream) {
  const float* x   = (const float*)d_in[0];
  const float* txr = (const float*)d_in[1];
  const int*   lbl = (const int*)  d_in[2];
  const float* cal = (const float*)d_in[3];
  const float* W1  = (const float*)d_in[4];
  const float* b1  = (const float*)d_in[5];
  const float* W2  = (const float*)d_in[6];
  const float* b2  = (const float*)d_in[7];
  const float* W3  = (const float*)d_in[8];
  const float* b3  = (const float*)d_in[9];
  const float* W4  = (const float*)d_in[10];
  const float* b4  = (const float*)d_in[11];
  float* out = (float*)d_out;
  float* ws  = (float*)d_ws;

  size_t off=0;
  float* xq0=ws+off; off+=(size_t)NB*96;
  float* xq1=ws+off; off+=(size_t)NB*128;
  float* xq2=ws+off; off+=(size_t)NB*128;
  float* xq3=ws+off; off+=(size_t)NB*128;
  float* xq4=ws+off; off+=(size_t)NB*32;
  float* tbA=ws+off; off+=(size_t)NT*128;
  float* tbB=ws+off; off+=(size_t)NT*128;
  float* tb4=ws+off; off+=(size_t)NT*32;
  float* qnb=ws+off; off+=(size_t)5*NB;
  float* tnb=ws+off; off+=(size_t)NT;
  float* Tsub=ws+off; off+=(size_t)NSUB*128;
  float* tnsub=ws+off; off+=(size_t)NSUB;
  float* tot=ws+off; off+=(size_t)NB*NL;
  unsigned* sT=(unsigned*)(ws+off); off+=NB;
  unsigned short* qH=(unsigned short*)(ws+off); off+=(size_t)NB*64;
  unsigned short* qL=(unsigned short*)(ws+off); off+=(size_t)NB*64;
  unsigned short* bankH=(unsigned short*)(ws+off); off+=(size_t)NT_PAD*64;
  unsigned short* bankL=(unsigned short*)(ws+off); off+=(size_t)NT_PAD*64;
  off=(off+3)&~(size_t)3;
  unsigned* slab=(unsigned*)(ws+off);   // NTB*NB*SLOTS = 25.6 MB
  unsigned* skeys=(unsigned*)(ws+off);  // NB*NSUB     =  8.4 MB (aliased)
  { size_t slab_sz=(size_t)NTB*NB*SLOTS, skey_sz=(size_t)NB*NSUB;
    off += (slab_sz > skey_sz ? slab_sz : skey_sz); }

  // query features; layer-0 features at stride 96
  pad_copy_k<<<(NB*96+255)/256,256,0,stream>>>(x, xq0, NB, 83, 96);
  pad_copy_k<<<((size_t)NT*96+255)/256,256,0,stream>>>(txr, tbA, NT, 83, 96);
  mlp_gemm_k<<<(NB+127)/128,256,0,stream>>>(xq0,96,3,W1,83,b1,xq1,NB);
  mlp_gemm_k<<<(NB+127)/128,256,0,stream>>>(xq1,128,4,W2,128,b2,xq2,NB);
  mlp_gemm_k<<<(NB+127)/128,256,0,stream>>>(xq2,128,4,W3,128,b3,xq3,NB);
  mlp8_k<<<(NB+31)/32,256,0,stream>>>(xq3,W4,b4,xq4,NB);
  softmax_k<<<(NB+255)/256,256,0,stream>>>(xq4,NB);

  auto knn_layer = [&](const float* Qm, const float* Bank, float* qnl,
                       int dp, int first){
    conv_norm_k<<<(NT+3)/4,256,0,stream>>>(Bank, bankH, bankL, tnb, NT, dp);
    conv_norm_k<<<(NB+3)/4,256,0,stream>>>(Qm, qH, qL, qnl, NB, dp);
    sub_gather_k<<<(NSUB*dp+NSUB+255)/256,256,0,stream>>>(Bank,tnb,Tsub,tnsub,dp);
    dist_key_k<<<dim3(NB/QT,NSUB/TT),256,0,stream>>>(Qm,Tsub,qnl,tnsub,lbl,skeys,dp,NSUB);
    sel64_k<<<NB,256,0,stream>>>(skeys,sT);
    dist_mfma_k<<<8*8*49,256,0,stream>>>(qH,qL,bankH,bankL,qnl,tnb,lbl,sT,slab,dp);
    final_k<<<NB,256,0,stream>>>(slab,Qm,Bank,qnl,tnb,lbl,tot,first,dp);
  };

  knn_layer(xq0, tbA, qnb+0*NB, 96, 1);
  mlp_gemm_k<<<(NT+127)/128,256,0,stream>>>(tbA,96,3,W1,83,b1,tbB,NT);
  knn_layer(xq1, tbB, qnb+1*NB, 128, 0);
  mlp_gemm_k<<<(NT+127)/128,256,0,stream>>>(tbB,128,4,W2,128,b2,tbA,NT);
  knn_layer(xq2, tbA, qnb+2*NB, 128, 0);
  mlp_gemm_k<<<(NT+127)/128,256,0,stream>>>(tbA,128,4,W3,128,b3,tbB,NT);
  knn_layer(xq3, tbB, qnb+3*NB, 128, 0);
  mlp8_k<<<(NT+31)/32,256,0,stream>>>(tbB,W4,b4,tb4,NT);
  softmax_k<<<(NT+255)/256,256,0,stream>>>(tb4,NT);
  knn_layer(xq4, tb4, qnb+4*NB, 32, 0);

  pvalue_k<<<NB,256,0,stream>>>(tot,cal,out);
}

// Round 3
// 1173.616 us; speedup vs baseline: 1.4458x; 1.0436x over previous
//
#include <hip/hip_runtime.h>
#include <math.h>

#define KNN 75
#define NL 8
#define NB 1024
#define NT 50000
#define NT_PAD 50048  // NTB*TT rows allocated for bf16 banks (pad rows masked)
#define NCALI 10000
#define KC 32
#define TT 128
#define NTB 391       // ceil(NT/TT)
#define SLOTS 16      // per (t-block, q) slab: [count, up to 15 hit keys] = 64B
#define CAP 6144      // candidate buffer per query
#define NSUB 2048     // sampled train points for threshold
#define NSB 16        // NSUB/TT subset t-blocks
#define SSTRIDE 24
#define SOFF 11       // 11 + 24*2047 = 49139 < 50000
#define RSEL 32       // sample rank -> expected |{k < T}| ~ 780, lambda/slab ~ 2

typedef __attribute__((ext_vector_type(8))) short bf16x8;
typedef __attribute__((ext_vector_type(4))) float f32x4;

__device__ __forceinline__ int swz(int c){ return c + ((c>>5)<<2); }

__device__ __forceinline__ unsigned short f2bf_rn(float x){
  unsigned u = __float_as_uint(x);
  unsigned r = (u + 0x7FFFu + ((u>>16)&1u)) >> 16;
  return (unsigned short)r;
}
__device__ __forceinline__ float bf2f(unsigned short h){
  return __uint_as_float(((unsigned)h)<<16);
}
__device__ __forceinline__ bf16x8 ld8(const unsigned short* p){
  return *(const bf16x8*)p;
}
// async global->LDS, 16B per lane; LDS dest = wave-uniform base + lane*16
__device__ __forceinline__ void gl_lds16(const unsigned short* g, unsigned short* l){
  __builtin_amdgcn_global_load_lds(
      (const __attribute__((address_space(1))) void*)g,
      (__attribute__((address_space(3))) void*)l, 16, 0, 0);
}

// ---------------- pad copy (zero-fill pad cols every call: ws is poisoned) ----
__global__ void pad_copy_k(const float* __restrict__ in, float* __restrict__ out,
                           int M, int Din, int Dout){
  int idx = blockIdx.x*256 + threadIdx.x;
  if (idx >= M*Dout) return;
  int r = idx / Dout, c = idx - r*Dout;
  out[idx] = (c < Din) ? in[r*Din + c] : 0.f;
}

// ---------------- MLP GEMM: Out[M][128] = relu(A[M][lda] @ W[kreal][128] + b) --
__global__ __launch_bounds__(256) void mlp_gemm_k(
    const float* __restrict__ A, int lda, int kchunks,
    const float* __restrict__ W, int kreal,
    const float* __restrict__ bias,
    float* __restrict__ Out, int M)
{
  __shared__ float As[KC][132];
  __shared__ float Bs[KC][148];
  int tid = threadIdx.x;
  int r0 = (tid>>4)*8, c0 = (tid&15)*8;
  int rowBase = blockIdx.x*128;
  float acc[8][8];
  #pragma unroll
  for (int i=0;i<8;i++)
    #pragma unroll
    for (int j=0;j<8;j++) acc[i][j]=0.f;

  for (int kc=0;kc<kchunks;kc++){
    { int rr = tid>>3, k4=(tid&7)*4;
      #pragma unroll
      for (int i=0;i<4;i++){
        int row = rr + i*32, gr = rowBase + row;
        float4 v = make_float4(0.f,0.f,0.f,0.f);
        if (gr < M) v = *(const float4*)&A[(size_t)gr*lda + kc*KC + k4];
        As[k4+0][row]=v.x; As[k4+1][row]=v.y; As[k4+2][row]=v.z; As[k4+3][row]=v.w;
      }
    }
    { int kk=tid>>5, c4=(tid&31)*4;
      #pragma unroll
      for (int i=0;i<4;i++){
        int k = kk + i*8, gk = kc*KC + k;
        float4 v = make_float4(0.f,0.f,0.f,0.f);
        if (gk < kreal) v = *(const float4*)&W[(size_t)gk*128 + c4];
        *(float4*)&Bs[k][swz(c4)] = v;
      }
    }
    __syncthreads();
    #pragma unroll 4
    for (int k=0;k<KC;k++){
      float4 a0 = *(const float4*)&As[k][r0];
      float4 a1 = *(const float4*)&As[k][r0+4];
      float4 b0 = *(const float4*)&Bs[k][swz(c0)];
      float4 b1 = *(const float4*)&Bs[k][swz(c0+4)];
      float av[8] = {a0.x,a0.y,a0.z,a0.w,a1.x,a1.y,a1.z,a1.w};
      float bv[8] = {b0.x,b0.y,b0.z,b0.w,b1.x,b1.y,b1.z,b1.w};
      #pragma unroll
      for (int i=0;i<8;i++)
        #pragma unroll
        for (int j=0;j<8;j++) acc[i][j] += av[i]*bv[j];
    }
    __syncthreads();
  }
  float bb[8];
  #pragma unroll
  for (int j=0;j<8;j++) bb[j]=bias[c0+j];
  #pragma unroll
  for (int i=0;i<8;i++){
    int gr = rowBase + r0 + i;
    if (gr < M){
      float o[8];
      #pragma unroll
      for (int j=0;j<8;j++){ float v=acc[i][j]+bb[j]; o[j]=v>0.f?v:0.f; }
      *(float4*)&Out[(size_t)gr*128 + c0]   = make_float4(o[0],o[1],o[2],o[3]);
      *(float4*)&Out[(size_t)gr*128 + c0+4] = make_float4(o[4],o[5],o[6],o[7]);
    }
  }
}

// ---------------- last layer: logits[M][8] into stride-32 rows ----------------
__global__ void mlp8_k(const float* __restrict__ A, const float* __restrict__ W4,
                       const float* __restrict__ b4, float* __restrict__ Out, int M){
  __shared__ float Ws[128*8];
  int tid = threadIdx.x;
  for (int i=tid;i<1024;i+=256) Ws[i]=W4[i];
  __syncthreads();
  int r = blockIdx.x*32 + (tid>>3), c = tid&7;
  if (r >= M) return;
  const float* a = &A[(size_t)r*128];
  float acc = b4[c];
  #pragma unroll 16
  for (int k=0;k<128;k++) acc += a[k]*Ws[k*8+c];
  Out[(size_t)r*32 + c] = acc;
}

// ---------------- softmax over 8 logits, zero cols 8..31 ----------------------
__global__ void softmax_k(float* __restrict__ X, int M){
  int r = blockIdx.x*256 + threadIdx.x;
  if (r >= M) return;
  float* p = &X[(size_t)r*32];
  float v[8], m=-1e30f;
  #pragma unroll
  for (int j=0;j<8;j++){ v[j]=p[j]; m = v[j]>m ? v[j] : m; }
  float s=0.f;
  #pragma unroll
  for (int j=0;j<8;j++){ v[j]=__expf(v[j]-m); s+=v[j]; }
  float inv=1.f/s;
  #pragma unroll
  for (int j=0;j<8;j++) p[j]=v[j]*inv;
  #pragma unroll
  for (int j=8;j<32;j++) p[j]=0.f;
}

// ---------------- fp32 -> (hi,lo) bf16 split + row squared-norms --------------
__global__ void conv_norm_k(const float* __restrict__ X,
                            unsigned short* __restrict__ H,
                            unsigned short* __restrict__ L,
                            float* __restrict__ nrm, int M, int dp){
  int w = threadIdx.x>>6, lane = threadIdx.x&63;
  int row = blockIdx.x*4 + w;
  if (row >= M) return;
  const float* src = &X[(size_t)row*dp];
  unsigned short* dh = &H[(size_t)row*dp];
  unsigned short* dl = &L[(size_t)row*dp];
  float s=0.f;
  for (int c=lane;c<dp;c+=64){
    float v = src[c];
    s += v*v;
    unsigned short h = f2bf_rn(v);
    float rem = v - bf2f(h);
    dh[c] = h;
    dl[c] = f2bf_rn(rem);
  }
  #pragma unroll
  for (int off=32;off>0;off>>=1) s += __shfl_down(s, off, 64);
  if (lane==0) nrm[row]=s;
}

// ---------------- scan helper: find bin containing rank Krem ------------------
__device__ __forceinline__ void find_bin(int* hist, int* part, int nb, int Krem,
                                         int tid, int* s_B, int* s_lob){
  int ch = nb>>8;
  int s=0;
  for (int b=tid*ch;b<tid*ch+ch;b++) s+=hist[b];
  part[tid]=s;
  __syncthreads();
  if (tid==0){
    int cum=0, B=nb-1, lob=0;
    for (int t=0;t<256;t++){
      if (cum+part[t] >= Krem){
        lob=cum;
        for (int b=t*ch;b<t*ch+ch;b++){
          if (lob+hist[b]>=Krem){ B=b; break; }
          lob+=hist[b];
        }
        break;
      }
      cum+=part[t];
    }
    *s_B=B; *s_lob=lob;
  }
  __syncthreads();
}

// ---------------- per-query threshold: exact RSEL-th smallest sample key ------
__global__ __launch_bounds__(256) void sel64_k(const unsigned* __restrict__ skeys,
                                               unsigned* __restrict__ Tthr){
  __shared__ unsigned buf[NSUB];
  __shared__ int hist[2048];
  __shared__ int part[256];
  __shared__ int sB, sLob;
  int tid=threadIdx.x, q=blockIdx.x;
  for (int i=tid;i<NSUB;i+=256) buf[i]=skeys[(size_t)q*NSUB+i];
  int Krem=RSEL;
  for (int i=tid;i<2048;i+=256) hist[i]=0;
  __syncthreads();
  for (int i=tid;i<NSUB;i+=256) atomicAdd(&hist[buf[i]>>21],1);
  __syncthreads();
  find_bin(hist,part,2048,Krem,tid,&sB,&sLob);
  unsigned pre=(unsigned)sB; Krem-=sLob;
  for (int i=tid;i<2048;i+=256) hist[i]=0;
  __syncthreads();
  for (int i=tid;i<NSUB;i+=256){ unsigned k=buf[i]; if ((k>>21)==pre) atomicAdd(&hist[(k>>10)&0x7FFu],1); }
  __syncthreads();
  find_bin(hist,part,2048,Krem,tid,&sB,&sLob);
  pre=(pre<<11)|(unsigned)sB; Krem-=sLob;
  for (int i=tid;i<1024;i+=256) hist[i]=0;
  __syncthreads();
  for (int i=tid;i<NSUB;i+=256){ unsigned k=buf[i]; if ((k>>10)==pre) atomicAdd(&hist[k&0x3FFu],1); }
  __syncthreads();
  find_bin(hist,part,1024,Krem,tid,&sB,&sLob);
  if (tid==0) Tthr[q]=(pre<<10)|(unsigned)sB;
}

// ====== shared MFMA K-loop (split-bf16, double-buffered gl_lds staging) =======
#define MFMA_SEC(CUR, A0H, A0L, A1H, A1L)                                        \
  _Pragma("unroll")                                                              \
  for (int tj=0;tj<8;tj++){                                                      \
    int rowB = tj*16 + col;                                                      \
    int sw = (((quad + (rowB>>1)) & 3) << 3);                                    \
    bf16x8 bh = *(const bf16x8*)&BH[CUR][rowB*32 + sw];                          \
    bf16x8 bl = *(const bf16x8*)&BL[CUR][rowB*32 + sw];                          \
    acc[0][tj] = __builtin_amdgcn_mfma_f32_16x16x32_bf16(A0H, bh, acc[0][tj], 0,0,0); \
    acc[0][tj] = __builtin_amdgcn_mfma_f32_16x16x32_bf16(A0H, bl, acc[0][tj], 0,0,0); \
    acc[0][tj] = __builtin_amdgcn_mfma_f32_16x16x32_bf16(A0L, bh, acc[0][tj], 0,0,0); \
    acc[1][tj] = __builtin_amdgcn_mfma_f32_16x16x32_bf16(A1H, bh, acc[1][tj], 0,0,0); \
    acc[1][tj] = __builtin_amdgcn_mfma_f32_16x16x32_bf16(A1H, bl, acc[1][tj], 0,0,0); \
    acc[1][tj] = __builtin_amdgcn_mfma_f32_16x16x32_bf16(A1L, bh, acc[1][tj], 0,0,0); \
  }

// K-loop body: stages B rows (global row = ROWMAP(local row)) and computes
// acc[2][8] for a 128q x 128t tile. Used by dist_mfma_k and dist_sub_k.
#define MFMA_KLOOP(ROWMAP)                                                       \
  size_t aoff = (size_t)(qbase + w*32 + col)*dp + quad*8;                        \
  const unsigned short* pAH = QH + aoff;                                         \
  const unsigned short* pAL = QL + aoff;                                         \
  size_t qi_step = (size_t)16*dp;                                                \
  int i0 = tid,      row0 = i0>>2, sg0 = ((i0&3) - (row0>>1)) & 3;               \
  int i1 = tid+256,  row1 = i1>>2, sg1 = ((i1&3) - (row1>>1)) & 3;               \
  size_t g0 = (size_t)(ROWMAP(n0+row0))*dp + (size_t)sg0*8;                      \
  size_t g1 = (size_t)(ROWMAP(n0+row1))*dp + (size_t)sg1*8;                      \
  f32x4 acc[2][8];                                                               \
  _Pragma("unroll")                                                              \
  for (int qi=0;qi<2;qi++)                                                       \
    _Pragma("unroll")                                                            \
    for (int tj=0;tj<8;tj++){ f32x4 z={0.f,0.f,0.f,0.f}; acc[qi][tj]=z; }        \
  gl_lds16(TH + g0, &BH[0][i0*8]);                                               \
  gl_lds16(TH + g1, &BH[0][i1*8]);                                               \
  gl_lds16(TL + g0, &BL[0][i0*8]);                                               \
  gl_lds16(TL + g1, &BL[0][i1*8]);                                               \
  bf16x8 x0h = ld8(pAH), x0l = ld8(pAL);                                         \
  bf16x8 x1h = ld8(pAH + qi_step), x1l = ld8(pAL + qi_step);                     \
  bf16x8 y0h = x0h, y0l = x0l, y1h = x1h, y1l = x1l;                             \
  for (int kc=0; kc<kchunks; kc+=2){                                             \
    __syncthreads();                                                             \
    if (kc+1 < kchunks){                                                         \
      size_t ko=(size_t)(kc+1)*32;                                               \
      gl_lds16(TH + g0 + ko, &BH[1][i0*8]);                                      \
      gl_lds16(TH + g1 + ko, &BH[1][i1*8]);                                      \
      gl_lds16(TL + g0 + ko, &BL[1][i0*8]);                                      \
      gl_lds16(TL + g1 + ko, &BL[1][i1*8]);                                      \
      y0h = ld8(pAH + ko);           y0l = ld8(pAL + ko);                        \
      y1h = ld8(pAH + qi_step + ko); y1l = ld8(pAL + qi_step + ko);              \
    }                                                                            \
    MFMA_SEC(0, x0h, x0l, x1h, x1l);                                             \
    if (kc+1 < kchunks){                                                         \
      __syncthreads();                                                           \
      if (kc+2 < kchunks){                                                       \
        size_t ko=(size_t)(kc+2)*32;                                             \
        gl_lds16(TH + g0 + ko, &BH[0][i0*8]);                                    \
        gl_lds16(TH + g1 + ko, &BH[0][i1*8]);                                    \
        gl_lds16(TL + g0 + ko, &BL[0][i0*8]);                                    \
        gl_lds16(TL + g1 + ko, &BL[0][i1*8]);                                    \
        x0h = ld8(pAH + ko);           x0l = ld8(pAL + ko);                      \
        x1h = ld8(pAH + qi_step + ko); x1l = ld8(pAL + qi_step + ko);            \
      }                                                                          \
      MFMA_SEC(1, y0h, y0l, y1h, y1l);                                           \
    }                                                                            \
  }

// ---------------- MFMA split-bf16 distance GEMM vs full bank ------------------
// 1D grid 8*8*49, XCD-swizzled (b&7 = stripe). Block = 128q x 128t.
// Epilogue: threshold compare -> LDS hitbuf -> slab[t_blk][q] (contiguous 8KB).
#define ROW_ID(r) (r)
__global__ __launch_bounds__(256) void dist_mfma_k(
    const unsigned short* __restrict__ QH, const unsigned short* __restrict__ QL,
    const unsigned short* __restrict__ TH, const unsigned short* __restrict__ TL,
    const float* __restrict__ qn, const float* __restrict__ tn,
    const int* __restrict__ labels, const unsigned* __restrict__ Tthr,
    unsigned* __restrict__ slab, int dp)
{
  __shared__ unsigned short BH[2][128*32];   // 16 KB
  __shared__ unsigned short BL[2][128*32];   // 16 KB
  __shared__ unsigned hitbuf[128][SLOTS];    // 8 KB
  __shared__ int hcnt[128];
  int b = blockIdx.x;
  int xcd = b & 7, s = b >> 3;
  int qb = s & 7, tslot = s >> 3;
  int t_blk = xcd + 8*tslot;
  if (t_blk >= NTB) return;
  int tid = threadIdx.x, w = tid>>6, lane = tid&63;
  int quad = lane>>4, col = lane&15;
  int qbase = qb*128;
  int n0 = t_blk*TT;
  int kchunks = dp >> 5;

  MFMA_KLOOP(ROW_ID)

  // epilogue: d2 from norms + acc, threshold compare, LDS slab compaction
  if (tid<128) hcnt[tid]=0;
  __syncthreads();
  float qnr[2][4]; unsigned Tq[2][4];
  #pragma unroll
  for (int qi=0;qi<2;qi++)
    #pragma unroll
    for (int r=0;r<4;r++){
      int q = qbase + w*32 + qi*16 + quad*4 + r;
      qnr[qi][r] = qn[q];
      Tq[qi][r]  = Tthr[q];
    }
  #pragma unroll
  for (int tj=0;tj<8;tj++){
    int t = n0 + tj*16 + col;
    if (t < NT){
      float tnv = tn[t];
      unsigned lab = (unsigned)labels[t];
      #pragma unroll
      for (int qi=0;qi<2;qi++)
        #pragma unroll
        for (int r=0;r<4;r++){
          float d2 = fmaxf(qnr[qi][r] - 2.f*acc[qi][tj][r] + tnv, 0.f);
          unsigned key = (__float_as_uint(d2)&0xFFFFFFF8u) | lab;
          if (key < Tq[qi][r]){
            int ql = w*32 + qi*16 + quad*4 + r;
            int idx = atomicAdd(&hcnt[ql], 1);
            if (idx < SLOTS-1) hitbuf[ql][1+idx] = key;
          }
        }
    }
  }
  __syncthreads();
  if (tid<128) hitbuf[tid][0]=(unsigned)hcnt[tid];
  __syncthreads();
  // transposed slab write: contiguous 8 KB per block
  #pragma unroll
  for (int rep=0; rep<2; rep++){
    int idx = rep*256 + tid;
    int q = idx>>2, sub = (idx&3)*4;
    uint4 v = *(uint4*)&hitbuf[q][sub];
    *(uint4*)&slab[((size_t)t_blk*NB + (qbase+q))*SLOTS + sub] = v;
  }
}

// ---------------- MFMA split-bf16 distance GEMM vs SAMPLED subset -------------
// Replaces fp32 dist_key_k (256 blocks, 1.6M LDS bank conflicts) + sub_gather_k.
// Stages directly from the full bf16 banks with row remap s -> s*24+11 and
// writes ALL keys for sel64_k. Grid 8 qb x 16 t_blk = 128 blocks, ~one round.
// Keys now use the SAME split-bf16 metric as dist_mfma_k -> threshold is a
// quantile cut in a consistent key space; final select/weights unchanged.
#define ROW_SUB(r) ((r)*SSTRIDE + SOFF)
__global__ __launch_bounds__(256) void dist_sub_k(
    const unsigned short* __restrict__ QH, const unsigned short* __restrict__ QL,
    const unsigned short* __restrict__ TH, const unsigned short* __restrict__ TL,
    const float* __restrict__ qn, const float* __restrict__ tn,
    const int* __restrict__ labels, unsigned* __restrict__ keys, int dp)
{
  __shared__ unsigned short BH[2][128*32];   // 16 KB
  __shared__ unsigned short BL[2][128*32];   // 16 KB
  int b = blockIdx.x;
  int qb = b & 7, t_blk = b >> 3;            // t_blk in [0, NSB)
  int tid = threadIdx.x, w = tid>>6, lane = tid&63;
  int quad = lane>>4, col = lane&15;
  int qbase = qb*128;
  int n0 = t_blk*TT;                         // subset-space row base
  int kchunks = dp >> 5;

  MFMA_KLOOP(ROW_SUB)

  // epilogue: write all keys; 16-lane quad -> 64B contiguous store per (qi,tj,r)
  float qnr[2][4];
  #pragma unroll
  for (int qi=0;qi<2;qi++)
    #pragma unroll
    for (int r=0;r<4;r++)
      qnr[qi][r] = qn[qbase + w*32 + qi*16 + quad*4 + r];
  #pragma unroll
  for (int tj=0;tj<8;tj++){
    int sI = n0 + tj*16 + col;
    int g  = sI*SSTRIDE + SOFF;
    float tnv = tn[g];
    unsigned lab = (unsigned)labels[g];
    #pragma unroll
    for (int qi=0;qi<2;qi++)
      #pragma unroll
      for (int r=0;r<4;r++){
        float d2 = fmaxf(qnr[qi][r] - 2.f*acc[qi][tj][r] + tnv, 0.f);
        unsigned key = (__float_as_uint(d2)&0xFFFFFFF8u) | lab;
        int q = qbase + w*32 + qi*16 + quad*4 + r;
        keys[(size_t)q*NSUB + sI] = key;
      }
  }
}

// ---------------- gather slabs, exact radix select + class sums ---------------
__global__ __launch_bounds__(256) void final_k(
    const unsigned* __restrict__ slab,
    const float* __restrict__ Qm, const float* __restrict__ Tm,
    const float* __restrict__ qn, const float* __restrict__ tn,
    const int* __restrict__ labels,
    float* __restrict__ tot, int first, int dp)
{
  __shared__ int hist[2048];
  __shared__ int part[256];
  __shared__ unsigned buf[CAP];
  __shared__ unsigned lowbuf[96];
  __shared__ float qrow[128];
  __shared__ int sB,sLob,s_cnt,s_low,s_bad;
  __shared__ float s_w[9];
  int tid=threadIdx.x, q=blockIdx.x;
  if (tid==0){ for (int j=0;j<9;j++) s_w[j]=0.f; s_cnt=0; s_low=0; s_bad=0; }
  __syncthreads();

  // transposed layout: query q's slab for t-block sidx is at (sidx*NB + q)
  for (int sidx=tid; sidx<NTB; sidx+=256){
    const unsigned* s = slab + ((size_t)sidx*NB + q)*SLOTS;
    uint4 a = *(const uint4*)s;
    unsigned cnt = a.x;
    if (cnt > SLOTS-1){ s_bad=1; continue; }
    if (!cnt) continue;
    int base = atomicAdd(&s_cnt, (int)cnt);
    if (base + (int)cnt <= CAP){
      buf[base] = a.y;
      if (cnt>=2) buf[base+1] = a.z;
      if (cnt>=3) buf[base+2] = a.w;
      for (unsigned w=4; w<=cnt; w++) buf[base+w-1] = s[w];
    }
  }
  __syncthreads();
  int total = s_cnt;
  int bad = s_bad;

#define CONTRIB(kk) do{ float d2_=__uint_as_float((kk)&0xFFFFFFF8u); \
    if (d2_>0.f){ float w_=1.0f/sqrtf(d2_); \
      atomicAdd(&s_w[8],w_); atomicAdd(&s_w[(kk)&7u],w_); } }while(0)

  unsigned T; int Krem=KNN;
  if (!bad && total>=KNN && total<=CAP){
    for (int i=tid;i<2048;i+=256) hist[i]=0;
    __syncthreads();
    for (int i=tid;i<total;i+=256) atomicAdd(&hist[buf[i]>>21],1);
    __syncthreads();
    find_bin(hist,part,2048,Krem,tid,&sB,&sLob);
    unsigned pre=(unsigned)sB; Krem-=sLob;
    for (int i=tid;i<2048;i+=256) hist[i]=0;
    __syncthreads();
    for (int i=tid;i<total;i+=256){ unsigned k=buf[i]; if ((k>>21)==pre) atomicAdd(&hist[(k>>10)&0x7FFu],1); }
    __syncthreads();
    find_bin(hist,part,2048,Krem,tid,&sB,&sLob);
    pre=(pre<<11)|(unsigned)sB; Krem-=sLob;
    for (int i=tid;i<1024;i+=256) hist[i]=0;
    __syncthreads();
    for (int i=tid;i<total;i+=256){ unsigned k=buf[i]; if ((k>>10)==pre) atomicAdd(&hist[k&0x3FFu],1); }
    __syncthreads();
    find_bin(hist,part,1024,Krem,tid,&sB,&sLob);
    T=(pre<<10)|(unsigned)sB; Krem-=sLob;
    __syncthreads();
    for (int i=tid;i<total;i+=256){ unsigned k=buf[i]; if (k<T) CONTRIB(k); }
  } else {
    // fallback (P ~ 1e-10): exact fp32 full recompute select
    if (tid==0) s_cnt=0;
    for (int i=tid;i<dp;i+=256) qrow[i]=Qm[(size_t)q*dp+i];
    __syncthreads();
    float qq=qn[q];
    auto KEY=[&](int t)->unsigned{
      const float* br=&Tm[(size_t)t*dp];
      float dot=0.f;
      for (int k2=0;k2<dp;k2++) dot+=qrow[k2]*br[k2];
      float d2=fmaxf(qq-2.f*dot+tn[t],0.f);
      return (__float_as_uint(d2)&0xFFFFFFF8u)|(unsigned)labels[t];
    };
    for (int i=tid;i<2048;i+=256) hist[i]=0;
    __syncthreads();
    for (int t=tid;t<NT;t+=256) atomicAdd(&hist[KEY(t)>>21],1);
    __syncthreads();
    find_bin(hist,part,2048,Krem,tid,&sB,&sLob);
    int c=hist[sB]; Krem-=sLob;
    unsigned prefix=(unsigned)sB; int shift=21;
    if (c > CAP){
      __syncthreads();
      for (int i=tid;i<2048;i+=256) hist[i]=0;
      __syncthreads();
      for (int t=tid;t<NT;t+=256){ unsigned k=KEY(t); if ((k>>21)==prefix) atomicAdd(&hist[(k>>10)&0x7FFu],1); }
      __syncthreads();
      find_bin(hist,part,2048,Krem,tid,&sB,&sLob);
      c=hist[sB]; Krem-=sLob; prefix=(prefix<<11)|(unsigned)sB; shift=10;
    }
    if (c > CAP){
      __syncthreads();
      for (int i=tid;i<1024;i+=256) hist[i]=0;
      __syncthreads();
      for (int t=tid;t<NT;t+=256){ unsigned k=KEY(t); if ((k>>10)==prefix) atomicAdd(&hist[k&0x3FFu],1); }
      __syncthreads();
      find_bin(hist,part,1024,Krem,tid,&sB,&sLob);
      c=hist[sB]; Krem-=sLob; prefix=(prefix<<10)|(unsigned)sB; shift=0;
    }
    if (c <= CAP){
      for (int t=tid;t<NT;t+=256){
        unsigned k=KEY(t); unsigned pp=k>>shift;
        if (pp==prefix){ int j=atomicAdd(&s_cnt,1); if (j<CAP) buf[j]=k; }
        else if (pp<prefix){ int j=atomicAdd(&s_low,1); if (j<96) lowbuf[j]=k; }
      }
      __syncthreads();
      int sh=shift;
      while (sh>0){
        int nsh=(sh==21)?10:0;
        int nb=1<<(sh-nsh);
        __syncthreads();
        for (int i=tid;i<nb;i+=256) hist[i]=0;
        __syncthreads();
        int cc=s_cnt;
        for (int i=tid;i<cc;i+=256) atomicAdd(&hist[(buf[i]>>nsh)&(unsigned)(nb-1)],1);
        __syncthreads();
        find_bin(hist,part,nb,Krem,tid,&sB,&sLob);
        Krem-=sLob; prefix=(prefix<<(sh-nsh))|(unsigned)sB; sh=nsh;
      }
      T=prefix;
      __syncthreads();
      int lowc=s_low, cc=s_cnt;
      for (int i=tid;i<lowc;i+=256){ unsigned k=lowbuf[i]; CONTRIB(k); }
      for (int i=tid;i<cc;i+=256){ unsigned k=buf[i]; if (k<T) CONTRIB(k); }
    } else {
      T=prefix;
      for (int t=tid;t<NT;t+=256){ unsigned k=KEY(t); if (k<T) CONTRIB(k); }
    }
  }
  __syncthreads();
  if (tid==0){
    float d2=__uint_as_float(T&0xFFFFFFF8u);
    float w=(d2>0.f)?(1.0f/sqrtf(d2)):0.f;
    s_w[8] += (float)Krem*w;
    s_w[T&7u] += (float)Krem*w;
  }
  __syncthreads();
  if (tid<8){
    float contrib = s_w[8]-s_w[tid];
    size_t o=(size_t)q*NL+tid;
    tot[o] = first ? contrib : tot[o]+contrib;
  }
#undef CONTRIB
}

// ---------------- empirical p-values ------------------------------------------
__global__ void pvalue_k(const float* __restrict__ tot, const float* __restrict__ cali,
                         float* __restrict__ out){
  __shared__ float t8[NL];
  __shared__ int part[4][NL];
  int tid=threadIdx.x, q=blockIdx.x;
  if (tid<NL) t8[tid]=tot[(size_t)q*NL+tid];
  __syncthreads();
  float th[NL];
  #pragma unroll
  for (int c=0;c<NL;c++) th[c]=t8[c];
  int cnt[NL];
  #pragma unroll
  for (int c=0;c<NL;c++) cnt[c]=0;
  for (int i=tid;i<NCALI;i+=256){
    float v=cali[i];
    #pragma unroll
    for (int c=0;c<NL;c++) cnt[c] += (v>=th[c]) ? 1 : 0;
  }
  #pragma unroll
  for (int c=0;c<NL;c++){
    #pragma unroll
    for (int off=32;off>0;off>>=1) cnt[c]+=__shfl_down(cnt[c],off,64);
  }
  if ((tid&63)==0){
    #pragma unroll
    for (int c=0;c<NL;c++) part[tid>>6][c]=cnt[c];
  }
  __syncthreads();
  if (tid<NL){
    int s=part[0][tid]+part[1][tid]+part[2][tid]+part[3][tid];
    out[(size_t)q*NL+tid] = (float)s / 10000.f;
  }
}

extern "C" void kernel_launch(void* const* d_in, const int* in_sizes, int n_in,
                              void* d_out, int out_size, void* d_ws, size_t ws_size,
                              hipStream_t stream) {
  const float* x   = (const float*)d_in[0];
  const float* txr = (const float*)d_in[1];
  const int*   lbl = (const int*)  d_in[2];
  const float* cal = (const float*)d_in[3];
  const float* W1  = (const float*)d_in[4];
  const float* b1  = (const float*)d_in[5];
  const float* W2  = (const float*)d_in[6];
  const float* b2  = (const float*)d_in[7];
  const float* W3  = (const float*)d_in[8];
  const float* b3  = (const float*)d_in[9];
  const float* W4  = (const float*)d_in[10];
  const float* b4  = (const float*)d_in[11];
  float* out = (float*)d_out;
  float* ws  = (float*)d_ws;

  size_t off=0;
  float* xq0=ws+off; off+=(size_t)NB*96;
  float* xq1=ws+off; off+=(size_t)NB*128;
  float* xq2=ws+off; off+=(size_t)NB*128;
  float* xq3=ws+off; off+=(size_t)NB*128;
  float* xq4=ws+off; off+=(size_t)NB*32;
  float* tbA=ws+off; off+=(size_t)NT*128;
  float* tbB=ws+off; off+=(size_t)NT*128;
  float* tb4=ws+off; off+=(size_t)NT*32;
  float* qnb=ws+off; off+=(size_t)5*NB;
  float* tnb=ws+off; off+=(size_t)NT;
  float* tot=ws+off; off+=(size_t)NB*NL;
  unsigned* sT=(unsigned*)(ws+off); off+=NB;
  unsigned short* qH=(unsigned short*)(ws+off); off+=(size_t)NB*64;
  unsigned short* qL=(unsigned short*)(ws+off); off+=(size_t)NB*64;
  unsigned short* bankH=(unsigned short*)(ws+off); off+=(size_t)NT_PAD*64;
  unsigned short* bankL=(unsigned short*)(ws+off); off+=(size_t)NT_PAD*64;
  off=(off+3)&~(size_t)3;
  unsigned* slab=(unsigned*)(ws+off);   // NTB*NB*SLOTS = 25.6 MB
  unsigned* skeys=(unsigned*)(ws+off);  // NB*NSUB     =  8.4 MB (aliased; skeys
                                        // dead before dist_mfma_k writes slab)
  { size_t slab_sz=(size_t)NTB*NB*SLOTS, skey_sz=(size_t)NB*NSUB;
    off += (slab_sz > skey_sz ? slab_sz : skey_sz); }

  // query features; layer-0 features at stride 96
  pad_copy_k<<<(NB*96+255)/256,256,0,stream>>>(x, xq0, NB, 83, 96);
  pad_copy_k<<<((size_t)NT*96+255)/256,256,0,stream>>>(txr, tbA, NT, 83, 96);
  mlp_gemm_k<<<(NB+127)/128,256,0,stream>>>(xq0,96,3,W1,83,b1,xq1,NB);
  mlp_gemm_k<<<(NB+127)/128,256,0,stream>>>(xq1,128,4,W2,128,b2,xq2,NB);
  mlp_gemm_k<<<(NB+127)/128,256,0,stream>>>(xq2,128,4,W3,128,b3,xq3,NB);
  mlp8_k<<<(NB+31)/32,256,0,stream>>>(xq3,W4,b4,xq4,NB);
  softmax_k<<<(NB+255)/256,256,0,stream>>>(xq4,NB);

  auto knn_layer = [&](const float* Qm, const float* Bank, float* qnl,
                       int dp, int first){
    conv_norm_k<<<(NT+3)/4,256,0,stream>>>(Bank, bankH, bankL, tnb, NT, dp);
    conv_norm_k<<<(NB+3)/4,256,0,stream>>>(Qm, qH, qL, qnl, NB, dp);
    dist_sub_k<<<8*NSB,256,0,stream>>>(qH,qL,bankH,bankL,qnl,tnb,lbl,skeys,dp);
    sel64_k<<<NB,256,0,stream>>>(skeys,sT);
    dist_mfma_k<<<8*8*49,256,0,stream>>>(qH,qL,bankH,bankL,qnl,tnb,lbl,sT,slab,dp);
    final_k<<<NB,256,0,stream>>>(slab,Qm,Bank,qnl,tnb,lbl,tot,first,dp);
  };

  knn_layer(xq0, tbA, qnb+0*NB, 96, 1);
  mlp_gemm_k<<<(NT+127)/128,256,0,stream>>>(tbA,96,3,W1,83,b1,tbB,NT);
  knn_layer(xq1, tbB, qnb+1*NB, 128, 0);
  mlp_gemm_k<<<(NT+127)/128,256,0,stream>>>(tbB,128,4,W2,128,b2,tbA,NT);
  knn_layer(xq2, tbA, qnb+2*NB, 128, 0);
  mlp_gemm_k<<<(NT+127)/128,256,0,stream>>>(tbA,128,4,W3,128,b3,tbB,NT);
  knn_layer(xq3, tbB, qnb+3*NB, 128, 0);
  mlp8_k<<<(NT+31)/32,256,0,stream>>>(tbB,W4,b4,tb4,NT);
  softmax_k<<<(NT+255)/256,256,0,stream>>>(tb4,NT);
  knn_layer(xq4, tb4, qnb+4*NB, 32, 0);

  pvalue_k<<<NB,256,0,stream>>>(tot,cal,out);
}

// Round 4
// 1171.538 us; speedup vs baseline: 1.4484x; 1.0018x over previous
//
#include <hip/hip_runtime.h>
#include <math.h>

#define KNN 75
#define NL 8
#define NB 1024
#define NT 50000
#define NT_PAD 50048  // NTB*TT rows allocated for bf16 banks (pad rows masked)
#define NCALI 10000
#define KC 32
#define TT 128
#define NTB 391       // ceil(NT/TT)
#define SLOTS 16      // per (t-block, q) slab: [count, up to 15 hit keys] = 64B
#define CAP 6144      // candidate buffer per query
#define NSUB 2048     // sampled train points for threshold
#define NSB 16        // NSUB/TT subset t-blocks
#define SSTRIDE 24
#define SOFF 11       // 11 + 24*2047 = 49139 < 50000
#define RSEL 32       // sample rank -> expected |{k < T}| ~ 780, lambda/slab ~ 2

typedef __attribute__((ext_vector_type(8))) short bf16x8;
typedef __attribute__((ext_vector_type(4))) float f32x4;
typedef __attribute__((ext_vector_type(4))) unsigned uint4v;

__device__ __forceinline__ int swz(int c){ return c + ((c>>5)<<2); }

__device__ __forceinline__ unsigned short f2bf_rn(float x){
  unsigned u = __float_as_uint(x);
  unsigned r = (u + 0x7FFFu + ((u>>16)&1u)) >> 16;
  return (unsigned short)r;
}
__device__ __forceinline__ float bf2f(unsigned short h){
  return __uint_as_float(((unsigned)h)<<16);
}
__device__ __forceinline__ bf16x8 ld8(const unsigned short* p){
  return *(const bf16x8*)p;
}
// async global->LDS, 16B per lane; LDS dest = wave-uniform base + lane*16
__device__ __forceinline__ void gl_lds16(const unsigned short* g, unsigned short* l){
  __builtin_amdgcn_global_load_lds(
      (const __attribute__((address_space(1))) void*)g,
      (__attribute__((address_space(3))) void*)l, 16, 0, 0);
}

// ---------------- pad copy (zero-fill pad cols every call: ws is poisoned) ----
__global__ void pad_copy_k(const float* __restrict__ in, float* __restrict__ out,
                           int M, int Din, int Dout){
  int idx = blockIdx.x*256 + threadIdx.x;
  if (idx >= M*Dout) return;
  int r = idx / Dout, c = idx - r*Dout;
  out[idx] = (c < Din) ? in[r*Din + c] : 0.f;
}

// ---------------- MLP GEMM: Out[M][128] = relu(A[M][lda] @ W[kreal][128] + b) --
__global__ __launch_bounds__(256) void mlp_gemm_k(
    const float* __restrict__ A, int lda, int kchunks,
    const float* __restrict__ W, int kreal,
    const float* __restrict__ bias,
    float* __restrict__ Out, int M)
{
  __shared__ float As[KC][132];
  __shared__ float Bs[KC][148];
  int tid = threadIdx.x;
  int r0 = (tid>>4)*8, c0 = (tid&15)*8;
  int rowBase = blockIdx.x*128;
  float acc[8][8];
  #pragma unroll
  for (int i=0;i<8;i++)
    #pragma unroll
    for (int j=0;j<8;j++) acc[i][j]=0.f;

  for (int kc=0;kc<kchunks;kc++){
    { int rr = tid>>3, k4=(tid&7)*4;
      #pragma unroll
      for (int i=0;i<4;i++){
        int row = rr + i*32, gr = rowBase + row;
        float4 v = make_float4(0.f,0.f,0.f,0.f);
        if (gr < M) v = *(const float4*)&A[(size_t)gr*lda + kc*KC + k4];
        As[k4+0][row]=v.x; As[k4+1][row]=v.y; As[k4+2][row]=v.z; As[k4+3][row]=v.w;
      }
    }
    { int kk=tid>>5, c4=(tid&31)*4;
      #pragma unroll
      for (int i=0;i<4;i++){
        int k = kk + i*8, gk = kc*KC + k;
        float4 v = make_float4(0.f,0.f,0.f,0.f);
        if (gk < kreal) v = *(const float4*)&W[(size_t)gk*128 + c4];
        *(float4*)&Bs[k][swz(c4)] = v;
      }
    }
    __syncthreads();
    #pragma unroll 4
    for (int k=0;k<KC;k++){
      float4 a0 = *(const float4*)&As[k][r0];
      float4 a1 = *(const float4*)&As[k][r0+4];
      float4 b0 = *(const float4*)&Bs[k][swz(c0)];
      float4 b1 = *(const float4*)&Bs[k][swz(c0+4)];
      float av[8] = {a0.x,a0.y,a0.z,a0.w,a1.x,a1.y,a1.z,a1.w};
      float bv[8] = {b0.x,b0.y,b0.z,b0.w,b1.x,b1.y,b1.z,b1.w};
      #pragma unroll
      for (int i=0;i<8;i++)
        #pragma unroll
        for (int j=0;j<8;j++) acc[i][j] += av[i]*bv[j];
    }
    __syncthreads();
  }
  float bb[8];
  #pragma unroll
  for (int j=0;j<8;j++) bb[j]=bias[c0+j];
  #pragma unroll
  for (int i=0;i<8;i++){
    int gr = rowBase + r0 + i;
    if (gr < M){
      float o[8];
      #pragma unroll
      for (int j=0;j<8;j++){ float v=acc[i][j]+bb[j]; o[j]=v>0.f?v:0.f; }
      *(float4*)&Out[(size_t)gr*128 + c0]   = make_float4(o[0],o[1],o[2],o[3]);
      *(float4*)&Out[(size_t)gr*128 + c0+4] = make_float4(o[4],o[5],o[6],o[7]);
    }
  }
}

// ---------------- last layer: logits[M][8] into stride-32 rows ----------------
__global__ void mlp8_k(const float* __restrict__ A, const float* __restrict__ W4,
                       const float* __restrict__ b4, float* __restrict__ Out, int M){
  __shared__ float Ws[128*8];
  int tid = threadIdx.x;
  for (int i=tid;i<1024;i+=256) Ws[i]=W4[i];
  __syncthreads();
  int r = blockIdx.x*32 + (tid>>3), c = tid&7;
  if (r >= M) return;
  const float* a = &A[(size_t)r*128];
  float acc = b4[c];
  #pragma unroll 16
  for (int k=0;k<128;k++) acc += a[k]*Ws[k*8+c];
  Out[(size_t)r*32 + c] = acc;
}

// ---------------- softmax over 8 logits, zero cols 8..31 ----------------------
__global__ void softmax_k(float* __restrict__ X, int M){
  int r = blockIdx.x*256 + threadIdx.x;
  if (r >= M) return;
  float* p = &X[(size_t)r*32];
  float v[8], m=-1e30f;
  #pragma unroll
  for (int j=0;j<8;j++){ v[j]=p[j]; m = v[j]>m ? v[j] : m; }
  float s=0.f;
  #pragma unroll
  for (int j=0;j<8;j++){ v[j]=__expf(v[j]-m); s+=v[j]; }
  float inv=1.f/s;
  #pragma unroll
  for (int j=0;j<8;j++) p[j]=v[j]*inv;
  #pragma unroll
  for (int j=8;j<32;j++) p[j]=0.f;
}

// ---------------- fp32 -> (hi,lo) bf16 split + row squared-norms --------------
__global__ void conv_norm_k(const float* __restrict__ X,
                            unsigned short* __restrict__ H,
                            unsigned short* __restrict__ L,
                            float* __restrict__ nrm, int M, int dp){
  int w = threadIdx.x>>6, lane = threadIdx.x&63;
  int row = blockIdx.x*4 + w;
  if (row >= M) return;
  const float* src = &X[(size_t)row*dp];
  unsigned short* dh = &H[(size_t)row*dp];
  unsigned short* dl = &L[(size_t)row*dp];
  float s=0.f;
  for (int c=lane;c<dp;c+=64){
    float v = src[c];
    s += v*v;
    unsigned short h = f2bf_rn(v);
    float rem = v - bf2f(h);
    dh[c] = h;
    dl[c] = f2bf_rn(rem);
  }
  #pragma unroll
  for (int off=32;off>0;off>>=1) s += __shfl_down(s, off, 64);
  if (lane==0) nrm[row]=s;
}

// ---------------- scan helper: find bin containing rank Krem ------------------
__device__ __forceinline__ void find_bin(int* hist, int* part, int nb, int Krem,
                                         int tid, int* s_B, int* s_lob){
  int ch = nb>>8;
  int s=0;
  for (int b=tid*ch;b<tid*ch+ch;b++) s+=hist[b];
  part[tid]=s;
  __syncthreads();
  if (tid==0){
    int cum=0, B=nb-1, lob=0;
    for (int t=0;t<256;t++){
      if (cum+part[t] >= Krem){
        lob=cum;
        for (int b=t*ch;b<t*ch+ch;b++){
          if (lob+hist[b]>=Krem){ B=b; break; }
          lob+=hist[b];
        }
        break;
      }
      cum+=part[t];
    }
    *s_B=B; *s_lob=lob;
  }
  __syncthreads();
}

// ---------------- per-query threshold: exact RSEL-th smallest sample key ------
__global__ __launch_bounds__(256) void sel64_k(const unsigned* __restrict__ skeys,
                                               unsigned* __restrict__ Tthr){
  __shared__ unsigned buf[NSUB];
  __shared__ int hist[2048];
  __shared__ int part[256];
  __shared__ int sB, sLob;
  int tid=threadIdx.x, q=blockIdx.x;
  for (int i=tid;i<NSUB;i+=256) buf[i]=skeys[(size_t)q*NSUB+i];
  int Krem=RSEL;
  for (int i=tid;i<2048;i+=256) hist[i]=0;
  __syncthreads();
  for (int i=tid;i<NSUB;i+=256) atomicAdd(&hist[buf[i]>>21],1);
  __syncthreads();
  find_bin(hist,part,2048,Krem,tid,&sB,&sLob);
  unsigned pre=(unsigned)sB; Krem-=sLob;
  for (int i=tid;i<2048;i+=256) hist[i]=0;
  __syncthreads();
  for (int i=tid;i<NSUB;i+=256){ unsigned k=buf[i]; if ((k>>21)==pre) atomicAdd(&hist[(k>>10)&0x7FFu],1); }
  __syncthreads();
  find_bin(hist,part,2048,Krem,tid,&sB,&sLob);
  pre=(pre<<11)|(unsigned)sB; Krem-=sLob;
  for (int i=tid;i<1024;i+=256) hist[i]=0;
  __syncthreads();
  for (int i=tid;i<NSUB;i+=256){ unsigned k=buf[i]; if ((k>>10)==pre) atomicAdd(&hist[k&0x3FFu],1); }
  __syncthreads();
  find_bin(hist,part,1024,Krem,tid,&sB,&sLob);
  if (tid==0) Tthr[q]=(pre<<10)|(unsigned)sB;
}

// ====== MFMA section: one 128x128 sub-tile x one K-chunk from LDS =============
#define MFMA_SEC(CUR, A0H, A0L, A1H, A1L)                                        \
  _Pragma("unroll")                                                              \
  for (int tj=0;tj<8;tj++){                                                      \
    int rowB = tj*16 + col;                                                      \
    int sw = (((quad + (rowB>>1)) & 3) << 3);                                    \
    bf16x8 bh = *(const bf16x8*)&BH[CUR][rowB*32 + sw];                          \
    bf16x8 bl = *(const bf16x8*)&BL[CUR][rowB*32 + sw];                          \
    acc[0][tj] = __builtin_amdgcn_mfma_f32_16x16x32_bf16(A0H, bh, acc[0][tj], 0,0,0); \
    acc[0][tj] = __builtin_amdgcn_mfma_f32_16x16x32_bf16(A0H, bl, acc[0][tj], 0,0,0); \
    acc[0][tj] = __builtin_amdgcn_mfma_f32_16x16x32_bf16(A0L, bh, acc[0][tj], 0,0,0); \
    acc[1][tj] = __builtin_amdgcn_mfma_f32_16x16x32_bf16(A1H, bh, acc[1][tj], 0,0,0); \
    acc[1][tj] = __builtin_amdgcn_mfma_f32_16x16x32_bf16(A1H, bl, acc[1][tj], 0,0,0); \
    acc[1][tj] = __builtin_amdgcn_mfma_f32_16x16x32_bf16(A1L, bh, acc[1][tj], 0,0,0); \
  }

// K-loop body (2-deep double-buffer) used by dist_sub_k.
#define MFMA_KLOOP(ROWMAP)                                                       \
  size_t aoff = (size_t)(qbase + w*32 + col)*dp + quad*8;                        \
  const unsigned short* pAH = QH + aoff;                                         \
  const unsigned short* pAL = QL + aoff;                                         \
  size_t qi_step = (size_t)16*dp;                                                \
  int i0 = tid,      row0 = i0>>2, sg0 = ((i0&3) - (row0>>1)) & 3;               \
  int i1 = tid+256,  row1 = i1>>2, sg1 = ((i1&3) - (row1>>1)) & 3;               \
  size_t g0 = (size_t)(ROWMAP(n0+row0))*dp + (size_t)sg0*8;                      \
  size_t g1 = (size_t)(ROWMAP(n0+row1))*dp + (size_t)sg1*8;                      \
  f32x4 acc[2][8];                                                               \
  _Pragma("unroll")                                                              \
  for (int qi=0;qi<2;qi++)                                                       \
    _Pragma("unroll")                                                            \
    for (int tj=0;tj<8;tj++){ f32x4 z={0.f,0.f,0.f,0.f}; acc[qi][tj]=z; }        \
  gl_lds16(TH + g0, &BH[0][i0*8]);                                               \
  gl_lds16(TH + g1, &BH[0][i1*8]);                                               \
  gl_lds16(TL + g0, &BL[0][i0*8]);                                               \
  gl_lds16(TL + g1, &BL[0][i1*8]);                                               \
  bf16x8 x0h = ld8(pAH), x0l = ld8(pAL);                                         \
  bf16x8 x1h = ld8(pAH + qi_step), x1l = ld8(pAL + qi_step);                     \
  bf16x8 y0h = x0h, y0l = x0l, y1h = x1h, y1l = x1l;                             \
  for (int kc=0; kc<kchunks; kc+=2){                                             \
    __syncthreads();                                                             \
    if (kc+1 < kchunks){                                                         \
      size_t ko=(size_t)(kc+1)*32;                                               \
      gl_lds16(TH + g0 + ko, &BH[1][i0*8]);                                      \
      gl_lds16(TH + g1 + ko, &BH[1][i1*8]);                                      \
      gl_lds16(TL + g0 + ko, &BL[1][i0*8]);                                      \
      gl_lds16(TL + g1 + ko, &BL[1][i1*8]);                                      \
      y0h = ld8(pAH + ko);           y0l = ld8(pAL + ko);                        \
      y1h = ld8(pAH + qi_step + ko); y1l = ld8(pAL + qi_step + ko);              \
    }                                                                            \
    MFMA_SEC(0, x0h, x0l, x1h, x1l);                                             \
    if (kc+1 < kchunks){                                                         \
      __syncthreads();                                                           \
      if (kc+2 < kchunks){                                                       \
        size_t ko=(size_t)(kc+2)*32;                                             \
        gl_lds16(TH + g0 + ko, &BH[0][i0*8]);                                    \
        gl_lds16(TH + g1 + ko, &BH[0][i1*8]);                                    \
        gl_lds16(TL + g0 + ko, &BL[0][i0*8]);                                    \
        gl_lds16(TL + g1 + ko, &BL[0][i1*8]);                                    \
        x0h = ld8(pAH + ko);           x0l = ld8(pAL + ko);                      \
        x1h = ld8(pAH + qi_step + ko); x1l = ld8(pAL + qi_step + ko);            \
      }                                                                          \
      MFMA_SEC(1, y0h, y0l, y1h, y1l);                                           \
    }                                                                            \
  }

// ---------------- MFMA split-bf16 distance GEMM vs full bank ------------------
// v3 restructure: FULL B-tile in LDS (all K-chunks, <=64KB) staged with ONE
// barrier; then 2 query-columns (256 q) computed per block from stable LDS with
// no further K-loop syncs. Grid 8 xcd x 4 qpair x 49 tslot = 1568 blocks.
// Rationale: kernel was dp-INDEPENDENT at 87us (kchunks 1 vs 4 identical) ->
// cost is per-block fixed (per-chunk barrier latency exposure + slab-store RFO:
// the dp-independent 14.9MB FETCH ~ 60% of slab lines read-for-ownership).
// Fixes: one barrier total; staging replication 8x->4x; nontemporal slab
// stores (no RFO). LDS 72.75KB -> 2 blocks/CU.
__global__ __launch_bounds__(256) void dist_mfma_k(
    const unsigned short* __restrict__ QH, const unsigned short* __restrict__ QL,
    const unsigned short* __restrict__ TH, const unsigned short* __restrict__ TL,
    const float* __restrict__ qn, const float* __restrict__ tn,
    const int* __restrict__ labels, const unsigned* __restrict__ Tthr,
    unsigned* __restrict__ slab, int dp)
{
  __shared__ unsigned short BH[4][128*32];   // 32 KB (full tile, chunk-major)
  __shared__ unsigned short BL[4][128*32];   // 32 KB
  __shared__ unsigned hitbuf[128][SLOTS];    // 8 KB
  __shared__ int hcnt[128];
  int b = blockIdx.x;
  int xcd = b & 7, s = b >> 3;
  int p = s & 3, tslot = s >> 2;
  int t_blk = xcd + 8*tslot;
  if (t_blk >= NTB) return;
  int tid = threadIdx.x, w = tid>>6, lane = tid&63;
  int quad = lane>>4, col = lane&15;
  int qbase0 = p*256;
  int n0 = t_blk*TT;
  int kchunks = dp >> 5;

  // ---- stage ALL chunks, one barrier ----
  {
    int i0 = tid,      row0 = i0>>2, sg0 = ((i0&3) - (row0>>1)) & 3;
    int i1 = tid+256,  row1 = i1>>2, sg1 = ((i1&3) - (row1>>1)) & 3;
    size_t g0 = (size_t)(n0+row0)*dp + (size_t)sg0*8;
    size_t g1 = (size_t)(n0+row1)*dp + (size_t)sg1*8;
    for (int kc=0;kc<kchunks;kc++){
      size_t ko=(size_t)kc*32;
      gl_lds16(TH + g0 + ko, &BH[kc][i0*8]);
      gl_lds16(TH + g1 + ko, &BH[kc][i1*8]);
      gl_lds16(TL + g0 + ko, &BL[kc][i0*8]);
      gl_lds16(TL + g1 + ko, &BL[kc][i1*8]);
    }
  }
  __syncthreads();

  size_t qi_step = (size_t)16*dp;
  for (int qbi=0; qbi<2; qbi++){
    int qbase = qbase0 + qbi*128;
    size_t aoff = (size_t)(qbase + w*32 + col)*dp + quad*8;
    const unsigned short* pAH = QH + aoff;
    const unsigned short* pAL = QL + aoff;

    f32x4 acc[2][8];
    #pragma unroll
    for (int qi=0;qi<2;qi++)
      #pragma unroll
      for (int tj=0;tj<8;tj++){ f32x4 z={0.f,0.f,0.f,0.f}; acc[qi][tj]=z; }

    for (int kc=0;kc<kchunks;kc++){
      size_t ko=(size_t)kc*32;
      bf16x8 a0h = ld8(pAH + ko),           a0l = ld8(pAL + ko);
      bf16x8 a1h = ld8(pAH + qi_step + ko), a1l = ld8(pAL + qi_step + ko);
      MFMA_SEC(kc, a0h, a0l, a1h, a1l);
    }

    // epilogue for this q-column
    if (tid<128) hcnt[tid]=0;
    __syncthreads();
    float qnr[2][4]; unsigned Tq[2][4];
    #pragma unroll
    for (int qi=0;qi<2;qi++)
      #pragma unroll
      for (int r=0;r<4;r++){
        int q = qbase + w*32 + qi*16 + quad*4 + r;
        qnr[qi][r] = qn[q];
        Tq[qi][r]  = Tthr[q];
      }
    #pragma unroll
    for (int tj=0;tj<8;tj++){
      int t = n0 + tj*16 + col;
      if (t < NT){
        float tnv = tn[t];
        unsigned lab = (unsigned)labels[t];
        #pragma unroll
        for (int qi=0;qi<2;qi++)
          #pragma unroll
          for (int r=0;r<4;r++){
            float d2 = fmaxf(qnr[qi][r] - 2.f*acc[qi][tj][r] + tnv, 0.f);
            unsigned key = (__float_as_uint(d2)&0xFFFFFFF8u) | lab;
            if (key < Tq[qi][r]){
              int ql = w*32 + qi*16 + quad*4 + r;
              int idx = atomicAdd(&hcnt[ql], 1);
              if (idx < SLOTS-1) hitbuf[ql][1+idx] = key;
            }
          }
      }
    }
    __syncthreads();
    if (tid<128) hitbuf[tid][0]=(unsigned)hcnt[tid];
    __syncthreads();
    // contiguous 8 KB per (block, qbi), nontemporal (streaming, no RFO)
    #pragma unroll
    for (int rep=0; rep<2; rep++){
      int idx = rep*256 + tid;
      int q = idx>>2, sub = (idx&3)*4;
      uint4v v = *(uint4v*)&hitbuf[q][sub];
      __builtin_nontemporal_store(v,
        (uint4v*)&slab[((size_t)t_blk*NB + (qbase+q))*SLOTS + sub]);
    }
    __syncthreads();   // hitbuf reads done before next qbi resets it
  }
}

// ---------------- MFMA split-bf16 distance GEMM vs SAMPLED subset -------------
#define ROW_SUB(r) ((r)*SSTRIDE + SOFF)
__global__ __launch_bounds__(256) void dist_sub_k(
    const unsigned short* __restrict__ QH, const unsigned short* __restrict__ QL,
    const unsigned short* __restrict__ TH, const unsigned short* __restrict__ TL,
    const float* __restrict__ qn, const float* __restrict__ tn,
    const int* __restrict__ labels, unsigned* __restrict__ keys, int dp)
{
  __shared__ unsigned short BH[2][128*32];   // 16 KB
  __shared__ unsigned short BL[2][128*32];   // 16 KB
  int b = blockIdx.x;
  int qb = b & 7, t_blk = b >> 3;            // t_blk in [0, NSB)
  int tid = threadIdx.x, w = tid>>6, lane = tid&63;
  int quad = lane>>4, col = lane&15;
  int qbase = qb*128;
  int n0 = t_blk*TT;                         // subset-space row base
  int kchunks = dp >> 5;

  MFMA_KLOOP(ROW_SUB)

  // epilogue: write all keys; 16-lane quad -> 64B contiguous store per (qi,tj,r)
  float qnr[2][4];
  #pragma unroll
  for (int qi=0;qi<2;qi++)
    #pragma unroll
    for (int r=0;r<4;r++)
      qnr[qi][r] = qn[qbase + w*32 + qi*16 + quad*4 + r];
  #pragma unroll
  for (int tj=0;tj<8;tj++){
    int sI = n0 + tj*16 + col;
    int g  = sI*SSTRIDE + SOFF;
    float tnv = tn[g];
    unsigned lab = (unsigned)labels[g];
    #pragma unroll
    for (int qi=0;qi<2;qi++)
      #pragma unroll
      for (int r=0;r<4;r++){
        float d2 = fmaxf(qnr[qi][r] - 2.f*acc[qi][tj][r] + tnv, 0.f);
        unsigned key = (__float_as_uint(d2)&0xFFFFFFF8u) | lab;
        int q = qbase + w*32 + qi*16 + quad*4 + r;
        keys[(size_t)q*NSUB + sI] = key;
      }
  }
}

// ---------------- gather slabs, exact radix select + class sums ---------------
__global__ __launch_bounds__(256) void final_k(
    const unsigned* __restrict__ slab,
    const float* __restrict__ Qm, const float* __restrict__ Tm,
    const float* __restrict__ qn, const float* __restrict__ tn,
    const int* __restrict__ labels,
    float* __restrict__ tot, int first, int dp)
{
  __shared__ int hist[2048];
  __shared__ int part[256];
  __shared__ unsigned buf[CAP];
  __shared__ unsigned lowbuf[96];
  __shared__ float qrow[128];
  __shared__ int sB,sLob,s_cnt,s_low,s_bad;
  __shared__ float s_w[9];
  int tid=threadIdx.x, q=blockIdx.x;
  if (tid==0){ for (int j=0;j<9;j++) s_w[j]=0.f; s_cnt=0; s_low=0; s_bad=0; }
  __syncthreads();

  // transposed layout: query q's slab for t-block sidx is at (sidx*NB + q)
  for (int sidx=tid; sidx<NTB; sidx+=256){
    const unsigned* s = slab + ((size_t)sidx*NB + q)*SLOTS;
    uint4 a = *(const uint4*)s;
    unsigned cnt = a.x;
    if (cnt > SLOTS-1){ s_bad=1; continue; }
    if (!cnt) continue;
    int base = atomicAdd(&s_cnt, (int)cnt);
    if (base + (int)cnt <= CAP){
      buf[base] = a.y;
      if (cnt>=2) buf[base+1] = a.z;
      if (cnt>=3) buf[base+2] = a.w;
      for (unsigned w=4; w<=cnt; w++) buf[base+w-1] = s[w];
    }
  }
  __syncthreads();
  int total = s_cnt;
  int bad = s_bad;

#define CONTRIB(kk) do{ float d2_=__uint_as_float((kk)&0xFFFFFFF8u); \
    if (d2_>0.f){ float w_=1.0f/sqrtf(d2_); \
      atomicAdd(&s_w[8],w_); atomicAdd(&s_w[(kk)&7u],w_); } }while(0)

  unsigned T; int Krem=KNN;
  if (!bad && total>=KNN && total<=CAP){
    for (int i=tid;i<2048;i+=256) hist[i]=0;
    __syncthreads();
    for (int i=tid;i<total;i+=256) atomicAdd(&hist[buf[i]>>21],1);
    __syncthreads();
    find_bin(hist,part,2048,Krem,tid,&sB,&sLob);
    unsigned pre=(unsigned)sB; Krem-=sLob;
    for (int i=tid;i<2048;i+=256) hist[i]=0;
    __syncthreads();
    for (int i=tid;i<total;i+=256){ unsigned k=buf[i]; if ((k>>21)==pre) atomicAdd(&hist[(k>>10)&0x7FFu],1); }
    __syncthreads();
    find_bin(hist,part,2048,Krem,tid,&sB,&sLob);
    pre=(pre<<11)|(unsigned)sB; Krem-=sLob;
    for (int i=tid;i<1024;i+=256) hist[i]=0;
    __syncthreads();
    for (int i=tid;i<total;i+=256){ unsigned k=buf[i]; if ((k>>10)==pre) atomicAdd(&hist[k&0x3FFu],1); }
    __syncthreads();
    find_bin(hist,part,1024,Krem,tid,&sB,&sLob);
    T=(pre<<10)|(unsigned)sB; Krem-=sLob;
    __syncthreads();
    for (int i=tid;i<total;i+=256){ unsigned k=buf[i]; if (k<T) CONTRIB(k); }
  } else {
    // fallback (P ~ 1e-10): exact fp32 full recompute select
    if (tid==0) s_cnt=0;
    for (int i=tid;i<dp;i+=256) qrow[i]=Qm[(size_t)q*dp+i];
    __syncthreads();
    float qq=qn[q];
    auto KEY=[&](int t)->unsigned{
      const float* br=&Tm[(size_t)t*dp];
      float dot=0.f;
      for (int k2=0;k2<dp;k2++) dot+=qrow[k2]*br[k2];
      float d2=fmaxf(qq-2.f*dot+tn[t],0.f);
      return (__float_as_uint(d2)&0xFFFFFFF8u)|(unsigned)labels[t];
    };
    for (int i=tid;i<2048;i+=256) hist[i]=0;
    __syncthreads();
    for (int t=tid;t<NT;t+=256) atomicAdd(&hist[KEY(t)>>21],1);
    __syncthreads();
    find_bin(hist,part,2048,Krem,tid,&sB,&sLob);
    int c=hist[sB]; Krem-=sLob;
    unsigned prefix=(unsigned)sB; int shift=21;
    if (c > CAP){
      __syncthreads();
      for (int i=tid;i<2048;i+=256) hist[i]=0;
      __syncthreads();
      for (int t=tid;t<NT;t+=256){ unsigned k=KEY(t); if ((k>>21)==prefix) atomicAdd(&hist[(k>>10)&0x7FFu],1); }
      __syncthreads();
      find_bin(hist,part,2048,Krem,tid,&sB,&sLob);
      c=hist[sB]; Krem-=sLob; prefix=(prefix<<11)|(unsigned)sB; shift=10;
    }
    if (c > CAP){
      __syncthreads();
      for (int i=tid;i<1024;i+=256) hist[i]=0;
      __syncthreads();
      for (int t=tid;t<NT;t+=256){ unsigned k=KEY(t); if ((k>>10)==prefix) atomicAdd(&hist[k&0x3FFu],1); }
      __syncthreads();
      find_bin(hist,part,1024,Krem,tid,&sB,&sLob);
      c=hist[sB]; Krem-=sLob; prefix=(prefix<<10)|(unsigned)sB; shift=0;
    }
    if (c <= CAP){
      for (int t=tid;t<NT;t+=256){
        unsigned k=KEY(t); unsigned pp=k>>shift;
        if (pp==prefix){ int j=atomicAdd(&s_cnt,1); if (j<CAP) buf[j]=k; }
        else if (pp<prefix){ int j=atomicAdd(&s_low,1); if (j<96) lowbuf[j]=k; }
      }
      __syncthreads();
      int sh=shift;
      while (sh>0){
        int nsh=(sh==21)?10:0;
        int nb=1<<(sh-nsh);
        __syncthreads();
        for (int i=tid;i<nb;i+=256) hist[i]=0;
        __syncthreads();
        int cc=s_cnt;
        for (int i=tid;i<cc;i+=256) atomicAdd(&hist[(buf[i]>>nsh)&(unsigned)(nb-1)],1);
        __syncthreads();
        find_bin(hist,part,nb,Krem,tid,&sB,&sLob);
        Krem-=sLob; prefix=(prefix<<(sh-nsh))|(unsigned)sB; sh=nsh;
      }
      T=prefix;
      __syncthreads();
      int lowc=s_low, cc=s_cnt;
      for (int i=tid;i<lowc;i+=256){ unsigned k=lowbuf[i]; CONTRIB(k); }
      for (int i=tid;i<cc;i+=256){ unsigned k=buf[i]; if (k<T) CONTRIB(k); }
    } else {
      T=prefix;
      for (int t=tid;t<NT;t+=256){ unsigned k=KEY(t); if (k<T) CONTRIB(k); }
    }
  }
  __syncthreads();
  if (tid==0){
    float d2=__uint_as_float(T&0xFFFFFFF8u);
    float w=(d2>0.f)?(1.0f/sqrtf(d2)):0.f;
    s_w[8] += (float)Krem*w;
    s_w[T&7u] += (float)Krem*w;
  }
  __syncthreads();
  if (tid<8){
    float contrib = s_w[8]-s_w[tid];
    size_t o=(size_t)q*NL+tid;
    tot[o] = first ? contrib : tot[o]+contrib;
  }
#undef CONTRIB
}

// ---------------- empirical p-values ------------------------------------------
__global__ void pvalue_k(const float* __restrict__ tot, const float* __restrict__ cali,
                         float* __restrict__ out){
  __shared__ float t8[NL];
  __shared__ int part[4][NL];
  int tid=threadIdx.x, q=blockIdx.x;
  if (tid<NL) t8[tid]=tot[(size_t)q*NL+tid];
  __syncthreads();
  float th[NL];
  #pragma unroll
  for (int c=0;c<NL;c++) th[c]=t8[c];
  int cnt[NL];
  #pragma unroll
  for (int c=0;c<NL;c++) cnt[c]=0;
  for (int i=tid;i<NCALI;i+=256){
    float v=cali[i];
    #pragma unroll
    for (int c=0;c<NL;c++) cnt[c] += (v>=th[c]) ? 1 : 0;
  }
  #pragma unroll
  for (int c=0;c<NL;c++){
    #pragma unroll
    for (int off=32;off>0;off>>=1) cnt[c]+=__shfl_down(cnt[c],off,64);
  }
  if ((tid&63)==0){
    #pragma unroll
    for (int c=0;c<NL;c++) part[tid>>6][c]=cnt[c];
  }
  __syncthreads();
  if (tid<NL){
    int s=part[0][tid]+part[1][tid]+part[2][tid]+part[3][tid];
    out[(size_t)q*NL+tid] = (float)s / 10000.f;
  }
}

extern "C" void kernel_launch(void* const* d_in, const int* in_sizes, int n_in,
                              void* d_out, int out_size, void* d_ws, size_t ws_size,
                              hipStream_t stream) {
  const float* x   = (const float*)d_in[0];
  const float* txr = (const float*)d_in[1];
  const int*   lbl = (const int*)  d_in[2];
  const float* cal = (const float*)d_in[3];
  const float* W1  = (const float*)d_in[4];
  const float* b1  = (const float*)d_in[5];
  const float* W2  = (const float*)d_in[6];
  const float* b2  = (const float*)d_in[7];
  const float* W3  = (const float*)d_in[8];
  const float* b3  = (const float*)d_in[9];
  const float* W4  = (const float*)d_in[10];
  const float* b4  = (const float*)d_in[11];
  float* out = (float*)d_out;
  float* ws  = (float*)d_ws;

  size_t off=0;
  float* xq0=ws+off; off+=(size_t)NB*96;
  float* xq1=ws+off; off+=(size_t)NB*128;
  float* xq2=ws+off; off+=(size_t)NB*128;
  float* xq3=ws+off; off+=(size_t)NB*128;
  float* xq4=ws+off; off+=(size_t)NB*32;
  float* tbA=ws+off; off+=(size_t)NT*128;
  float* tbB=ws+off; off+=(size_t)NT*128;
  float* tb4=ws+off; off+=(size_t)NT*32;
  float* qnb=ws+off; off+=(size_t)5*NB;
  float* tnb=ws+off; off+=(size_t)NT;
  float* tot=ws+off; off+=(size_t)NB*NL;
  unsigned* sT=(unsigned*)(ws+off); off+=NB;
  unsigned short* qH=(unsigned short*)(ws+off); off+=(size_t)NB*64;
  unsigned short* qL=(unsigned short*)(ws+off); off+=(size_t)NB*64;
  unsigned short* bankH=(unsigned short*)(ws+off); off+=(size_t)NT_PAD*64;
  unsigned short* bankL=(unsigned short*)(ws+off); off+=(size_t)NT_PAD*64;
  off=(off+3)&~(size_t)3;
  unsigned* slab=(unsigned*)(ws+off);   // NTB*NB*SLOTS = 25.6 MB
  unsigned* skeys=(unsigned*)(ws+off);  // NB*NSUB     =  8.4 MB (aliased; skeys
                                        // dead before dist_mfma_k writes slab)
  { size_t slab_sz=(size_t)NTB*NB*SLOTS, skey_sz=(size_t)NB*NSUB;
    off += (slab_sz > skey_sz ? slab_sz : skey_sz); }

  // query features; layer-0 features at stride 96
  pad_copy_k<<<(NB*96+255)/256,256,0,stream>>>(x, xq0, NB, 83, 96);
  pad_copy_k<<<((size_t)NT*96+255)/256,256,0,stream>>>(txr, tbA, NT, 83, 96);
  mlp_gemm_k<<<(NB+127)/128,256,0,stream>>>(xq0,96,3,W1,83,b1,xq1,NB);
  mlp_gemm_k<<<(NB+127)/128,256,0,stream>>>(xq1,128,4,W2,128,b2,xq2,NB);
  mlp_gemm_k<<<(NB+127)/128,256,0,stream>>>(xq2,128,4,W3,128,b3,xq3,NB);
  mlp8_k<<<(NB+31)/32,256,0,stream>>>(xq3,W4,b4,xq4,NB);
  softmax_k<<<(NB+255)/256,256,0,stream>>>(xq4,NB);

  auto knn_layer = [&](const float* Qm, const float* Bank, float* qnl,
                       int dp, int first){
    conv_norm_k<<<(NT+3)/4,256,0,stream>>>(Bank, bankH, bankL, tnb, NT, dp);
    conv_norm_k<<<(NB+3)/4,256,0,stream>>>(Qm, qH, qL, qnl, NB, dp);
    dist_sub_k<<<8*NSB,256,0,stream>>>(qH,qL,bankH,bankL,qnl,tnb,lbl,skeys,dp);
    sel64_k<<<NB,256,0,stream>>>(skeys,sT);
    dist_mfma_k<<<8*4*49,256,0,stream>>>(qH,qL,bankH,bankL,qnl,tnb,lbl,sT,slab,dp);
    final_k<<<NB,256,0,stream>>>(slab,Qm,Bank,qnl,tnb,lbl,tot,first,dp);
  };

  knn_layer(xq0, tbA, qnb+0*NB, 96, 1);
  mlp_gemm_k<<<(NT+127)/128,256,0,stream>>>(tbA,96,3,W1,83,b1,tbB,NT);
  knn_layer(xq1, tbB, qnb+1*NB, 128, 0);
  mlp_gemm_k<<<(NT+127)/128,256,0,stream>>>(tbB,128,4,W2,128,b2,tbA,NT);
  knn_layer(xq2, tbA, qnb+2*NB, 128, 0);
  mlp_gemm_k<<<(NT+127)/128,256,0,stream>>>(tbA,128,4,W3,128,b3,tbB,NT);
  knn_layer(xq3, tbB, qnb+3*NB, 128, 0);
  mlp8_k<<<(NT+31)/32,256,0,stream>>>(tbB,W4,b4,tb4,NT);
  softmax_k<<<(NT+255)/256,256,0,stream>>>(tb4,NT);
  knn_layer(xq4, tb4, qnb+4*NB, 32, 0);

  pvalue_k<<<NB,256,0,stream>>>(tot,cal,out);
}

// Round 6
// 1155.991 us; speedup vs baseline: 1.4679x; 1.0134x over previous
//
#include <hip/hip_runtime.h>
#include <math.h>

#define KNN 75
#define NL 8
#define NB 1024
#define NT 50000
#define NT_PAD 50048  // NTB*TT rows allocated for bf16 banks (pad rows masked)
#define NCALI 10000
#define KC 32
#define TT 128
#define NTB 391       // ceil(NT/TT)
#define SLOTS 16      // per (q, t-block) slab: [count, up to 15 hit keys] = 64B
#define CAP 6144      // candidate buffer per query
#define NSUB 2048     // sampled train points for threshold
#define NSB 16        // NSUB/TT subset t-blocks
#define SSTRIDE 24
#define SOFF 11       // 11 + 24*2047 = 49139 < 50000
#define RSEL 32       // sample rank -> expected |{k < T}| ~ 780, lambda/slab ~ 2

typedef __attribute__((ext_vector_type(8))) short bf16x8;
typedef __attribute__((ext_vector_type(4))) float f32x4;
typedef __attribute__((ext_vector_type(4))) unsigned uint4v;

__device__ __forceinline__ int swz(int c){ return c + ((c>>5)<<2); }

__device__ __forceinline__ unsigned short f2bf_rn(float x){
  unsigned u = __float_as_uint(x);
  unsigned r = (u + 0x7FFFu + ((u>>16)&1u)) >> 16;
  return (unsigned short)r;
}
__device__ __forceinline__ float bf2f(unsigned short h){
  return __uint_as_float(((unsigned)h)<<16);
}
__device__ __forceinline__ bf16x8 ld8(const unsigned short* p){
  return *(const bf16x8*)p;
}
// async global->LDS, 16B per lane; LDS dest = wave-uniform base + lane*16
__device__ __forceinline__ void gl_lds16(const unsigned short* g, unsigned short* l){
  __builtin_amdgcn_global_load_lds(
      (const __attribute__((address_space(1))) void*)g,
      (__attribute__((address_space(3))) void*)l, 16, 0, 0);
}

// ---------------- pad copy (zero-fill pad cols every call: ws is poisoned) ----
__global__ void pad_copy_k(const float* __restrict__ in, float* __restrict__ out,
                           int M, int Din, int Dout){
  int idx = blockIdx.x*256 + threadIdx.x;
  if (idx >= M*Dout) return;
  int r = idx / Dout, c = idx - r*Dout;
  out[idx] = (c < Din) ? in[r*Din + c] : 0.f;
}

// ---------------- MLP GEMM: Out[M][128] = relu(A[M][lda] @ W[kreal][128] + b) --
__global__ __launch_bounds__(256) void mlp_gemm_k(
    const float* __restrict__ A, int lda, int kchunks,
    const float* __restrict__ W, int kreal,
    const float* __restrict__ bias,
    float* __restrict__ Out, int M)
{
  __shared__ float As[KC][132];
  __shared__ float Bs[KC][148];
  int tid = threadIdx.x;
  int r0 = (tid>>4)*8, c0 = (tid&15)*8;
  int rowBase = blockIdx.x*128;
  float acc[8][8];
  #pragma unroll
  for (int i=0;i<8;i++)
    #pragma unroll
    for (int j=0;j<8;j++) acc[i][j]=0.f;

  for (int kc=0;kc<kchunks;kc++){
    { int rr = tid>>3, k4=(tid&7)*4;
      #pragma unroll
      for (int i=0;i<4;i++){
        int row = rr + i*32, gr = rowBase + row;
        float4 v = make_float4(0.f,0.f,0.f,0.f);
        if (gr < M) v = *(const float4*)&A[(size_t)gr*lda + kc*KC + k4];
        As[k4+0][row]=v.x; As[k4+1][row]=v.y; As[k4+2][row]=v.z; As[k4+3][row]=v.w;
      }
    }
    { int kk=tid>>5, c4=(tid&31)*4;
      #pragma unroll
      for (int i=0;i<4;i++){
        int k = kk + i*8, gk = kc*KC + k;
        float4 v = make_float4(0.f,0.f,0.f,0.f);
        if (gk < kreal) v = *(const float4*)&W[(size_t)gk*128 + c4];
        *(float4*)&Bs[k][swz(c4)] = v;
      }
    }
    __syncthreads();
    #pragma unroll 4
    for (int k=0;k<KC;k++){
      float4 a0 = *(const float4*)&As[k][r0];
      float4 a1 = *(const float4*)&As[k][r0+4];
      float4 b0 = *(const float4*)&Bs[k][swz(c0)];
      float4 b1 = *(const float4*)&Bs[k][swz(c0+4)];
      float av[8] = {a0.x,a0.y,a0.z,a0.w,a1.x,a1.y,a1.z,a1.w};
      float bv[8] = {b0.x,b0.y,b0.z,b0.w,b1.x,b1.y,b1.z,b1.w};
      #pragma unroll
      for (int i=0;i<8;i++)
        #pragma unroll
        for (int j=0;j<8;j++) acc[i][j] += av[i]*bv[j];
    }
    __syncthreads();
  }
  float bb[8];
  #pragma unroll
  for (int j=0;j<8;j++) bb[j]=bias[c0+j];
  #pragma unroll
  for (int i=0;i<8;i++){
    int gr = rowBase + r0 + i;
    if (gr < M){
      float o[8];
      #pragma unroll
      for (int j=0;j<8;j++){ float v=acc[i][j]+bb[j]; o[j]=v>0.f?v:0.f; }
      *(float4*)&Out[(size_t)gr*128 + c0]   = make_float4(o[0],o[1],o[2],o[3]);
      *(float4*)&Out[(size_t)gr*128 + c0+4] = make_float4(o[4],o[5],o[6],o[7]);
    }
  }
}

// ---------------- last layer: logits[M][8] into stride-32 rows ----------------
__global__ void mlp8_k(const float* __restrict__ A, const float* __restrict__ W4,
                       const float* __restrict__ b4, float* __restrict__ Out, int M){
  __shared__ float Ws[128*8];
  int tid = threadIdx.x;
  for (int i=tid;i<1024;i+=256) Ws[i]=W4[i];
  __syncthreads();
  int r = blockIdx.x*32 + (tid>>3), c = tid&7;
  if (r >= M) return;
  const float* a = &A[(size_t)r*128];
  float acc = b4[c];
  #pragma unroll 16
  for (int k=0;k<128;k++) acc += a[k]*Ws[k*8+c];
  Out[(size_t)r*32 + c] = acc;
}

// ---------------- softmax over 8 logits, zero cols 8..31 ----------------------
__global__ void softmax_k(float* __restrict__ X, int M){
  int r = blockIdx.x*256 + threadIdx.x;
  if (r >= M) return;
  float* p = &X[(size_t)r*32];
  float v[8], m=-1e30f;
  #pragma unroll
  for (int j=0;j<8;j++){ v[j]=p[j]; m = v[j]>m ? v[j] : m; }
  float s=0.f;
  #pragma unroll
  for (int j=0;j<8;j++){ v[j]=__expf(v[j]-m); s+=v[j]; }
  float inv=1.f/s;
  #pragma unroll
  for (int j=0;j<8;j++) p[j]=v[j]*inv;
  #pragma unroll
  for (int j=8;j<32;j++) p[j]=0.f;
}

// ---- fp32 -> (hi,lo) bf16 split + row squared-norms, bank+queries fused ------
// Vectorized: float2 loads, ushort2 (4B) stores -> full 256B wave stores
// (was scalar 2B stores = half-line writes, Common-mistake #2).
// MA (=NT) and MB (=NB) both divisible by 4 -> clean block split.
__global__ void conv_norm_k(
    const float* __restrict__ XA, unsigned short* __restrict__ HA,
    unsigned short* __restrict__ LA, float* __restrict__ nA, int MA,
    const float* __restrict__ XB, unsigned short* __restrict__ HB,
    unsigned short* __restrict__ LB, float* __restrict__ nB, int MB,
    int dp)
{
  int w = threadIdx.x>>6, lane = threadIdx.x&63;
  int row = blockIdx.x*4 + w;
  const float* src; unsigned short* dh; unsigned short* dl; float* nrm;
  if (row < MA){
    src=&XA[(size_t)row*dp]; dh=&HA[(size_t)row*dp]; dl=&LA[(size_t)row*dp]; nrm=&nA[row];
  } else {
    int r2 = row - MA;
    if (r2 >= MB) return;
    src=&XB[(size_t)r2*dp]; dh=&HB[(size_t)r2*dp]; dl=&LB[(size_t)r2*dp]; nrm=&nB[r2];
  }
  float s=0.f;
  for (int c=lane*2; c<dp; c+=128){
    float2 v = *(const float2*)&src[c];
    s += v.x*v.x + v.y*v.y;
    unsigned short h0 = f2bf_rn(v.x), h1 = f2bf_rn(v.y);
    float r0 = v.x - bf2f(h0), r1 = v.y - bf2f(h1);
    ushort2 hh; hh.x=h0; hh.y=h1;
    ushort2 ll; ll.x=f2bf_rn(r0); ll.y=f2bf_rn(r1);
    *(ushort2*)&dh[c]=hh;
    *(ushort2*)&dl[c]=ll;
  }
  #pragma unroll
  for (int off=32;off>0;off>>=1) s += __shfl_down(s, off, 64);
  if (lane==0) *nrm=s;
}

// ---------------- scan helper: find bin containing rank Krem ------------------
__device__ __forceinline__ void find_bin(int* hist, int* part, int nb, int Krem,
                                         int tid, int* s_B, int* s_lob){
  int ch = nb>>8;
  int s=0;
  for (int b=tid*ch;b<tid*ch+ch;b++) s+=hist[b];
  part[tid]=s;
  __syncthreads();
  if (tid==0){
    int cum=0, B=nb-1, lob=0;
    for (int t=0;t<256;t++){
      if (cum+part[t] >= Krem){
        lob=cum;
        for (int b=t*ch;b<t*ch+ch;b++){
          if (lob+hist[b]>=Krem){ B=b; break; }
          lob+=hist[b];
        }
        break;
      }
      cum+=part[t];
    }
    *s_B=B; *s_lob=lob;
  }
  __syncthreads();
}

// ---------------- per-query threshold: exact RSEL-th smallest sample key ------
__global__ __launch_bounds__(256) void sel64_k(const unsigned* __restrict__ skeys,
                                               unsigned* __restrict__ Tthr){
  __shared__ unsigned buf[NSUB];
  __shared__ int hist[2048];
  __shared__ int part[256];
  __shared__ int sB, sLob;
  int tid=threadIdx.x, q=blockIdx.x;
  for (int i=tid;i<NSUB;i+=256) buf[i]=skeys[(size_t)q*NSUB+i];
  int Krem=RSEL;
  for (int i=tid;i<2048;i+=256) hist[i]=0;
  __syncthreads();
  for (int i=tid;i<NSUB;i+=256) atomicAdd(&hist[buf[i]>>21],1);
  __syncthreads();
  find_bin(hist,part,2048,Krem,tid,&sB,&sLob);
  unsigned pre=(unsigned)sB; Krem-=sLob;
  for (int i=tid;i<2048;i+=256) hist[i]=0;
  __syncthreads();
  for (int i=tid;i<NSUB;i+=256){ unsigned k=buf[i]; if ((k>>21)==pre) atomicAdd(&hist[(k>>10)&0x7FFu],1); }
  __syncthreads();
  find_bin(hist,part,2048,Krem,tid,&sB,&sLob);
  pre=(pre<<11)|(unsigned)sB; Krem-=sLob;
  for (int i=tid;i<1024;i+=256) hist[i]=0;
  __syncthreads();
  for (int i=tid;i<NSUB;i+=256){ unsigned k=buf[i]; if ((k>>10)==pre) atomicAdd(&hist[k&0x3FFu],1); }
  __syncthreads();
  find_bin(hist,part,1024,Krem,tid,&sB,&sLob);
  if (tid==0) Tthr[q]=(pre<<10)|(unsigned)sB;
}

// ====== MFMA section: one 128x128 sub-tile x one K-chunk from LDS =============
#define MFMA_SEC(CUR, A0H, A0L, A1H, A1L)                                        \
  _Pragma("unroll")                                                              \
  for (int tj=0;tj<8;tj++){                                                      \
    int rowB = tj*16 + col;                                                      \
    int sw = (((quad + (rowB>>1)) & 3) << 3);                                    \
    bf16x8 bh = *(const bf16x8*)&BH[CUR][rowB*32 + sw];                          \
    bf16x8 bl = *(const bf16x8*)&BL[CUR][rowB*32 + sw];                          \
    acc[0][tj] = __builtin_amdgcn_mfma_f32_16x16x32_bf16(A0H, bh, acc[0][tj], 0,0,0); \
    acc[0][tj] = __builtin_amdgcn_mfma_f32_16x16x32_bf16(A0H, bl, acc[0][tj], 0,0,0); \
    acc[0][tj] = __builtin_amdgcn_mfma_f32_16x16x32_bf16(A0L, bh, acc[0][tj], 0,0,0); \
    acc[1][tj] = __builtin_amdgcn_mfma_f32_16x16x32_bf16(A1H, bh, acc[1][tj], 0,0,0); \
    acc[1][tj] = __builtin_amdgcn_mfma_f32_16x16x32_bf16(A1H, bl, acc[1][tj], 0,0,0); \
    acc[1][tj] = __builtin_amdgcn_mfma_f32_16x16x32_bf16(A1L, bh, acc[1][tj], 0,0,0); \
  }

// K-loop body (2-deep double-buffer) used by dist_sub_k.
#define MFMA_KLOOP(ROWMAP)                                                       \
  size_t aoff = (size_t)(qbase + w*32 + col)*dp + quad*8;                        \
  const unsigned short* pAH = QH + aoff;                                         \
  const unsigned short* pAL = QL + aoff;                                         \
  size_t qi_step = (size_t)16*dp;                                                \
  int i0 = tid,      row0 = i0>>2, sg0 = ((i0&3) - (row0>>1)) & 3;               \
  int i1 = tid+256,  row1 = i1>>2, sg1 = ((i1&3) - (row1>>1)) & 3;               \
  size_t g0 = (size_t)(ROWMAP(n0+row0))*dp + (size_t)sg0*8;                      \
  size_t g1 = (size_t)(ROWMAP(n0+row1))*dp + (size_t)sg1*8;                      \
  f32x4 acc[2][8];                                                               \
  _Pragma("unroll")                                                              \
  for (int qi=0;qi<2;qi++)                                                       \
    _Pragma("unroll")                                                            \
    for (int tj=0;tj<8;tj++){ f32x4 z={0.f,0.f,0.f,0.f}; acc[qi][tj]=z; }        \
  gl_lds16(TH + g0, &BH[0][i0*8]);                                               \
  gl_lds16(TH + g1, &BH[0][i1*8]);                                               \
  gl_lds16(TL + g0, &BL[0][i0*8]);                                               \
  gl_lds16(TL + g1, &BL[0][i1*8]);                                               \
  bf16x8 x0h = ld8(pAH), x0l = ld8(pAL);                                         \
  bf16x8 x1h = ld8(pAH + qi_step), x1l = ld8(pAL + qi_step);                     \
  bf16x8 y0h = x0h, y0l = x0l, y1h = x1h, y1l = x1l;                             \
  for (int kc=0; kc<kchunks; kc+=2){                                             \
    __syncthreads();                                                             \
    if (kc+1 < kchunks){                                                         \
      size_t ko=(size_t)(kc+1)*32;                                               \
      gl_lds16(TH + g0 + ko, &BH[1][i0*8]);                                      \
      gl_lds16(TH + g1 + ko, &BH[1][i1*8]);                                      \
      gl_lds16(TL + g0 + ko, &BL[1][i0*8]);                                      \
      gl_lds16(TL + g1 + ko, &BL[1][i1*8]);                                      \
      y0h = ld8(pAH + ko);           y0l = ld8(pAL + ko);                        \
      y1h = ld8(pAH + qi_step + ko); y1l = ld8(pAL + qi_step + ko);              \
    }                                                                            \
    MFMA_SEC(0, x0h, x0l, x1h, x1l);                                             \
    if (kc+1 < kchunks){                                                         \
      __syncthreads();                                                           \
      if (kc+2 < kchunks){                                                       \
        size_t ko=(size_t)(kc+2)*32;                                             \
        gl_lds16(TH + g0 + ko, &BH[0][i0*8]);                                    \
        gl_lds16(TH + g1 + ko, &BH[0][i1*8]);                                    \
        gl_lds16(TL + g0 + ko, &BL[0][i0*8]);                                    \
        gl_lds16(TL + g1 + ko, &BL[0][i1*8]);                                    \
        x0h = ld8(pAH + ko);           x0l = ld8(pAL + ko);                      \
        x1h = ld8(pAH + qi_step + ko); x1l = ld8(pAL + qi_step + ko);            \
      }                                                                          \
      MFMA_SEC(1, y0h, y0l, y1h, y1l);                                           \
    }                                                                            \
  }

// ---------------- MFMA split-bf16 distance GEMM vs full bank ------------------
// Full B-tile in LDS (all K-chunks) staged with ONE barrier; 2 query-columns
// (256 q) per block. Grid 8 xcd x 4 qpair x 49 tslot = 1568 blocks.
// Slab layout [q][t_blk]: final_k reads each query's 391 slabs as ONE
// contiguous 25KB run (the [t_blk][q] transpose made final_k's gather a
// 64KB-strided latency chain; dist_mfma time measured layout-INVARIANT
// r0/r2 vs r3/r4, so contiguous-read side wins).
__global__ __launch_bounds__(256) void dist_mfma_k(
    const unsigned short* __restrict__ QH, const unsigned short* __restrict__ QL,
    const unsigned short* __restrict__ TH, const unsigned short* __restrict__ TL,
    const float* __restrict__ qn, const float* __restrict__ tn,
    const int* __restrict__ labels, const unsigned* __restrict__ Tthr,
    unsigned* __restrict__ slab, int dp)
{
  __shared__ unsigned short BH[4][128*32];   // 32 KB (full tile, chunk-major)
  __shared__ unsigned short BL[4][128*32];   // 32 KB
  __shared__ unsigned hitbuf[128][SLOTS];    // 8 KB
  __shared__ int hcnt[128];
  int b = blockIdx.x;
  int xcd = b & 7, s = b >> 3;
  int p = s & 3, tslot = s >> 2;
  int t_blk = xcd + 8*tslot;
  if (t_blk >= NTB) return;
  int tid = threadIdx.x, w = tid>>6, lane = tid&63;
  int quad = lane>>4, col = lane&15;
  int qbase0 = p*256;
  int n0 = t_blk*TT;
  int kchunks = dp >> 5;

  // ---- stage ALL chunks, one barrier ----
  {
    int i0 = tid,      row0 = i0>>2, sg0 = ((i0&3) - (row0>>1)) & 3;
    int i1 = tid+256,  row1 = i1>>2, sg1 = ((i1&3) - (row1>>1)) & 3;
    size_t g0 = (size_t)(n0+row0)*dp + (size_t)sg0*8;
    size_t g1 = (size_t)(n0+row1)*dp + (size_t)sg1*8;
    for (int kc=0;kc<kchunks;kc++){
      size_t ko=(size_t)kc*32;
      gl_lds16(TH + g0 + ko, &BH[kc][i0*8]);
      gl_lds16(TH + g1 + ko, &BH[kc][i1*8]);
      gl_lds16(TL + g0 + ko, &BL[kc][i0*8]);
      gl_lds16(TL + g1 + ko, &BL[kc][i1*8]);
    }
  }
  __syncthreads();

  size_t qi_step = (size_t)16*dp;
  for (int qbi=0; qbi<2; qbi++){
    int qbase = qbase0 + qbi*128;
    size_t aoff = (size_t)(qbase + w*32 + col)*dp + quad*8;
    const unsigned short* pAH = QH + aoff;
    const unsigned short* pAL = QL + aoff;

    f32x4 acc[2][8];
    #pragma unroll
    for (int qi=0;qi<2;qi++)
      #pragma unroll
      for (int tj=0;tj<8;tj++){ f32x4 z={0.f,0.f,0.f,0.f}; acc[qi][tj]=z; }

    for (int kc=0;kc<kchunks;kc++){
      size_t ko=(size_t)kc*32;
      bf16x8 a0h = ld8(pAH + ko),           a0l = ld8(pAL + ko);
      bf16x8 a1h = ld8(pAH + qi_step + ko), a1l = ld8(pAL + qi_step + ko);
      MFMA_SEC(kc, a0h, a0l, a1h, a1l);
    }

    // epilogue for this q-column
    if (tid<128) hcnt[tid]=0;
    __syncthreads();
    float qnr[2][4]; unsigned Tq[2][4];
    #pragma unroll
    for (int qi=0;qi<2;qi++)
      #pragma unroll
      for (int r=0;r<4;r++){
        int q = qbase + w*32 + qi*16 + quad*4 + r;
        qnr[qi][r] = qn[q];
        Tq[qi][r]  = Tthr[q];
      }
    #pragma unroll
    for (int tj=0;tj<8;tj++){
      int t = n0 + tj*16 + col;
      if (t < NT){
        float tnv = tn[t];
        unsigned lab = (unsigned)labels[t];
        #pragma unroll
        for (int qi=0;qi<2;qi++)
          #pragma unroll
          for (int r=0;r<4;r++){
            float d2 = fmaxf(qnr[qi][r] - 2.f*acc[qi][tj][r] + tnv, 0.f);
            unsigned key = (__float_as_uint(d2)&0xFFFFFFF8u) | lab;
            if (key < Tq[qi][r]){
              int ql = w*32 + qi*16 + quad*4 + r;
              int idx = atomicAdd(&hcnt[ql], 1);
              if (idx < SLOTS-1) hitbuf[ql][1+idx] = key;
            }
          }
      }
    }
    __syncthreads();
    if (tid<128) hitbuf[tid][0]=(unsigned)hcnt[tid];
    __syncthreads();
    // slab[q][t_blk]: 4 threads per q write its 64B slab (nontemporal)
    #pragma unroll
    for (int rep=0; rep<2; rep++){
      int idx = rep*256 + tid;
      int q = idx>>2, sub = (idx&3)*4;
      uint4v v = *(uint4v*)&hitbuf[q][sub];
      __builtin_nontemporal_store(v,
        (uint4v*)&slab[((size_t)(qbase+q)*NTB + t_blk)*SLOTS + sub]);
    }
    __syncthreads();   // hitbuf reads done before next qbi resets it
  }
}

// ---------------- MFMA split-bf16 distance GEMM vs SAMPLED subset -------------
#define ROW_SUB(r) ((r)*SSTRIDE + SOFF)
__global__ __launch_bounds__(256) void dist_sub_k(
    const unsigned short* __restrict__ QH, const unsigned short* __restrict__ QL,
    const unsigned short* __restrict__ TH, const unsigned short* __restrict__ TL,
    const float* __restrict__ qn, const float* __restrict__ tn,
    const int* __restrict__ labels, unsigned* __restrict__ keys, int dp)
{
  __shared__ unsigned short BH[2][128*32];   // 16 KB
  __shared__ unsigned short BL[2][128*32];   // 16 KB
  int b = blockIdx.x;
  int qb = b & 7, t_blk = b >> 3;            // t_blk in [0, NSB)
  int tid = threadIdx.x, w = tid>>6, lane = tid&63;
  int quad = lane>>4, col = lane&15;
  int qbase = qb*128;
  int n0 = t_blk*TT;                         // subset-space row base
  int kchunks = dp >> 5;

  MFMA_KLOOP(ROW_SUB)

  // epilogue: write all keys; 16-lane quad -> 64B contiguous store per (qi,tj,r)
  float qnr[2][4];
  #pragma unroll
  for (int qi=0;qi<2;qi++)
    #pragma unroll
    for (int r=0;r<4;r++)
      qnr[qi][r] = qn[qbase + w*32 + qi*16 + quad*4 + r];
  #pragma unroll
  for (int tj=0;tj<8;tj++){
    int sI = n0 + tj*16 + col;
    int g  = sI*SSTRIDE + SOFF;
    float tnv = tn[g];
    unsigned lab = (unsigned)labels[g];
    #pragma unroll
    for (int qi=0;qi<2;qi++)
      #pragma unroll
      for (int r=0;r<4;r++){
        float d2 = fmaxf(qnr[qi][r] - 2.f*acc[qi][tj][r] + tnv, 0.f);
        unsigned key = (__float_as_uint(d2)&0xFFFFFFF8u) | lab;
        int q = qbase + w*32 + qi*16 + quad*4 + r;
        keys[(size_t)q*NSUB + sI] = key;
      }
  }
}

// ---------------- gather slabs, exact radix select + class sums ---------------
__global__ __launch_bounds__(256) void final_k(
    const unsigned* __restrict__ slab,
    const float* __restrict__ Qm, const float* __restrict__ Tm,
    const float* __restrict__ qn, const float* __restrict__ tn,
    const int* __restrict__ labels,
    float* __restrict__ tot, int first, int dp)
{
  __shared__ int hist[2048];
  __shared__ int part[256];
  __shared__ unsigned buf[CAP];
  __shared__ unsigned lowbuf[96];
  __shared__ float qrow[128];
  __shared__ int sB,sLob,s_cnt,s_low,s_bad;
  __shared__ float s_w[9];
  int tid=threadIdx.x, q=blockIdx.x;
  if (tid==0){ for (int j=0;j<9;j++) s_w[j]=0.f; s_cnt=0; s_low=0; s_bad=0; }
  __syncthreads();

  // [q][t_blk] layout: query q's slabs are ONE contiguous 25KB run
  const unsigned* sq = slab + (size_t)q*NTB*SLOTS;
  for (int sidx=tid; sidx<NTB; sidx+=256){
    const unsigned* s = sq + (size_t)sidx*SLOTS;
    uint4 a = *(const uint4*)s;
    unsigned cnt = a.x;
    if (cnt > SLOTS-1){ s_bad=1; continue; }
    if (!cnt) continue;
    int base = atomicAdd(&s_cnt, (int)cnt);
    if (base + (int)cnt <= CAP){
      buf[base] = a.y;
      if (cnt>=2) buf[base+1] = a.z;
      if (cnt>=3) buf[base+2] = a.w;
      for (unsigned w=4; w<=cnt; w++) buf[base+w-1] = s[w];
    }
  }
  __syncthreads();
  int total = s_cnt;
  int bad = s_bad;

#define CONTRIB(kk) do{ float d2_=__uint_as_float((kk)&0xFFFFFFF8u); \
    if (d2_>0.f){ float w_=1.0f/sqrtf(d2_); \
      atomicAdd(&s_w[8],w_); atomicAdd(&s_w[(kk)&7u],w_); } }while(0)

  unsigned T; int Krem=KNN;
  if (!bad && total>=KNN && total<=CAP){
    for (int i=tid;i<2048;i+=256) hist[i]=0;
    __syncthreads();
    for (int i=tid;i<total;i+=256) atomicAdd(&hist[buf[i]>>21],1);
    __syncthreads();
    find_bin(hist,part,2048,Krem,tid,&sB,&sLob);
    unsigned pre=(unsigned)sB; Krem-=sLob;
    for (int i=tid;i<2048;i+=256) hist[i]=0;
    __syncthreads();
    for (int i=tid;i<total;i+=256){ unsigned k=buf[i]; if ((k>>21)==pre) atomicAdd(&hist[(k>>10)&0x7FFu],1); }
    __syncthreads();
    find_bin(hist,part,2048,Krem,tid,&sB,&sLob);
    pre=(pre<<11)|(unsigned)sB; Krem-=sLob;
    for (int i=tid;i<1024;i+=256) hist[i]=0;
    __syncthreads();
    for (int i=tid;i<total;i+=256){ unsigned k=buf[i]; if ((k>>10)==pre) atomicAdd(&hist[k&0x3FFu],1); }
    __syncthreads();
    find_bin(hist,part,1024,Krem,tid,&sB,&sLob);
    T=(pre<<10)|(unsigned)sB; Krem-=sLob;
    __syncthreads();
    for (int i=tid;i<total;i+=256){ unsigned k=buf[i]; if (k<T) CONTRIB(k); }
  } else {
    // fallback (P ~ 1e-10): exact fp32 full recompute select
    if (tid==0) s_cnt=0;
    for (int i=tid;i<dp;i+=256) qrow[i]=Qm[(size_t)q*dp+i];
    __syncthreads();
    float qq=qn[q];
    auto KEY=[&](int t)->unsigned{
      const float* br=&Tm[(size_t)t*dp];
      float dot=0.f;
      for (int k2=0;k2<dp;k2++) dot+=qrow[k2]*br[k2];
      float d2=fmaxf(qq-2.f*dot+tn[t],0.f);
      return (__float_as_uint(d2)&0xFFFFFFF8u)|(unsigned)labels[t];
    };
    for (int i=tid;i<2048;i+=256) hist[i]=0;
    __syncthreads();
    for (int t=tid;t<NT;t+=256) atomicAdd(&hist[KEY(t)>>21],1);
    __syncthreads();
    find_bin(hist,part,2048,Krem,tid,&sB,&sLob);
    int c=hist[sB]; Krem-=sLob;
    unsigned prefix=(unsigned)sB; int shift=21;
    if (c > CAP){
      __syncthreads();
      for (int i=tid;i<2048;i+=256) hist[i]=0;
      __syncthreads();
      for (int t=tid;t<NT;t+=256){ unsigned k=KEY(t); if ((k>>21)==prefix) atomicAdd(&hist[(k>>10)&0x7FFu],1); }
      __syncthreads();
      find_bin(hist,part,2048,Krem,tid,&sB,&sLob);
      c=hist[sB]; Krem-=sLob; prefix=(prefix<<11)|(unsigned)sB; shift=10;
    }
    if (c > CAP){
      __syncthreads();
      for (int i=tid;i<1024;i+=256) hist[i]=0;
      __syncthreads();
      for (int t=tid;t<NT;t+=256){ unsigned k=KEY(t); if ((k>>10)==prefix) atomicAdd(&hist[k&0x3FFu],1); }
      __syncthreads();
      find_bin(hist,part,1024,Krem,tid,&sB,&sLob);
      c=hist[sB]; Krem-=sLob; prefix=(prefix<<10)|(unsigned)sB; shift=0;
    }
    if (c <= CAP){
      for (int t=tid;t<NT;t+=256){
        unsigned k=KEY(t); unsigned pp=k>>shift;
        if (pp==prefix){ int j=atomicAdd(&s_cnt,1); if (j<CAP) buf[j]=k; }
        else if (pp<prefix){ int j=atomicAdd(&s_low,1); if (j<96) lowbuf[j]=k; }
      }
      __syncthreads();
      int sh=shift;
      while (sh>0){
        int nsh=(sh==21)?10:0;
        int nb=1<<(sh-nsh);
        __syncthreads();
        for (int i=tid;i<nb;i+=256) hist[i]=0;
        __syncthreads();
        int cc=s_cnt;
        for (int i=tid;i<cc;i+=256) atomicAdd(&hist[(buf[i]>>nsh)&(unsigned)(nb-1)],1);
        __syncthreads();
        find_bin(hist,part,nb,Krem,tid,&sB,&sLob);
        Krem-=sLob; prefix=(prefix<<(sh-nsh))|(unsigned)sB; sh=nsh;
      }
      T=prefix;
      __syncthreads();
      int lowc=s_low, cc=s_cnt;
      for (int i=tid;i<lowc;i+=256){ unsigned k=lowbuf[i]; CONTRIB(k); }
      for (int i=tid;i<cc;i+=256){ unsigned k=buf[i]; if (k<T) CONTRIB(k); }
    } else {
      T=prefix;
      for (int t=tid;t<NT;t+=256){ unsigned k=KEY(t); if (k<T) CONTRIB(k); }
    }
  }
  __syncthreads();
  if (tid==0){
    float d2=__uint_as_float(T&0xFFFFFFF8u);
    float w=(d2>0.f)?(1.0f/sqrtf(d2)):0.f;
    s_w[8] += (float)Krem*w;
    s_w[T&7u] += (float)Krem*w;
  }
  __syncthreads();
  if (tid<8){
    float contrib = s_w[8]-s_w[tid];
    size_t o=(size_t)q*NL+tid;
    tot[o] = first ? contrib : tot[o]+contrib;
  }
#undef CONTRIB
}

// ---------------- empirical p-values ------------------------------------------
__global__ void pvalue_k(const float* __restrict__ tot, const float* __restrict__ cali,
                         float* __restrict__ out){
  __shared__ float t8[NL];
  __shared__ int part[4][NL];
  int tid=threadIdx.x, q=blockIdx.x;
  if (tid<NL) t8[tid]=tot[(size_t)q*NL+tid];
  __syncthreads();
  float th[NL];
  #pragma unroll
  for (int c=0;c<NL;c++) th[c]=t8[c];
  int cnt[NL];
  #pragma unroll
  for (int c=0;c<NL;c++) cnt[c]=0;
  for (int i=tid;i<NCALI;i+=256){
    float v=cali[i];
    #pragma unroll
    for (int c=0;c<NL;c++) cnt[c] += (v>=th[c]) ? 1 : 0;
  }
  #pragma unroll
  for (int c=0;c<NL;c++){
    #pragma unroll
    for (int off=32;off>0;off>>=1) cnt[c]+=__shfl_down(cnt[c],off,64);
  }
  if ((tid&63)==0){
    #pragma unroll
    for (int c=0;c<NL;c++) part[tid>>6][c]=cnt[c];
  }
  __syncthreads();
  if (tid<NL){
    int s=part[0][tid]+part[1][tid]+part[2][tid]+part[3][tid];
    out[(size_t)q*NL+tid] = (float)s / 10000.f;
  }
}

extern "C" void kernel_launch(void* const* d_in, const int* in_sizes, int n_in,
                              void* d_out, int out_size, void* d_ws, size_t ws_size,
                              hipStream_t stream) {
  const float* x   = (const float*)d_in[0];
  const float* txr = (const float*)d_in[1];
  const int*   lbl = (const int*)  d_in[2];
  const float* cal = (const float*)d_in[3];
  const float* W1  = (const float*)d_in[4];
  const float* b1  = (const float*)d_in[5];
  const float* W2  = (const float*)d_in[6];
  const float* b2  = (const float*)d_in[7];
  const float* W3  = (const float*)d_in[8];
  const float* b3  = (const float*)d_in[9];
  const float* W4  = (const float*)d_in[10];
  const float* b4  = (const float*)d_in[11];
  float* out = (float*)d_out;
  float* ws  = (float*)d_ws;

  size_t off=0;
  float* xq0=ws+off; off+=(size_t)NB*96;
  float* xq1=ws+off; off+=(size_t)NB*128;
  float* xq2=ws+off; off+=(size_t)NB*128;
  float* xq3=ws+off; off+=(size_t)NB*128;
  float* xq4=ws+off; off+=(size_t)NB*32;
  float* tbA=ws+off; off+=(size_t)NT*128;
  float* tbB=ws+off; off+=(size_t)NT*128;
  float* tb4=ws+off; off+=(size_t)NT*32;
  float* qnb=ws+off; off+=(size_t)5*NB;
  float* tnb=ws+off; off+=(size_t)NT;
  float* tot=ws+off; off+=(size_t)NB*NL;
  unsigned* sT=(unsigned*)(ws+off); off+=NB;
  unsigned short* qH=(unsigned short*)(ws+off); off+=(size_t)NB*64;
  unsigned short* qL=(unsigned short*)(ws+off); off+=(size_t)NB*64;
  unsigned short* bankH=(unsigned short*)(ws+off); off+=(size_t)NT_PAD*64;
  unsigned short* bankL=(unsigned short*)(ws+off); off+=(size_t)NT_PAD*64;
  off=(off+3)&~(size_t)3;
  unsigned* slab=(unsigned*)(ws+off);   // NB*NTB*SLOTS = 25.6 MB
  unsigned* skeys=(unsigned*)(ws+off);  // NB*NSUB     =  8.4 MB (aliased; skeys
                                        // dead before dist_mfma_k writes slab)
  { size_t slab_sz=(size_t)NB*NTB*SLOTS, skey_sz=(size_t)NB*NSUB;
    off += (slab_sz > skey_sz ? slab_sz : skey_sz); }

  // query features; layer-0 features at stride 96
  pad_copy_k<<<(NB*96+255)/256,256,0,stream>>>(x, xq0, NB, 83, 96);
  pad_copy_k<<<((size_t)NT*96+255)/256,256,0,stream>>>(txr, tbA, NT, 83, 96);
  mlp_gemm_k<<<(NB+127)/128,256,0,stream>>>(xq0,96,3,W1,83,b1,xq1,NB);
  mlp_gemm_k<<<(NB+127)/128,256,0,stream>>>(xq1,128,4,W2,128,b2,xq2,NB);
  mlp_gemm_k<<<(NB+127)/128,256,0,stream>>>(xq2,128,4,W3,128,b3,xq3,NB);
  mlp8_k<<<(NB+31)/32,256,0,stream>>>(xq3,W4,b4,xq4,NB);
  softmax_k<<<(NB+255)/256,256,0,stream>>>(xq4,NB);

  auto knn_layer = [&](const float* Qm, const float* Bank, float* qnl,
                       int dp, int first){
    // fused bank+query conv/norm (NT and NB both /4)
    conv_norm_k<<<(NT+NB)/4,256,0,stream>>>(Bank, bankH, bankL, tnb, NT,
                                            Qm, qH, qL, qnl, NB, dp);
    dist_sub_k<<<8*NSB,256,0,stream>>>(qH,qL,bankH,bankL,qnl,tnb,lbl,skeys,dp);
    sel64_k<<<NB,256,0,stream>>>(skeys,sT);
    dist_mfma_k<<<8*4*49,256,0,stream>>>(qH,qL,bankH,bankL,qnl,tnb,lbl,sT,slab,dp);
    final_k<<<NB,256,0,stream>>>(slab,Qm,Bank,qnl,tnb,lbl,tot,first,dp);
  };

  knn_layer(xq0, tbA, qnb+0*NB, 96, 1);
  mlp_gemm_k<<<(NT+127)/128,256,0,stream>>>(tbA,96,3,W1,83,b1,tbB,NT);
  knn_layer(xq1, tbB, qnb+1*NB, 128, 0);
  mlp_gemm_k<<<(NT+127)/128,256,0,stream>>>(tbB,128,4,W2,128,b2,tbA,NT);
  knn_layer(xq2, tbA, qnb+2*NB, 128, 0);
  mlp_gemm_k<<<(NT+127)/128,256,0,stream>>>(tbA,128,4,W3,128,b3,tbB,NT);
  knn_layer(xq3, tbB, qnb+3*NB, 128, 0);
  mlp8_k<<<(NT+31)/32,256,0,stream>>>(tbB,W4,b4,tb4,NT);
  softmax_k<<<(NT+255)/256,256,0,stream>>>(tb4,NT);
  knn_layer(xq4, tb4, qnb+4*NB, 32, 0);

  pvalue_k<<<NB,256,0,stream>>>(tot,cal,out);
}

// Round 7
// 1077.212 us; speedup vs baseline: 1.5752x; 1.0731x over previous
//
#include <hip/hip_runtime.h>
#include <math.h>

#define KNN 75
#define NL 8
#define NB 1024
#define NT 50000
#define NT_PAD 50048  // NTB*TT rows allocated for bf16 banks (pad rows masked)
#define NCALI 10000
#define KC 32
#define TT 128
#define NTB 391       // ceil(NT/TT)
#define SLOTS 16      // per (q, t-block) slab: [count, up to 15 hit keys] = 64B
#define CAP 6144      // candidate buffer per query
#define NSUB 2048     // sampled train points for threshold
#define NSB 16        // NSUB/TT subset t-blocks
#define SSTRIDE 24
#define SOFF 11       // 11 + 24*2047 = 49139 < 50000
#define RSEL 32       // sample rank -> expected |{k < T}| ~ 780, lambda/slab ~ 2

typedef __attribute__((ext_vector_type(8))) short bf16x8;
typedef __attribute__((ext_vector_type(4))) float f32x4;

__device__ __forceinline__ int swz(int c){ return c + ((c>>5)<<2); }

__device__ __forceinline__ unsigned short f2bf_rn(float x){
  unsigned u = __float_as_uint(x);
  unsigned r = (u + 0x7FFFu + ((u>>16)&1u)) >> 16;
  return (unsigned short)r;
}
__device__ __forceinline__ float bf2f(unsigned short h){
  return __uint_as_float(((unsigned)h)<<16);
}
__device__ __forceinline__ bf16x8 ld8(const unsigned short* p){
  return *(const bf16x8*)p;
}
// async global->LDS, 16B per lane; LDS dest = wave-uniform base + lane*16
__device__ __forceinline__ void gl_lds16(const unsigned short* g, unsigned short* l){
  __builtin_amdgcn_global_load_lds(
      (const __attribute__((address_space(1))) void*)g,
      (__attribute__((address_space(3))) void*)l, 16, 0, 0);
}

// ---------------- pad copy (zero-fill pad cols every call: ws is poisoned) ----
__global__ void pad_copy_k(const float* __restrict__ in, float* __restrict__ out,
                           int M, int Din, int Dout){
  int idx = blockIdx.x*256 + threadIdx.x;
  if (idx >= M*Dout) return;
  int r = idx / Dout, c = idx - r*Dout;
  out[idx] = (c < Din) ? in[r*Din + c] : 0.f;
}

// ---------------- MLP GEMM: Out[M][128] = relu(A[M][lda] @ W[kreal][128] + b) --
__global__ __launch_bounds__(256) void mlp_gemm_k(
    const float* __restrict__ A, int lda, int kchunks,
    const float* __restrict__ W, int kreal,
    const float* __restrict__ bias,
    float* __restrict__ Out, int M)
{
  __shared__ float As[KC][132];
  __shared__ float Bs[KC][148];
  int tid = threadIdx.x;
  int r0 = (tid>>4)*8, c0 = (tid&15)*8;
  int rowBase = blockIdx.x*128;
  float acc[8][8];
  #pragma unroll
  for (int i=0;i<8;i++)
    #pragma unroll
    for (int j=0;j<8;j++) acc[i][j]=0.f;

  for (int kc=0;kc<kchunks;kc++){
    { int rr = tid>>3, k4=(tid&7)*4;
      #pragma unroll
      for (int i=0;i<4;i++){
        int row = rr + i*32, gr = rowBase + row;
        float4 v = make_float4(0.f,0.f,0.f,0.f);
        if (gr < M) v = *(const float4*)&A[(size_t)gr*lda + kc*KC + k4];
        As[k4+0][row]=v.x; As[k4+1][row]=v.y; As[k4+2][row]=v.z; As[k4+3][row]=v.w;
      }
    }
    { int kk=tid>>5, c4=(tid&31)*4;
      #pragma unroll
      for (int i=0;i<4;i++){
        int k = kk + i*8, gk = kc*KC + k;
        float4 v = make_float4(0.f,0.f,0.f,0.f);
        if (gk < kreal) v = *(const float4*)&W[(size_t)gk*128 + c4];
        *(float4*)&Bs[k][swz(c4)] = v;
      }
    }
    __syncthreads();
    #pragma unroll 4
    for (int k=0;k<KC;k++){
      float4 a0 = *(const float4*)&As[k][r0];
      float4 a1 = *(const float4*)&As[k][r0+4];
      float4 b0 = *(const float4*)&Bs[k][swz(c0)];
      float4 b1 = *(const float4*)&Bs[k][swz(c0+4)];
      float av[8] = {a0.x,a0.y,a0.z,a0.w,a1.x,a1.y,a1.z,a1.w};
      float bv[8] = {b0.x,b0.y,b0.z,b0.w,b1.x,b1.y,b1.z,b1.w};
      #pragma unroll
      for (int i=0;i<8;i++)
        #pragma unroll
        for (int j=0;j<8;j++) acc[i][j] += av[i]*bv[j];
    }
    __syncthreads();
  }
  float bb[8];
  #pragma unroll
  for (int j=0;j<8;j++) bb[j]=bias[c0+j];
  #pragma unroll
  for (int i=0;i<8;i++){
    int gr = rowBase + r0 + i;
    if (gr < M){
      float o[8];
      #pragma unroll
      for (int j=0;j<8;j++){ float v=acc[i][j]+bb[j]; o[j]=v>0.f?v:0.f; }
      *(float4*)&Out[(size_t)gr*128 + c0]   = make_float4(o[0],o[1],o[2],o[3]);
      *(float4*)&Out[(size_t)gr*128 + c0+4] = make_float4(o[4],o[5],o[6],o[7]);
    }
  }
}

// ---------------- last layer: logits[M][8] into stride-32 rows ----------------
__global__ void mlp8_k(const float* __restrict__ A, const float* __restrict__ W4,
                       const float* __restrict__ b4, float* __restrict__ Out, int M){
  __shared__ float Ws[128*8];
  int tid = threadIdx.x;
  for (int i=tid;i<1024;i+=256) Ws[i]=W4[i];
  __syncthreads();
  int r = blockIdx.x*32 + (tid>>3), c = tid&7;
  if (r >= M) return;
  const float* a = &A[(size_t)r*128];
  float acc = b4[c];
  #pragma unroll 16
  for (int k=0;k<128;k++) acc += a[k]*Ws[k*8+c];
  Out[(size_t)r*32 + c] = acc;
}

// ---------------- softmax over 8 logits, zero cols 8..31 ----------------------
__global__ void softmax_k(float* __restrict__ X, int M){
  int r = blockIdx.x*256 + threadIdx.x;
  if (r >= M) return;
  float* p = &X[(size_t)r*32];
  float v[8], m=-1e30f;
  #pragma unroll
  for (int j=0;j<8;j++){ v[j]=p[j]; m = v[j]>m ? v[j] : m; }
  float s=0.f;
  #pragma unroll
  for (int j=0;j<8;j++){ v[j]=__expf(v[j]-m); s+=v[j]; }
  float inv=1.f/s;
  #pragma unroll
  for (int j=0;j<8;j++) p[j]=v[j]*inv;
  #pragma unroll
  for (int j=8;j<32;j++) p[j]=0.f;
}

// ---- fp32 -> (hi,lo) bf16 split + row squared-norms, bank+queries fused ------
__global__ void conv_norm_k(
    const float* __restrict__ XA, unsigned short* __restrict__ HA,
    unsigned short* __restrict__ LA, float* __restrict__ nA, int MA,
    const float* __restrict__ XB, unsigned short* __restrict__ HB,
    unsigned short* __restrict__ LB, float* __restrict__ nB, int MB,
    int dp)
{
  int w = threadIdx.x>>6, lane = threadIdx.x&63;
  int row = blockIdx.x*4 + w;
  const float* src; unsigned short* dh; unsigned short* dl; float* nrm;
  if (row < MA){
    src=&XA[(size_t)row*dp]; dh=&HA[(size_t)row*dp]; dl=&LA[(size_t)row*dp]; nrm=&nA[row];
  } else {
    int r2 = row - MA;
    if (r2 >= MB) return;
    src=&XB[(size_t)r2*dp]; dh=&HB[(size_t)r2*dp]; dl=&LB[(size_t)r2*dp]; nrm=&nB[r2];
  }
  float s=0.f;
  for (int c=lane*2; c<dp; c+=128){
    float2 v = *(const float2*)&src[c];
    s += v.x*v.x + v.y*v.y;
    unsigned short h0 = f2bf_rn(v.x), h1 = f2bf_rn(v.y);
    float r0 = v.x - bf2f(h0), r1 = v.y - bf2f(h1);
    ushort2 hh; hh.x=h0; hh.y=h1;
    ushort2 ll; ll.x=f2bf_rn(r0); ll.y=f2bf_rn(r1);
    *(ushort2*)&dh[c]=hh;
    *(ushort2*)&dl[c]=ll;
  }
  #pragma unroll
  for (int off=32;off>0;off>>=1) s += __shfl_down(s, off, 64);
  if (lane==0) *nrm=s;
}

// ---------------- scan helper: find bin containing rank Krem ------------------
__device__ __forceinline__ void find_bin(int* hist, int* part, int nb, int Krem,
                                         int tid, int* s_B, int* s_lob){
  int ch = nb>>8;
  int s=0;
  for (int b=tid*ch;b<tid*ch+ch;b++) s+=hist[b];
  part[tid]=s;
  __syncthreads();
  if (tid==0){
    int cum=0, B=nb-1, lob=0;
    for (int t=0;t<256;t++){
      if (cum+part[t] >= Krem){
        lob=cum;
        for (int b=t*ch;b<t*ch+ch;b++){
          if (lob+hist[b]>=Krem){ B=b; break; }
          lob+=hist[b];
        }
        break;
      }
      cum+=part[t];
    }
    *s_B=B; *s_lob=lob;
  }
  __syncthreads();
}

// ---------------- per-query threshold: exact RSEL-th smallest sample key ------
__global__ __launch_bounds__(256) void sel64_k(const unsigned* __restrict__ skeys,
                                               unsigned* __restrict__ Tthr){
  __shared__ unsigned buf[NSUB];
  __shared__ int hist[2048];
  __shared__ int part[256];
  __shared__ int sB, sLob;
  int tid=threadIdx.x, q=blockIdx.x;
  for (int i=tid;i<NSUB;i+=256) buf[i]=skeys[(size_t)q*NSUB+i];
  int Krem=RSEL;
  for (int i=tid;i<2048;i+=256) hist[i]=0;
  __syncthreads();
  for (int i=tid;i<NSUB;i+=256) atomicAdd(&hist[buf[i]>>21],1);
  __syncthreads();
  find_bin(hist,part,2048,Krem,tid,&sB,&sLob);
  unsigned pre=(unsigned)sB; Krem-=sLob;
  for (int i=tid;i<2048;i+=256) hist[i]=0;
  __syncthreads();
  for (int i=tid;i<NSUB;i+=256){ unsigned k=buf[i]; if ((k>>21)==pre) atomicAdd(&hist[(k>>10)&0x7FFu],1); }
  __syncthreads();
  find_bin(hist,part,2048,Krem,tid,&sB,&sLob);
  pre=(pre<<11)|(unsigned)sB; Krem-=sLob;
  for (int i=tid;i<1024;i+=256) hist[i]=0;
  __syncthreads();
  for (int i=tid;i<NSUB;i+=256){ unsigned k=buf[i]; if ((k>>10)==pre) atomicAdd(&hist[k&0x3FFu],1); }
  __syncthreads();
  find_bin(hist,part,1024,Krem,tid,&sB,&sLob);
  if (tid==0) Tthr[q]=(pre<<10)|(unsigned)sB;
}

// ====== MFMA section: one 128x128 sub-tile x one K-chunk from LDS =============
#define MFMA_SEC(CUR, A0H, A0L, A1H, A1L)                                        \
  _Pragma("unroll")                                                              \
  for (int tj=0;tj<8;tj++){                                                      \
    int rowB = tj*16 + col;                                                      \
    int sw = (((quad + (rowB>>1)) & 3) << 3);                                    \
    bf16x8 bh = *(const bf16x8*)&BH[CUR][rowB*32 + sw];                          \
    bf16x8 bl = *(const bf16x8*)&BL[CUR][rowB*32 + sw];                          \
    acc[0][tj] = __builtin_amdgcn_mfma_f32_16x16x32_bf16(A0H, bh, acc[0][tj], 0,0,0); \
    acc[0][tj] = __builtin_amdgcn_mfma_f32_16x16x32_bf16(A0H, bl, acc[0][tj], 0,0,0); \
    acc[0][tj] = __builtin_amdgcn_mfma_f32_16x16x32_bf16(A0L, bh, acc[0][tj], 0,0,0); \
    acc[1][tj] = __builtin_amdgcn_mfma_f32_16x16x32_bf16(A1H, bh, acc[1][tj], 0,0,0); \
    acc[1][tj] = __builtin_amdgcn_mfma_f32_16x16x32_bf16(A1H, bl, acc[1][tj], 0,0,0); \
    acc[1][tj] = __builtin_amdgcn_mfma_f32_16x16x32_bf16(A1L, bh, acc[1][tj], 0,0,0); \
  }

// K-loop body (2-deep double-buffer). kchunks is constexpr in template callers
// -> fully unrolled. acc[2][8] declared here.
#define MFMA_KLOOP(ROWMAP)                                                       \
  size_t aoff = (size_t)(qbase + w*32 + col)*dp + quad*8;                        \
  const unsigned short* pAH = QH + aoff;                                         \
  const unsigned short* pAL = QL + aoff;                                         \
  size_t qi_step = (size_t)16*dp;                                                \
  int i0 = tid,      row0 = i0>>2, sg0 = ((i0&3) - (row0>>1)) & 3;               \
  int i1 = tid+256,  row1 = i1>>2, sg1 = ((i1&3) - (row1>>1)) & 3;               \
  size_t g0 = (size_t)(ROWMAP(n0+row0))*dp + (size_t)sg0*8;                      \
  size_t g1 = (size_t)(ROWMAP(n0+row1))*dp + (size_t)sg1*8;                      \
  f32x4 acc[2][8];                                                               \
  _Pragma("unroll")                                                              \
  for (int qi=0;qi<2;qi++)                                                       \
    _Pragma("unroll")                                                            \
    for (int tj=0;tj<8;tj++){ f32x4 z={0.f,0.f,0.f,0.f}; acc[qi][tj]=z; }        \
  gl_lds16(TH + g0, &BH[0][i0*8]);                                               \
  gl_lds16(TH + g1, &BH[0][i1*8]);                                               \
  gl_lds16(TL + g0, &BL[0][i0*8]);                                               \
  gl_lds16(TL + g1, &BL[0][i1*8]);                                               \
  bf16x8 x0h = ld8(pAH), x0l = ld8(pAL);                                         \
  bf16x8 x1h = ld8(pAH + qi_step), x1l = ld8(pAL + qi_step);                     \
  bf16x8 y0h = x0h, y0l = x0l, y1h = x1h, y1l = x1l;                             \
  _Pragma("unroll")                                                              \
  for (int kc=0; kc<kchunks; kc+=2){                                             \
    __syncthreads();                                                             \
    if (kc+1 < kchunks){                                                         \
      size_t ko=(size_t)(kc+1)*32;                                               \
      gl_lds16(TH + g0 + ko, &BH[1][i0*8]);                                      \
      gl_lds16(TH + g1 + ko, &BH[1][i1*8]);                                      \
      gl_lds16(TL + g0 + ko, &BL[1][i0*8]);                                      \
      gl_lds16(TL + g1 + ko, &BL[1][i1*8]);                                      \
      y0h = ld8(pAH + ko);           y0l = ld8(pAL + ko);                        \
      y1h = ld8(pAH + qi_step + ko); y1l = ld8(pAL + qi_step + ko);              \
    }                                                                            \
    MFMA_SEC(0, x0h, x0l, x1h, x1l);                                             \
    if (kc+1 < kchunks){                                                         \
      __syncthreads();                                                           \
      if (kc+2 < kchunks){                                                       \
        size_t ko=(size_t)(kc+2)*32;                                             \
        gl_lds16(TH + g0 + ko, &BH[0][i0*8]);                                    \
        gl_lds16(TH + g1 + ko, &BH[0][i1*8]);                                    \
        gl_lds16(TL + g0 + ko, &BL[0][i0*8]);                                    \
        gl_lds16(TL + g1 + ko, &BL[0][i1*8]);                                    \
        x0h = ld8(pAH + ko);           x0l = ld8(pAL + ko);                      \
        x1h = ld8(pAH + qi_step + ko); x1l = ld8(pAL + qi_step + ko);            \
      }                                                                          \
      MFMA_SEC(1, y0h, y0l, y1h, y1l);                                           \
    }                                                                            \
  }

#define ROW_ID(r) (r)
#define ROW_SUB(r) ((r)*SSTRIDE + SOFF)

// ---------------- MFMA split-bf16 distance GEMM vs full bank ------------------
// Templated on KCH (=dp/32): distinct kernel name per layer (per-layer rocprof
// visibility after discovering top-5 rows were 5 ITERATIONS of one layer, not
// 5 layers: FETCH identical to 0.01% across rows -> same workload) + static
// K-loop unroll. Structure = r0's 3-blocks/CU (LDS 40.5KB) 2-chunk dbuf.
// Epilogue fast path: float compare d2 <= uif(Tq|7) (superset of key<Tq,
// exact uint check only on the ~2/128 hit path) -> ~3x less epilogue VALU
// (theory: wall = sum of pipe times at 3 waves/SIMD; VALUBusy 29% was the
// largest reducible term).
template<int KCH>
__global__ __launch_bounds__(256) void dist_mfma_k(
    const unsigned short* __restrict__ QH, const unsigned short* __restrict__ QL,
    const unsigned short* __restrict__ TH, const unsigned short* __restrict__ TL,
    const float* __restrict__ qn, const float* __restrict__ tn,
    const int* __restrict__ labels, const unsigned* __restrict__ Tthr,
    unsigned* __restrict__ slab)
{
  constexpr int dp = KCH*32;
  __shared__ unsigned short BH[2][128*32];   // 16 KB
  __shared__ unsigned short BL[2][128*32];   // 16 KB
  __shared__ unsigned hitbuf[128][SLOTS];    // 8 KB
  __shared__ int hcnt[128];
  int b = blockIdx.x;
  int xcd = b & 7, s = b >> 3;
  int qb = s & 7, tslot = s >> 3;
  int t_blk = xcd + 8*tslot;
  if (t_blk >= NTB) return;
  int tid = threadIdx.x, w = tid>>6, lane = tid&63;
  int quad = lane>>4, col = lane&15;
  int qbase = qb*128;
  int n0 = t_blk*TT;
  constexpr int kchunks = KCH;

  MFMA_KLOOP(ROW_ID)

  // epilogue: d2 fast-path compare, LDS slab compaction
  if (tid<128) hcnt[tid]=0;
  __syncthreads();
  float qnr[2][4]; unsigned Tq[2][4]; float thrF[2][4];
  #pragma unroll
  for (int qi=0;qi<2;qi++)
    #pragma unroll
    for (int r=0;r<4;r++){
      int q = qbase + w*32 + qi*16 + quad*4 + r;
      qnr[qi][r]  = qn[q];
      Tq[qi][r]   = Tthr[q];
      thrF[qi][r] = __uint_as_float(Tq[qi][r] | 7u);  // superset boundary
    }
  #pragma unroll
  for (int tj=0;tj<8;tj++){
    int t = n0 + tj*16 + col;
    if (t < NT){
      float tnv = tn[t];
      unsigned lab = (unsigned)labels[t];
      #pragma unroll
      for (int qi=0;qi<2;qi++)
        #pragma unroll
        for (int r=0;r<4;r++){
          // d2 may be slightly negative pre-clamp; negative <= thr -> hit path,
          // clamped+exact-checked there. Non-neg float cmp == uint cmp on bits.
          float d2 = fmaf(-2.f, acc[qi][tj][r], qnr[qi][r] + tnv);
          if (d2 <= thrF[qi][r]){
            float d2c = fmaxf(d2, 0.f);
            unsigned key = (__float_as_uint(d2c)&0xFFFFFFF8u) | lab;
            if (key < Tq[qi][r]){
              int ql = w*32 + qi*16 + quad*4 + r;
              int idx = atomicAdd(&hcnt[ql], 1);
              if (idx < SLOTS-1) hitbuf[ql][1+idx] = key;
            }
          }
        }
    }
  }
  __syncthreads();
  if (tid<128) hitbuf[tid][0]=(unsigned)hcnt[tid];
  __syncthreads();
  // slab[q][t_blk]: final_k reads each query's 391 slabs contiguously
  #pragma unroll
  for (int rep=0; rep<2; rep++){
    int idx = rep*256 + tid;
    int q = idx>>2, sub = (idx&3)*4;
    uint4 v = *(uint4*)&hitbuf[q][sub];
    *(uint4*)&slab[((size_t)(qbase+q)*NTB + t_blk)*SLOTS + sub] = v;
  }
}

// ---------------- MFMA split-bf16 distance GEMM vs SAMPLED subset -------------
template<int KCH>
__global__ __launch_bounds__(256) void dist_sub_k(
    const unsigned short* __restrict__ QH, const unsigned short* __restrict__ QL,
    const unsigned short* __restrict__ TH, const unsigned short* __restrict__ TL,
    const float* __restrict__ qn, const float* __restrict__ tn,
    const int* __restrict__ labels, unsigned* __restrict__ keys)
{
  constexpr int dp = KCH*32;
  __shared__ unsigned short BH[2][128*32];   // 16 KB
  __shared__ unsigned short BL[2][128*32];   // 16 KB
  int b = blockIdx.x;
  int qb = b & 7, t_blk = b >> 3;            // t_blk in [0, NSB)
  int tid = threadIdx.x, w = tid>>6, lane = tid&63;
  int quad = lane>>4, col = lane&15;
  int qbase = qb*128;
  int n0 = t_blk*TT;                         // subset-space row base
  constexpr int kchunks = KCH;

  MFMA_KLOOP(ROW_SUB)

  // epilogue: write all keys; 16-lane quad -> 64B contiguous store per (qi,tj,r)
  float qnr[2][4];
  #pragma unroll
  for (int qi=0;qi<2;qi++)
    #pragma unroll
    for (int r=0;r<4;r++)
      qnr[qi][r] = qn[qbase + w*32 + qi*16 + quad*4 + r];
  #pragma unroll
  for (int tj=0;tj<8;tj++){
    int sI = n0 + tj*16 + col;
    int g  = sI*SSTRIDE + SOFF;
    float tnv = tn[g];
    unsigned lab = (unsigned)labels[g];
    #pragma unroll
    for (int qi=0;qi<2;qi++)
      #pragma unroll
      for (int r=0;r<4;r++){
        float d2 = fmaxf(fmaf(-2.f, acc[qi][tj][r], qnr[qi][r] + tnv), 0.f);
        unsigned key = (__float_as_uint(d2)&0xFFFFFFF8u) | lab;
        int q = qbase + w*32 + qi*16 + quad*4 + r;
        keys[(size_t)q*NSUB + sI] = key;
      }
  }
}

// ---------------- gather slabs, exact radix select + class sums ---------------
__global__ __launch_bounds__(256) void final_k(
    const unsigned* __restrict__ slab,
    const float* __restrict__ Qm, const float* __restrict__ Tm,
    const float* __restrict__ qn, const float* __restrict__ tn,
    const int* __restrict__ labels,
    float* __restrict__ tot, int first, int dp)
{
  __shared__ int hist[2048];
  __shared__ int part[256];
  __shared__ unsigned buf[CAP];
  __shared__ unsigned lowbuf[96];
  __shared__ float qrow[128];
  __shared__ int sB,sLob,s_cnt,s_low,s_bad;
  __shared__ float s_w[9];
  int tid=threadIdx.x, q=blockIdx.x;
  if (tid==0){ for (int j=0;j<9;j++) s_w[j]=0.f; s_cnt=0; s_low=0; s_bad=0; }
  __syncthreads();

  // [q][t_blk] layout: query q's slabs are ONE contiguous 25KB run
  const unsigned* sq = slab + (size_t)q*NTB*SLOTS;
  for (int sidx=tid; sidx<NTB; sidx+=256){
    const unsigned* s = sq + (size_t)sidx*SLOTS;
    uint4 a = *(const uint4*)s;
    unsigned cnt = a.x;
    if (cnt > SLOTS-1){ s_bad=1; continue; }
    if (!cnt) continue;
    int base = atomicAdd(&s_cnt, (int)cnt);
    if (base + (int)cnt <= CAP){
      buf[base] = a.y;
      if (cnt>=2) buf[base+1] = a.z;
      if (cnt>=3) buf[base+2] = a.w;
      for (unsigned w=4; w<=cnt; w++) buf[base+w-1] = s[w];
    }
  }
  __syncthreads();
  int total = s_cnt;
  int bad = s_bad;

#define CONTRIB(kk) do{ float d2_=__uint_as_float((kk)&0xFFFFFFF8u); \
    if (d2_>0.f){ float w_=1.0f/sqrtf(d2_); \
      atomicAdd(&s_w[8],w_); atomicAdd(&s_w[(kk)&7u],w_); } }while(0)

  unsigned T; int Krem=KNN;
  if (!bad && total>=KNN && total<=CAP){
    for (int i=tid;i<2048;i+=256) hist[i]=0;
    __syncthreads();
    for (int i=tid;i<total;i+=256) atomicAdd(&hist[buf[i]>>21],1);
    __syncthreads();
    find_bin(hist,part,2048,Krem,tid,&sB,&sLob);
    unsigned pre=(unsigned)sB; Krem-=sLob;
    for (int i=tid;i<2048;i+=256) hist[i]=0;
    __syncthreads();
    for (int i=tid;i<total;i+=256){ unsigned k=buf[i]; if ((k>>21)==pre) atomicAdd(&hist[(k>>10)&0x7FFu],1); }
    __syncthreads();
    find_bin(hist,part,2048,Krem,tid,&sB,&sLob);
    pre=(pre<<11)|(unsigned)sB; Krem-=sLob;
    for (int i=tid;i<1024;i+=256) hist[i]=0;
    __syncthreads();
    for (int i=tid;i<total;i+=256){ unsigned k=buf[i]; if ((k>>10)==pre) atomicAdd(&hist[k&0x3FFu],1); }
    __syncthreads();
    find_bin(hist,part,1024,Krem,tid,&sB,&sLob);
    T=(pre<<10)|(unsigned)sB; Krem-=sLob;
    __syncthreads();
    for (int i=tid;i<total;i+=256){ unsigned k=buf[i]; if (k<T) CONTRIB(k); }
  } else {
    // fallback (P ~ 1e-10): exact fp32 full recompute select
    if (tid==0) s_cnt=0;
    for (int i=tid;i<dp;i+=256) qrow[i]=Qm[(size_t)q*dp+i];
    __syncthreads();
    float qq=qn[q];
    auto KEY=[&](int t)->unsigned{
      const float* br=&Tm[(size_t)t*dp];
      float dot=0.f;
      for (int k2=0;k2<dp;k2++) dot+=qrow[k2]*br[k2];
      float d2=fmaxf(qq-2.f*dot+tn[t],0.f);
      return (__float_as_uint(d2)&0xFFFFFFF8u)|(unsigned)labels[t];
    };
    for (int i=tid;i<2048;i+=256) hist[i]=0;
    __syncthreads();
    for (int t=tid;t<NT;t+=256) atomicAdd(&hist[KEY(t)>>21],1);
    __syncthreads();
    find_bin(hist,part,2048,Krem,tid,&sB,&sLob);
    int c=hist[sB]; Krem-=sLob;
    unsigned prefix=(unsigned)sB; int shift=21;
    if (c > CAP){
      __syncthreads();
      for (int i=tid;i<2048;i+=256) hist[i]=0;
      __syncthreads();
      for (int t=tid;t<NT;t+=256){ unsigned k=KEY(t); if ((k>>21)==prefix) atomicAdd(&hist[(k>>10)&0x7FFu],1); }
      __syncthreads();
      find_bin(hist,part,2048,Krem,tid,&sB,&sLob);
      c=hist[sB]; Krem-=sLob; prefix=(prefix<<11)|(unsigned)sB; shift=10;
    }
    if (c > CAP){
      __syncthreads();
      for (int i=tid;i<1024;i+=256) hist[i]=0;
      __syncthreads();
      for (int t=tid;t<NT;t+=256){ unsigned k=KEY(t); if ((k>>10)==prefix) atomicAdd(&hist[k&0x3FFu],1); }
      __syncthreads();
      find_bin(hist,part,1024,Krem,tid,&sB,&sLob);
      c=hist[sB]; Krem-=sLob; prefix=(prefix<<10)|(unsigned)sB; shift=0;
    }
    if (c <= CAP){
      for (int t=tid;t<NT;t+=256){
        unsigned k=KEY(t); unsigned pp=k>>shift;
        if (pp==prefix){ int j=atomicAdd(&s_cnt,1); if (j<CAP) buf[j]=k; }
        else if (pp<prefix){ int j=atomicAdd(&s_low,1); if (j<96) lowbuf[j]=k; }
      }
      __syncthreads();
      int sh=shift;
      while (sh>0){
        int nsh=(sh==21)?10:0;
        int nb=1<<(sh-nsh);
        __syncthreads();
        for (int i=tid;i<nb;i+=256) hist[i]=0;
        __syncthreads();
        int cc=s_cnt;
        for (int i=tid;i<cc;i+=256) atomicAdd(&hist[(buf[i]>>nsh)&(unsigned)(nb-1)],1);
        __syncthreads();
        find_bin(hist,part,nb,Krem,tid,&sB,&sLob);
        Krem-=sLob; prefix=(prefix<<(sh-nsh))|(unsigned)sB; sh=nsh;
      }
      T=prefix;
      __syncthreads();
      int lowc=s_low, cc=s_cnt;
      for (int i=tid;i<lowc;i+=256){ unsigned k=lowbuf[i]; CONTRIB(k); }
      for (int i=tid;i<cc;i+=256){ unsigned k=buf[i]; if (k<T) CONTRIB(k); }
    } else {
      T=prefix;
      for (int t=tid;t<NT;t+=256){ unsigned k=KEY(t); if (k<T) CONTRIB(k); }
    }
  }
  __syncthreads();
  if (tid==0){
    float d2=__uint_as_float(T&0xFFFFFFF8u);
    float w=(d2>0.f)?(1.0f/sqrtf(d2)):0.f;
    s_w[8] += (float)Krem*w;
    s_w[T&7u] += (float)Krem*w;
  }
  __syncthreads();
  if (tid<8){
    float contrib = s_w[8]-s_w[tid];
    size_t o=(size_t)q*NL+tid;
    tot[o] = first ? contrib : tot[o]+contrib;
  }
#undef CONTRIB
}

// ---------------- empirical p-values ------------------------------------------
__global__ void pvalue_k(const float* __restrict__ tot, const float* __restrict__ cali,
                         float* __restrict__ out){
  __shared__ float t8[NL];
  __shared__ int part[4][NL];
  int tid=threadIdx.x, q=blockIdx.x;
  if (tid<NL) t8[tid]=tot[(size_t)q*NL+tid];
  __syncthreads();
  float th[NL];
  #pragma unroll
  for (int c=0;c<NL;c++) th[c]=t8[c];
  int cnt[NL];
  #pragma unroll
  for (int c=0;c<NL;c++) cnt[c]=0;
  for (int i=tid;i<NCALI;i+=256){
    float v=cali[i];
    #pragma unroll
    for (int c=0;c<NL;c++) cnt[c] += (v>=th[c]) ? 1 : 0;
  }
  #pragma unroll
  for (int c=0;c<NL;c++){
    #pragma unroll
    for (int off=32;off>0;off>>=1) cnt[c]+=__shfl_down(cnt[c],off,64);
  }
  if ((tid&63)==0){
    #pragma unroll
    for (int c=0;c<NL;c++) part[tid>>6][c]=cnt[c];
  }
  __syncthreads();
  if (tid<NL){
    int s=part[0][tid]+part[1][tid]+part[2][tid]+part[3][tid];
    out[(size_t)q*NL+tid] = (float)s / 10000.f;
  }
}

// ---------------- one kNN layer (templated on KCH = dp/32) --------------------
template<int KCH>
static void knn_layer(const float* Qm, const float* Bank, float* qnl, int first,
                      const int* lbl, float* tnb,
                      unsigned short* qH, unsigned short* qL,
                      unsigned short* bankH, unsigned short* bankL,
                      unsigned* skeys, unsigned* sT, unsigned* slab,
                      float* tot, hipStream_t stream){
  constexpr int dp = KCH*32;
  conv_norm_k<<<(NT+NB)/4,256,0,stream>>>(Bank, bankH, bankL, tnb, NT,
                                          Qm, qH, qL, qnl, NB, dp);
  dist_sub_k<KCH><<<8*NSB,256,0,stream>>>(qH,qL,bankH,bankL,qnl,tnb,lbl,skeys);
  sel64_k<<<NB,256,0,stream>>>(skeys,sT);
  dist_mfma_k<KCH><<<8*8*49,256,0,stream>>>(qH,qL,bankH,bankL,qnl,tnb,lbl,sT,slab);
  final_k<<<NB,256,0,stream>>>(slab,Qm,Bank,qnl,tnb,lbl,tot,first,dp);
}

extern "C" void kernel_launch(void* const* d_in, const int* in_sizes, int n_in,
                              void* d_out, int out_size, void* d_ws, size_t ws_size,
                              hipStream_t stream) {
  const float* x   = (const float*)d_in[0];
  const float* txr = (const float*)d_in[1];
  const int*   lbl = (const int*)  d_in[2];
  const float* cal = (const float*)d_in[3];
  const float* W1  = (const float*)d_in[4];
  const float* b1  = (const float*)d_in[5];
  const float* W2  = (const float*)d_in[6];
  const float* b2  = (const float*)d_in[7];
  const float* W3  = (const float*)d_in[8];
  const float* b3  = (const float*)d_in[9];
  const float* W4  = (const float*)d_in[10];
  const float* b4  = (const float*)d_in[11];
  float* out = (float*)d_out;
  float* ws  = (float*)d_ws;

  size_t off=0;
  float* xq0=ws+off; off+=(size_t)NB*96;
  float* xq1=ws+off; off+=(size_t)NB*128;
  float* xq2=ws+off; off+=(size_t)NB*128;
  float* xq3=ws+off; off+=(size_t)NB*128;
  float* xq4=ws+off; off+=(size_t)NB*32;
  float* tbA=ws+off; off+=(size_t)NT*128;
  float* tbB=ws+off; off+=(size_t)NT*128;
  float* tb4=ws+off; off+=(size_t)NT*32;
  float* qnb=ws+off; off+=(size_t)5*NB;
  float* tnb=ws+off; off+=(size_t)NT;
  float* tot=ws+off; off+=(size_t)NB*NL;
  unsigned* sT=(unsigned*)(ws+off); off+=NB;
  unsigned short* qH=(unsigned short*)(ws+off); off+=(size_t)NB*64;
  unsigned short* qL=(unsigned short*)(ws+off); off+=(size_t)NB*64;
  unsigned short* bankH=(unsigned short*)(ws+off); off+=(size_t)NT_PAD*64;
  unsigned short* bankL=(unsigned short*)(ws+off); off+=(size_t)NT_PAD*64;
  off=(off+3)&~(size_t)3;
  unsigned* slab=(unsigned*)(ws+off);   // NB*NTB*SLOTS = 25.6 MB
  unsigned* skeys=(unsigned*)(ws+off);  // NB*NSUB     =  8.4 MB (aliased; skeys
                                        // dead before dist_mfma_k writes slab)
  { size_t slab_sz=(size_t)NB*NTB*SLOTS, skey_sz=(size_t)NB*NSUB;
    off += (slab_sz > skey_sz ? slab_sz : skey_sz); }

  // query features; layer-0 features at stride 96
  pad_copy_k<<<(NB*96+255)/256,256,0,stream>>>(x, xq0, NB, 83, 96);
  pad_copy_k<<<((size_t)NT*96+255)/256,256,0,stream>>>(txr, tbA, NT, 83, 96);
  mlp_gemm_k<<<(NB+127)/128,256,0,stream>>>(xq0,96,3,W1,83,b1,xq1,NB);
  mlp_gemm_k<<<(NB+127)/128,256,0,stream>>>(xq1,128,4,W2,128,b2,xq2,NB);
  mlp_gemm_k<<<(NB+127)/128,256,0,stream>>>(xq2,128,4,W3,128,b3,xq3,NB);
  mlp8_k<<<(NB+31)/32,256,0,stream>>>(xq3,W4,b4,xq4,NB);
  softmax_k<<<(NB+255)/256,256,0,stream>>>(xq4,NB);

  knn_layer<3>(xq0, tbA, qnb+0*NB, 1, lbl, tnb, qH,qL,bankH,bankL, skeys,sT,slab, tot, stream);
  mlp_gemm_k<<<(NT+127)/128,256,0,stream>>>(tbA,96,3,W1,83,b1,tbB,NT);
  knn_layer<4>(xq1, tbB, qnb+1*NB, 0, lbl, tnb, qH,qL,bankH,bankL, skeys,sT,slab, tot, stream);
  mlp_gemm_k<<<(NT+127)/128,256,0,stream>>>(tbB,128,4,W2,128,b2,tbA,NT);
  knn_layer<4>(xq2, tbA, qnb+2*NB, 0, lbl, tnb, qH,qL,bankH,bankL, skeys,sT,slab, tot, stream);
  mlp_gemm_k<<<(NT+127)/128,256,0,stream>>>(tbA,128,4,W3,128,b3,tbB,NT);
  knn_layer<4>(xq3, tbB, qnb+3*NB, 0, lbl, tnb, qH,qL,bankH,bankL, skeys,sT,slab, tot, stream);
  mlp8_k<<<(NT+31)/32,256,0,stream>>>(tbB,W4,b4,tb4,NT);
  softmax_k<<<(NT+255)/256,256,0,stream>>>(tb4,NT);
  knn_layer<1>(xq4, tb4, qnb+4*NB, 0, lbl, tnb, qH,qL,bankH,bankL, skeys,sT,slab, tot, stream);

  pvalue_k<<<NB,256,0,stream>>>(tot,cal,out);
}

// Round 8
// 826.168 us; speedup vs baseline: 2.0539x; 1.3039x over previous
//
#include <hip/hip_runtime.h>
#include <math.h>

#define KNN 75
#define NL 8
#define NB 1024
#define NT 50000
#define NT_PAD 50048  // NTB*TT rows allocated for bf16 banks (pad rows masked)
#define NCALI 10000
#define KC 32
#define TT 128
#define NTB 391       // ceil(NT/TT)
#define SLOTS 16      // per (q, t-block) slab: [count, up to 15 hit keys] = 64B
#define CAP 6144      // candidate buffer per query
#define NSUB 2048     // sampled train points for threshold
#define NSB 16        // NSUB/TT subset t-blocks
#define SSTRIDE 24
#define SOFF 11       // 11 + 24*2047 = 49139 < 50000
#define RSEL 32       // sample rank -> expected |{k < T}| ~ 780, lambda/slab ~ 2

typedef __attribute__((ext_vector_type(8))) short bf16x8;
typedef __attribute__((ext_vector_type(4))) float f32x4;

__device__ __forceinline__ int swz(int c){ return c + ((c>>5)<<2); }

__device__ __forceinline__ unsigned short f2bf_rn(float x){
  unsigned u = __float_as_uint(x);
  unsigned r = (u + 0x7FFFu + ((u>>16)&1u)) >> 16;
  return (unsigned short)r;
}
__device__ __forceinline__ float bf2f(unsigned short h){
  return __uint_as_float(((unsigned)h)<<16);
}
__device__ __forceinline__ bf16x8 ld8(const unsigned short* p){
  return *(const bf16x8*)p;
}
// async global->LDS, 16B per lane; LDS dest = wave-uniform base + lane*16
__device__ __forceinline__ void gl_lds16(const unsigned short* g, unsigned short* l){
  __builtin_amdgcn_global_load_lds(
      (const __attribute__((address_space(1))) void*)g,
      (__attribute__((address_space(3))) void*)l, 16, 0, 0);
}

// ---------------- pad copy (zero-fill pad cols every call: ws is poisoned) ----
__global__ void pad_copy_k(const float* __restrict__ in, float* __restrict__ out,
                           int M, int Din, int Dout){
  int idx = blockIdx.x*256 + threadIdx.x;
  if (idx >= M*Dout) return;
  int r = idx / Dout, c = idx - r*Dout;
  out[idx] = (c < Din) ? in[r*Din + c] : 0.f;
}

// ---------------- MLP GEMM: Out[M][128] = relu(A[M][lda] @ W[kreal][128] + b) --
__global__ __launch_bounds__(256) void mlp_gemm_k(
    const float* __restrict__ A, int lda, int kchunks,
    const float* __restrict__ W, int kreal,
    const float* __restrict__ bias,
    float* __restrict__ Out, int M)
{
  __shared__ float As[KC][132];
  __shared__ float Bs[KC][148];
  int tid = threadIdx.x;
  int r0 = (tid>>4)*8, c0 = (tid&15)*8;
  int rowBase = blockIdx.x*128;
  float acc[8][8];
  #pragma unroll
  for (int i=0;i<8;i++)
    #pragma unroll
    for (int j=0;j<8;j++) acc[i][j]=0.f;

  for (int kc=0;kc<kchunks;kc++){
    { int rr = tid>>3, k4=(tid&7)*4;
      #pragma unroll
      for (int i=0;i<4;i++){
        int row = rr + i*32, gr = rowBase + row;
        float4 v = make_float4(0.f,0.f,0.f,0.f);
        if (gr < M) v = *(const float4*)&A[(size_t)gr*lda + kc*KC + k4];
        As[k4+0][row]=v.x; As[k4+1][row]=v.y; As[k4+2][row]=v.z; As[k4+3][row]=v.w;
      }
    }
    { int kk=tid>>5, c4=(tid&31)*4;
      #pragma unroll
      for (int i=0;i<4;i++){
        int k = kk + i*8, gk = kc*KC + k;
        float4 v = make_float4(0.f,0.f,0.f,0.f);
        if (gk < kreal) v = *(const float4*)&W[(size_t)gk*128 + c4];
        *(float4*)&Bs[k][swz(c4)] = v;
      }
    }
    __syncthreads();
    #pragma unroll 4
    for (int k=0;k<KC;k++){
      float4 a0 = *(const float4*)&As[k][r0];
      float4 a1 = *(const float4*)&As[k][r0+4];
      float4 b0 = *(const float4*)&Bs[k][swz(c0)];
      float4 b1 = *(const float4*)&Bs[k][swz(c0+4)];
      float av[8] = {a0.x,a0.y,a0.z,a0.w,a1.x,a1.y,a1.z,a1.w};
      float bv[8] = {b0.x,b0.y,b0.z,b0.w,b1.x,b1.y,b1.z,b1.w};
      #pragma unroll
      for (int i=0;i<8;i++)
        #pragma unroll
        for (int j=0;j<8;j++) acc[i][j] += av[i]*bv[j];
    }
    __syncthreads();
  }
  float bb[8];
  #pragma unroll
  for (int j=0;j<8;j++) bb[j]=bias[c0+j];
  #pragma unroll
  for (int i=0;i<8;i++){
    int gr = rowBase + r0 + i;
    if (gr < M){
      float o[8];
      #pragma unroll
      for (int j=0;j<8;j++){ float v=acc[i][j]+bb[j]; o[j]=v>0.f?v:0.f; }
      *(float4*)&Out[(size_t)gr*128 + c0]   = make_float4(o[0],o[1],o[2],o[3]);
      *(float4*)&Out[(size_t)gr*128 + c0+4] = make_float4(o[4],o[5],o[6],o[7]);
    }
  }
}

// ---------------- last layer: logits[M][8] into stride-32 rows ----------------
__global__ void mlp8_k(const float* __restrict__ A, const float* __restrict__ W4,
                       const float* __restrict__ b4, float* __restrict__ Out, int M){
  __shared__ float Ws[128*8];
  int tid = threadIdx.x;
  for (int i=tid;i<1024;i+=256) Ws[i]=W4[i];
  __syncthreads();
  int r = blockIdx.x*32 + (tid>>3), c = tid&7;
  if (r >= M) return;
  const float* a = &A[(size_t)r*128];
  float acc = b4[c];
  #pragma unroll 16
  for (int k=0;k<128;k++) acc += a[k]*Ws[k*8+c];
  Out[(size_t)r*32 + c] = acc;
}

// ---------------- softmax over 8 logits, zero cols 8..31 ----------------------
__global__ void softmax_k(float* __restrict__ X, int M){
  int r = blockIdx.x*256 + threadIdx.x;
  if (r >= M) return;
  float* p = &X[(size_t)r*32];
  float v[8], m=-1e30f;
  #pragma unroll
  for (int j=0;j<8;j++){ v[j]=p[j]; m = v[j]>m ? v[j] : m; }
  float s=0.f;
  #pragma unroll
  for (int j=0;j<8;j++){ v[j]=__expf(v[j]-m); s+=v[j]; }
  float inv=1.f/s;
  #pragma unroll
  for (int j=0;j<8;j++) p[j]=v[j]*inv;
  #pragma unroll
  for (int j=8;j<32;j++) p[j]=0.f;
}

// ---- fp32 -> (hi,lo) bf16 split + row squared-norms, bank+queries fused ------
__global__ void conv_norm_k(
    const float* __restrict__ XA, unsigned short* __restrict__ HA,
    unsigned short* __restrict__ LA, float* __restrict__ nA, int MA,
    const float* __restrict__ XB, unsigned short* __restrict__ HB,
    unsigned short* __restrict__ LB, float* __restrict__ nB, int MB,
    int dp)
{
  int w = threadIdx.x>>6, lane = threadIdx.x&63;
  int row = blockIdx.x*4 + w;
  const float* src; unsigned short* dh; unsigned short* dl; float* nrm;
  if (row < MA){
    src=&XA[(size_t)row*dp]; dh=&HA[(size_t)row*dp]; dl=&LA[(size_t)row*dp]; nrm=&nA[row];
  } else {
    int r2 = row - MA;
    if (r2 >= MB) return;
    src=&XB[(size_t)r2*dp]; dh=&HB[(size_t)r2*dp]; dl=&LB[(size_t)r2*dp]; nrm=&nB[r2];
  }
  float s=0.f;
  for (int c=lane*2; c<dp; c+=128){
    float2 v = *(const float2*)&src[c];
    s += v.x*v.x + v.y*v.y;
    unsigned short h0 = f2bf_rn(v.x), h1 = f2bf_rn(v.y);
    float r0 = v.x - bf2f(h0), r1 = v.y - bf2f(h1);
    ushort2 hh; hh.x=h0; hh.y=h1;
    ushort2 ll; ll.x=f2bf_rn(r0); ll.y=f2bf_rn(r1);
    *(ushort2*)&dh[c]=hh;
    *(ushort2*)&dl[c]=ll;
  }
  #pragma unroll
  for (int off=32;off>0;off>>=1) s += __shfl_down(s, off, 64);
  if (lane==0) *nrm=s;
}

// ---------------- scan helper: find bin containing rank Krem ------------------
// Parallel version: wave-level shfl_up inclusive scan over per-thread chunk
// sums, unique winner thread does the <=8-iter chunk walk. Replaces the old
// tid==0 serial 256-scan (~2.5K idle-cycles x 30 calls/iteration).
__device__ __forceinline__ void find_bin(int* hist, int* part, int nb, int Krem,
                                         int tid, int* s_B, int* s_lob){
  int ch = nb>>8;
  int base = tid*ch;
  int s=0;
  for (int b=base;b<base+ch;b++) s+=hist[b];
  int lane = tid & 63, wv = tid>>6;
  int v = s;
  #pragma unroll
  for (int off=1; off<64; off<<=1){
    int u = __shfl_up(v, off, 64);
    if (lane >= off) v += u;
  }
  if (lane==63) part[wv] = v;
  __syncthreads();
  int wbase = 0;
  #pragma unroll
  for (int w2=0; w2<4; w2++) wbase += (w2 < wv) ? part[w2] : 0;
  v += wbase;
  int excl = v - s;
  if (v >= Krem && excl < Krem){
    int lob = excl, B = base + ch - 1;
    for (int b=base;b<base+ch;b++){
      if (lob + hist[b] >= Krem){ B=b; break; }
      lob += hist[b];
    }
    *s_B = B; *s_lob = lob;
  }
  if (tid==255 && v < Krem){ *s_B = nb-1; *s_lob = 0; }  // preserve old default
  __syncthreads();
}

// ---------------- per-query threshold: exact RSEL-th smallest sample key ------
__global__ __launch_bounds__(256) void sel64_k(const unsigned* __restrict__ skeys,
                                               unsigned* __restrict__ Tthr){
  __shared__ unsigned buf[NSUB];
  __shared__ int hist[2048];
  __shared__ int part[256];
  __shared__ int sB, sLob;
  int tid=threadIdx.x, q=blockIdx.x;
  for (int i=tid;i<NSUB;i+=256) buf[i]=skeys[(size_t)q*NSUB+i];
  int Krem=RSEL;
  for (int i=tid;i<2048;i+=256) hist[i]=0;
  __syncthreads();
  for (int i=tid;i<NSUB;i+=256) atomicAdd(&hist[buf[i]>>21],1);
  __syncthreads();
  find_bin(hist,part,2048,Krem,tid,&sB,&sLob);
  unsigned pre=(unsigned)sB; Krem-=sLob;
  for (int i=tid;i<2048;i+=256) hist[i]=0;
  __syncthreads();
  for (int i=tid;i<NSUB;i+=256){ unsigned k=buf[i]; if ((k>>21)==pre) atomicAdd(&hist[(k>>10)&0x7FFu],1); }
  __syncthreads();
  find_bin(hist,part,2048,Krem,tid,&sB,&sLob);
  pre=(pre<<11)|(unsigned)sB; Krem-=sLob;
  for (int i=tid;i<1024;i+=256) hist[i]=0;
  __syncthreads();
  for (int i=tid;i<NSUB;i+=256){ unsigned k=buf[i]; if ((k>>10)==pre) atomicAdd(&hist[k&0x3FFu],1); }
  __syncthreads();
  find_bin(hist,part,1024,Krem,tid,&sB,&sLob);
  if (tid==0) Tthr[q]=(pre<<10)|(unsigned)sB;
}

// ====== MFMA section: one 128x128 sub-tile x one K-chunk from LDS =============
// BHC/BLC are ushort* LDS base pointers for the chunk buffer.
#define MFMA_SEC(BHC, BLC, A0H, A0L, A1H, A1L)                                   \
  _Pragma("unroll")                                                              \
  for (int tj=0;tj<8;tj++){                                                      \
    int rowB = tj*16 + col;                                                      \
    int sw = (((quad + (rowB>>1)) & 3) << 3);                                    \
    bf16x8 bh = *(const bf16x8*)&(BHC)[rowB*32 + sw];                            \
    bf16x8 bl = *(const bf16x8*)&(BLC)[rowB*32 + sw];                            \
    acc[0][tj] = __builtin_amdgcn_mfma_f32_16x16x32_bf16(A0H, bh, acc[0][tj], 0,0,0); \
    acc[0][tj] = __builtin_amdgcn_mfma_f32_16x16x32_bf16(A0H, bl, acc[0][tj], 0,0,0); \
    acc[0][tj] = __builtin_amdgcn_mfma_f32_16x16x32_bf16(A0L, bh, acc[0][tj], 0,0,0); \
    acc[1][tj] = __builtin_amdgcn_mfma_f32_16x16x32_bf16(A1H, bh, acc[1][tj], 0,0,0); \
    acc[1][tj] = __builtin_amdgcn_mfma_f32_16x16x32_bf16(A1H, bl, acc[1][tj], 0,0,0); \
    acc[1][tj] = __builtin_amdgcn_mfma_f32_16x16x32_bf16(A1L, bh, acc[1][tj], 0,0,0); \
  }

// K-loop body (2-deep double-buffer). Requires BH0/BH1/BL0/BL1 ushort* LDS
// pointers in scope. kchunks is constexpr -> fully unrolled.
#define MFMA_KLOOP(ROWMAP)                                                       \
  size_t aoff = (size_t)(qbase + w*32 + col)*dp + quad*8;                        \
  const unsigned short* pAH = QH + aoff;                                         \
  const unsigned short* pAL = QL + aoff;                                         \
  size_t qi_step = (size_t)16*dp;                                                \
  int i0 = tid,      row0 = i0>>2, sg0 = ((i0&3) - (row0>>1)) & 3;               \
  int i1 = tid+256,  row1 = i1>>2, sg1 = ((i1&3) - (row1>>1)) & 3;               \
  size_t g0 = (size_t)(ROWMAP(n0+row0))*dp + (size_t)sg0*8;                      \
  size_t g1 = (size_t)(ROWMAP(n0+row1))*dp + (size_t)sg1*8;                      \
  f32x4 acc[2][8];                                                               \
  _Pragma("unroll")                                                              \
  for (int qi=0;qi<2;qi++)                                                       \
    _Pragma("unroll")                                                            \
    for (int tj=0;tj<8;tj++){ f32x4 z={0.f,0.f,0.f,0.f}; acc[qi][tj]=z; }        \
  gl_lds16(TH + g0, BH0 + i0*8);                                                 \
  gl_lds16(TH + g1, BH0 + i1*8);                                                 \
  gl_lds16(TL + g0, BL0 + i0*8);                                                 \
  gl_lds16(TL + g1, BL0 + i1*8);                                                 \
  bf16x8 x0h = ld8(pAH), x0l = ld8(pAL);                                         \
  bf16x8 x1h = ld8(pAH + qi_step), x1l = ld8(pAL + qi_step);                     \
  bf16x8 y0h = x0h, y0l = x0l, y1h = x1h, y1l = x1l;                             \
  _Pragma("unroll")                                                              \
  for (int kc=0; kc<kchunks; kc+=2){                                             \
    __syncthreads();                                                             \
    if (kc+1 < kchunks){                                                         \
      size_t ko=(size_t)(kc+1)*32;                                               \
      gl_lds16(TH + g0 + ko, BH1 + i0*8);                                        \
      gl_lds16(TH + g1 + ko, BH1 + i1*8);                                        \
      gl_lds16(TL + g0 + ko, BL1 + i0*8);                                        \
      gl_lds16(TL + g1 + ko, BL1 + i1*8);                                        \
      y0h = ld8(pAH + ko);           y0l = ld8(pAL + ko);                        \
      y1h = ld8(pAH + qi_step + ko); y1l = ld8(pAL + qi_step + ko);              \
    }                                                                            \
    MFMA_SEC(BH0, BL0, x0h, x0l, x1h, x1l);                                      \
    if (kc+1 < kchunks){                                                         \
      __syncthreads();                                                           \
      if (kc+2 < kchunks){                                                       \
        size_t ko=(size_t)(kc+2)*32;                                             \
        gl_lds16(TH + g0 + ko, BH0 + i0*8);                                      \
        gl_lds16(TH + g1 + ko, BH0 + i1*8);                                      \
        gl_lds16(TL + g0 + ko, BL0 + i0*8);                                      \
        gl_lds16(TL + g1 + ko, BL0 + i1*8);                                      \
        x0h = ld8(pAH + ko);           x0l = ld8(pAL + ko);                      \
        x1h = ld8(pAH + qi_step + ko); x1l = ld8(pAL + qi_step + ko);            \
      }                                                                          \
      MFMA_SEC(BH1, BL1, y0h, y0l, y1h, y1l);                                    \
    }                                                                            \
  }

#define ROW_ID(r) (r)
#define ROW_SUB(r) ((r)*SSTRIDE + SOFF)

// ---------------- MFMA split-bf16 distance GEMM vs full bank ------------------
// LDS = ONE 32 KB arena: K-loop double buffers [BH0|BH1|BL0|BL1] (8 KB each);
// epilogue ALIASES hitbuf (8 KB) onto BH0 and hcnt (512 B) onto BH1 — the
// hitbuf is only live after the K-loop's last LDS read (barrier at epilogue
// entry guarantees this for both loop parities). 40.5 -> 32 KB cuts LDS-bound
// residency 3 -> 5 blocks/CU (r7 showed all pipes <30% with Occupancy 27% ->
// latency-exposure was the remaining cost).
template<int KCH>
__global__ __launch_bounds__(256) void dist_mfma_k(
    const unsigned short* __restrict__ QH, const unsigned short* __restrict__ QL,
    const unsigned short* __restrict__ TH, const unsigned short* __restrict__ TL,
    const float* __restrict__ qn, const float* __restrict__ tn,
    const int* __restrict__ labels, const unsigned* __restrict__ Tthr,
    unsigned* __restrict__ slab)
{
  constexpr int dp = KCH*32;
  __shared__ __align__(16) unsigned short smem[4*4096];   // 32 KB
  unsigned short* BH0 = smem;
  unsigned short* BH1 = smem + 4096;
  unsigned short* BL0 = smem + 8192;
  unsigned short* BL1 = smem + 12288;
  unsigned (*hitbuf)[SLOTS] = (unsigned (*)[SLOTS])smem;  // aliases BH0 (8 KB)
  int* hcnt = (int*)(smem + 4096);                        // aliases BH1 head
  int b = blockIdx.x;
  int xcd = b & 7, s = b >> 3;
  int qb = s & 7, tslot = s >> 3;
  int t_blk = xcd + 8*tslot;
  if (t_blk >= NTB) return;
  int tid = threadIdx.x, w = tid>>6, lane = tid&63;
  int quad = lane>>4, col = lane&15;
  int qbase = qb*128;
  int n0 = t_blk*TT;
  constexpr int kchunks = KCH;

  MFMA_KLOOP(ROW_ID)

  // epilogue: barrier FIRST (K-loop LDS reads must complete before aliasing)
  __syncthreads();
  if (tid<128) hcnt[tid]=0;
  __syncthreads();
  float qnr[2][4]; unsigned Tq[2][4]; float thrF[2][4];
  #pragma unroll
  for (int qi=0;qi<2;qi++)
    #pragma unroll
    for (int r=0;r<4;r++){
      int q = qbase + w*32 + qi*16 + quad*4 + r;
      qnr[qi][r]  = qn[q];
      Tq[qi][r]   = Tthr[q];
      thrF[qi][r] = __uint_as_float(Tq[qi][r] | 7u);  // superset boundary
    }
  #pragma unroll
  for (int tj=0;tj<8;tj++){
    int t = n0 + tj*16 + col;
    if (t < NT){
      float tnv = tn[t];
      unsigned lab = (unsigned)labels[t];
      #pragma unroll
      for (int qi=0;qi<2;qi++)
        #pragma unroll
        for (int r=0;r<4;r++){
          float d2 = fmaf(-2.f, acc[qi][tj][r], qnr[qi][r] + tnv);
          if (d2 <= thrF[qi][r]){
            float d2c = fmaxf(d2, 0.f);
            unsigned key = (__float_as_uint(d2c)&0xFFFFFFF8u) | lab;
            if (key < Tq[qi][r]){
              int ql = w*32 + qi*16 + quad*4 + r;
              int idx = atomicAdd(&hcnt[ql], 1);
              if (idx < SLOTS-1) hitbuf[ql][1+idx] = key;
            }
          }
        }
    }
  }
  __syncthreads();
  if (tid<128) hitbuf[tid][0]=(unsigned)hcnt[tid];
  __syncthreads();
  // slab[q][t_blk]: final_k reads each query's 391 slabs contiguously
  #pragma unroll
  for (int rep=0; rep<2; rep++){
    int idx = rep*256 + tid;
    int q = idx>>2, sub = (idx&3)*4;
    uint4 v = *(uint4*)&hitbuf[q][sub];
    *(uint4*)&slab[((size_t)(qbase+q)*NTB + t_blk)*SLOTS + sub] = v;
  }
}

// ---------------- MFMA split-bf16 distance GEMM vs SAMPLED subset -------------
template<int KCH>
__global__ __launch_bounds__(256) void dist_sub_k(
    const unsigned short* __restrict__ QH, const unsigned short* __restrict__ QL,
    const unsigned short* __restrict__ TH, const unsigned short* __restrict__ TL,
    const float* __restrict__ qn, const float* __restrict__ tn,
    const int* __restrict__ labels, unsigned* __restrict__ keys)
{
  constexpr int dp = KCH*32;
  __shared__ __align__(16) unsigned short smem[4*4096];   // 32 KB
  unsigned short* BH0 = smem;
  unsigned short* BH1 = smem + 4096;
  unsigned short* BL0 = smem + 8192;
  unsigned short* BL1 = smem + 12288;
  int b = blockIdx.x;
  int qb = b & 7, t_blk = b >> 3;            // t_blk in [0, NSB)
  int tid = threadIdx.x, w = tid>>6, lane = tid&63;
  int quad = lane>>4, col = lane&15;
  int qbase = qb*128;
  int n0 = t_blk*TT;                         // subset-space row base
  constexpr int kchunks = KCH;

  MFMA_KLOOP(ROW_SUB)

  // epilogue: write all keys; 16-lane quad -> 64B contiguous store per (qi,tj,r)
  float qnr[2][4];
  #pragma unroll
  for (int qi=0;qi<2;qi++)
    #pragma unroll
    for (int r=0;r<4;r++)
      qnr[qi][r] = qn[qbase + w*32 + qi*16 + quad*4 + r];
  #pragma unroll
  for (int tj=0;tj<8;tj++){
    int sI = n0 + tj*16 + col;
    int g  = sI*SSTRIDE + SOFF;
    float tnv = tn[g];
    unsigned lab = (unsigned)labels[g];
    #pragma unroll
    for (int qi=0;qi<2;qi++)
      #pragma unroll
      for (int r=0;r<4;r++){
        float d2 = fmaxf(fmaf(-2.f, acc[qi][tj][r], qnr[qi][r] + tnv), 0.f);
        unsigned key = (__float_as_uint(d2)&0xFFFFFFF8u) | lab;
        int q = qbase + w*32 + qi*16 + quad*4 + r;
        keys[(size_t)q*NSUB + sI] = key;
      }
  }
}

// ---------------- gather slabs, exact radix select + class sums ---------------
__global__ __launch_bounds__(256) void final_k(
    const unsigned* __restrict__ slab,
    const float* __restrict__ Qm, const float* __restrict__ Tm,
    const float* __restrict__ qn, const float* __restrict__ tn,
    const int* __restrict__ labels,
    float* __restrict__ tot, int first, int dp)
{
  __shared__ int hist[2048];
  __shared__ int part[256];
  __shared__ unsigned buf[CAP];
  __shared__ unsigned lowbuf[96];
  __shared__ float qrow[128];
  __shared__ int sB,sLob,s_cnt,s_low,s_bad;
  __shared__ float s_w[9];
  int tid=threadIdx.x, q=blockIdx.x;
  if (tid==0){ for (int j=0;j<9;j++) s_w[j]=0.f; s_cnt=0; s_low=0; s_bad=0; }
  __syncthreads();

  // [q][t_blk] layout: query q's slabs are ONE contiguous 25KB run
  const unsigned* sq = slab + (size_t)q*NTB*SLOTS;
  for (int sidx=tid; sidx<NTB; sidx+=256){
    const unsigned* s = sq + (size_t)sidx*SLOTS;
    uint4 a = *(const uint4*)s;
    unsigned cnt = a.x;
    if (cnt > SLOTS-1){ s_bad=1; continue; }
    if (!cnt) continue;
    int base = atomicAdd(&s_cnt, (int)cnt);
    if (base + (int)cnt <= CAP){
      buf[base] = a.y;
      if (cnt>=2) buf[base+1] = a.z;
      if (cnt>=3) buf[base+2] = a.w;
      for (unsigned w=4; w<=cnt; w++) buf[base+w-1] = s[w];
    }
  }
  __syncthreads();
  int total = s_cnt;
  int bad = s_bad;

#define CONTRIB(kk) do{ float d2_=__uint_as_float((kk)&0xFFFFFFF8u); \
    if (d2_>0.f){ float w_=1.0f/sqrtf(d2_); \
      atomicAdd(&s_w[8],w_); atomicAdd(&s_w[(kk)&7u],w_); } }while(0)

  unsigned T; int Krem=KNN;
  if (!bad && total>=KNN && total<=CAP){
    for (int i=tid;i<2048;i+=256) hist[i]=0;
    __syncthreads();
    for (int i=tid;i<total;i+=256) atomicAdd(&hist[buf[i]>>21],1);
    __syncthreads();
    find_bin(hist,part,2048,Krem,tid,&sB,&sLob);
    unsigned pre=(unsigned)sB; Krem-=sLob;
    for (int i=tid;i<2048;i+=256) hist[i]=0;
    __syncthreads();
    for (int i=tid;i<total;i+=256){ unsigned k=buf[i]; if ((k>>21)==pre) atomicAdd(&hist[(k>>10)&0x7FFu],1); }
    __syncthreads();
    find_bin(hist,part,2048,Krem,tid,&sB,&sLob);
    pre=(pre<<11)|(unsigned)sB; Krem-=sLob;
    for (int i=tid;i<1024;i+=256) hist[i]=0;
    __syncthreads();
    for (int i=tid;i<total;i+=256){ unsigned k=buf[i]; if ((k>>10)==pre) atomicAdd(&hist[k&0x3FFu],1); }
    __syncthreads();
    find_bin(hist,part,1024,Krem,tid,&sB,&sLob);
    T=(pre<<10)|(unsigned)sB; Krem-=sLob;
    __syncthreads();
    for (int i=tid;i<total;i+=256){ unsigned k=buf[i]; if (k<T) CONTRIB(k); }
  } else {
    // fallback (P ~ 1e-10): exact fp32 full recompute select
    if (tid==0) s_cnt=0;
    for (int i=tid;i<dp;i+=256) qrow[i]=Qm[(size_t)q*dp+i];
    __syncthreads();
    float qq=qn[q];
    auto KEY=[&](int t)->unsigned{
      const float* br=&Tm[(size_t)t*dp];
      float dot=0.f;
      for (int k2=0;k2<dp;k2++) dot+=qrow[k2]*br[k2];
      float d2=fmaxf(qq-2.f*dot+tn[t],0.f);
      return (__float_as_uint(d2)&0xFFFFFFF8u)|(unsigned)labels[t];
    };
    for (int i=tid;i<2048;i+=256) hist[i]=0;
    __syncthreads();
    for (int t=tid;t<NT;t+=256) atomicAdd(&hist[KEY(t)>>21],1);
    __syncthreads();
    find_bin(hist,part,2048,Krem,tid,&sB,&sLob);
    int c=hist[sB]; Krem-=sLob;
    unsigned prefix=(unsigned)sB; int shift=21;
    if (c > CAP){
      __syncthreads();
      for (int i=tid;i<2048;i+=256) hist[i]=0;
      __syncthreads();
      for (int t=tid;t<NT;t+=256){ unsigned k=KEY(t); if ((k>>21)==prefix) atomicAdd(&hist[(k>>10)&0x7FFu],1); }
      __syncthreads();
      find_bin(hist,part,2048,Krem,tid,&sB,&sLob);
      c=hist[sB]; Krem-=sLob; prefix=(prefix<<11)|(unsigned)sB; shift=10;
    }
    if (c > CAP){
      __syncthreads();
      for (int i=tid;i<1024;i+=256) hist[i]=0;
      __syncthreads();
      for (int t=tid;t<NT;t+=256){ unsigned k=KEY(t); if ((k>>10)==prefix) atomicAdd(&hist[k&0x3FFu],1); }
      __syncthreads();
      find_bin(hist,part,1024,Krem,tid,&sB,&sLob);
      c=hist[sB]; Krem-=sLob; prefix=(prefix<<10)|(unsigned)sB; shift=0;
    }
    if (c <= CAP){
      for (int t=tid;t<NT;t+=256){
        unsigned k=KEY(t); unsigned pp=k>>shift;
        if (pp==prefix){ int j=atomicAdd(&s_cnt,1); if (j<CAP) buf[j]=k; }
        else if (pp<prefix){ int j=atomicAdd(&s_low,1); if (j<96) lowbuf[j]=k; }
      }
      __syncthreads();
      int sh=shift;
      while (sh>0){
        int nsh=(sh==21)?10:0;
        int nb=1<<(sh-nsh);
        __syncthreads();
        for (int i=tid;i<nb;i+=256) hist[i]=0;
        __syncthreads();
        int cc=s_cnt;
        for (int i=tid;i<cc;i+=256) atomicAdd(&hist[(buf[i]>>nsh)&(unsigned)(nb-1)],1);
        __syncthreads();
        find_bin(hist,part,nb,Krem,tid,&sB,&sLob);
        Krem-=sLob; prefix=(prefix<<(sh-nsh))|(unsigned)sB; sh=nsh;
      }
      T=prefix;
      __syncthreads();
      int lowc=s_low, cc=s_cnt;
      for (int i=tid;i<lowc;i+=256){ unsigned k=lowbuf[i]; CONTRIB(k); }
      for (int i=tid;i<cc;i+=256){ unsigned k=buf[i]; if (k<T) CONTRIB(k); }
    } else {
      T=prefix;
      for (int t=tid;t<NT;t+=256){ unsigned k=KEY(t); if (k<T) CONTRIB(k); }
    }
  }
  __syncthreads();
  if (tid==0){
    float d2=__uint_as_float(T&0xFFFFFFF8u);
    float w=(d2>0.f)?(1.0f/sqrtf(d2)):0.f;
    s_w[8] += (float)Krem*w;
    s_w[T&7u] += (float)Krem*w;
  }
  __syncthreads();
  if (tid<8){
    float contrib = s_w[8]-s_w[tid];
    size_t o=(size_t)q*NL+tid;
    tot[o] = first ? contrib : tot[o]+contrib;
  }
#undef CONTRIB
}

// ---------------- empirical p-values ------------------------------------------
__global__ void pvalue_k(const float* __restrict__ tot, const float* __restrict__ cali,
                         float* __restrict__ out){
  __shared__ float t8[NL];
  __shared__ int part[4][NL];
  int tid=threadIdx.x, q=blockIdx.x;
  if (tid<NL) t8[tid]=tot[(size_t)q*NL+tid];
  __syncthreads();
  float th[NL];
  #pragma unroll
  for (int c=0;c<NL;c++) th[c]=t8[c];
  int cnt[NL];
  #pragma unroll
  for (int c=0;c<NL;c++) cnt[c]=0;
  for (int i=tid;i<NCALI;i+=256){
    float v=cali[i];
    #pragma unroll
    for (int c=0;c<NL;c++) cnt[c] += (v>=th[c]) ? 1 : 0;
  }
  #pragma unroll
  for (int c=0;c<NL;c++){
    #pragma unroll
    for (int off=32;off>0;off>>=1) cnt[c]+=__shfl_down(cnt[c],off,64);
  }
  if ((tid&63)==0){
    #pragma unroll
    for (int c=0;c<NL;c++) part[tid>>6][c]=cnt[c];
  }
  __syncthreads();
  if (tid<NL){
    int s=part[0][tid]+part[1][tid]+part[2][tid]+part[3][tid];
    out[(size_t)q*NL+tid] = (float)s / 10000.f;
  }
}

// ---------------- one kNN layer (templated on KCH = dp/32) --------------------
template<int KCH>
static void knn_layer(const float* Qm, const float* Bank, float* qnl, int first,
                      const int* lbl, float* tnb,
                      unsigned short* qH, unsigned short* qL,
                      unsigned short* bankH, unsigned short* bankL,
                      unsigned* skeys, unsigned* sT, unsigned* slab,
                      float* tot, hipStream_t stream){
  constexpr int dp = KCH*32;
  conv_norm_k<<<(NT+NB)/4,256,0,stream>>>(Bank, bankH, bankL, tnb, NT,
                                          Qm, qH, qL, qnl, NB, dp);
  dist_sub_k<KCH><<<8*NSB,256,0,stream>>>(qH,qL,bankH,bankL,qnl,tnb,lbl,skeys);
  sel64_k<<<NB,256,0,stream>>>(skeys,sT);
  dist_mfma_k<KCH><<<8*8*49,256,0,stream>>>(qH,qL,bankH,bankL,qnl,tnb,lbl,sT,slab);
  final_k<<<NB,256,0,stream>>>(slab,Qm,Bank,qnl,tnb,lbl,tot,first,dp);
}

extern "C" void kernel_launch(void* const* d_in, const int* in_sizes, int n_in,
                              void* d_out, int out_size, void* d_ws, size_t ws_size,
                              hipStream_t stream) {
  const float* x   = (const float*)d_in[0];
  const float* txr = (const float*)d_in[1];
  const int*   lbl = (const int*)  d_in[2];
  const float* cal = (const float*)d_in[3];
  const float* W1  = (const float*)d_in[4];
  const float* b1  = (const float*)d_in[5];
  const float* W2  = (const float*)d_in[6];
  const float* b2  = (const float*)d_in[7];
  const float* W3  = (const float*)d_in[8];
  const float* b3  = (const float*)d_in[9];
  const float* W4  = (const float*)d_in[10];
  const float* b4  = (const float*)d_in[11];
  float* out = (float*)d_out;
  float* ws  = (float*)d_ws;

  size_t off=0;
  float* xq0=ws+off; off+=(size_t)NB*96;
  float* xq1=ws+off; off+=(size_t)NB*128;
  float* xq2=ws+off; off+=(size_t)NB*128;
  float* xq3=ws+off; off+=(size_t)NB*128;
  float* xq4=ws+off; off+=(size_t)NB*32;
  float* tbA=ws+off; off+=(size_t)NT*128;
  float* tbB=ws+off; off+=(size_t)NT*128;
  float* tb4=ws+off; off+=(size_t)NT*32;
  float* qnb=ws+off; off+=(size_t)5*NB;
  float* tnb=ws+off; off+=(size_t)NT;
  float* tot=ws+off; off+=(size_t)NB*NL;
  unsigned* sT=(unsigned*)(ws+off); off+=NB;
  unsigned short* qH=(unsigned short*)(ws+off); off+=(size_t)NB*64;
  unsigned short* qL=(unsigned short*)(ws+off); off+=(size_t)NB*64;
  unsigned short* bankH=(unsigned short*)(ws+off); off+=(size_t)NT_PAD*64;
  unsigned short* bankL=(unsigned short*)(ws+off); off+=(size_t)NT_PAD*64;
  off=(off+3)&~(size_t)3;
  unsigned* slab=(unsigned*)(ws+off);   // NB*NTB*SLOTS = 25.6 MB
  unsigned* skeys=(unsigned*)(ws+off);  // NB*NSUB     =  8.4 MB (aliased; skeys
                                        // dead before dist_mfma_k writes slab)
  { size_t slab_sz=(size_t)NB*NTB*SLOTS, skey_sz=(size_t)NB*NSUB;
    off += (slab_sz > skey_sz ? slab_sz : skey_sz); }

  // query features; layer-0 features at stride 96
  pad_copy_k<<<(NB*96+255)/256,256,0,stream>>>(x, xq0, NB, 83, 96);
  pad_copy_k<<<((size_t)NT*96+255)/256,256,0,stream>>>(txr, tbA, NT, 83, 96);
  mlp_gemm_k<<<(NB+127)/128,256,0,stream>>>(xq0,96,3,W1,83,b1,xq1,NB);
  mlp_gemm_k<<<(NB+127)/128,256,0,stream>>>(xq1,128,4,W2,128,b2,xq2,NB);
  mlp_gemm_k<<<(NB+127)/128,256,0,stream>>>(xq2,128,4,W3,128,b3,xq3,NB);
  mlp8_k<<<(NB+31)/32,256,0,stream>>>(xq3,W4,b4,xq4,NB);
  softmax_k<<<(NB+255)/256,256,0,stream>>>(xq4,NB);

  knn_layer<3>(xq0, tbA, qnb+0*NB, 1, lbl, tnb, qH,qL,bankH,bankL, skeys,sT,slab, tot, stream);
  mlp_gemm_k<<<(NT+127)/128,256,0,stream>>>(tbA,96,3,W1,83,b1,tbB,NT);
  knn_layer<4>(xq1, tbB, qnb+1*NB, 0, lbl, tnb, qH,qL,bankH,bankL, skeys,sT,slab, tot, stream);
  mlp_gemm_k<<<(NT+127)/128,256,0,stream>>>(tbB,128,4,W2,128,b2,tbA,NT);
  knn_layer<4>(xq2, tbA, qnb+2*NB, 0, lbl, tnb, qH,qL,bankH,bankL, skeys,sT,slab, tot, stream);
  mlp_gemm_k<<<(NT+127)/128,256,0,stream>>>(tbA,128,4,W3,128,b3,tbB,NT);
  knn_layer<4>(xq3, tbB, qnb+3*NB, 0, lbl, tnb, qH,qL,bankH,bankL, skeys,sT,slab, tot, stream);
  mlp8_k<<<(NT+31)/32,256,0,stream>>>(tbB,W4,b4,tb4,NT);
  softmax_k<<<(NT+255)/256,256,0,stream>>>(tb4,NT);
  knn_layer<1>(xq4, tb4, qnb+4*NB, 0, lbl, tnb, qH,qL,bankH,bankL, skeys,sT,slab, tot, stream);

  pvalue_k<<<NB,256,0,stream>>>(tot,cal,out);
}

// Round 9
// 769.132 us; speedup vs baseline: 2.2062x; 1.0742x over previous
//
#include <hip/hip_runtime.h>
#include <math.h>

#define KNN 75
#define NL 8
#define NB 1024
#define NT 50000
#define NT_PAD 50048  // NTB*TT rows allocated for bf16 banks (pad rows masked)
#define NCALI 10000
#define KC 32
#define TT 128
#define NTB 391       // ceil(NT/TT)
#define SLOTS 16      // per (q, t-block) slab: [count, up to 15 hit keys] = 64B
#define CAP 6144      // candidate buffer per query
#define NSUB 2048     // sampled train points for threshold
#define NSB 16        // NSUB/TT subset t-blocks
#define SSTRIDE 24
#define SOFF 11       // 11 + 24*2047 = 49139 < 50000
#define RSEL 32       // sample rank -> expected |{k < T}| ~ 780, lambda/slab ~ 2

typedef __attribute__((ext_vector_type(8))) short bf16x8;
typedef __attribute__((ext_vector_type(4))) float f32x4;

__device__ __forceinline__ int swz(int c){ return c + ((c>>5)<<2); }

__device__ __forceinline__ unsigned short f2bf_rn(float x){
  unsigned u = __float_as_uint(x);
  unsigned r = (u + 0x7FFFu + ((u>>16)&1u)) >> 16;
  return (unsigned short)r;
}
__device__ __forceinline__ float bf2f(unsigned short h){
  return __uint_as_float(((unsigned)h)<<16);
}
__device__ __forceinline__ bf16x8 ld8(const unsigned short* p){
  return *(const bf16x8*)p;
}
// async global->LDS, 16B per lane; LDS dest = wave-uniform base + lane*16
__device__ __forceinline__ void gl_lds16(const unsigned short* g, unsigned short* l){
  __builtin_amdgcn_global_load_lds(
      (const __attribute__((address_space(1))) void*)g,
      (__attribute__((address_space(3))) void*)l, 16, 0, 0);
}

// ---------------- pad copy (zero-fill pad cols every call: ws is poisoned) ----
__global__ void pad_copy_k(const float* __restrict__ in, float* __restrict__ out,
                           int M, int Din, int Dout){
  int idx = blockIdx.x*256 + threadIdx.x;
  if (idx >= M*Dout) return;
  int r = idx / Dout, c = idx - r*Dout;
  out[idx] = (c < Din) ? in[r*Din + c] : 0.f;
}

// ---------------- weight transpose + bf16 hi/lo split: Wt[n][k] --------------
__global__ void wsplit_k(const float* __restrict__ W, int kreal, int dp,
                         unsigned short* __restrict__ WtH,
                         unsigned short* __restrict__ WtL){
  int idx = blockIdx.x*256 + threadIdx.x;
  if (idx >= 128*dp) return;
  int n = idx / dp, k = idx - n*dp;
  float v = (k < kreal) ? W[(size_t)k*128 + n] : 0.f;
  unsigned short h = f2bf_rn(v);
  WtH[idx] = h;
  WtL[idx] = f2bf_rn(v - bf2f(h));
}

// ---------------- MLP GEMM (fp32, query path only: M=1024, cheap) ------------
__global__ __launch_bounds__(256) void mlp_gemm_k(
    const float* __restrict__ A, int lda, int kchunks,
    const float* __restrict__ W, int kreal,
    const float* __restrict__ bias,
    float* __restrict__ Out, int M)
{
  __shared__ float As[KC][132];
  __shared__ float Bs[KC][148];
  int tid = threadIdx.x;
  int r0 = (tid>>4)*8, c0 = (tid&15)*8;
  int rowBase = blockIdx.x*128;
  float acc[8][8];
  #pragma unroll
  for (int i=0;i<8;i++)
    #pragma unroll
    for (int j=0;j<8;j++) acc[i][j]=0.f;

  for (int kc=0;kc<kchunks;kc++){
    { int rr = tid>>3, k4=(tid&7)*4;
      #pragma unroll
      for (int i=0;i<4;i++){
        int row = rr + i*32, gr = rowBase + row;
        float4 v = make_float4(0.f,0.f,0.f,0.f);
        if (gr < M) v = *(const float4*)&A[(size_t)gr*lda + kc*KC + k4];
        As[k4+0][row]=v.x; As[k4+1][row]=v.y; As[k4+2][row]=v.z; As[k4+3][row]=v.w;
      }
    }
    { int kk=tid>>5, c4=(tid&31)*4;
      #pragma unroll
      for (int i=0;i<4;i++){
        int k = kk + i*8, gk = kc*KC + k;
        float4 v = make_float4(0.f,0.f,0.f,0.f);
        if (gk < kreal) v = *(const float4*)&W[(size_t)gk*128 + c4];
        *(float4*)&Bs[k][swz(c4)] = v;
      }
    }
    __syncthreads();
    #pragma unroll 4
    for (int k=0;k<KC;k++){
      float4 a0 = *(const float4*)&As[k][r0];
      float4 a1 = *(const float4*)&As[k][r0+4];
      float4 b0 = *(const float4*)&Bs[k][swz(c0)];
      float4 b1 = *(const float4*)&Bs[k][swz(c0+4)];
      float av[8] = {a0.x,a0.y,a0.z,a0.w,a1.x,a1.y,a1.z,a1.w};
      float bv[8] = {b0.x,b0.y,b0.z,b0.w,b1.x,b1.y,b1.z,b1.w};
      #pragma unroll
      for (int i=0;i<8;i++)
        #pragma unroll
        for (int j=0;j<8;j++) acc[i][j] += av[i]*bv[j];
    }
    __syncthreads();
  }
  float bb[8];
  #pragma unroll
  for (int j=0;j<8;j++) bb[j]=bias[c0+j];
  #pragma unroll
  for (int i=0;i<8;i++){
    int gr = rowBase + r0 + i;
    if (gr < M){
      float o[8];
      #pragma unroll
      for (int j=0;j<8;j++){ float v=acc[i][j]+bb[j]; o[j]=v>0.f?v:0.f; }
      *(float4*)&Out[(size_t)gr*128 + c0]   = make_float4(o[0],o[1],o[2],o[3]);
      *(float4*)&Out[(size_t)gr*128 + c0+4] = make_float4(o[4],o[5],o[6],o[7]);
    }
  }
}

// ---------------- last layer: logits[M][8] into stride-32 rows ----------------
__global__ void mlp8_k(const float* __restrict__ A, const float* __restrict__ W4,
                       const float* __restrict__ b4, float* __restrict__ Out, int M){
  __shared__ float Ws[128*8];
  int tid = threadIdx.x;
  for (int i=tid;i<1024;i+=256) Ws[i]=W4[i];
  __syncthreads();
  int r = blockIdx.x*32 + (tid>>3), c = tid&7;
  if (r >= M) return;
  const float* a = &A[(size_t)r*128];
  float acc = b4[c];
  #pragma unroll 16
  for (int k=0;k<128;k++) acc += a[k]*Ws[k*8+c];
  Out[(size_t)r*32 + c] = acc;
}

// ---------------- softmax over 8 logits, zero cols 8..31 ----------------------
__global__ void softmax_k(float* __restrict__ X, int M){
  int r = blockIdx.x*256 + threadIdx.x;
  if (r >= M) return;
  float* p = &X[(size_t)r*32];
  float v[8], m=-1e30f;
  #pragma unroll
  for (int j=0;j<8;j++){ v[j]=p[j]; m = v[j]>m ? v[j] : m; }
  float s=0.f;
  #pragma unroll
  for (int j=0;j<8;j++){ v[j]=__expf(v[j]-m); s+=v[j]; }
  float inv=1.f/s;
  #pragma unroll
  for (int j=0;j<8;j++) p[j]=v[j]*inv;
  #pragma unroll
  for (int j=8;j<32;j++) p[j]=0.f;
}

// ---- fp32 -> (hi,lo) bf16 split + row squared-norms, bank+queries fused ------
__global__ void conv_norm_k(
    const float* __restrict__ XA, unsigned short* __restrict__ HA,
    unsigned short* __restrict__ LA, float* __restrict__ nA, int MA,
    const float* __restrict__ XB, unsigned short* __restrict__ HB,
    unsigned short* __restrict__ LB, float* __restrict__ nB, int MB,
    int dp)
{
  int w = threadIdx.x>>6, lane = threadIdx.x&63;
  int row = blockIdx.x*4 + w;
  const float* src; unsigned short* dh; unsigned short* dl; float* nrm;
  if (row < MA){
    src=&XA[(size_t)row*dp]; dh=&HA[(size_t)row*dp]; dl=&LA[(size_t)row*dp]; nrm=&nA[row];
  } else {
    int r2 = row - MA;
    if (r2 >= MB) return;
    src=&XB[(size_t)r2*dp]; dh=&HB[(size_t)r2*dp]; dl=&LB[(size_t)r2*dp]; nrm=&nB[r2];
  }
  float s=0.f;
  for (int c=lane*2; c<dp; c+=128){
    float2 v = *(const float2*)&src[c];
    s += v.x*v.x + v.y*v.y;
    unsigned short h0 = f2bf_rn(v.x), h1 = f2bf_rn(v.y);
    float r0 = v.x - bf2f(h0), r1 = v.y - bf2f(h1);
    ushort2 hh; hh.x=h0; hh.y=h1;
    ushort2 ll; ll.x=f2bf_rn(r0); ll.y=f2bf_rn(r1);
    *(ushort2*)&dh[c]=hh;
    *(ushort2*)&dl[c]=ll;
  }
  #pragma unroll
  for (int off=32;off>0;off>>=1) s += __shfl_down(s, off, 64);
  if (lane==0) *nrm=s;
}

// ---------------- scan helper: find bin containing rank Krem ------------------
// Wave-level shfl_up inclusive scan over per-thread chunk sums; unique winner
// thread does the <=8-iter chunk walk.
__device__ __forceinline__ void find_bin(int* hist, int* part, int nb, int Krem,
                                         int tid, int* s_B, int* s_lob){
  int ch = nb>>8;
  int base = tid*ch;
  int s=0;
  for (int b=base;b<base+ch;b++) s+=hist[b];
  int lane = tid & 63, wv = tid>>6;
  int v = s;
  #pragma unroll
  for (int off=1; off<64; off<<=1){
    int u = __shfl_up(v, off, 64);
    if (lane >= off) v += u;
  }
  if (lane==63) part[wv] = v;
  __syncthreads();
  int wbase = 0;
  #pragma unroll
  for (int w2=0; w2<4; w2++) wbase += (w2 < wv) ? part[w2] : 0;
  v += wbase;
  int excl = v - s;
  if (v >= Krem && excl < Krem){
    int lob = excl, B = base + ch - 1;
    for (int b=base;b<base+ch;b++){
      if (lob + hist[b] >= Krem){ B=b; break; }
      lob += hist[b];
    }
    *s_B = B; *s_lob = lob;
  }
  if (tid==255 && v < Krem){ *s_B = nb-1; *s_lob = 0; }  // preserve old default
  __syncthreads();
}

// ---------------- per-query threshold: exact RSEL-th smallest sample key ------
__global__ __launch_bounds__(256) void sel64_k(const unsigned* __restrict__ skeys,
                                               unsigned* __restrict__ Tthr){
  __shared__ unsigned buf[NSUB];
  __shared__ int hist[2048];
  __shared__ int part[256];
  __shared__ int sB, sLob;
  int tid=threadIdx.x, q=blockIdx.x;
  for (int i=tid;i<NSUB;i+=256) buf[i]=skeys[(size_t)q*NSUB+i];
  int Krem=RSEL;
  for (int i=tid;i<2048;i+=256) hist[i]=0;
  __syncthreads();
  for (int i=tid;i<NSUB;i+=256) atomicAdd(&hist[buf[i]>>21],1);
  __syncthreads();
  find_bin(hist,part,2048,Krem,tid,&sB,&sLob);
  unsigned pre=(unsigned)sB; Krem-=sLob;
  for (int i=tid;i<2048;i+=256) hist[i]=0;
  __syncthreads();
  for (int i=tid;i<NSUB;i+=256){ unsigned k=buf[i]; if ((k>>21)==pre) atomicAdd(&hist[(k>>10)&0x7FFu],1); }
  __syncthreads();
  find_bin(hist,part,2048,Krem,tid,&sB,&sLob);
  pre=(pre<<11)|(unsigned)sB; Krem-=sLob;
  for (int i=tid;i<1024;i+=256) hist[i]=0;
  __syncthreads();
  for (int i=tid;i<NSUB;i+=256){ unsigned k=buf[i]; if ((k>>10)==pre) atomicAdd(&hist[k&0x3FFu],1); }
  __syncthreads();
  find_bin(hist,part,1024,Krem,tid,&sB,&sLob);
  if (tid==0) Tthr[q]=(pre<<10)|(unsigned)sB;
}

// ====== MFMA section: one 128x128 sub-tile x one K-chunk from LDS =============
#define MFMA_SEC(BHC, BLC, A0H, A0L, A1H, A1L)                                   \
  _Pragma("unroll")                                                              \
  for (int tj=0;tj<8;tj++){                                                      \
    int rowB = tj*16 + col;                                                      \
    int sw = (((quad + (rowB>>1)) & 3) << 3);                                    \
    bf16x8 bh = *(const bf16x8*)&(BHC)[rowB*32 + sw];                            \
    bf16x8 bl = *(const bf16x8*)&(BLC)[rowB*32 + sw];                            \
    acc[0][tj] = __builtin_amdgcn_mfma_f32_16x16x32_bf16(A0H, bh, acc[0][tj], 0,0,0); \
    acc[0][tj] = __builtin_amdgcn_mfma_f32_16x16x32_bf16(A0H, bl, acc[0][tj], 0,0,0); \
    acc[0][tj] = __builtin_amdgcn_mfma_f32_16x16x32_bf16(A0L, bh, acc[0][tj], 0,0,0); \
    acc[1][tj] = __builtin_amdgcn_mfma_f32_16x16x32_bf16(A1H, bh, acc[1][tj], 0,0,0); \
    acc[1][tj] = __builtin_amdgcn_mfma_f32_16x16x32_bf16(A1H, bl, acc[1][tj], 0,0,0); \
    acc[1][tj] = __builtin_amdgcn_mfma_f32_16x16x32_bf16(A1L, bh, acc[1][tj], 0,0,0); \
  }

// K-loop body (2-deep double-buffer). Requires BH0/BH1/BL0/BL1 ushort* LDS
// pointers in scope. kchunks is constexpr -> fully unrolled.
#define MFMA_KLOOP(ROWMAP)                                                       \
  size_t aoff = (size_t)(qbase + w*32 + col)*dp + quad*8;                        \
  const unsigned short* pAH = QH + aoff;                                         \
  const unsigned short* pAL = QL + aoff;                                         \
  size_t qi_step = (size_t)16*dp;                                                \
  int i0 = tid,      row0 = i0>>2, sg0 = ((i0&3) - (row0>>1)) & 3;               \
  int i1 = tid+256,  row1 = i1>>2, sg1 = ((i1&3) - (row1>>1)) & 3;               \
  size_t g0 = (size_t)(ROWMAP(n0+row0))*dp + (size_t)sg0*8;                      \
  size_t g1 = (size_t)(ROWMAP(n0+row1))*dp + (size_t)sg1*8;                      \
  f32x4 acc[2][8];                                                               \
  _Pragma("unroll")                                                              \
  for (int qi=0;qi<2;qi++)                                                       \
    _Pragma("unroll")                                                            \
    for (int tj=0;tj<8;tj++){ f32x4 z={0.f,0.f,0.f,0.f}; acc[qi][tj]=z; }        \
  gl_lds16(TH + g0, BH0 + i0*8);                                                 \
  gl_lds16(TH + g1, BH0 + i1*8);                                                 \
  gl_lds16(TL + g0, BL0 + i0*8);                                                 \
  gl_lds16(TL + g1, BL0 + i1*8);                                                 \
  bf16x8 x0h = ld8(pAH), x0l = ld8(pAL);                                         \
  bf16x8 x1h = ld8(pAH + qi_step), x1l = ld8(pAL + qi_step);                     \
  bf16x8 y0h = x0h, y0l = x0l, y1h = x1h, y1l = x1l;                             \
  _Pragma("unroll")                                                              \
  for (int kc=0; kc<kchunks; kc+=2){                                             \
    __syncthreads();                                                             \
    if (kc+1 < kchunks){                                                         \
      size_t ko=(size_t)(kc+1)*32;                                               \
      gl_lds16(TH + g0 + ko, BH1 + i0*8);                                        \
      gl_lds16(TH + g1 + ko, BH1 + i1*8);                                        \
      gl_lds16(TL + g0 + ko, BL1 + i0*8);                                        \
      gl_lds16(TL + g1 + ko, BL1 + i1*8);                                        \
      y0h = ld8(pAH + ko);           y0l = ld8(pAL + ko);                        \
      y1h = ld8(pAH + qi_step + ko); y1l = ld8(pAL + qi_step + ko);              \
    }                                                                            \
    MFMA_SEC(BH0, BL0, x0h, x0l, x1h, x1l);                                      \
    if (kc+1 < kchunks){                                                         \
      __syncthreads();                                                           \
      if (kc+2 < kchunks){                                                       \
        size_t ko=(size_t)(kc+2)*32;                                             \
        gl_lds16(TH + g0 + ko, BH0 + i0*8);                                      \
        gl_lds16(TH + g1 + ko, BH0 + i1*8);                                      \
        gl_lds16(TL + g0 + ko, BL0 + i0*8);                                      \
        gl_lds16(TL + g1 + ko, BL0 + i1*8);                                      \
        x0h = ld8(pAH + ko);           x0l = ld8(pAL + ko);                      \
        x1h = ld8(pAH + qi_step + ko); x1l = ld8(pAL + qi_step + ko);            \
      }                                                                          \
      MFMA_SEC(BH1, BL1, y0h, y0l, y1h, y1l);                                    \
    }                                                                            \
  }

#define ROW_ID(r) (r)
#define ROW_SUB(r) ((r)*SSTRIDE + SOFF)

// ---------------- MFMA split-bf16 distance GEMM vs full bank ------------------
// LDS = ONE 32 KB arena; epilogue aliases hitbuf/hcnt onto the K-buffers.
template<int KCH>
__global__ __launch_bounds__(256) void dist_mfma_k(
    const unsigned short* __restrict__ QH, const unsigned short* __restrict__ QL,
    const unsigned short* __restrict__ TH, const unsigned short* __restrict__ TL,
    const float* __restrict__ qn, const float* __restrict__ tn,
    const int* __restrict__ labels, const unsigned* __restrict__ Tthr,
    unsigned* __restrict__ slab)
{
  constexpr int dp = KCH*32;
  __shared__ __align__(16) unsigned short smem[4*4096];   // 32 KB
  unsigned short* BH0 = smem;
  unsigned short* BH1 = smem + 4096;
  unsigned short* BL0 = smem + 8192;
  unsigned short* BL1 = smem + 12288;
  unsigned (*hitbuf)[SLOTS] = (unsigned (*)[SLOTS])smem;  // aliases BH0 (8 KB)
  int* hcnt = (int*)(smem + 4096);                        // aliases BH1 head
  int b = blockIdx.x;
  int xcd = b & 7, s = b >> 3;
  int qb = s & 7, tslot = s >> 3;
  int t_blk = xcd + 8*tslot;
  if (t_blk >= NTB) return;
  int tid = threadIdx.x, w = tid>>6, lane = tid&63;
  int quad = lane>>4, col = lane&15;
  int qbase = qb*128;
  int n0 = t_blk*TT;
  constexpr int kchunks = KCH;

  MFMA_KLOOP(ROW_ID)

  // epilogue: barrier FIRST (K-loop LDS reads must complete before aliasing)
  __syncthreads();
  if (tid<128) hcnt[tid]=0;
  __syncthreads();
  float qnr[2][4]; unsigned Tq[2][4]; float thrF[2][4];
  #pragma unroll
  for (int qi=0;qi<2;qi++)
    #pragma unroll
    for (int r=0;r<4;r++){
      int q = qbase + w*32 + qi*16 + quad*4 + r;
      qnr[qi][r]  = qn[q];
      Tq[qi][r]   = Tthr[q];
      thrF[qi][r] = __uint_as_float(Tq[qi][r] | 7u);  // superset boundary
    }
  #pragma unroll
  for (int tj=0;tj<8;tj++){
    int t = n0 + tj*16 + col;
    if (t < NT){
      float tnv = tn[t];
      unsigned lab = (unsigned)labels[t];
      #pragma unroll
      for (int qi=0;qi<2;qi++)
        #pragma unroll
        for (int r=0;r<4;r++){
          float d2 = fmaf(-2.f, acc[qi][tj][r], qnr[qi][r] + tnv);
          if (d2 <= thrF[qi][r]){
            float d2c = fmaxf(d2, 0.f);
            unsigned key = (__float_as_uint(d2c)&0xFFFFFFF8u) | lab;
            if (key < Tq[qi][r]){
              int ql = w*32 + qi*16 + quad*4 + r;
              int idx = atomicAdd(&hcnt[ql], 1);
              if (idx < SLOTS-1) hitbuf[ql][1+idx] = key;
            }
          }
        }
    }
  }
  __syncthreads();
  if (tid<128) hitbuf[tid][0]=(unsigned)hcnt[tid];
  __syncthreads();
  // slab[q][t_blk]: final_k reads each query's 391 slabs contiguously
  #pragma unroll
  for (int rep=0; rep<2; rep++){
    int idx = rep*256 + tid;
    int q = idx>>2, sub = (idx&3)*4;
    uint4 v = *(uint4*)&hitbuf[q][sub];
    *(uint4*)&slab[((size_t)(qbase+q)*NTB + t_blk)*SLOTS + sub] = v;
  }
}

// ---------------- MFMA split-bf16 distance GEMM vs SAMPLED subset -------------
template<int KCH>
__global__ __launch_bounds__(256) void dist_sub_k(
    const unsigned short* __restrict__ QH, const unsigned short* __restrict__ QL,
    const unsigned short* __restrict__ TH, const unsigned short* __restrict__ TL,
    const float* __restrict__ qn, const float* __restrict__ tn,
    const int* __restrict__ labels, unsigned* __restrict__ keys)
{
  constexpr int dp = KCH*32;
  __shared__ __align__(16) unsigned short smem[4*4096];   // 32 KB
  unsigned short* BH0 = smem;
  unsigned short* BH1 = smem + 4096;
  unsigned short* BL0 = smem + 8192;
  unsigned short* BL1 = smem + 12288;
  int b = blockIdx.x;
  int qb = b & 7, t_blk = b >> 3;            // t_blk in [0, NSB)
  int tid = threadIdx.x, w = tid>>6, lane = tid&63;
  int quad = lane>>4, col = lane&15;
  int qbase = qb*128;
  int n0 = t_blk*TT;                         // subset-space row base
  constexpr int kchunks = KCH;

  MFMA_KLOOP(ROW_SUB)

  // epilogue: write all keys; 16-lane quad -> 64B contiguous store per (qi,tj,r)
  float qnr[2][4];
  #pragma unroll
  for (int qi=0;qi<2;qi++)
    #pragma unroll
    for (int r=0;r<4;r++)
      qnr[qi][r] = qn[qbase + w*32 + qi*16 + quad*4 + r];
  #pragma unroll
  for (int tj=0;tj<8;tj++){
    int sI = n0 + tj*16 + col;
    int g  = sI*SSTRIDE + SOFF;
    float tnv = tn[g];
    unsigned lab = (unsigned)labels[g];
    #pragma unroll
    for (int qi=0;qi<2;qi++)
      #pragma unroll
      for (int r=0;r<4;r++){
        float d2 = fmaxf(fmaf(-2.f, acc[qi][tj][r], qnr[qi][r] + tnv), 0.f);
        unsigned key = (__float_as_uint(d2)&0xFFFFFFF8u) | lab;
        int q = qbase + w*32 + qi*16 + quad*4 + r;
        keys[(size_t)q*NSUB + sI] = key;
      }
  }
}

// ---------------- MFMA split-bf16 bank MLP: Out = relu(A @ Wt^T + b) ----------
// Replaces fp32 mlp_gemm_k on the NT-row bank (Common-mistake #4: fp32 matmul
// on the 157-TF vector ALU while split-bf16 MFMA machinery exists). Inputs:
// A = bankH/bankL (already split by conv_norm for this layer's kNN!); B = Wt
// hi/lo [128 neurons][dp], staged in LDS (L2-hot, same for all blocks).
// Structure = dist_sub_k with n0=0; epilogue adds bias, relu, fp32 store.
template<int KCH>
__global__ __launch_bounds__(256) void mlp_mfma_k(
    const unsigned short* __restrict__ QH, const unsigned short* __restrict__ QL,
    const unsigned short* __restrict__ TH, const unsigned short* __restrict__ TL,
    const float* __restrict__ bias, float* __restrict__ Out, int M)
{
  constexpr int dp = KCH*32;
  __shared__ __align__(16) unsigned short smem[4*4096];   // 32 KB
  unsigned short* BH0 = smem;
  unsigned short* BH1 = smem + 4096;
  unsigned short* BL0 = smem + 8192;
  unsigned short* BL1 = smem + 12288;
  int tid = threadIdx.x, w = tid>>6, lane = tid&63;
  int quad = lane>>4, col = lane&15;
  int qbase = blockIdx.x*128;                // bank-row base (grid=NTB -> 50048)
  int n0 = 0;                                // Wt rows 0..127
  constexpr int kchunks = KCH;

  MFMA_KLOOP(ROW_ID)

  // epilogue: bias + relu + fp32 store; 16-lane groups write 64B runs
  float bb[8];
  #pragma unroll
  for (int tj=0;tj<8;tj++) bb[tj] = bias[tj*16 + col];
  #pragma unroll
  for (int qi=0;qi<2;qi++)
    #pragma unroll
    for (int r=0;r<4;r++){
      int row = qbase + w*32 + qi*16 + quad*4 + r;
      if (row < M){
        #pragma unroll
        for (int tj=0;tj<8;tj++){
          float v = acc[qi][tj][r] + bb[tj];
          Out[(size_t)row*128 + tj*16 + col] = v > 0.f ? v : 0.f;
        }
      }
    }
}

// ---------------- gather slabs, exact radix select + class sums ---------------
__global__ __launch_bounds__(256) void final_k(
    const unsigned* __restrict__ slab,
    const float* __restrict__ Qm, const float* __restrict__ Tm,
    const float* __restrict__ qn, const float* __restrict__ tn,
    const int* __restrict__ labels,
    float* __restrict__ tot, int first, int dp)
{
  __shared__ int hist[2048];
  __shared__ int part[256];
  __shared__ unsigned buf[CAP];
  __shared__ unsigned lowbuf[96];
  __shared__ float qrow[128];
  __shared__ int sB,sLob,s_cnt,s_low,s_bad;
  __shared__ float s_w[9];
  int tid=threadIdx.x, q=blockIdx.x;
  if (tid==0){ for (int j=0;j<9;j++) s_w[j]=0.f; s_cnt=0; s_low=0; s_bad=0; }
  __syncthreads();

  // [q][t_blk] layout: query q's slabs are ONE contiguous 25KB run
  const unsigned* sq = slab + (size_t)q*NTB*SLOTS;
  for (int sidx=tid; sidx<NTB; sidx+=256){
    const unsigned* s = sq + (size_t)sidx*SLOTS;
    uint4 a = *(const uint4*)s;
    unsigned cnt = a.x;
    if (cnt > SLOTS-1){ s_bad=1; continue; }
    if (!cnt) continue;
    int base = atomicAdd(&s_cnt, (int)cnt);
    if (base + (int)cnt <= CAP){
      buf[base] = a.y;
      if (cnt>=2) buf[base+1] = a.z;
      if (cnt>=3) buf[base+2] = a.w;
      for (unsigned w=4; w<=cnt; w++) buf[base+w-1] = s[w];
    }
  }
  __syncthreads();
  int total = s_cnt;
  int bad = s_bad;

#define CONTRIB(kk) do{ float d2_=__uint_as_float((kk)&0xFFFFFFF8u); \
    if (d2_>0.f){ float w_=1.0f/sqrtf(d2_); \
      atomicAdd(&s_w[8],w_); atomicAdd(&s_w[(kk)&7u],w_); } }while(0)

  unsigned T; int Krem=KNN;
  if (!bad && total>=KNN && total<=CAP){
    for (int i=tid;i<2048;i+=256) hist[i]=0;
    __syncthreads();
    for (int i=tid;i<total;i+=256) atomicAdd(&hist[buf[i]>>21],1);
    __syncthreads();
    find_bin(hist,part,2048,Krem,tid,&sB,&sLob);
    unsigned pre=(unsigned)sB; Krem-=sLob;
    for (int i=tid;i<2048;i+=256) hist[i]=0;
    __syncthreads();
    for (int i=tid;i<total;i+=256){ unsigned k=buf[i]; if ((k>>21)==pre) atomicAdd(&hist[(k>>10)&0x7FFu],1); }
    __syncthreads();
    find_bin(hist,part,2048,Krem,tid,&sB,&sLob);
    pre=(pre<<11)|(unsigned)sB; Krem-=sLob;
    for (int i=tid;i<1024;i+=256) hist[i]=0;
    __syncthreads();
    for (int i=tid;i<total;i+=256){ unsigned k=buf[i]; if ((k>>10)==pre) atomicAdd(&hist[k&0x3FFu],1); }
    __syncthreads();
    find_bin(hist,part,1024,Krem,tid,&sB,&sLob);
    T=(pre<<10)|(unsigned)sB; Krem-=sLob;
    __syncthreads();
    for (int i=tid;i<total;i+=256){ unsigned k=buf[i]; if (k<T) CONTRIB(k); }
  } else {
    // fallback (P ~ 1e-10): exact fp32 full recompute select
    if (tid==0) s_cnt=0;
    for (int i=tid;i<dp;i+=256) qrow[i]=Qm[(size_t)q*dp+i];
    __syncthreads();
    float qq=qn[q];
    auto KEY=[&](int t)->unsigned{
      const float* br=&Tm[(size_t)t*dp];
      float dot=0.f;
      for (int k2=0;k2<dp;k2++) dot+=qrow[k2]*br[k2];
      float d2=fmaxf(qq-2.f*dot+tn[t],0.f);
      return (__float_as_uint(d2)&0xFFFFFFF8u)|(unsigned)labels[t];
    };
    for (int i=tid;i<2048;i+=256) hist[i]=0;
    __syncthreads();
    for (int t=tid;t<NT;t+=256) atomicAdd(&hist[KEY(t)>>21],1);
    __syncthreads();
    find_bin(hist,part,2048,Krem,tid,&sB,&sLob);
    int c=hist[sB]; Krem-=sLob;
    unsigned prefix=(unsigned)sB; int shift=21;
    if (c > CAP){
      __syncthreads();
      for (int i=tid;i<2048;i+=256) hist[i]=0;
      __syncthreads();
      for (int t=tid;t<NT;t+=256){ unsigned k=KEY(t); if ((k>>21)==prefix) atomicAdd(&hist[(k>>10)&0x7FFu],1); }
      __syncthreads();
      find_bin(hist,part,2048,Krem,tid,&sB,&sLob);
      c=hist[sB]; Krem-=sLob; prefix=(prefix<<11)|(unsigned)sB; shift=10;
    }
    if (c > CAP){
      __syncthreads();
      for (int i=tid;i<1024;i+=256) hist[i]=0;
      __syncthreads();
      for (int t=tid;t<NT;t+=256){ unsigned k=KEY(t); if ((k>>10)==prefix) atomicAdd(&hist[k&0x3FFu],1); }
      __syncthreads();
      find_bin(hist,part,1024,Krem,tid,&sB,&sLob);
      c=hist[sB]; Krem-=sLob; prefix=(prefix<<10)|(unsigned)sB; shift=0;
    }
    if (c <= CAP){
      for (int t=tid;t<NT;t+=256){
        unsigned k=KEY(t); unsigned pp=k>>shift;
        if (pp==prefix){ int j=atomicAdd(&s_cnt,1); if (j<CAP) buf[j]=k; }
        else if (pp<prefix){ int j=atomicAdd(&s_low,1); if (j<96) lowbuf[j]=k; }
      }
      __syncthreads();
      int sh=shift;
      while (sh>0){
        int nsh=(sh==21)?10:0;
        int nb=1<<(sh-nsh);
        __syncthreads();
        for (int i=tid;i<nb;i+=256) hist[i]=0;
        __syncthreads();
        int cc=s_cnt;
        for (int i=tid;i<cc;i+=256) atomicAdd(&hist[(buf[i]>>nsh)&(unsigned)(nb-1)],1);
        __syncthreads();
        find_bin(hist,part,nb,Krem,tid,&sB,&sLob);
        Krem-=sLob; prefix=(prefix<<(sh-nsh))|(unsigned)sB; sh=nsh;
      }
      T=prefix;
      __syncthreads();
      int lowc=s_low, cc=s_cnt;
      for (int i=tid;i<lowc;i+=256){ unsigned k=lowbuf[i]; CONTRIB(k); }
      for (int i=tid;i<cc;i+=256){ unsigned k=buf[i]; if (k<T) CONTRIB(k); }
    } else {
      T=prefix;
      for (int t=tid;t<NT;t+=256){ unsigned k=KEY(t); if (k<T) CONTRIB(k); }
    }
  }
  __syncthreads();
  if (tid==0){
    float d2=__uint_as_float(T&0xFFFFFFF8u);
    float w=(d2>0.f)?(1.0f/sqrtf(d2)):0.f;
    s_w[8] += (float)Krem*w;
    s_w[T&7u] += (float)Krem*w;
  }
  __syncthreads();
  if (tid<8){
    float contrib = s_w[8]-s_w[tid];
    size_t o=(size_t)q*NL+tid;
    tot[o] = first ? contrib : tot[o]+contrib;
  }
#undef CONTRIB
}

// ---------------- empirical p-values ------------------------------------------
__global__ void pvalue_k(const float* __restrict__ tot, const float* __restrict__ cali,
                         float* __restrict__ out){
  __shared__ float t8[NL];
  __shared__ int part[4][NL];
  int tid=threadIdx.x, q=blockIdx.x;
  if (tid<NL) t8[tid]=tot[(size_t)q*NL+tid];
  __syncthreads();
  float th[NL];
  #pragma unroll
  for (int c=0;c<NL;c++) th[c]=t8[c];
  int cnt[NL];
  #pragma unroll
  for (int c=0;c<NL;c++) cnt[c]=0;
  for (int i=tid;i<NCALI;i+=256){
    float v=cali[i];
    #pragma unroll
    for (int c=0;c<NL;c++) cnt[c] += (v>=th[c]) ? 1 : 0;
  }
  #pragma unroll
  for (int c=0;c<NL;c++){
    #pragma unroll
    for (int off=32;off>0;off>>=1) cnt[c]+=__shfl_down(cnt[c],off,64);
  }
  if ((tid&63)==0){
    #pragma unroll
    for (int c=0;c<NL;c++) part[tid>>6][c]=cnt[c];
  }
  __syncthreads();
  if (tid<NL){
    int s=part[0][tid]+part[1][tid]+part[2][tid]+part[3][tid];
    out[(size_t)q*NL+tid] = (float)s / 10000.f;
  }
}

// ---------------- one kNN layer (templated on KCH = dp/32) --------------------
template<int KCH>
static void knn_layer(const float* Qm, const float* Bank, float* qnl, int first,
                      const int* lbl, float* tnb,
                      unsigned short* qH, unsigned short* qL,
                      unsigned short* bankH, unsigned short* bankL,
                      unsigned* skeys, unsigned* sT, unsigned* slab,
                      float* tot, hipStream_t stream){
  constexpr int dp = KCH*32;
  conv_norm_k<<<(NT+NB)/4,256,0,stream>>>(Bank, bankH, bankL, tnb, NT,
                                          Qm, qH, qL, qnl, NB, dp);
  dist_sub_k<KCH><<<8*NSB,256,0,stream>>>(qH,qL,bankH,bankL,qnl,tnb,lbl,skeys);
  sel64_k<<<NB,256,0,stream>>>(skeys,sT);
  dist_mfma_k<KCH><<<8*8*49,256,0,stream>>>(qH,qL,bankH,bankL,qnl,tnb,lbl,sT,slab);
  final_k<<<NB,256,0,stream>>>(slab,Qm,Bank,qnl,tnb,lbl,tot,first,dp);
}

extern "C" void kernel_launch(void* const* d_in, const int* in_sizes, int n_in,
                              void* d_out, int out_size, void* d_ws, size_t ws_size,
                              hipStream_t stream) {
  const float* x   = (const float*)d_in[0];
  const float* txr = (const float*)d_in[1];
  const int*   lbl = (const int*)  d_in[2];
  const float* cal = (const float*)d_in[3];
  const float* W1  = (const float*)d_in[4];
  const float* b1  = (const float*)d_in[5];
  const float* W2  = (const float*)d_in[6];
  const float* b2  = (const float*)d_in[7];
  const float* W3  = (const float*)d_in[8];
  const float* b3  = (const float*)d_in[9];
  const float* W4  = (const float*)d_in[10];
  const float* b4  = (const float*)d_in[11];
  float* out = (float*)d_out;
  float* ws  = (float*)d_ws;

  size_t off=0;
  float* xq0=ws+off; off+=(size_t)NB*96;
  float* xq1=ws+off; off+=(size_t)NB*128;
  float* xq2=ws+off; off+=(size_t)NB*128;
  float* xq3=ws+off; off+=(size_t)NB*128;
  float* xq4=ws+off; off+=(size_t)NB*32;
  float* tbA=ws+off; off+=(size_t)NT*128;
  float* tbB=ws+off; off+=(size_t)NT*128;
  float* tb4=ws+off; off+=(size_t)NT*32;
  float* qnb=ws+off; off+=(size_t)5*NB;
  float* tnb=ws+off; off+=(size_t)NT;
  float* tot=ws+off; off+=(size_t)NB*NL;
  unsigned* sT=(unsigned*)(ws+off); off+=NB;
  unsigned short* qH=(unsigned short*)(ws+off); off+=(size_t)NB*64;
  unsigned short* qL=(unsigned short*)(ws+off); off+=(size_t)NB*64;
  unsigned short* bankH=(unsigned short*)(ws+off); off+=(size_t)NT_PAD*64;
  unsigned short* bankL=(unsigned short*)(ws+off); off+=(size_t)NT_PAD*64;
  unsigned short* wt1H=(unsigned short*)(ws+off); off+=(size_t)128*48;
  unsigned short* wt1L=(unsigned short*)(ws+off); off+=(size_t)128*48;
  unsigned short* wt2H=(unsigned short*)(ws+off); off+=(size_t)128*64;
  unsigned short* wt2L=(unsigned short*)(ws+off); off+=(size_t)128*64;
  unsigned short* wt3H=(unsigned short*)(ws+off); off+=(size_t)128*64;
  unsigned short* wt3L=(unsigned short*)(ws+off); off+=(size_t)128*64;
  off=(off+3)&~(size_t)3;
  unsigned* slab=(unsigned*)(ws+off);   // NB*NTB*SLOTS = 25.6 MB
  unsigned* skeys=(unsigned*)(ws+off);  // NB*NSUB     =  8.4 MB (aliased; skeys
                                        // dead before dist_mfma_k writes slab)
  { size_t slab_sz=(size_t)NB*NTB*SLOTS, skey_sz=(size_t)NB*NSUB;
    off += (slab_sz > skey_sz ? slab_sz : skey_sz); }

  // query features; layer-0 features at stride 96; weight splits (Wt^T hi/lo)
  pad_copy_k<<<(NB*96+255)/256,256,0,stream>>>(x, xq0, NB, 83, 96);
  pad_copy_k<<<((size_t)NT*96+255)/256,256,0,stream>>>(txr, tbA, NT, 83, 96);
  wsplit_k<<<(128*96+255)/256,256,0,stream>>>(W1, 83, 96, wt1H, wt1L);
  wsplit_k<<<(128*128+255)/256,256,0,stream>>>(W2, 128, 128, wt2H, wt2L);
  wsplit_k<<<(128*128+255)/256,256,0,stream>>>(W3, 128, 128, wt3H, wt3L);
  mlp_gemm_k<<<(NB+127)/128,256,0,stream>>>(xq0,96,3,W1,83,b1,xq1,NB);
  mlp_gemm_k<<<(NB+127)/128,256,0,stream>>>(xq1,128,4,W2,128,b2,xq2,NB);
  mlp_gemm_k<<<(NB+127)/128,256,0,stream>>>(xq2,128,4,W3,128,b3,xq3,NB);
  mlp8_k<<<(NB+31)/32,256,0,stream>>>(xq3,W4,b4,xq4,NB);
  softmax_k<<<(NB+255)/256,256,0,stream>>>(xq4,NB);

  // Bank MLPs use split-bf16 MFMA: bankH/bankL (split of the CURRENT bank,
  // produced by this layer's conv_norm) @ Wt^T. grid=NTB covers 50048 rows.
  knn_layer<3>(xq0, tbA, qnb+0*NB, 1, lbl, tnb, qH,qL,bankH,bankL, skeys,sT,slab, tot, stream);
  mlp_mfma_k<3><<<NTB,256,0,stream>>>(bankH,bankL,wt1H,wt1L,b1,tbB,NT);
  knn_layer<4>(xq1, tbB, qnb+1*NB, 0, lbl, tnb, qH,qL,bankH,bankL, skeys,sT,slab, tot, stream);
  mlp_mfma_k<4><<<NTB,256,0,stream>>>(bankH,bankL,wt2H,wt2L,b2,tbA,NT);
  knn_layer<4>(xq2, tbA, qnb+2*NB, 0, lbl, tnb, qH,qL,bankH,bankL, skeys,sT,slab, tot, stream);
  mlp_mfma_k<4><<<NTB,256,0,stream>>>(bankH,bankL,wt3H,wt3L,b3,tbB,NT);
  knn_layer<4>(xq3, tbB, qnb+3*NB, 0, lbl, tnb, qH,qL,bankH,bankL, skeys,sT,slab, tot, stream);
  mlp8_k<<<(NT+31)/32,256,0,stream>>>(tbB,W4,b4,tb4,NT);
  softmax_k<<<(NT+255)/256,256,0,stream>>>(tb4,NT);
  knn_layer<1>(xq4, tb4, qnb+4*NB, 0, lbl, tnb, qH,qL,bankH,bankL, skeys,sT,slab, tot, stream);

  pvalue_k<<<NB,256,0,stream>>>(tot,cal,out);
}

// Round 10
// 760.248 us; speedup vs baseline: 2.2319x; 1.0117x over previous
//
#include <hip/hip_runtime.h>
#include <math.h>

#define KNN 75
#define NL 8
#define NB 1024
#define NT 50000
#define NT_PAD 50048  // NTB*TT rows allocated for bf16 banks (pad rows masked)
#define NCALI 10000
#define KC 32
#define TT 128
#define NTB 391       // ceil(NT/TT)
#define SLOTS 16      // per (q, t-block) slab: [count, up to 15 hit keys] = 64B
#define CAP 6144      // candidate buffer per query
#define NSUB 2048     // sampled train points for threshold
#define NSB 16        // NSUB/TT subset t-blocks
#define SSTRIDE 24
#define SOFF 11       // 11 + 24*2047 = 49139 < 50000
#define RSEL 32       // sample rank -> expected |{k < T}| ~ 780, lambda/slab ~ 2

typedef __attribute__((ext_vector_type(8))) short bf16x8;
typedef __attribute__((ext_vector_type(4))) float f32x4;

__device__ __forceinline__ int swz(int c){ return c + ((c>>5)<<2); }

__device__ __forceinline__ unsigned short f2bf_rn(float x){
  unsigned u = __float_as_uint(x);
  unsigned r = (u + 0x7FFFu + ((u>>16)&1u)) >> 16;
  return (unsigned short)r;
}
__device__ __forceinline__ float bf2f(unsigned short h){
  return __uint_as_float(((unsigned)h)<<16);
}
__device__ __forceinline__ bf16x8 ld8(const unsigned short* p){
  return *(const bf16x8*)p;
}
// async global->LDS, 16B per lane; LDS dest = wave-uniform base + lane*16
__device__ __forceinline__ void gl_lds16(const unsigned short* g, unsigned short* l){
  __builtin_amdgcn_global_load_lds(
      (const __attribute__((address_space(1))) void*)g,
      (__attribute__((address_space(3))) void*)l, 16, 0, 0);
}

// ---------------- pad copy (zero-fill pad cols every call: ws is poisoned) ----
__global__ void pad_copy_k(const float* __restrict__ in, float* __restrict__ out,
                           int M, int Din, int Dout){
  int idx = blockIdx.x*256 + threadIdx.x;
  if (idx >= M*Dout) return;
  int r = idx / Dout, c = idx - r*Dout;
  out[idx] = (c < Din) ? in[r*Din + c] : 0.f;
}

// ---------------- weight transpose + bf16 hi/lo split: Wt[n][k] --------------
__global__ void wsplit_k(const float* __restrict__ W, int kreal, int dp,
                         unsigned short* __restrict__ WtH,
                         unsigned short* __restrict__ WtL){
  int idx = blockIdx.x*256 + threadIdx.x;
  if (idx >= 128*dp) return;
  int n = idx / dp, k = idx - n*dp;
  float v = (k < kreal) ? W[(size_t)k*128 + n] : 0.f;
  unsigned short h = f2bf_rn(v);
  WtH[idx] = h;
  WtL[idx] = f2bf_rn(v - bf2f(h));
}

// ---------------- MLP GEMM (fp32, query path only: M=1024, cheap) ------------
__global__ __launch_bounds__(256) void mlp_gemm_k(
    const float* __restrict__ A, int lda, int kchunks,
    const float* __restrict__ W, int kreal,
    const float* __restrict__ bias,
    float* __restrict__ Out, int M)
{
  __shared__ float As[KC][132];
  __shared__ float Bs[KC][148];
  int tid = threadIdx.x;
  int r0 = (tid>>4)*8, c0 = (tid&15)*8;
  int rowBase = blockIdx.x*128;
  float acc[8][8];
  #pragma unroll
  for (int i=0;i<8;i++)
    #pragma unroll
    for (int j=0;j<8;j++) acc[i][j]=0.f;

  for (int kc=0;kc<kchunks;kc++){
    { int rr = tid>>3, k4=(tid&7)*4;
      #pragma unroll
      for (int i=0;i<4;i++){
        int row = rr + i*32, gr = rowBase + row;
        float4 v = make_float4(0.f,0.f,0.f,0.f);
        if (gr < M) v = *(const float4*)&A[(size_t)gr*lda + kc*KC + k4];
        As[k4+0][row]=v.x; As[k4+1][row]=v.y; As[k4+2][row]=v.z; As[k4+3][row]=v.w;
      }
    }
    { int kk=tid>>5, c4=(tid&31)*4;
      #pragma unroll
      for (int i=0;i<4;i++){
        int k = kk + i*8, gk = kc*KC + k;
        float4 v = make_float4(0.f,0.f,0.f,0.f);
        if (gk < kreal) v = *(const float4*)&W[(size_t)gk*128 + c4];
        *(float4*)&Bs[k][swz(c4)] = v;
      }
    }
    __syncthreads();
    #pragma unroll 4
    for (int k=0;k<KC;k++){
      float4 a0 = *(const float4*)&As[k][r0];
      float4 a1 = *(const float4*)&As[k][r0+4];
      float4 b0 = *(const float4*)&Bs[k][swz(c0)];
      float4 b1 = *(const float4*)&Bs[k][swz(c0+4)];
      float av[8] = {a0.x,a0.y,a0.z,a0.w,a1.x,a1.y,a1.z,a1.w};
      float bv[8] = {b0.x,b0.y,b0.z,b0.w,b1.x,b1.y,b1.z,b1.w};
      #pragma unroll
      for (int i=0;i<8;i++)
        #pragma unroll
        for (int j=0;j<8;j++) acc[i][j] += av[i]*bv[j];
    }
    __syncthreads();
  }
  float bb[8];
  #pragma unroll
  for (int j=0;j<8;j++) bb[j]=bias[c0+j];
  #pragma unroll
  for (int i=0;i<8;i++){
    int gr = rowBase + r0 + i;
    if (gr < M){
      float o[8];
      #pragma unroll
      for (int j=0;j<8;j++){ float v=acc[i][j]+bb[j]; o[j]=v>0.f?v:0.f; }
      *(float4*)&Out[(size_t)gr*128 + c0]   = make_float4(o[0],o[1],o[2],o[3]);
      *(float4*)&Out[(size_t)gr*128 + c0+4] = make_float4(o[4],o[5],o[6],o[7]);
    }
  }
}

// ---------------- last layer: logits[M][8] into stride-32 rows ----------------
__global__ void mlp8_k(const float* __restrict__ A, const float* __restrict__ W4,
                       const float* __restrict__ b4, float* __restrict__ Out, int M){
  __shared__ float Ws[128*8];
  int tid = threadIdx.x;
  for (int i=tid;i<1024;i+=256) Ws[i]=W4[i];
  __syncthreads();
  int r = blockIdx.x*32 + (tid>>3), c = tid&7;
  if (r >= M) return;
  const float* a = &A[(size_t)r*128];
  float acc = b4[c];
  #pragma unroll 16
  for (int k=0;k<128;k++) acc += a[k]*Ws[k*8+c];
  Out[(size_t)r*32 + c] = acc;
}

// ---------------- softmax over 8 logits, zero cols 8..31 ----------------------
__global__ void softmax_k(float* __restrict__ X, int M){
  int r = blockIdx.x*256 + threadIdx.x;
  if (r >= M) return;
  float* p = &X[(size_t)r*32];
  float v[8], m=-1e30f;
  #pragma unroll
  for (int j=0;j<8;j++){ v[j]=p[j]; m = v[j]>m ? v[j] : m; }
  float s=0.f;
  #pragma unroll
  for (int j=0;j<8;j++){ v[j]=__expf(v[j]-m); s+=v[j]; }
  float inv=1.f/s;
  #pragma unroll
  for (int j=0;j<8;j++) p[j]=v[j]*inv;
  #pragma unroll
  for (int j=8;j<32;j++) p[j]=0.f;
}

// ---- fp32 -> (hi,lo) bf16 split + row squared-norms, bank+queries fused ------
__global__ void conv_norm_k(
    const float* __restrict__ XA, unsigned short* __restrict__ HA,
    unsigned short* __restrict__ LA, float* __restrict__ nA, int MA,
    const float* __restrict__ XB, unsigned short* __restrict__ HB,
    unsigned short* __restrict__ LB, float* __restrict__ nB, int MB,
    int dp)
{
  int w = threadIdx.x>>6, lane = threadIdx.x&63;
  int row = blockIdx.x*4 + w;
  const float* src; unsigned short* dh; unsigned short* dl; float* nrm;
  if (row < MA){
    src=&XA[(size_t)row*dp]; dh=&HA[(size_t)row*dp]; dl=&LA[(size_t)row*dp]; nrm=&nA[row];
  } else {
    int r2 = row - MA;
    if (r2 >= MB) return;
    src=&XB[(size_t)r2*dp]; dh=&HB[(size_t)r2*dp]; dl=&LB[(size_t)r2*dp]; nrm=&nB[r2];
  }
  float s=0.f;
  for (int c=lane*2; c<dp; c+=128){
    float2 v = *(const float2*)&src[c];
    s += v.x*v.x + v.y*v.y;
    unsigned short h0 = f2bf_rn(v.x), h1 = f2bf_rn(v.y);
    float r0 = v.x - bf2f(h0), r1 = v.y - bf2f(h1);
    ushort2 hh; hh.x=h0; hh.y=h1;
    ushort2 ll; ll.x=f2bf_rn(r0); ll.y=f2bf_rn(r1);
    *(ushort2*)&dh[c]=hh;
    *(ushort2*)&dl[c]=ll;
  }
  #pragma unroll
  for (int off=32;off>0;off>>=1) s += __shfl_down(s, off, 64);
  if (lane==0) *nrm=s;
}

// ---------------- scan helper: find bin containing rank Krem ------------------
// Wave-level shfl_up inclusive scan over per-thread chunk sums; unique winner
// thread does the <=8-iter chunk walk.
__device__ __forceinline__ void find_bin(int* hist, int* part, int nb, int Krem,
                                         int tid, int* s_B, int* s_lob){
  int ch = nb>>8;
  int base = tid*ch;
  int s=0;
  for (int b=base;b<base+ch;b++) s+=hist[b];
  int lane = tid & 63, wv = tid>>6;
  int v = s;
  #pragma unroll
  for (int off=1; off<64; off<<=1){
    int u = __shfl_up(v, off, 64);
    if (lane >= off) v += u;
  }
  if (lane==63) part[wv] = v;
  __syncthreads();
  int wbase = 0;
  #pragma unroll
  for (int w2=0; w2<4; w2++) wbase += (w2 < wv) ? part[w2] : 0;
  v += wbase;
  int excl = v - s;
  if (v >= Krem && excl < Krem){
    int lob = excl, B = base + ch - 1;
    for (int b=base;b<base+ch;b++){
      if (lob + hist[b] >= Krem){ B=b; break; }
      lob += hist[b];
    }
    *s_B = B; *s_lob = lob;
  }
  if (tid==255 && v < Krem){ *s_B = nb-1; *s_lob = 0; }  // preserve old default
  __syncthreads();
}

// ---------------- per-query threshold: exact RSEL-th smallest sample key ------
__global__ __launch_bounds__(256) void sel64_k(const unsigned* __restrict__ skeys,
                                               unsigned* __restrict__ Tthr){
  __shared__ unsigned buf[NSUB];
  __shared__ int hist[2048];
  __shared__ int part[256];
  __shared__ int sB, sLob;
  int tid=threadIdx.x, q=blockIdx.x;
  for (int i=tid;i<NSUB;i+=256) buf[i]=skeys[(size_t)q*NSUB+i];
  int Krem=RSEL;
  for (int i=tid;i<2048;i+=256) hist[i]=0;
  __syncthreads();
  for (int i=tid;i<NSUB;i+=256) atomicAdd(&hist[buf[i]>>21],1);
  __syncthreads();
  find_bin(hist,part,2048,Krem,tid,&sB,&sLob);
  unsigned pre=(unsigned)sB; Krem-=sLob;
  for (int i=tid;i<2048;i+=256) hist[i]=0;
  __syncthreads();
  for (int i=tid;i<NSUB;i+=256){ unsigned k=buf[i]; if ((k>>21)==pre) atomicAdd(&hist[(k>>10)&0x7FFu],1); }
  __syncthreads();
  find_bin(hist,part,2048,Krem,tid,&sB,&sLob);
  pre=(pre<<11)|(unsigned)sB; Krem-=sLob;
  for (int i=tid;i<1024;i+=256) hist[i]=0;
  __syncthreads();
  for (int i=tid;i<NSUB;i+=256){ unsigned k=buf[i]; if ((k>>10)==pre) atomicAdd(&hist[k&0x3FFu],1); }
  __syncthreads();
  find_bin(hist,part,1024,Krem,tid,&sB,&sLob);
  if (tid==0) Tthr[q]=(pre<<10)|(unsigned)sB;
}

// ====== MFMA section: one 64x128 sub-tile x one K-chunk from LDS ==============
// r9 restructure: each wave owns 16 q-rows (was 32) -> acc[8] (32 regs, was
// 64) + half the A-fragments. Register footprint ~148 -> ~85/wave was the
// occupancy cap (r8: LDS cut to 32KB left Occupancy pinned at 27% -> register
// file, not LDS, limits waves/SIMD to 3). Target 5 waves/SIMD.
#define MFMA_SEC(BHC, BLC, AH, AL)                                               \
  _Pragma("unroll")                                                              \
  for (int tj=0;tj<8;tj++){                                                      \
    int rowB = tj*16 + col;                                                      \
    int sw = (((quad + (rowB>>1)) & 3) << 3);                                    \
    bf16x8 bh = *(const bf16x8*)&(BHC)[rowB*32 + sw];                            \
    bf16x8 bl = *(const bf16x8*)&(BLC)[rowB*32 + sw];                            \
    acc[tj] = __builtin_amdgcn_mfma_f32_16x16x32_bf16(AH, bh, acc[tj], 0,0,0);   \
    acc[tj] = __builtin_amdgcn_mfma_f32_16x16x32_bf16(AH, bl, acc[tj], 0,0,0);   \
    acc[tj] = __builtin_amdgcn_mfma_f32_16x16x32_bf16(AL, bh, acc[tj], 0,0,0);   \
  }

// K-loop body (2-deep double-buffer). Requires BH0/BH1/BL0/BL1 ushort* LDS
// pointers in scope. kchunks is constexpr -> fully unrolled. Wave w covers
// q-rows [qbase + w*16, +16); B tile = 128 t-rows (staged by all 4 waves).
#define MFMA_KLOOP(ROWMAP)                                                       \
  size_t aoff = (size_t)(qbase + w*16 + col)*dp + quad*8;                        \
  const unsigned short* pAH = QH + aoff;                                         \
  const unsigned short* pAL = QL + aoff;                                         \
  int i0 = tid,      row0 = i0>>2, sg0 = ((i0&3) - (row0>>1)) & 3;               \
  int i1 = tid+256,  row1 = i1>>2, sg1 = ((i1&3) - (row1>>1)) & 3;               \
  size_t g0 = (size_t)(ROWMAP(n0+row0))*dp + (size_t)sg0*8;                      \
  size_t g1 = (size_t)(ROWMAP(n0+row1))*dp + (size_t)sg1*8;                      \
  f32x4 acc[8];                                                                  \
  _Pragma("unroll")                                                              \
  for (int tj=0;tj<8;tj++){ f32x4 z={0.f,0.f,0.f,0.f}; acc[tj]=z; }              \
  gl_lds16(TH + g0, BH0 + i0*8);                                                 \
  gl_lds16(TH + g1, BH0 + i1*8);                                                 \
  gl_lds16(TL + g0, BL0 + i0*8);                                                 \
  gl_lds16(TL + g1, BL0 + i1*8);                                                 \
  bf16x8 xh = ld8(pAH), xl = ld8(pAL);                                           \
  bf16x8 yh = xh, yl = xl;                                                       \
  _Pragma("unroll")                                                              \
  for (int kc=0; kc<kchunks; kc+=2){                                             \
    __syncthreads();                                                             \
    if (kc+1 < kchunks){                                                         \
      size_t ko=(size_t)(kc+1)*32;                                               \
      gl_lds16(TH + g0 + ko, BH1 + i0*8);                                        \
      gl_lds16(TH + g1 + ko, BH1 + i1*8);                                        \
      gl_lds16(TL + g0 + ko, BL1 + i0*8);                                        \
      gl_lds16(TL + g1 + ko, BL1 + i1*8);                                        \
      yh = ld8(pAH + ko); yl = ld8(pAL + ko);                                    \
    }                                                                            \
    MFMA_SEC(BH0, BL0, xh, xl);                                                  \
    if (kc+1 < kchunks){                                                         \
      __syncthreads();                                                           \
      if (kc+2 < kchunks){                                                       \
        size_t ko=(size_t)(kc+2)*32;                                             \
        gl_lds16(TH + g0 + ko, BH0 + i0*8);                                      \
        gl_lds16(TH + g1 + ko, BH0 + i1*8);                                      \
        gl_lds16(TL + g0 + ko, BL0 + i0*8);                                      \
        gl_lds16(TL + g1 + ko, BL0 + i1*8);                                      \
        xh = ld8(pAH + ko); xl = ld8(pAL + ko);                                  \
      }                                                                          \
      MFMA_SEC(BH1, BL1, yh, yl);                                                \
    }                                                                            \
  }

#define ROW_ID(r) (r)
#define ROW_SUB(r) ((r)*SSTRIDE + SOFF)

// ---------------- MFMA split-bf16 distance GEMM vs full bank ------------------
// Block = 64q x 128t; grid 8 xcd x 16 qb x 49 tslot = 6272. LDS = one 32 KB
// arena; epilogue aliases hitbuf[64]/hcnt onto the dead K-buffers.
template<int KCH>
__global__ __launch_bounds__(256) void dist_mfma_k(
    const unsigned short* __restrict__ QH, const unsigned short* __restrict__ QL,
    const unsigned short* __restrict__ TH, const unsigned short* __restrict__ TL,
    const float* __restrict__ qn, const float* __restrict__ tn,
    const int* __restrict__ labels, const unsigned* __restrict__ Tthr,
    unsigned* __restrict__ slab)
{
  constexpr int dp = KCH*32;
  __shared__ __align__(16) unsigned short smem[4*4096];   // 32 KB
  unsigned short* BH0 = smem;
  unsigned short* BH1 = smem + 4096;
  unsigned short* BL0 = smem + 8192;
  unsigned short* BL1 = smem + 12288;
  unsigned (*hitbuf)[SLOTS] = (unsigned (*)[SLOTS])smem;  // aliases BH0 (4 KB)
  int* hcnt = (int*)(smem + 4096);                        // aliases BH1 head
  int b = blockIdx.x;
  int xcd = b & 7, s = b >> 3;
  int qb = s & 15, tslot = s >> 4;
  int t_blk = xcd + 8*tslot;
  if (t_blk >= NTB) return;
  int tid = threadIdx.x, w = tid>>6, lane = tid&63;
  int quad = lane>>4, col = lane&15;
  int qbase = qb*64;
  int n0 = t_blk*TT;
  constexpr int kchunks = KCH;

  MFMA_KLOOP(ROW_ID)

  // epilogue: barrier FIRST (K-loop LDS reads must complete before aliasing)
  __syncthreads();
  if (tid<64) hcnt[tid]=0;
  __syncthreads();
  float qnr[4]; unsigned Tq[4]; float thrF[4];
  #pragma unroll
  for (int r=0;r<4;r++){
    int q = qbase + w*16 + quad*4 + r;
    qnr[r]  = qn[q];
    Tq[r]   = Tthr[q];
    thrF[r] = __uint_as_float(Tq[r] | 7u);  // superset boundary
  }
  #pragma unroll
  for (int tj=0;tj<8;tj++){
    int t = n0 + tj*16 + col;
    if (t < NT){
      float tnv = tn[t];
      unsigned lab = (unsigned)labels[t];
      #pragma unroll
      for (int r=0;r<4;r++){
        float d2 = fmaf(-2.f, acc[tj][r], qnr[r] + tnv);
        if (d2 <= thrF[r]){
          float d2c = fmaxf(d2, 0.f);
          unsigned key = (__float_as_uint(d2c)&0xFFFFFFF8u) | lab;
          if (key < Tq[r]){
            int ql = w*16 + quad*4 + r;
            int idx = atomicAdd(&hcnt[ql], 1);
            if (idx < SLOTS-1) hitbuf[ql][1+idx] = key;
          }
        }
      }
    }
  }
  __syncthreads();
  if (tid<64) hitbuf[tid][0]=(unsigned)hcnt[tid];
  __syncthreads();
  // slab[q][t_blk]: final_k reads each query's 391 slabs contiguously
  {
    int q = tid>>2, sub = (tid&3)*4;
    uint4 v = *(uint4*)&hitbuf[q][sub];
    *(uint4*)&slab[((size_t)(qbase+q)*NTB + t_blk)*SLOTS + sub] = v;
  }
}

// ---------------- MFMA split-bf16 distance GEMM vs SAMPLED subset -------------
// Block = 64q x 128t; grid 16 qb x NSB = 256 blocks (was 128: half-idle GPU).
template<int KCH>
__global__ __launch_bounds__(256) void dist_sub_k(
    const unsigned short* __restrict__ QH, const unsigned short* __restrict__ QL,
    const unsigned short* __restrict__ TH, const unsigned short* __restrict__ TL,
    const float* __restrict__ qn, const float* __restrict__ tn,
    const int* __restrict__ labels, unsigned* __restrict__ keys)
{
  constexpr int dp = KCH*32;
  __shared__ __align__(16) unsigned short smem[4*4096];   // 32 KB
  unsigned short* BH0 = smem;
  unsigned short* BH1 = smem + 4096;
  unsigned short* BL0 = smem + 8192;
  unsigned short* BL1 = smem + 12288;
  int b = blockIdx.x;
  int qb = b & 15, t_blk = b >> 4;           // t_blk in [0, NSB)
  int tid = threadIdx.x, w = tid>>6, lane = tid&63;
  int quad = lane>>4, col = lane&15;
  int qbase = qb*64;
  int n0 = t_blk*TT;                         // subset-space row base
  constexpr int kchunks = KCH;

  MFMA_KLOOP(ROW_SUB)

  // epilogue: write all keys; 16-lane quad -> 64B contiguous store per (tj,r)
  float qnr[4];
  #pragma unroll
  for (int r=0;r<4;r++)
    qnr[r] = qn[qbase + w*16 + quad*4 + r];
  #pragma unroll
  for (int tj=0;tj<8;tj++){
    int sI = n0 + tj*16 + col;
    int g  = sI*SSTRIDE + SOFF;
    float tnv = tn[g];
    unsigned lab = (unsigned)labels[g];
    #pragma unroll
    for (int r=0;r<4;r++){
      float d2 = fmaxf(fmaf(-2.f, acc[tj][r], qnr[r] + tnv), 0.f);
      unsigned key = (__float_as_uint(d2)&0xFFFFFFF8u) | lab;
      int q = qbase + w*16 + quad*4 + r;
      keys[(size_t)q*NSUB + sI] = key;
    }
  }
}

// ---------------- MFMA split-bf16 bank MLP: Out = relu(A @ Wt^T + b) ----------
// A = bankH/bankL (already split by conv_norm); B = Wt hi/lo [128][dp] (L2-hot).
// Block = 64 rows; grid 2*NTB = 782 covers NT_PAD rows.
template<int KCH>
__global__ __launch_bounds__(256) void mlp_mfma_k(
    const unsigned short* __restrict__ QH, const unsigned short* __restrict__ QL,
    const unsigned short* __restrict__ TH, const unsigned short* __restrict__ TL,
    const float* __restrict__ bias, float* __restrict__ Out, int M)
{
  constexpr int dp = KCH*32;
  __shared__ __align__(16) unsigned short smem[4*4096];   // 32 KB
  unsigned short* BH0 = smem;
  unsigned short* BH1 = smem + 4096;
  unsigned short* BL0 = smem + 8192;
  unsigned short* BL1 = smem + 12288;
  int tid = threadIdx.x, w = tid>>6, lane = tid&63;
  int quad = lane>>4, col = lane&15;
  int qbase = blockIdx.x*64;                 // bank-row base
  int n0 = 0;                                // Wt rows 0..127
  constexpr int kchunks = KCH;

  MFMA_KLOOP(ROW_ID)

  // epilogue: bias + relu + fp32 store; 16-lane groups write 64B runs
  float bb[8];
  #pragma unroll
  for (int tj=0;tj<8;tj++) bb[tj] = bias[tj*16 + col];
  #pragma unroll
  for (int r=0;r<4;r++){
    int row = qbase + w*16 + quad*4 + r;
    if (row < M){
      #pragma unroll
      for (int tj=0;tj<8;tj++){
        float v = acc[tj][r] + bb[tj];
        Out[(size_t)row*128 + tj*16 + col] = v > 0.f ? v : 0.f;
      }
    }
  }
}

// ---------------- gather slabs, exact radix select + class sums ---------------
__global__ __launch_bounds__(256) void final_k(
    const unsigned* __restrict__ slab,
    const float* __restrict__ Qm, const float* __restrict__ Tm,
    const float* __restrict__ qn, const float* __restrict__ tn,
    const int* __restrict__ labels,
    float* __restrict__ tot, int first, int dp)
{
  __shared__ int hist[2048];
  __shared__ int part[256];
  __shared__ unsigned buf[CAP];
  __shared__ unsigned lowbuf[96];
  __shared__ float qrow[128];
  __shared__ int sB,sLob,s_cnt,s_low,s_bad;
  __shared__ float s_w[9];
  int tid=threadIdx.x, q=blockIdx.x;
  if (tid==0){ for (int j=0;j<9;j++) s_w[j]=0.f; s_cnt=0; s_low=0; s_bad=0; }
  __syncthreads();

  // [q][t_blk] layout: query q's slabs are ONE contiguous 25KB run
  const unsigned* sq = slab + (size_t)q*NTB*SLOTS;
  for (int sidx=tid; sidx<NTB; sidx+=256){
    const unsigned* s = sq + (size_t)sidx*SLOTS;
    uint4 a = *(const uint4*)s;
    unsigned cnt = a.x;
    if (cnt > SLOTS-1){ s_bad=1; continue; }
    if (!cnt) continue;
    int base = atomicAdd(&s_cnt, (int)cnt);
    if (base + (int)cnt <= CAP){
      buf[base] = a.y;
      if (cnt>=2) buf[base+1] = a.z;
      if (cnt>=3) buf[base+2] = a.w;
      for (unsigned w=4; w<=cnt; w++) buf[base+w-1] = s[w];
    }
  }
  __syncthreads();
  int total = s_cnt;
  int bad = s_bad;

#define CONTRIB(kk) do{ float d2_=__uint_as_float((kk)&0xFFFFFFF8u); \
    if (d2_>0.f){ float w_=1.0f/sqrtf(d2_); \
      atomicAdd(&s_w[8],w_); atomicAdd(&s_w[(kk)&7u],w_); } }while(0)

  unsigned T; int Krem=KNN;
  if (!bad && total>=KNN && total<=CAP){
    for (int i=tid;i<2048;i+=256) hist[i]=0;
    __syncthreads();
    for (int i=tid;i<total;i+=256) atomicAdd(&hist[buf[i]>>21],1);
    __syncthreads();
    find_bin(hist,part,2048,Krem,tid,&sB,&sLob);
    unsigned pre=(unsigned)sB; Krem-=sLob;
    for (int i=tid;i<2048;i+=256) hist[i]=0;
    __syncthreads();
    for (int i=tid;i<total;i+=256){ unsigned k=buf[i]; if ((k>>21)==pre) atomicAdd(&hist[(k>>10)&0x7FFu],1); }
    __syncthreads();
    find_bin(hist,part,2048,Krem,tid,&sB,&sLob);
    pre=(pre<<11)|(unsigned)sB; Krem-=sLob;
    for (int i=tid;i<1024;i+=256) hist[i]=0;
    __syncthreads();
    for (int i=tid;i<total;i+=256){ unsigned k=buf[i]; if ((k>>10)==pre) atomicAdd(&hist[k&0x3FFu],1); }
    __syncthreads();
    find_bin(hist,part,1024,Krem,tid,&sB,&sLob);
    T=(pre<<10)|(unsigned)sB; Krem-=sLob;
    __syncthreads();
    for (int i=tid;i<total;i+=256){ unsigned k=buf[i]; if (k<T) CONTRIB(k); }
  } else {
    // fallback (P ~ 1e-10): exact fp32 full recompute select
    if (tid==0) s_cnt=0;
    for (int i=tid;i<dp;i+=256) qrow[i]=Qm[(size_t)q*dp+i];
    __syncthreads();
    float qq=qn[q];
    auto KEY=[&](int t)->unsigned{
      const float* br=&Tm[(size_t)t*dp];
      float dot=0.f;
      for (int k2=0;k2<dp;k2++) dot+=qrow[k2]*br[k2];
      float d2=fmaxf(qq-2.f*dot+tn[t],0.f);
      return (__float_as_uint(d2)&0xFFFFFFF8u)|(unsigned)labels[t];
    };
    for (int i=tid;i<2048;i+=256) hist[i]=0;
    __syncthreads();
    for (int t=tid;t<NT;t+=256) atomicAdd(&hist[KEY(t)>>21],1);
    __syncthreads();
    find_bin(hist,part,2048,Krem,tid,&sB,&sLob);
    int c=hist[sB]; Krem-=sLob;
    unsigned prefix=(unsigned)sB; int shift=21;
    if (c > CAP){
      __syncthreads();
      for (int i=tid;i<2048;i+=256) hist[i]=0;
      __syncthreads();
      for (int t=tid;t<NT;t+=256){ unsigned k=KEY(t); if ((k>>21)==prefix) atomicAdd(&hist[(k>>10)&0x7FFu],1); }
      __syncthreads();
      find_bin(hist,part,2048,Krem,tid,&sB,&sLob);
      c=hist[sB]; Krem-=sLob; prefix=(prefix<<11)|(unsigned)sB; shift=10;
    }
    if (c > CAP){
      __syncthreads();
      for (int i=tid;i<1024;i+=256) hist[i]=0;
      __syncthreads();
      for (int t=tid;t<NT;t+=256){ unsigned k=KEY(t); if ((k>>10)==prefix) atomicAdd(&hist[k&0x3FFu],1); }
      __syncthreads();
      find_bin(hist,part,1024,Krem,tid,&sB,&sLob);
      c=hist[sB]; Krem-=sLob; prefix=(prefix<<10)|(unsigned)sB; shift=0;
    }
    if (c <= CAP){
      for (int t=tid;t<NT;t+=256){
        unsigned k=KEY(t); unsigned pp=k>>shift;
        if (pp==prefix){ int j=atomicAdd(&s_cnt,1); if (j<CAP) buf[j]=k; }
        else if (pp<prefix){ int j=atomicAdd(&s_low,1); if (j<96) lowbuf[j]=k; }
      }
      __syncthreads();
      int sh=shift;
      while (sh>0){
        int nsh=(sh==21)?10:0;
        int nb=1<<(sh-nsh);
        __syncthreads();
        for (int i=tid;i<nb;i+=256) hist[i]=0;
        __syncthreads();
        int cc=s_cnt;
        for (int i=tid;i<cc;i+=256) atomicAdd(&hist[(buf[i]>>nsh)&(unsigned)(nb-1)],1);
        __syncthreads();
        find_bin(hist,part,nb,Krem,tid,&sB,&sLob);
        Krem-=sLob; prefix=(prefix<<(sh-nsh))|(unsigned)sB; sh=nsh;
      }
      T=prefix;
      __syncthreads();
      int lowc=s_low, cc=s_cnt;
      for (int i=tid;i<lowc;i+=256){ unsigned k=lowbuf[i]; CONTRIB(k); }
      for (int i=tid;i<cc;i+=256){ unsigned k=buf[i]; if (k<T) CONTRIB(k); }
    } else {
      T=prefix;
      for (int t=tid;t<NT;t+=256){ unsigned k=KEY(t); if (k<T) CONTRIB(k); }
    }
  }
  __syncthreads();
  if (tid==0){
    float d2=__uint_as_float(T&0xFFFFFFF8u);
    float w=(d2>0.f)?(1.0f/sqrtf(d2)):0.f;
    s_w[8] += (float)Krem*w;
    s_w[T&7u] += (float)Krem*w;
  }
  __syncthreads();
  if (tid<8){
    float contrib = s_w[8]-s_w[tid];
    size_t o=(size_t)q*NL+tid;
    tot[o] = first ? contrib : tot[o]+contrib;
  }
#undef CONTRIB
}

// ---------------- empirical p-values ------------------------------------------
__global__ void pvalue_k(const float* __restrict__ tot, const float* __restrict__ cali,
                         float* __restrict__ out){
  __shared__ float t8[NL];
  __shared__ int part[4][NL];
  int tid=threadIdx.x, q=blockIdx.x;
  if (tid<NL) t8[tid]=tot[(size_t)q*NL+tid];
  __syncthreads();
  float th[NL];
  #pragma unroll
  for (int c=0;c<NL;c++) th[c]=t8[c];
  int cnt[NL];
  #pragma unroll
  for (int c=0;c<NL;c++) cnt[c]=0;
  for (int i=tid;i<NCALI;i+=256){
    float v=cali[i];
    #pragma unroll
    for (int c=0;c<NL;c++) cnt[c] += (v>=th[c]) ? 1 : 0;
  }
  #pragma unroll
  for (int c=0;c<NL;c++){
    #pragma unroll
    for (int off=32;off>0;off>>=1) cnt[c]+=__shfl_down(cnt[c],off,64);
  }
  if ((tid&63)==0){
    #pragma unroll
    for (int c=0;c<NL;c++) part[tid>>6][c]=cnt[c];
  }
  __syncthreads();
  if (tid<NL){
    int s=part[0][tid]+part[1][tid]+part[2][tid]+part[3][tid];
    out[(size_t)q*NL+tid] = (float)s / 10000.f;
  }
}

// ---------------- one kNN layer (templated on KCH = dp/32) --------------------
template<int KCH>
static void knn_layer(const float* Qm, const float* Bank, float* qnl, int first,
                      const int* lbl, float* tnb,
                      unsigned short* qH, unsigned short* qL,
                      unsigned short* bankH, unsigned short* bankL,
                      unsigned* skeys, unsigned* sT, unsigned* slab,
                      float* tot, hipStream_t stream){
  constexpr int dp = KCH*32;
  conv_norm_k<<<(NT+NB)/4,256,0,stream>>>(Bank, bankH, bankL, tnb, NT,
                                          Qm, qH, qL, qnl, NB, dp);
  dist_sub_k<KCH><<<16*NSB,256,0,stream>>>(qH,qL,bankH,bankL,qnl,tnb,lbl,skeys);
  sel64_k<<<NB,256,0,stream>>>(skeys,sT);
  dist_mfma_k<KCH><<<8*16*49,256,0,stream>>>(qH,qL,bankH,bankL,qnl,tnb,lbl,sT,slab);
  final_k<<<NB,256,0,stream>>>(slab,Qm,Bank,qnl,tnb,lbl,tot,first,dp);
}

extern "C" void kernel_launch(void* const* d_in, const int* in_sizes, int n_in,
                              void* d_out, int out_size, void* d_ws, size_t ws_size,
                              hipStream_t stream) {
  const float* x   = (const float*)d_in[0];
  const float* txr = (const float*)d_in[1];
  const int*   lbl = (const int*)  d_in[2];
  const float* cal = (const float*)d_in[3];
  const float* W1  = (const float*)d_in[4];
  const float* b1  = (const float*)d_in[5];
  const float* W2  = (const float*)d_in[6];
  const float* b2  = (const float*)d_in[7];
  const float* W3  = (const float*)d_in[8];
  const float* b3  = (const float*)d_in[9];
  const float* W4  = (const float*)d_in[10];
  const float* b4  = (const float*)d_in[11];
  float* out = (float*)d_out;
  float* ws  = (float*)d_ws;

  size_t off=0;
  float* xq0=ws+off; off+=(size_t)NB*96;
  float* xq1=ws+off; off+=(size_t)NB*128;
  float* xq2=ws+off; off+=(size_t)NB*128;
  float* xq3=ws+off; off+=(size_t)NB*128;
  float* xq4=ws+off; off+=(size_t)NB*32;
  float* tbA=ws+off; off+=(size_t)NT*128;
  float* tbB=ws+off; off+=(size_t)NT*128;
  float* tb4=ws+off; off+=(size_t)NT*32;
  float* qnb=ws+off; off+=(size_t)5*NB;
  float* tnb=ws+off; off+=(size_t)NT;
  float* tot=ws+off; off+=(size_t)NB*NL;
  unsigned* sT=(unsigned*)(ws+off); off+=NB;
  unsigned short* qH=(unsigned short*)(ws+off); off+=(size_t)NB*64;
  unsigned short* qL=(unsigned short*)(ws+off); off+=(size_t)NB*64;
  unsigned short* bankH=(unsigned short*)(ws+off); off+=(size_t)NT_PAD*64;
  unsigned short* bankL=(unsigned short*)(ws+off); off+=(size_t)NT_PAD*64;
  unsigned short* wt1H=(unsigned short*)(ws+off); off+=(size_t)128*48;
  unsigned short* wt1L=(unsigned short*)(ws+off); off+=(size_t)128*48;
  unsigned short* wt2H=(unsigned short*)(ws+off); off+=(size_t)128*64;
  unsigned short* wt2L=(unsigned short*)(ws+off); off+=(size_t)128*64;
  unsigned short* wt3H=(unsigned short*)(ws+off); off+=(size_t)128*64;
  unsigned short* wt3L=(unsigned short*)(ws+off); off+=(size_t)128*64;
  off=(off+3)&~(size_t)3;
  unsigned* slab=(unsigned*)(ws+off);   // NB*NTB*SLOTS = 25.6 MB
  unsigned* skeys=(unsigned*)(ws+off);  // NB*NSUB     =  8.4 MB (aliased; skeys
                                        // dead before dist_mfma_k writes slab)
  { size_t slab_sz=(size_t)NB*NTB*SLOTS, skey_sz=(size_t)NB*NSUB;
    off += (slab_sz > skey_sz ? slab_sz : skey_sz); }

  // query features; layer-0 features at stride 96; weight splits (Wt^T hi/lo)
  pad_copy_k<<<(NB*96+255)/256,256,0,stream>>>(x, xq0, NB, 83, 96);
  pad_copy_k<<<((size_t)NT*96+255)/256,256,0,stream>>>(txr, tbA, NT, 83, 96);
  wsplit_k<<<(128*96+255)/256,256,0,stream>>>(W1, 83, 96, wt1H, wt1L);
  wsplit_k<<<(128*128+255)/256,256,0,stream>>>(W2, 128, 128, wt2H, wt2L);
  wsplit_k<<<(128*128+255)/256,256,0,stream>>>(W3, 128, 128, wt3H, wt3L);
  mlp_gemm_k<<<(NB+127)/128,256,0,stream>>>(xq0,96,3,W1,83,b1,xq1,NB);
  mlp_gemm_k<<<(NB+127)/128,256,0,stream>>>(xq1,128,4,W2,128,b2,xq2,NB);
  mlp_gemm_k<<<(NB+127)/128,256,0,stream>>>(xq2,128,4,W3,128,b3,xq3,NB);
  mlp8_k<<<(NB+31)/32,256,0,stream>>>(xq3,W4,b4,xq4,NB);
  softmax_k<<<(NB+255)/256,256,0,stream>>>(xq4,NB);

  // Bank MLPs use split-bf16 MFMA: bankH/bankL (split of the CURRENT bank,
  // produced by this layer's conv_norm) @ Wt^T. grid=2*NTB covers 50048 rows.
  knn_layer<3>(xq0, tbA, qnb+0*NB, 1, lbl, tnb, qH,qL,bankH,bankL, skeys,sT,slab, tot, stream);
  mlp_mfma_k<3><<<2*NTB,256,0,stream>>>(bankH,bankL,wt1H,wt1L,b1,tbB,NT);
  knn_layer<4>(xq1, tbB, qnb+1*NB, 0, lbl, tnb, qH,qL,bankH,bankL, skeys,sT,slab, tot, stream);
  mlp_mfma_k<4><<<2*NTB,256,0,stream>>>(bankH,bankL,wt2H,wt2L,b2,tbA,NT);
  knn_layer<4>(xq2, tbA, qnb+2*NB, 0, lbl, tnb, qH,qL,bankH,bankL, skeys,sT,slab, tot, stream);
  mlp_mfma_k<4><<<2*NTB,256,0,stream>>>(bankH,bankL,wt3H,wt3L,b3,tbB,NT);
  knn_layer<4>(xq3, tbB, qnb+3*NB, 0, lbl, tnb, qH,qL,bankH,bankL, skeys,sT,slab, tot, stream);
  mlp8_k<<<(NT+31)/32,256,0,stream>>>(tbB,W4,b4,tb4,NT);
  softmax_k<<<(NT+255)/256,256,0,stream>>>(tb4,NT);
  knn_layer<1>(xq4, tb4, qnb+4*NB, 0, lbl, tnb, qH,qL,bankH,bankL, skeys,sT,slab, tot, stream);

  pvalue_k<<<NB,256,0,stream>>>(tot,cal,out);
}

// Round 11
// 727.747 us; speedup vs baseline: 2.3316x; 1.0447x over previous
//
#include <hip/hip_runtime.h>
#include <math.h>

#define KNN 75
#define NL 8
#define NB 1024
#define NT 50000
#define NT_PAD 50048  // NTB*TT rows allocated for bf16 banks (pad rows masked)
#define NCALI 10000
#define KC 32
#define TT 128
#define NTB 391       // ceil(NT/TT)
#define SLOTS 16      // per (q, t-block) slab: [count, up to 15 hit keys] = 64B
#define CAP 6144      // candidate buffer per query
#define NSUB 2048     // sampled train points for threshold
#define NSB 16        // NSUB/TT subset t-blocks
#define SSTRIDE 24
#define SOFF 11       // 11 + 24*2047 = 49139 < 50000
#define RSEL 32       // sample rank -> expected |{k < T}| ~ 780, lambda/slab ~ 2

// prep_k block ranges
#define PB_Q    384                   // NB*96/256
#define PB_BANK 18750                 // NT*96/256
#define PB_W1   48                    // 128*96/256
#define PB_W23  64                    // 128*128/256
#define PREP_BLOCKS (PB_Q+PB_BANK+PB_W1+2*PB_W23)

typedef __attribute__((ext_vector_type(8))) short bf16x8;
typedef __attribute__((ext_vector_type(4))) float f32x4;

__device__ __forceinline__ int swz(int c){ return c + ((c>>5)<<2); }

__device__ __forceinline__ unsigned short f2bf_rn(float x){
  unsigned u = __float_as_uint(x);
  unsigned r = (u + 0x7FFFu + ((u>>16)&1u)) >> 16;
  return (unsigned short)r;
}
__device__ __forceinline__ float bf2f(unsigned short h){
  return __uint_as_float(((unsigned)h)<<16);
}
__device__ __forceinline__ bf16x8 ld8(const unsigned short* p){
  return *(const bf16x8*)p;
}
// async global->LDS, 16B per lane; LDS dest = wave-uniform base + lane*16
__device__ __forceinline__ void gl_lds16(const unsigned short* g, unsigned short* l){
  __builtin_amdgcn_global_load_lds(
      (const __attribute__((address_space(1))) void*)g,
      (__attribute__((address_space(3))) void*)l, 16, 0, 0);
}

// ---------------- fused prologue: pad copies + weight splits ------------------
__device__ __forceinline__ void pad_one(const float* __restrict__ in,
                                        float* __restrict__ out, int M,
                                        int Din, int Dout, int idx){
  if (idx >= M*Dout) return;
  int r = idx / Dout, c = idx - r*Dout;
  out[idx] = (c < Din) ? in[r*Din + c] : 0.f;
}
__device__ __forceinline__ void wsplit_one(const float* __restrict__ W, int kreal,
                                           int dp, unsigned short* __restrict__ WtH,
                                           unsigned short* __restrict__ WtL, int idx){
  int n = idx / dp, k = idx - n*dp;
  float v = (k < kreal) ? W[(size_t)k*128 + n] : 0.f;
  unsigned short h = f2bf_rn(v);
  WtH[idx] = h;
  WtL[idx] = f2bf_rn(v - bf2f(h));
}
__global__ void prep_k(const float* __restrict__ x, float* __restrict__ xq0,
                       const float* __restrict__ txr, float* __restrict__ tbA,
                       const float* __restrict__ W1, unsigned short* wt1H, unsigned short* wt1L,
                       const float* __restrict__ W2, unsigned short* wt2H, unsigned short* wt2L,
                       const float* __restrict__ W3, unsigned short* wt3H, unsigned short* wt3L){
  int b = blockIdx.x, tid = threadIdx.x;
  if (b < PB_Q){
    pad_one(x, xq0, NB, 83, 96, b*256 + tid);
  } else if (b < PB_Q + PB_BANK){
    pad_one(txr, tbA, NT, 83, 96, (b-PB_Q)*256 + tid);
  } else if (b < PB_Q + PB_BANK + PB_W1){
    wsplit_one(W1, 83, 96,  wt1H, wt1L, (b-PB_Q-PB_BANK)*256 + tid);
  } else if (b < PB_Q + PB_BANK + PB_W1 + PB_W23){
    wsplit_one(W2, 128, 128, wt2H, wt2L, (b-PB_Q-PB_BANK-PB_W1)*256 + tid);
  } else {
    wsplit_one(W3, 128, 128, wt3H, wt3L, (b-PB_Q-PB_BANK-PB_W1-PB_W23)*256 + tid);
  }
}

// ---------------- fused query MLP: 3 relu layers + logits + softmax -----------
// 8 blocks x 128 queries. h-state lives in LDS (H[128][132]); per-layer weight
// staging identical to the old mlp_gemm_k; all FP accumulation orders preserved
// bitwise vs the old per-layer kernels. Replaces 5 launches.
__device__ __forceinline__ void qmlp_layer(
    const float* __restrict__ srcG, int lda,   // srcG!=null: layer-0 global read
    float (*H)[132], float (*As)[132], float (*Bs)[148],
    int kchunks, int kreal,
    const float* __restrict__ W, const float* __restrict__ bias,
    float* __restrict__ OutG, int rowBase, int tid)
{
  int r0 = (tid>>4)*8, c0 = (tid&15)*8;
  float acc[8][8];
  #pragma unroll
  for (int i=0;i<8;i++)
    #pragma unroll
    for (int j=0;j<8;j++) acc[i][j]=0.f;

  for (int kc=0;kc<kchunks;kc++){
    { int rr = tid>>3, k4=(tid&7)*4;
      #pragma unroll
      for (int i=0;i<4;i++){
        int row = rr + i*32;
        float4 v;
        if (srcG) v = *(const float4*)&srcG[(size_t)(rowBase+row)*lda + kc*KC + k4];
        else      v = *(const float4*)&H[row][kc*KC + k4];
        As[k4+0][row]=v.x; As[k4+1][row]=v.y; As[k4+2][row]=v.z; As[k4+3][row]=v.w;
      }
    }
    { int kk=tid>>5, c4=(tid&31)*4;
      #pragma unroll
      for (int i=0;i<4;i++){
        int k = kk + i*8, gk = kc*KC + k;
        float4 v = make_float4(0.f,0.f,0.f,0.f);
        if (gk < kreal) v = *(const float4*)&W[(size_t)gk*128 + c4];
        *(float4*)&Bs[k][swz(c4)] = v;
      }
    }
    __syncthreads();
    #pragma unroll 4
    for (int k=0;k<KC;k++){
      float4 a0 = *(const float4*)&As[k][r0];
      float4 a1 = *(const float4*)&As[k][r0+4];
      float4 b0 = *(const float4*)&Bs[k][swz(c0)];
      float4 b1 = *(const float4*)&Bs[k][swz(c0+4)];
      float av[8] = {a0.x,a0.y,a0.z,a0.w,a1.x,a1.y,a1.z,a1.w};
      float bv[8] = {b0.x,b0.y,b0.z,b0.w,b1.x,b1.y,b1.z,b1.w};
      #pragma unroll
      for (int i=0;i<8;i++)
        #pragma unroll
        for (int j=0;j<8;j++) acc[i][j] += av[i]*bv[j];
    }
    __syncthreads();
  }
  float bb[8];
  #pragma unroll
  for (int j=0;j<8;j++) bb[j]=bias[c0+j];
  #pragma unroll
  for (int i=0;i<8;i++){
    int row = r0 + i;
    float o[8];
    #pragma unroll
    for (int j=0;j<8;j++){ float v=acc[i][j]+bb[j]; o[j]=v>0.f?v:0.f; }
    *(float4*)&H[row][c0]   = make_float4(o[0],o[1],o[2],o[3]);
    *(float4*)&H[row][c0+4] = make_float4(o[4],o[5],o[6],o[7]);
    *(float4*)&OutG[(size_t)(rowBase+row)*128 + c0]   = make_float4(o[0],o[1],o[2],o[3]);
    *(float4*)&OutG[(size_t)(rowBase+row)*128 + c0+4] = make_float4(o[4],o[5],o[6],o[7]);
  }
  __syncthreads();   // H writes visible before next layer stages from H
}

__global__ __launch_bounds__(256) void qmlp_k(
    const float* __restrict__ xq0,
    const float* __restrict__ W1, const float* __restrict__ b1,
    const float* __restrict__ W2, const float* __restrict__ b2,
    const float* __restrict__ W3, const float* __restrict__ b3,
    const float* __restrict__ W4, const float* __restrict__ b4,
    float* __restrict__ xq1, float* __restrict__ xq2, float* __restrict__ xq3,
    float* __restrict__ xq4)
{
  __shared__ float As[KC][132];
  __shared__ float Bs[KC][148];
  __shared__ float H[128][132];
  int tid = threadIdx.x;
  int rowBase = blockIdx.x*128;

  qmlp_layer(xq0, 96, H, As, Bs, 3, 83,  W1, b1, xq1, rowBase, tid);
  qmlp_layer(nullptr, 0, H, As, Bs, 4, 128, W2, b2, xq2, rowBase, tid);
  qmlp_layer(nullptr, 0, H, As, Bs, 4, 128, W3, b3, xq3, rowBase, tid);

  // logits + softmax (one thread per query row; old mlp8_k/softmax_k order)
  float* W4s = (float*)Bs;
  for (int i=tid;i<1024;i+=256) W4s[i]=W4[i];
  __syncthreads();
  if (tid < 128){
    int row = rowBase + tid;
    float v[8];
    #pragma unroll
    for (int c=0;c<8;c++) v[c]=b4[c];
    for (int k=0;k<128;k++){
      float a = H[tid][k];
      #pragma unroll
      for (int c=0;c<8;c++) v[c] += a*W4s[k*8+c];
    }
    float m=-1e30f;
    #pragma unroll
    for (int c=0;c<8;c++) m = v[c]>m ? v[c] : m;
    float s=0.f;
    #pragma unroll
    for (int c=0;c<8;c++){ v[c]=__expf(v[c]-m); s+=v[c]; }
    float inv=1.f/s;
    float* p = &xq4[(size_t)row*32];
    #pragma unroll
    for (int c=0;c<8;c++) p[c]=v[c]*inv;
    #pragma unroll
    for (int j=8;j<32;j++) p[j]=0.f;
  }
}

// ---------------- bank logits + softmax fused (stride-32 rows) ----------------
// Softmax replicated per-lane in the OLD index order (bitwise identical).
__global__ void mlp8sm_k(const float* __restrict__ A, const float* __restrict__ W4,
                         const float* __restrict__ b4, float* __restrict__ Out, int M){
  __shared__ float Ws[128*8];
  int tid = threadIdx.x;
  for (int i=tid;i<1024;i+=256) Ws[i]=W4[i];
  __syncthreads();
  int r = blockIdx.x*32 + (tid>>3), c = tid&7;
  if (r >= M) return;
  const float* a = &A[(size_t)r*128];
  float acc = b4[c];
  #pragma unroll 16
  for (int k=0;k<128;k++) acc += a[k]*Ws[k*8+c];
  int lane = tid & 63, base = lane & ~7;
  float v[8];
  #pragma unroll
  for (int j=0;j<8;j++) v[j] = __shfl(acc, base+j, 64);
  float m=-1e30f;
  #pragma unroll
  for (int j=0;j<8;j++) m = v[j]>m ? v[j] : m;
  float s=0.f;
  #pragma unroll
  for (int j=0;j<8;j++){ v[j]=__expf(v[j]-m); s+=v[j]; }
  float inv=1.f/s;
  float* p = &Out[(size_t)r*32];
  p[c]    = v[c]*inv;
  p[8+c]  = 0.f;
  p[16+c] = 0.f;
  p[24+c] = 0.f;
}

// ---- fp32 -> (hi,lo) bf16 split + row squared-norms, bank+queries fused ------
__global__ void conv_norm_k(
    const float* __restrict__ XA, unsigned short* __restrict__ HA,
    unsigned short* __restrict__ LA, float* __restrict__ nA, int MA,
    const float* __restrict__ XB, unsigned short* __restrict__ HB,
    unsigned short* __restrict__ LB, float* __restrict__ nB, int MB,
    int dp)
{
  int w = threadIdx.x>>6, lane = threadIdx.x&63;
  int row = blockIdx.x*4 + w;
  const float* src; unsigned short* dh; unsigned short* dl; float* nrm;
  if (row < MA){
    src=&XA[(size_t)row*dp]; dh=&HA[(size_t)row*dp]; dl=&LA[(size_t)row*dp]; nrm=&nA[row];
  } else {
    int r2 = row - MA;
    if (r2 >= MB) return;
    src=&XB[(size_t)r2*dp]; dh=&HB[(size_t)r2*dp]; dl=&LB[(size_t)r2*dp]; nrm=&nB[r2];
  }
  float s=0.f;
  for (int c=lane*2; c<dp; c+=128){
    float2 v = *(const float2*)&src[c];
    s += v.x*v.x + v.y*v.y;
    unsigned short h0 = f2bf_rn(v.x), h1 = f2bf_rn(v.y);
    float r0 = v.x - bf2f(h0), r1 = v.y - bf2f(h1);
    ushort2 hh; hh.x=h0; hh.y=h1;
    ushort2 ll; ll.x=f2bf_rn(r0); ll.y=f2bf_rn(r1);
    *(ushort2*)&dh[c]=hh;
    *(ushort2*)&dl[c]=ll;
  }
  #pragma unroll
  for (int off=32;off>0;off>>=1) s += __shfl_down(s, off, 64);
  if (lane==0) *nrm=s;
}

// ---------------- scan helper: find bin containing rank Krem ------------------
__device__ __forceinline__ void find_bin(int* hist, int* part, int nb, int Krem,
                                         int tid, int* s_B, int* s_lob){
  int ch = nb>>8;
  int base = tid*ch;
  int s=0;
  for (int b=base;b<base+ch;b++) s+=hist[b];
  int lane = tid & 63, wv = tid>>6;
  int v = s;
  #pragma unroll
  for (int off=1; off<64; off<<=1){
    int u = __shfl_up(v, off, 64);
    if (lane >= off) v += u;
  }
  if (lane==63) part[wv] = v;
  __syncthreads();
  int wbase = 0;
  #pragma unroll
  for (int w2=0; w2<4; w2++) wbase += (w2 < wv) ? part[w2] : 0;
  v += wbase;
  int excl = v - s;
  if (v >= Krem && excl < Krem){
    int lob = excl, B = base + ch - 1;
    for (int b=base;b<base+ch;b++){
      if (lob + hist[b] >= Krem){ B=b; break; }
      lob += hist[b];
    }
    *s_B = B; *s_lob = lob;
  }
  if (tid==255 && v < Krem){ *s_B = nb-1; *s_lob = 0; }  // preserve old default
  __syncthreads();
}

// ---------------- per-query threshold: exact RSEL-th smallest sample key ------
__global__ __launch_bounds__(256) void sel64_k(const unsigned* __restrict__ skeys,
                                               unsigned* __restrict__ Tthr){
  __shared__ unsigned buf[NSUB];
  __shared__ int hist[2048];
  __shared__ int part[256];
  __shared__ int sB, sLob;
  int tid=threadIdx.x, q=blockIdx.x;
  for (int i=tid;i<NSUB;i+=256) buf[i]=skeys[(size_t)q*NSUB+i];
  int Krem=RSEL;
  for (int i=tid;i<2048;i+=256) hist[i]=0;
  __syncthreads();
  for (int i=tid;i<NSUB;i+=256) atomicAdd(&hist[buf[i]>>21],1);
  __syncthreads();
  find_bin(hist,part,2048,Krem,tid,&sB,&sLob);
  unsigned pre=(unsigned)sB; Krem-=sLob;
  for (int i=tid;i<2048;i+=256) hist[i]=0;
  __syncthreads();
  for (int i=tid;i<NSUB;i+=256){ unsigned k=buf[i]; if ((k>>21)==pre) atomicAdd(&hist[(k>>10)&0x7FFu],1); }
  __syncthreads();
  find_bin(hist,part,2048,Krem,tid,&sB,&sLob);
  pre=(pre<<11)|(unsigned)sB; Krem-=sLob;
  for (int i=tid;i<1024;i+=256) hist[i]=0;
  __syncthreads();
  for (int i=tid;i<NSUB;i+=256){ unsigned k=buf[i]; if ((k>>10)==pre) atomicAdd(&hist[k&0x3FFu],1); }
  __syncthreads();
  find_bin(hist,part,1024,Krem,tid,&sB,&sLob);
  if (tid==0) Tthr[q]=(pre<<10)|(unsigned)sB;
}

// ====== MFMA section: one 64x128 sub-tile x one K-chunk from LDS ==============
#define MFMA_SEC(BHC, BLC, AH, AL)                                               \
  _Pragma("unroll")                                                              \
  for (int tj=0;tj<8;tj++){                                                      \
    int rowB = tj*16 + col;                                                      \
    int sw = (((quad + (rowB>>1)) & 3) << 3);                                    \
    bf16x8 bh = *(const bf16x8*)&(BHC)[rowB*32 + sw];                            \
    bf16x8 bl = *(const bf16x8*)&(BLC)[rowB*32 + sw];                            \
    acc[tj] = __builtin_amdgcn_mfma_f32_16x16x32_bf16(AH, bh, acc[tj], 0,0,0);   \
    acc[tj] = __builtin_amdgcn_mfma_f32_16x16x32_bf16(AH, bl, acc[tj], 0,0,0);   \
    acc[tj] = __builtin_amdgcn_mfma_f32_16x16x32_bf16(AL, bh, acc[tj], 0,0,0);   \
  }

#define MFMA_KLOOP(ROWMAP)                                                       \
  size_t aoff = (size_t)(qbase + w*16 + col)*dp + quad*8;                        \
  const unsigned short* pAH = QH + aoff;                                         \
  const unsigned short* pAL = QL + aoff;                                         \
  int i0 = tid,      row0 = i0>>2, sg0 = ((i0&3) - (row0>>1)) & 3;               \
  int i1 = tid+256,  row1 = i1>>2, sg1 = ((i1&3) - (row1>>1)) & 3;               \
  size_t g0 = (size_t)(ROWMAP(n0+row0))*dp + (size_t)sg0*8;                      \
  size_t g1 = (size_t)(ROWMAP(n0+row1))*dp + (size_t)sg1*8;                      \
  f32x4 acc[8];                                                                  \
  _Pragma("unroll")                                                              \
  for (int tj=0;tj<8;tj++){ f32x4 z={0.f,0.f,0.f,0.f}; acc[tj]=z; }              \
  gl_lds16(TH + g0, BH0 + i0*8);                                                 \
  gl_lds16(TH + g1, BH0 + i1*8);                                                 \
  gl_lds16(TL + g0, BL0 + i0*8);                                                 \
  gl_lds16(TL + g1, BL0 + i1*8);                                                 \
  bf16x8 xh = ld8(pAH), xl = ld8(pAL);                                           \
  bf16x8 yh = xh, yl = xl;                                                       \
  _Pragma("unroll")                                                              \
  for (int kc=0; kc<kchunks; kc+=2){                                             \
    __syncthreads();                                                             \
    if (kc+1 < kchunks){                                                         \
      size_t ko=(size_t)(kc+1)*32;                                               \
      gl_lds16(TH + g0 + ko, BH1 + i0*8);                                        \
      gl_lds16(TH + g1 + ko, BH1 + i1*8);                                        \
      gl_lds16(TL + g0 + ko, BL1 + i0*8);                                        \
      gl_lds16(TL + g1 + ko, BL1 + i1*8);                                        \
      yh = ld8(pAH + ko); yl = ld8(pAL + ko);                                    \
    }                                                                            \
    MFMA_SEC(BH0, BL0, xh, xl);                                                  \
    if (kc+1 < kchunks){                                                         \
      __syncthreads();                                                           \
      if (kc+2 < kchunks){                                                       \
        size_t ko=(size_t)(kc+2)*32;                                             \
        gl_lds16(TH + g0 + ko, BH0 + i0*8);                                      \
        gl_lds16(TH + g1 + ko, BH0 + i1*8);                                      \
        gl_lds16(TL + g0 + ko, BL0 + i0*8);                                      \
        gl_lds16(TL + g1 + ko, BL0 + i1*8);                                      \
        xh = ld8(pAH + ko); xl = ld8(pAL + ko);                                  \
      }                                                                            \
      MFMA_SEC(BH1, BL1, yh, yl);                                                \
    }                                                                            \
  }

#define ROW_ID(r) (r)
#define ROW_SUB(r) ((r)*SSTRIDE + SOFF)

// ---------------- MFMA split-bf16 distance GEMM vs full bank ------------------
template<int KCH>
__global__ __launch_bounds__(256) void dist_mfma_k(
    const unsigned short* __restrict__ QH, const unsigned short* __restrict__ QL,
    const unsigned short* __restrict__ TH, const unsigned short* __restrict__ TL,
    const float* __restrict__ qn, const float* __restrict__ tn,
    const int* __restrict__ labels, const unsigned* __restrict__ Tthr,
    unsigned* __restrict__ slab)
{
  constexpr int dp = KCH*32;
  __shared__ __align__(16) unsigned short smem[4*4096];   // 32 KB
  unsigned short* BH0 = smem;
  unsigned short* BH1 = smem + 4096;
  unsigned short* BL0 = smem + 8192;
  unsigned short* BL1 = smem + 12288;
  unsigned (*hitbuf)[SLOTS] = (unsigned (*)[SLOTS])smem;  // aliases BH0 (4 KB)
  int* hcnt = (int*)(smem + 4096);                        // aliases BH1 head
  int b = blockIdx.x;
  int xcd = b & 7, s = b >> 3;
  int qb = s & 15, tslot = s >> 4;
  int t_blk = xcd + 8*tslot;
  if (t_blk >= NTB) return;
  int tid = threadIdx.x, w = tid>>6, lane = tid&63;
  int quad = lane>>4, col = lane&15;
  int qbase = qb*64;
  int n0 = t_blk*TT;
  constexpr int kchunks = KCH;

  MFMA_KLOOP(ROW_ID)

  // epilogue: barrier FIRST (K-loop LDS reads must complete before aliasing)
  __syncthreads();
  if (tid<64) hcnt[tid]=0;
  __syncthreads();
  float qnr[4]; unsigned Tq[4]; float thrF[4];
  #pragma unroll
  for (int r=0;r<4;r++){
    int q = qbase + w*16 + quad*4 + r;
    qnr[r]  = qn[q];
    Tq[r]   = Tthr[q];
    thrF[r] = __uint_as_float(Tq[r] | 7u);  // superset boundary
  }
  #pragma unroll
  for (int tj=0;tj<8;tj++){
    int t = n0 + tj*16 + col;
    if (t < NT){
      float tnv = tn[t];
      unsigned lab = (unsigned)labels[t];
      #pragma unroll
      for (int r=0;r<4;r++){
        float d2 = fmaf(-2.f, acc[tj][r], qnr[r] + tnv);
        if (d2 <= thrF[r]){
          float d2c = fmaxf(d2, 0.f);
          unsigned key = (__float_as_uint(d2c)&0xFFFFFFF8u) | lab;
          if (key < Tq[r]){
            int ql = w*16 + quad*4 + r;
            int idx = atomicAdd(&hcnt[ql], 1);
            if (idx < SLOTS-1) hitbuf[ql][1+idx] = key;
          }
        }
      }
    }
  }
  __syncthreads();
  if (tid<64) hitbuf[tid][0]=(unsigned)hcnt[tid];
  __syncthreads();
  // slab[q][t_blk]: final_k reads each query's 391 slabs contiguously
  {
    int q = tid>>2, sub = (tid&3)*4;
    uint4 v = *(uint4*)&hitbuf[q][sub];
    *(uint4*)&slab[((size_t)(qbase+q)*NTB + t_blk)*SLOTS + sub] = v;
  }
}

// ---------------- MFMA split-bf16 distance GEMM vs SAMPLED subset -------------
template<int KCH>
__global__ __launch_bounds__(256) void dist_sub_k(
    const unsigned short* __restrict__ QH, const unsigned short* __restrict__ QL,
    const unsigned short* __restrict__ TH, const unsigned short* __restrict__ TL,
    const float* __restrict__ qn, const float* __restrict__ tn,
    const int* __restrict__ labels, unsigned* __restrict__ keys)
{
  constexpr int dp = KCH*32;
  __shared__ __align__(16) unsigned short smem[4*4096];   // 32 KB
  unsigned short* BH0 = smem;
  unsigned short* BH1 = smem + 4096;
  unsigned short* BL0 = smem + 8192;
  unsigned short* BL1 = smem + 12288;
  int b = blockIdx.x;
  int qb = b & 15, t_blk = b >> 4;           // t_blk in [0, NSB)
  int tid = threadIdx.x, w = tid>>6, lane = tid&63;
  int quad = lane>>4, col = lane&15;
  int qbase = qb*64;
  int n0 = t_blk*TT;                         // subset-space row base
  constexpr int kchunks = KCH;

  MFMA_KLOOP(ROW_SUB)

  // epilogue: write all keys; 16-lane quad -> 64B contiguous store per (tj,r)
  float qnr[4];
  #pragma unroll
  for (int r=0;r<4;r++)
    qnr[r] = qn[qbase + w*16 + quad*4 + r];
  #pragma unroll
  for (int tj=0;tj<8;tj++){
    int sI = n0 + tj*16 + col;
    int g  = sI*SSTRIDE + SOFF;
    float tnv = tn[g];
    unsigned lab = (unsigned)labels[g];
    #pragma unroll
    for (int r=0;r<4;r++){
      float d2 = fmaxf(fmaf(-2.f, acc[tj][r], qnr[r] + tnv), 0.f);
      unsigned key = (__float_as_uint(d2)&0xFFFFFFF8u) | lab;
      int q = qbase + w*16 + quad*4 + r;
      keys[(size_t)q*NSUB + sI] = key;
    }
  }
}

// ---------------- MFMA split-bf16 bank MLP: Out = relu(A @ Wt^T + b) ----------
template<int KCH>
__global__ __launch_bounds__(256) void mlp_mfma_k(
    const unsigned short* __restrict__ QH, const unsigned short* __restrict__ QL,
    const unsigned short* __restrict__ TH, const unsigned short* __restrict__ TL,
    const float* __restrict__ bias, float* __restrict__ Out, int M)
{
  constexpr int dp = KCH*32;
  __shared__ __align__(16) unsigned short smem[4*4096];   // 32 KB
  unsigned short* BH0 = smem;
  unsigned short* BH1 = smem + 4096;
  unsigned short* BL0 = smem + 8192;
  unsigned short* BL1 = smem + 12288;
  int tid = threadIdx.x, w = tid>>6, lane = tid&63;
  int quad = lane>>4, col = lane&15;
  int qbase = blockIdx.x*64;                 // bank-row base
  int n0 = 0;                                // Wt rows 0..127
  constexpr int kchunks = KCH;

  MFMA_KLOOP(ROW_ID)

  // epilogue: bias + relu + fp32 store; 16-lane groups write 64B runs
  float bb[8];
  #pragma unroll
  for (int tj=0;tj<8;tj++) bb[tj] = bias[tj*16 + col];
  #pragma unroll
  for (int r=0;r<4;r++){
    int row = qbase + w*16 + quad*4 + r;
    if (row < M){
      #pragma unroll
      for (int tj=0;tj<8;tj++){
        float v = acc[tj][r] + bb[tj];
        Out[(size_t)row*128 + tj*16 + col] = v > 0.f ? v : 0.f;
      }
    }
  }
}

// ---------------- gather slabs, exact radix select + class sums ---------------
__global__ __launch_bounds__(256) void final_k(
    const unsigned* __restrict__ slab,
    const float* __restrict__ Qm, const float* __restrict__ Tm,
    const float* __restrict__ qn, const float* __restrict__ tn,
    const int* __restrict__ labels,
    float* __restrict__ tot, int first, int dp)
{
  __shared__ int hist[2048];
  __shared__ int part[256];
  __shared__ unsigned buf[CAP];
  __shared__ unsigned lowbuf[96];
  __shared__ float qrow[128];
  __shared__ int sB,sLob,s_cnt,s_low,s_bad;
  __shared__ float s_w[9];
  int tid=threadIdx.x, q=blockIdx.x;
  if (tid==0){ for (int j=0;j<9;j++) s_w[j]=0.f; s_cnt=0; s_low=0; s_bad=0; }
  __syncthreads();

  // [q][t_blk] layout: query q's slabs are ONE contiguous 25KB run
  const unsigned* sq = slab + (size_t)q*NTB*SLOTS;
  for (int sidx=tid; sidx<NTB; sidx+=256){
    const unsigned* s = sq + (size_t)sidx*SLOTS;
    uint4 a = *(const uint4*)s;
    unsigned cnt = a.x;
    if (cnt > SLOTS-1){ s_bad=1; continue; }
    if (!cnt) continue;
    int base = atomicAdd(&s_cnt, (int)cnt);
    if (base + (int)cnt <= CAP){
      buf[base] = a.y;
      if (cnt>=2) buf[base+1] = a.z;
      if (cnt>=3) buf[base+2] = a.w;
      for (unsigned w=4; w<=cnt; w++) buf[base+w-1] = s[w];
    }
  }
  __syncthreads();
  int total = s_cnt;
  int bad = s_bad;

#define CONTRIB(kk) do{ float d2_=__uint_as_float((kk)&0xFFFFFFF8u); \
    if (d2_>0.f){ float w_=1.0f/sqrtf(d2_); \
      atomicAdd(&s_w[8],w_); atomicAdd(&s_w[(kk)&7u],w_); } }while(0)

  unsigned T; int Krem=KNN;
  if (!bad && total>=KNN && total<=CAP){
    for (int i=tid;i<2048;i+=256) hist[i]=0;
    __syncthreads();
    for (int i=tid;i<total;i+=256) atomicAdd(&hist[buf[i]>>21],1);
    __syncthreads();
    find_bin(hist,part,2048,Krem,tid,&sB,&sLob);
    unsigned pre=(unsigned)sB; Krem-=sLob;
    for (int i=tid;i<2048;i+=256) hist[i]=0;
    __syncthreads();
    for (int i=tid;i<total;i+=256){ unsigned k=buf[i]; if ((k>>21)==pre) atomicAdd(&hist[(k>>10)&0x7FFu],1); }
    __syncthreads();
    find_bin(hist,part,2048,Krem,tid,&sB,&sLob);
    pre=(pre<<11)|(unsigned)sB; Krem-=sLob;
    for (int i=tid;i<1024;i+=256) hist[i]=0;
    __syncthreads();
    for (int i=tid;i<total;i+=256){ unsigned k=buf[i]; if ((k>>10)==pre) atomicAdd(&hist[k&0x3FFu],1); }
    __syncthreads();
    find_bin(hist,part,1024,Krem,tid,&sB,&sLob);
    T=(pre<<10)|(unsigned)sB; Krem-=sLob;
    __syncthreads();
    for (int i=tid;i<total;i+=256){ unsigned k=buf[i]; if (k<T) CONTRIB(k); }
  } else {
    // fallback (P ~ 1e-10): exact fp32 full recompute select
    if (tid==0) s_cnt=0;
    for (int i=tid;i<dp;i+=256) qrow[i]=Qm[(size_t)q*dp+i];
    __syncthreads();
    float qq=qn[q];
    auto KEY=[&](int t)->unsigned{
      const float* br=&Tm[(size_t)t*dp];
      float dot=0.f;
      for (int k2=0;k2<dp;k2++) dot+=qrow[k2]*br[k2];
      float d2=fmaxf(qq-2.f*dot+tn[t],0.f);
      return (__float_as_uint(d2)&0xFFFFFFF8u)|(unsigned)labels[t];
    };
    for (int i=tid;i<2048;i+=256) hist[i]=0;
    __syncthreads();
    for (int t=tid;t<NT;t+=256) atomicAdd(&hist[KEY(t)>>21],1);
    __syncthreads();
    find_bin(hist,part,2048,Krem,tid,&sB,&sLob);
    int c=hist[sB]; Krem-=sLob;
    unsigned prefix=(unsigned)sB; int shift=21;
    if (c > CAP){
      __syncthreads();
      for (int i=tid;i<2048;i+=256) hist[i]=0;
      __syncthreads();
      for (int t=tid;t<NT;t+=256){ unsigned k=KEY(t); if ((k>>21)==prefix) atomicAdd(&hist[(k>>10)&0x7FFu],1); }
      __syncthreads();
      find_bin(hist,part,2048,Krem,tid,&sB,&sLob);
      c=hist[sB]; Krem-=sLob; prefix=(prefix<<11)|(unsigned)sB; shift=10;
    }
    if (c > CAP){
      __syncthreads();
      for (int i=tid;i<1024;i+=256) hist[i]=0;
      __syncthreads();
      for (int t=tid;t<NT;t+=256){ unsigned k=KEY(t); if ((k>>10)==prefix) atomicAdd(&hist[k&0x3FFu],1); }
      __syncthreads();
      find_bin(hist,part,1024,Krem,tid,&sB,&sLob);
      c=hist[sB]; Krem-=sLob; prefix=(prefix<<10)|(unsigned)sB; shift=0;
    }
    if (c <= CAP){
      for (int t=tid;t<NT;t+=256){
        unsigned k=KEY(t); unsigned pp=k>>shift;
        if (pp==prefix){ int j=atomicAdd(&s_cnt,1); if (j<CAP) buf[j]=k; }
        else if (pp<prefix){ int j=atomicAdd(&s_low,1); if (j<96) lowbuf[j]=k; }
      }
      __syncthreads();
      int sh=shift;
      while (sh>0){
        int nsh=(sh==21)?10:0;
        int nb=1<<(sh-nsh);
        __syncthreads();
        for (int i=tid;i<nb;i+=256) hist[i]=0;
        __syncthreads();
        int cc=s_cnt;
        for (int i=tid;i<cc;i+=256) atomicAdd(&hist[(buf[i]>>nsh)&(unsigned)(nb-1)],1);
        __syncthreads();
        find_bin(hist,part,nb,Krem,tid,&sB,&sLob);
        Krem-=sLob; prefix=(prefix<<(sh-nsh))|(unsigned)sB; sh=nsh;
      }
      T=prefix;
      __syncthreads();
      int lowc=s_low, cc=s_cnt;
      for (int i=tid;i<lowc;i+=256){ unsigned k=lowbuf[i]; CONTRIB(k); }
      for (int i=tid;i<cc;i+=256){ unsigned k=buf[i]; if (k<T) CONTRIB(k); }
    } else {
      T=prefix;
      for (int t=tid;t<NT;t+=256){ unsigned k=KEY(t); if (k<T) CONTRIB(k); }
    }
  }
  __syncthreads();
  if (tid==0){
    float d2=__uint_as_float(T&0xFFFFFFF8u);
    float w=(d2>0.f)?(1.0f/sqrtf(d2)):0.f;
    s_w[8] += (float)Krem*w;
    s_w[T&7u] += (float)Krem*w;
  }
  __syncthreads();
  if (tid<8){
    float contrib = s_w[8]-s_w[tid];
    size_t o=(size_t)q*NL+tid;
    tot[o] = first ? contrib : tot[o]+contrib;
  }
#undef CONTRIB
}

// ---------------- empirical p-values ------------------------------------------
__global__ void pvalue_k(const float* __restrict__ tot, const float* __restrict__ cali,
                         float* __restrict__ out){
  __shared__ float t8[NL];
  __shared__ int part[4][NL];
  int tid=threadIdx.x, q=blockIdx.x;
  if (tid<NL) t8[tid]=tot[(size_t)q*NL+tid];
  __syncthreads();
  float th[NL];
  #pragma unroll
  for (int c=0;c<NL;c++) th[c]=t8[c];
  int cnt[NL];
  #pragma unroll
  for (int c=0;c<NL;c++) cnt[c]=0;
  for (int i=tid;i<NCALI;i+=256){
    float v=cali[i];
    #pragma unroll
    for (int c=0;c<NL;c++) cnt[c] += (v>=th[c]) ? 1 : 0;
  }
  #pragma unroll
  for (int c=0;c<NL;c++){
    #pragma unroll
    for (int off=32;off>0;off>>=1) cnt[c]+=__shfl_down(cnt[c],off,64);
  }
  if ((tid&63)==0){
    #pragma unroll
    for (int c=0;c<NL;c++) part[tid>>6][c]=cnt[c];
  }
  __syncthreads();
  if (tid<NL){
    int s=part[0][tid]+part[1][tid]+part[2][tid]+part[3][tid];
    out[(size_t)q*NL+tid] = (float)s / 10000.f;
  }
}

// ---------------- one kNN layer (templated on KCH = dp/32) --------------------
template<int KCH>
static void knn_layer(const float* Qm, const float* Bank, float* qnl, int first,
                      const int* lbl, float* tnb,
                      unsigned short* qH, unsigned short* qL,
                      unsigned short* bankH, unsigned short* bankL,
                      unsigned* skeys, unsigned* sT, unsigned* slab,
                      float* tot, hipStream_t stream){
  constexpr int dp = KCH*32;
  conv_norm_k<<<(NT+NB)/4,256,0,stream>>>(Bank, bankH, bankL, tnb, NT,
                                          Qm, qH, qL, qnl, NB, dp);
  dist_sub_k<KCH><<<16*NSB,256,0,stream>>>(qH,qL,bankH,bankL,qnl,tnb,lbl,skeys);
  sel64_k<<<NB,256,0,stream>>>(skeys,sT);
  dist_mfma_k<KCH><<<8*16*49,256,0,stream>>>(qH,qL,bankH,bankL,qnl,tnb,lbl,sT,slab);
  final_k<<<NB,256,0,stream>>>(slab,Qm,Bank,qnl,tnb,lbl,tot,first,dp);
}

extern "C" void kernel_launch(void* const* d_in, const int* in_sizes, int n_in,
                              void* d_out, int out_size, void* d_ws, size_t ws_size,
                              hipStream_t stream) {
  const float* x   = (const float*)d_in[0];
  const float* txr = (const float*)d_in[1];
  const int*   lbl = (const int*)  d_in[2];
  const float* cal = (const float*)d_in[3];
  const float* W1  = (const float*)d_in[4];
  const float* b1  = (const float*)d_in[5];
  const float* W2  = (const float*)d_in[6];
  const float* b2  = (const float*)d_in[7];
  const float* W3  = (const float*)d_in[8];
  const float* b3  = (const float*)d_in[9];
  const float* W4  = (const float*)d_in[10];
  const float* b4  = (const float*)d_in[11];
  float* out = (float*)d_out;
  float* ws  = (float*)d_ws;

  size_t off=0;
  float* xq0=ws+off; off+=(size_t)NB*96;
  float* xq1=ws+off; off+=(size_t)NB*128;
  float* xq2=ws+off; off+=(size_t)NB*128;
  float* xq3=ws+off; off+=(size_t)NB*128;
  float* xq4=ws+off; off+=(size_t)NB*32;
  float* tbA=ws+off; off+=(size_t)NT*128;
  float* tbB=ws+off; off+=(size_t)NT*128;
  float* tb4=ws+off; off+=(size_t)NT*32;
  float* qnb=ws+off; off+=(size_t)5*NB;
  float* tnb=ws+off; off+=(size_t)NT;
  float* tot=ws+off; off+=(size_t)NB*NL;
  unsigned* sT=(unsigned*)(ws+off); off+=NB;
  unsigned short* qH=(unsigned short*)(ws+off); off+=(size_t)NB*64;
  unsigned short* qL=(unsigned short*)(ws+off); off+=(size_t)NB*64;
  unsigned short* bankH=(unsigned short*)(ws+off); off+=(size_t)NT_PAD*64;
  unsigned short* bankL=(unsigned short*)(ws+off); off+=(size_t)NT_PAD*64;
  unsigned short* wt1H=(unsigned short*)(ws+off); off+=(size_t)128*48;
  unsigned short* wt1L=(unsigned short*)(ws+off); off+=(size_t)128*48;
  unsigned short* wt2H=(unsigned short*)(ws+off); off+=(size_t)128*64;
  unsigned short* wt2L=(unsigned short*)(ws+off); off+=(size_t)128*64;
  unsigned short* wt3H=(unsigned short*)(ws+off); off+=(size_t)128*64;
  unsigned short* wt3L=(unsigned short*)(ws+off); off+=(size_t)128*64;
  off=(off+3)&~(size_t)3;
  unsigned* slab=(unsigned*)(ws+off);   // NB*NTB*SLOTS = 25.6 MB
  unsigned* skeys=(unsigned*)(ws+off);  // NB*NSUB     =  8.4 MB (aliased; skeys
                                        // dead before dist_mfma_k writes slab)
  { size_t slab_sz=(size_t)NB*NTB*SLOTS, skey_sz=(size_t)NB*NSUB;
    off += (slab_sz > skey_sz ? slab_sz : skey_sz); }

  // fused prologue: pads + weight splits (1 launch), then fused query MLP (1)
  prep_k<<<PREP_BLOCKS,256,0,stream>>>(x,xq0,txr,tbA,
                                       W1,wt1H,wt1L,W2,wt2H,wt2L,W3,wt3H,wt3L);
  qmlp_k<<<8,256,0,stream>>>(xq0,W1,b1,W2,b2,W3,b3,W4,b4,xq1,xq2,xq3,xq4);

  // Bank MLPs use split-bf16 MFMA: bankH/bankL (split of the CURRENT bank,
  // produced by this layer's conv_norm) @ Wt^T. grid=2*NTB covers 50048 rows.
  knn_layer<3>(xq0, tbA, qnb+0*NB, 1, lbl, tnb, qH,qL,bankH,bankL, skeys,sT,slab, tot, stream);
  mlp_mfma_k<3><<<2*NTB,256,0,stream>>>(bankH,bankL,wt1H,wt1L,b1,tbB,NT);
  knn_layer<4>(xq1, tbB, qnb+1*NB, 0, lbl, tnb, qH,qL,bankH,bankL, skeys,sT,slab, tot, stream);
  mlp_mfma_k<4><<<2*NTB,256,0,stream>>>(bankH,bankL,wt2H,wt2L,b2,tbA,NT);
  knn_layer<4>(xq2, tbA, qnb+2*NB, 0, lbl, tnb, qH,qL,bankH,bankL, skeys,sT,slab, tot, stream);
  mlp_mfma_k<4><<<2*NTB,256,0,stream>>>(bankH,bankL,wt3H,wt3L,b3,tbB,NT);
  knn_layer<4>(xq3, tbB, qnb+3*NB, 0, lbl, tnb, qH,qL,bankH,bankL, skeys,sT,slab, tot, stream);
  mlp8sm_k<<<(NT+31)/32,256,0,stream>>>(tbB,W4,b4,tb4,NT);
  knn_layer<1>(xq4, tb4, qnb+4*NB, 0, lbl, tnb, qH,qL,bankH,bankL, skeys,sT,slab, tot, stream);

  pvalue_k<<<NB,256,0,stream>>>(tot,cal,out);
}

// Round 12
// 725.849 us; speedup vs baseline: 2.3377x; 1.0026x over previous
//
#include <hip/hip_runtime.h>
#include <math.h>

#define KNN 75
#define NL 8
#define NB 1024
#define NT 50000
#define NT_PAD 50048  // NTB*TT rows allocated for bf16 banks (pad rows masked)
#define NCALI 10000
#define KC 32
#define TT 128
#define NTB 391       // ceil(NT/TT)
#define SLOTS 16      // per (q, t-block) slab: [count, up to 15 hit keys] = 64B
#define CAP 6144      // candidate buffer per query
#define NSUB 2048     // sampled train points for threshold
#define NSB 16        // NSUB/TT subset t-blocks
#define SSTRIDE 24
#define SOFF 11       // 11 + 24*2047 = 49139 < 50000
#define RSEL 32       // sample rank -> expected |{k < T}| ~ 780, lambda/slab ~ 2

// prep_k block ranges
#define PB_Q    384                   // NB*96/256
#define PB_BANK 18750                 // NT*96/256
#define PB_W1   48                    // 128*96/256
#define PB_W23  64                    // 128*128/256
#define PREP_BLOCKS (PB_Q+PB_BANK+PB_W1+2*PB_W23)

typedef __attribute__((ext_vector_type(8))) short bf16x8;
typedef __attribute__((ext_vector_type(4))) float f32x4;

__device__ __forceinline__ int swz(int c){ return c + ((c>>5)<<2); }

__device__ __forceinline__ unsigned short f2bf_rn(float x){
  unsigned u = __float_as_uint(x);
  unsigned r = (u + 0x7FFFu + ((u>>16)&1u)) >> 16;
  return (unsigned short)r;
}
__device__ __forceinline__ float bf2f(unsigned short h){
  return __uint_as_float(((unsigned)h)<<16);
}
__device__ __forceinline__ bf16x8 ld8(const unsigned short* p){
  return *(const bf16x8*)p;
}
// async global->LDS, 16B per lane; LDS dest = wave-uniform base + lane*16
__device__ __forceinline__ void gl_lds16(const unsigned short* g, unsigned short* l){
  __builtin_amdgcn_global_load_lds(
      (const __attribute__((address_space(1))) void*)g,
      (__attribute__((address_space(3))) void*)l, 16, 0, 0);
}

// ---------------- fused prologue: pad copies + weight splits ------------------
__device__ __forceinline__ void pad_one(const float* __restrict__ in,
                                        float* __restrict__ out, int M,
                                        int Din, int Dout, int idx){
  if (idx >= M*Dout) return;
  int r = idx / Dout, c = idx - r*Dout;
  out[idx] = (c < Din) ? in[r*Din + c] : 0.f;
}
__device__ __forceinline__ void wsplit_one(const float* __restrict__ W, int kreal,
                                           int dp, unsigned short* __restrict__ WtH,
                                           unsigned short* __restrict__ WtL, int idx){
  int n = idx / dp, k = idx - n*dp;
  float v = (k < kreal) ? W[(size_t)k*128 + n] : 0.f;
  unsigned short h = f2bf_rn(v);
  WtH[idx] = h;
  WtL[idx] = f2bf_rn(v - bf2f(h));
}
__global__ void prep_k(const float* __restrict__ x, float* __restrict__ xq0,
                       const float* __restrict__ txr, float* __restrict__ tbA,
                       const float* __restrict__ W1, unsigned short* wt1H, unsigned short* wt1L,
                       const float* __restrict__ W2, unsigned short* wt2H, unsigned short* wt2L,
                       const float* __restrict__ W3, unsigned short* wt3H, unsigned short* wt3L){
  int b = blockIdx.x, tid = threadIdx.x;
  if (b < PB_Q){
    pad_one(x, xq0, NB, 83, 96, b*256 + tid);
  } else if (b < PB_Q + PB_BANK){
    pad_one(txr, tbA, NT, 83, 96, (b-PB_Q)*256 + tid);
  } else if (b < PB_Q + PB_BANK + PB_W1){
    wsplit_one(W1, 83, 96,  wt1H, wt1L, (b-PB_Q-PB_BANK)*256 + tid);
  } else if (b < PB_Q + PB_BANK + PB_W1 + PB_W23){
    wsplit_one(W2, 128, 128, wt2H, wt2L, (b-PB_Q-PB_BANK-PB_W1)*256 + tid);
  } else {
    wsplit_one(W3, 128, 128, wt3H, wt3L, (b-PB_Q-PB_BANK-PB_W1-PB_W23)*256 + tid);
  }
}

// ---------------- fused query MLP: 3 relu layers + logits + softmax -----------
// 8 blocks x 128 queries; h-state in LDS. NOW ALSO emits per-layer bf16 hi/lo
// splits + row norms (replaces query-side conv_norm for layers 1-4: producer
// has the values on-chip; the old path re-read them from HBM next launch).
__device__ __forceinline__ void qmlp_layer(
    const float* __restrict__ srcG, int lda,   // srcG!=null: layer-0 global read
    float (*H)[132], float (*As)[132], float (*Bs)[148],
    int kchunks, int kreal,
    const float* __restrict__ W, const float* __restrict__ bias,
    float* __restrict__ OutG, int rowBase, int tid)
{
  int r0 = (tid>>4)*8, c0 = (tid&15)*8;
  float acc[8][8];
  #pragma unroll
  for (int i=0;i<8;i++)
    #pragma unroll
    for (int j=0;j<8;j++) acc[i][j]=0.f;

  for (int kc=0;kc<kchunks;kc++){
    { int rr = tid>>3, k4=(tid&7)*4;
      #pragma unroll
      for (int i=0;i<4;i++){
        int row = rr + i*32;
        float4 v;
        if (srcG) v = *(const float4*)&srcG[(size_t)(rowBase+row)*lda + kc*KC + k4];
        else      v = *(const float4*)&H[row][kc*KC + k4];
        As[k4+0][row]=v.x; As[k4+1][row]=v.y; As[k4+2][row]=v.z; As[k4+3][row]=v.w;
      }
    }
    { int kk=tid>>5, c4=(tid&31)*4;
      #pragma unroll
      for (int i=0;i<4;i++){
        int k = kk + i*8, gk = kc*KC + k;
        float4 v = make_float4(0.f,0.f,0.f,0.f);
        if (gk < kreal) v = *(const float4*)&W[(size_t)gk*128 + c4];
        *(float4*)&Bs[k][swz(c4)] = v;
      }
    }
    __syncthreads();
    #pragma unroll 4
    for (int k=0;k<KC;k++){
      float4 a0 = *(const float4*)&As[k][r0];
      float4 a1 = *(const float4*)&As[k][r0+4];
      float4 b0 = *(const float4*)&Bs[k][swz(c0)];
      float4 b1 = *(const float4*)&Bs[k][swz(c0+4)];
      float av[8] = {a0.x,a0.y,a0.z,a0.w,a1.x,a1.y,a1.z,a1.w};
      float bv[8] = {b0.x,b0.y,b0.z,b0.w,b1.x,b1.y,b1.z,b1.w};
      #pragma unroll
      for (int i=0;i<8;i++)
        #pragma unroll
        for (int j=0;j<8;j++) acc[i][j] += av[i]*bv[j];
    }
    __syncthreads();
  }
  float bb[8];
  #pragma unroll
  for (int j=0;j<8;j++) bb[j]=bias[c0+j];
  #pragma unroll
  for (int i=0;i<8;i++){
    int row = r0 + i;
    float o[8];
    #pragma unroll
    for (int j=0;j<8;j++){ float v=acc[i][j]+bb[j]; o[j]=v>0.f?v:0.f; }
    *(float4*)&H[row][c0]   = make_float4(o[0],o[1],o[2],o[3]);
    *(float4*)&H[row][c0+4] = make_float4(o[4],o[5],o[6],o[7]);
    *(float4*)&OutG[(size_t)(rowBase+row)*128 + c0]   = make_float4(o[0],o[1],o[2],o[3]);
    *(float4*)&OutG[(size_t)(rowBase+row)*128 + c0+4] = make_float4(o[4],o[5],o[6],o[7]);
  }
  __syncthreads();   // H writes visible before next layer stages from H
}

// split+norm of current H (128 dims) to global; tid<128 each owns one row
__device__ __forceinline__ void qsplit(float (*H)[132],
                                       unsigned short* __restrict__ qh,
                                       unsigned short* __restrict__ ql,
                                       float* __restrict__ qn,
                                       int rowBase, int tid){
  if (tid < 128){
    int gr = rowBase + tid;
    float s = 0.f;
    for (int k=0;k<128;k++){
      float v = H[tid][k];
      s += v*v;
      unsigned short h = f2bf_rn(v);
      qh[(size_t)gr*128 + k] = h;
      ql[(size_t)gr*128 + k] = f2bf_rn(v - bf2f(h));
    }
    qn[gr] = s;
  }
}

__global__ __launch_bounds__(256) void qmlp_k(
    const float* __restrict__ xq0,
    const float* __restrict__ W1, const float* __restrict__ b1,
    const float* __restrict__ W2, const float* __restrict__ b2,
    const float* __restrict__ W3, const float* __restrict__ b3,
    const float* __restrict__ W4, const float* __restrict__ b4,
    float* __restrict__ xq1, float* __restrict__ xq2, float* __restrict__ xq3,
    float* __restrict__ xq4,
    unsigned short* qH1, unsigned short* qL1,
    unsigned short* qH2, unsigned short* qL2,
    unsigned short* qH3, unsigned short* qL3,
    unsigned short* qH4, unsigned short* qL4,
    float* __restrict__ qnb)
{
  __shared__ float As[KC][132];
  __shared__ float Bs[KC][148];
  __shared__ float H[128][132];
  int tid = threadIdx.x;
  int rowBase = blockIdx.x*128;

  qmlp_layer(xq0, 96, H, As, Bs, 3, 83,  W1, b1, xq1, rowBase, tid);
  qsplit(H, qH1, qL1, qnb+1*NB, rowBase, tid);
  qmlp_layer(nullptr, 0, H, As, Bs, 4, 128, W2, b2, xq2, rowBase, tid);
  qsplit(H, qH2, qL2, qnb+2*NB, rowBase, tid);
  qmlp_layer(nullptr, 0, H, As, Bs, 4, 128, W3, b3, xq3, rowBase, tid);
  qsplit(H, qH3, qL3, qnb+3*NB, rowBase, tid);

  // logits + softmax + layer-4 split/norm (stride-32 rows, cols 8..31 zero)
  float* W4s = (float*)Bs;
  for (int i=tid;i<1024;i+=256) W4s[i]=W4[i];
  __syncthreads();
  if (tid < 128){
    int row = rowBase + tid;
    float v[8];
    #pragma unroll
    for (int c=0;c<8;c++) v[c]=b4[c];
    for (int k=0;k<128;k++){
      float a = H[tid][k];
      #pragma unroll
      for (int c=0;c<8;c++) v[c] += a*W4s[k*8+c];
    }
    float m=-1e30f;
    #pragma unroll
    for (int c=0;c<8;c++) m = v[c]>m ? v[c] : m;
    float s=0.f;
    #pragma unroll
    for (int c=0;c<8;c++){ v[c]=__expf(v[c]-m); s+=v[c]; }
    float inv=1.f/s;
    float* p = &xq4[(size_t)row*32];
    float nn=0.f;
    #pragma unroll
    for (int c=0;c<8;c++){
      float pv = v[c]*inv;
      p[c]=pv;
      nn += pv*pv;
      unsigned short h = f2bf_rn(pv);
      qH4[(size_t)row*32 + c] = h;
      qL4[(size_t)row*32 + c] = f2bf_rn(pv - bf2f(h));
    }
    #pragma unroll
    for (int j=8;j<32;j++){ p[j]=0.f; qH4[(size_t)row*32+j]=0; qL4[(size_t)row*32+j]=0; }
    qnb[4*NB + row] = nn;
  }
}

// ---------------- bank logits + softmax + split/norm (stride-32 rows) ---------
__global__ void mlp8sm_k(const float* __restrict__ A, const float* __restrict__ W4,
                         const float* __restrict__ b4, float* __restrict__ Out,
                         unsigned short* __restrict__ SH, unsigned short* __restrict__ SL,
                         float* __restrict__ nrm, int M){
  __shared__ float Ws[128*8];
  int tid = threadIdx.x;
  for (int i=tid;i<1024;i+=256) Ws[i]=W4[i];
  __syncthreads();
  int r = blockIdx.x*32 + (tid>>3), c = tid&7;
  if (r >= M) return;
  const float* a = &A[(size_t)r*128];
  float acc = b4[c];
  #pragma unroll 16
  for (int k=0;k<128;k++) acc += a[k]*Ws[k*8+c];
  int lane = tid & 63, base = lane & ~7;
  float v[8];
  #pragma unroll
  for (int j=0;j<8;j++) v[j] = __shfl(acc, base+j, 64);
  float m=-1e30f;
  #pragma unroll
  for (int j=0;j<8;j++) m = v[j]>m ? v[j] : m;
  float s=0.f;
  #pragma unroll
  for (int j=0;j<8;j++){ v[j]=__expf(v[j]-m); s+=v[j]; }
  float inv=1.f/s;
  float nn=0.f;
  #pragma unroll
  for (int j=0;j<8;j++){ float pv=v[j]*inv; v[j]=pv; nn+=pv*pv; }
  float* p = &Out[(size_t)r*32];
  float pv = v[c];
  p[c]    = pv;
  p[8+c]  = 0.f;
  p[16+c] = 0.f;
  p[24+c] = 0.f;
  unsigned short h = f2bf_rn(pv);
  SH[(size_t)r*32 + c]    = h;
  SL[(size_t)r*32 + c]    = f2bf_rn(pv - bf2f(h));
  SH[(size_t)r*32 + 8+c]  = 0; SL[(size_t)r*32 + 8+c]  = 0;
  SH[(size_t)r*32 + 16+c] = 0; SL[(size_t)r*32 + 16+c] = 0;
  SH[(size_t)r*32 + 24+c] = 0; SL[(size_t)r*32 + 24+c] = 0;
  if (c==0) nrm[r] = nn;
}

// ---- fp32 -> (hi,lo) bf16 split + row squared-norms (layer 0 only now) -------
__global__ void conv_norm_k(
    const float* __restrict__ XA, unsigned short* __restrict__ HA,
    unsigned short* __restrict__ LA, float* __restrict__ nA, int MA,
    const float* __restrict__ XB, unsigned short* __restrict__ HB,
    unsigned short* __restrict__ LB, float* __restrict__ nB, int MB,
    int dp)
{
  int w = threadIdx.x>>6, lane = threadIdx.x&63;
  int row = blockIdx.x*4 + w;
  const float* src; unsigned short* dh; unsigned short* dl; float* nrm;
  if (row < MA){
    src=&XA[(size_t)row*dp]; dh=&HA[(size_t)row*dp]; dl=&LA[(size_t)row*dp]; nrm=&nA[row];
  } else {
    int r2 = row - MA;
    if (r2 >= MB) return;
    src=&XB[(size_t)r2*dp]; dh=&HB[(size_t)r2*dp]; dl=&LB[(size_t)r2*dp]; nrm=&nB[r2];
  }
  float s=0.f;
  for (int c=lane*2; c<dp; c+=128){
    float2 v = *(const float2*)&src[c];
    s += v.x*v.x + v.y*v.y;
    unsigned short h0 = f2bf_rn(v.x), h1 = f2bf_rn(v.y);
    float r0 = v.x - bf2f(h0), r1 = v.y - bf2f(h1);
    ushort2 hh; hh.x=h0; hh.y=h1;
    ushort2 ll; ll.x=f2bf_rn(r0); ll.y=f2bf_rn(r1);
    *(ushort2*)&dh[c]=hh;
    *(ushort2*)&dl[c]=ll;
  }
  #pragma unroll
  for (int off=32;off>0;off>>=1) s += __shfl_down(s, off, 64);
  if (lane==0) *nrm=s;
}

// ---------------- scan helper: find bin containing rank Krem ------------------
__device__ __forceinline__ void find_bin(int* hist, int* part, int nb, int Krem,
                                         int tid, int* s_B, int* s_lob){
  int ch = nb>>8;
  int base = tid*ch;
  int s=0;
  for (int b=base;b<base+ch;b++) s+=hist[b];
  int lane = tid & 63, wv = tid>>6;
  int v = s;
  #pragma unroll
  for (int off=1; off<64; off<<=1){
    int u = __shfl_up(v, off, 64);
    if (lane >= off) v += u;
  }
  if (lane==63) part[wv] = v;
  __syncthreads();
  int wbase = 0;
  #pragma unroll
  for (int w2=0; w2<4; w2++) wbase += (w2 < wv) ? part[w2] : 0;
  v += wbase;
  int excl = v - s;
  if (v >= Krem && excl < Krem){
    int lob = excl, B = base + ch - 1;
    for (int b=base;b<base+ch;b++){
      if (lob + hist[b] >= Krem){ B=b; break; }
      lob += hist[b];
    }
    *s_B = B; *s_lob = lob;
  }
  if (tid==255 && v < Krem){ *s_B = nb-1; *s_lob = 0; }  // preserve old default
  __syncthreads();
}

// ---------------- per-query threshold: exact RSEL-th smallest sample key ------
__global__ __launch_bounds__(256) void sel64_k(const unsigned* __restrict__ skeys,
                                               unsigned* __restrict__ Tthr){
  __shared__ unsigned buf[NSUB];
  __shared__ int hist[2048];
  __shared__ int part[256];
  __shared__ int sB, sLob;
  int tid=threadIdx.x, q=blockIdx.x;
  for (int i=tid;i<NSUB;i+=256) buf[i]=skeys[(size_t)q*NSUB+i];
  int Krem=RSEL;
  for (int i=tid;i<2048;i+=256) hist[i]=0;
  __syncthreads();
  for (int i=tid;i<NSUB;i+=256) atomicAdd(&hist[buf[i]>>21],1);
  __syncthreads();
  find_bin(hist,part,2048,Krem,tid,&sB,&sLob);
  unsigned pre=(unsigned)sB; Krem-=sLob;
  for (int i=tid;i<2048;i+=256) hist[i]=0;
  __syncthreads();
  for (int i=tid;i<NSUB;i+=256){ unsigned k=buf[i]; if ((k>>21)==pre) atomicAdd(&hist[(k>>10)&0x7FFu],1); }
  __syncthreads();
  find_bin(hist,part,2048,Krem,tid,&sB,&sLob);
  pre=(pre<<11)|(unsigned)sB; Krem-=sLob;
  for (int i=tid;i<1024;i+=256) hist[i]=0;
  __syncthreads();
  for (int i=tid;i<NSUB;i+=256){ unsigned k=buf[i]; if ((k>>10)==pre) atomicAdd(&hist[k&0x3FFu],1); }
  __syncthreads();
  find_bin(hist,part,1024,Krem,tid,&sB,&sLob);
  if (tid==0) Tthr[q]=(pre<<10)|(unsigned)sB;
}

// ====== MFMA section: one 64x128 sub-tile x one K-chunk from LDS ==============
#define MFMA_SEC(BHC, BLC, AH, AL)                                               \
  _Pragma("unroll")                                                              \
  for (int tj=0;tj<8;tj++){                                                      \
    int rowB = tj*16 + col;                                                      \
    int sw = (((quad + (rowB>>1)) & 3) << 3);                                    \
    bf16x8 bh = *(const bf16x8*)&(BHC)[rowB*32 + sw];                            \
    bf16x8 bl = *(const bf16x8*)&(BLC)[rowB*32 + sw];                            \
    acc[tj] = __builtin_amdgcn_mfma_f32_16x16x32_bf16(AH, bh, acc[tj], 0,0,0);   \
    acc[tj] = __builtin_amdgcn_mfma_f32_16x16x32_bf16(AH, bl, acc[tj], 0,0,0);   \
    acc[tj] = __builtin_amdgcn_mfma_f32_16x16x32_bf16(AL, bh, acc[tj], 0,0,0);   \
  }

#define MFMA_KLOOP(ROWMAP)                                                       \
  size_t aoff = (size_t)(qbase + w*16 + col)*dp + quad*8;                        \
  const unsigned short* pAH = QH + aoff;                                         \
  const unsigned short* pAL = QL + aoff;                                         \
  int i0 = tid,      row0 = i0>>2, sg0 = ((i0&3) - (row0>>1)) & 3;               \
  int i1 = tid+256,  row1 = i1>>2, sg1 = ((i1&3) - (row1>>1)) & 3;               \
  size_t g0 = (size_t)(ROWMAP(n0+row0))*dp + (size_t)sg0*8;                      \
  size_t g1 = (size_t)(ROWMAP(n0+row1))*dp + (size_t)sg1*8;                      \
  f32x4 acc[8];                                                                  \
  _Pragma("unroll")                                                              \
  for (int tj=0;tj<8;tj++){ f32x4 z={0.f,0.f,0.f,0.f}; acc[tj]=z; }              \
  gl_lds16(TH + g0, BH0 + i0*8);                                                 \
  gl_lds16(TH + g1, BH0 + i1*8);                                                 \
  gl_lds16(TL + g0, BL0 + i0*8);                                                 \
  gl_lds16(TL + g1, BL0 + i1*8);                                                 \
  bf16x8 xh = ld8(pAH), xl = ld8(pAL);                                           \
  bf16x8 yh = xh, yl = xl;                                                       \
  _Pragma("unroll")                                                              \
  for (int kc=0; kc<kchunks; kc+=2){                                             \
    __syncthreads();                                                             \
    if (kc+1 < kchunks){                                                         \
      size_t ko=(size_t)(kc+1)*32;                                               \
      gl_lds16(TH + g0 + ko, BH1 + i0*8);                                        \
      gl_lds16(TH + g1 + ko, BH1 + i1*8);                                        \
      gl_lds16(TL + g0 + ko, BL1 + i0*8);                                        \
      gl_lds16(TL + g1 + ko, BL1 + i1*8);                                        \
      yh = ld8(pAH + ko); yl = ld8(pAL + ko);                                    \
    }                                                                            \
    MFMA_SEC(BH0, BL0, xh, xl);                                                  \
    if (kc+1 < kchunks){                                                         \
      __syncthreads();                                                           \
      if (kc+2 < kchunks){                                                       \
        size_t ko=(size_t)(kc+2)*32;                                             \
        gl_lds16(TH + g0 + ko, BH0 + i0*8);                                      \
        gl_lds16(TH + g1 + ko, BH0 + i1*8);                                      \
        gl_lds16(TL + g0 + ko, BL0 + i0*8);                                      \
        gl_lds16(TL + g1 + ko, BL0 + i1*8);                                      \
        xh = ld8(pAH + ko); xl = ld8(pAL + ko);                                  \
      }                                                                          \
      MFMA_SEC(BH1, BL1, yh, yl);                                                \
    }                                                                            \
  }

#define ROW_ID(r) (r)
#define ROW_SUB(r) ((r)*SSTRIDE + SOFF)

// ---------------- MFMA split-bf16 distance GEMM vs full bank ------------------
template<int KCH>
__global__ __launch_bounds__(256) void dist_mfma_k(
    const unsigned short* __restrict__ QH, const unsigned short* __restrict__ QL,
    const unsigned short* __restrict__ TH, const unsigned short* __restrict__ TL,
    const float* __restrict__ qn, const float* __restrict__ tn,
    const int* __restrict__ labels, const unsigned* __restrict__ Tthr,
    unsigned* __restrict__ slab)
{
  constexpr int dp = KCH*32;
  __shared__ __align__(16) unsigned short smem[4*4096];   // 32 KB
  unsigned short* BH0 = smem;
  unsigned short* BH1 = smem + 4096;
  unsigned short* BL0 = smem + 8192;
  unsigned short* BL1 = smem + 12288;
  unsigned (*hitbuf)[SLOTS] = (unsigned (*)[SLOTS])smem;  // aliases BH0 (4 KB)
  int* hcnt = (int*)(smem + 4096);                        // aliases BH1 head
  int b = blockIdx.x;
  int xcd = b & 7, s = b >> 3;
  int qb = s & 15, tslot = s >> 4;
  int t_blk = xcd + 8*tslot;
  if (t_blk >= NTB) return;
  int tid = threadIdx.x, w = tid>>6, lane = tid&63;
  int quad = lane>>4, col = lane&15;
  int qbase = qb*64;
  int n0 = t_blk*TT;
  constexpr int kchunks = KCH;

  MFMA_KLOOP(ROW_ID)

  // epilogue: barrier FIRST (K-loop LDS reads must complete before aliasing)
  __syncthreads();
  if (tid<64) hcnt[tid]=0;
  __syncthreads();
  float qnr[4]; unsigned Tq[4]; float thrF[4];
  #pragma unroll
  for (int r=0;r<4;r++){
    int q = qbase + w*16 + quad*4 + r;
    qnr[r]  = qn[q];
    Tq[r]   = Tthr[q];
    thrF[r] = __uint_as_float(Tq[r] | 7u);  // superset boundary
  }
  #pragma unroll
  for (int tj=0;tj<8;tj++){
    int t = n0 + tj*16 + col;
    if (t < NT){
      float tnv = tn[t];
      unsigned lab = (unsigned)labels[t];
      #pragma unroll
      for (int r=0;r<4;r++){
        float d2 = fmaf(-2.f, acc[tj][r], qnr[r] + tnv);
        if (d2 <= thrF[r]){
          float d2c = fmaxf(d2, 0.f);
          unsigned key = (__float_as_uint(d2c)&0xFFFFFFF8u) | lab;
          if (key < Tq[r]){
            int ql = w*16 + quad*4 + r;
            int idx = atomicAdd(&hcnt[ql], 1);
            if (idx < SLOTS-1) hitbuf[ql][1+idx] = key;
          }
        }
      }
    }
  }
  __syncthreads();
  if (tid<64) hitbuf[tid][0]=(unsigned)hcnt[tid];
  __syncthreads();
  // slab[q][t_blk]: final_k reads each query's 391 slabs contiguously
  {
    int q = tid>>2, sub = (tid&3)*4;
    uint4 v = *(uint4*)&hitbuf[q][sub];
    *(uint4*)&slab[((size_t)(qbase+q)*NTB + t_blk)*SLOTS + sub] = v;
  }
}

// ---------------- MFMA split-bf16 distance GEMM vs SAMPLED subset -------------
template<int KCH>
__global__ __launch_bounds__(256) void dist_sub_k(
    const unsigned short* __restrict__ QH, const unsigned short* __restrict__ QL,
    const unsigned short* __restrict__ TH, const unsigned short* __restrict__ TL,
    const float* __restrict__ qn, const float* __restrict__ tn,
    const int* __restrict__ labels, unsigned* __restrict__ keys)
{
  constexpr int dp = KCH*32;
  __shared__ __align__(16) unsigned short smem[4*4096];   // 32 KB
  unsigned short* BH0 = smem;
  unsigned short* BH1 = smem + 4096;
  unsigned short* BL0 = smem + 8192;
  unsigned short* BL1 = smem + 12288;
  int b = blockIdx.x;
  int qb = b & 15, t_blk = b >> 4;           // t_blk in [0, NSB)
  int tid = threadIdx.x, w = tid>>6, lane = tid&63;
  int quad = lane>>4, col = lane&15;
  int qbase = qb*64;
  int n0 = t_blk*TT;                         // subset-space row base
  constexpr int kchunks = KCH;

  MFMA_KLOOP(ROW_SUB)

  // epilogue: write all keys; 16-lane quad -> 64B contiguous store per (tj,r)
  float qnr[4];
  #pragma unroll
  for (int r=0;r<4;r++)
    qnr[r] = qn[qbase + w*16 + quad*4 + r];
  #pragma unroll
  for (int tj=0;tj<8;tj++){
    int sI = n0 + tj*16 + col;
    int g  = sI*SSTRIDE + SOFF;
    float tnv = tn[g];
    unsigned lab = (unsigned)labels[g];
    #pragma unroll
    for (int r=0;r<4;r++){
      float d2 = fmaxf(fmaf(-2.f, acc[tj][r], qnr[r] + tnv), 0.f);
      unsigned key = (__float_as_uint(d2)&0xFFFFFFF8u) | lab;
      int q = qbase + w*16 + quad*4 + r;
      keys[(size_t)q*NSUB + sI] = key;
    }
  }
}

// ---------------- MFMA split-bf16 bank MLP: Out = relu(A @ Wt^T + b) ----------
// NOW ALSO emits the bf16 hi/lo split + row norms of the OUTPUT (the next
// layer's bank features) straight from registers -> bank-side conv_norm gone.
template<int KCH>
__global__ __launch_bounds__(256) void mlp_mfma_k(
    const unsigned short* __restrict__ QH, const unsigned short* __restrict__ QL,
    const unsigned short* __restrict__ TH, const unsigned short* __restrict__ TL,
    const float* __restrict__ bias, float* __restrict__ Out,
    unsigned short* __restrict__ SH, unsigned short* __restrict__ SL,
    float* __restrict__ nrm, int M)
{
  constexpr int dp = KCH*32;
  __shared__ __align__(16) unsigned short smem[4*4096];   // 32 KB
  unsigned short* BH0 = smem;
  unsigned short* BH1 = smem + 4096;
  unsigned short* BL0 = smem + 8192;
  unsigned short* BL1 = smem + 12288;
  int tid = threadIdx.x, w = tid>>6, lane = tid&63;
  int quad = lane>>4, col = lane&15;
  int qbase = blockIdx.x*64;                 // bank-row base
  int n0 = 0;                                // Wt rows 0..127
  constexpr int kchunks = KCH;

  MFMA_KLOOP(ROW_ID)

  // epilogue: bias + relu + fp32 store + bf16 split + row norm
  float bb[8];
  #pragma unroll
  for (int tj=0;tj<8;tj++) bb[tj] = bias[tj*16 + col];
  #pragma unroll
  for (int r=0;r<4;r++){
    int row = qbase + w*16 + quad*4 + r;
    if (row < M){
      float vv[8]; float s=0.f;
      #pragma unroll
      for (int tj=0;tj<8;tj++){
        float v = acc[tj][r] + bb[tj];
        v = v > 0.f ? v : 0.f;
        vv[tj] = v;
        s += v*v;
        Out[(size_t)row*128 + tj*16 + col] = v;
      }
      // 16-lane (quad) reduce for the row norm
      #pragma unroll
      for (int off=1; off<16; off<<=1) s += __shfl_xor(s, off, 16);
      if (col==0) nrm[row] = s;
      #pragma unroll
      for (int tj=0;tj<8;tj++){
        unsigned short h = f2bf_rn(vv[tj]);
        SH[(size_t)row*128 + tj*16 + col] = h;
        SL[(size_t)row*128 + tj*16 + col] = f2bf_rn(vv[tj] - bf2f(h));
      }
    }
  }
}

// ---------------- gather slabs, exact radix select + class sums ---------------
__global__ __launch_bounds__(256) void final_k(
    const unsigned* __restrict__ slab,
    const float* __restrict__ Qm, const float* __restrict__ Tm,
    const float* __restrict__ qn, const float* __restrict__ tn,
    const int* __restrict__ labels,
    float* __restrict__ tot, int first, int dp)
{
  __shared__ int hist[2048];
  __shared__ int part[256];
  __shared__ unsigned buf[CAP];
  __shared__ unsigned lowbuf[96];
  __shared__ float qrow[128];
  __shared__ int sB,sLob,s_cnt,s_low,s_bad;
  __shared__ float s_w[9];
  int tid=threadIdx.x, q=blockIdx.x;
  if (tid==0){ for (int j=0;j<9;j++) s_w[j]=0.f; s_cnt=0; s_low=0; s_bad=0; }
  __syncthreads();

  // [q][t_blk] layout: query q's slabs are ONE contiguous 25KB run
  const unsigned* sq = slab + (size_t)q*NTB*SLOTS;
  for (int sidx=tid; sidx<NTB; sidx+=256){
    const unsigned* s = sq + (size_t)sidx*SLOTS;
    uint4 a = *(const uint4*)s;
    unsigned cnt = a.x;
    if (cnt > SLOTS-1){ s_bad=1; continue; }
    if (!cnt) continue;
    int base = atomicAdd(&s_cnt, (int)cnt);
    if (base + (int)cnt <= CAP){
      buf[base] = a.y;
      if (cnt>=2) buf[base+1] = a.z;
      if (cnt>=3) buf[base+2] = a.w;
      for (unsigned w=4; w<=cnt; w++) buf[base+w-1] = s[w];
    }
  }
  __syncthreads();
  int total = s_cnt;
  int bad = s_bad;

#define CONTRIB(kk) do{ float d2_=__uint_as_float((kk)&0xFFFFFFF8u); \
    if (d2_>0.f){ float w_=1.0f/sqrtf(d2_); \
      atomicAdd(&s_w[8],w_); atomicAdd(&s_w[(kk)&7u],w_); } }while(0)

  unsigned T; int Krem=KNN;
  if (!bad && total>=KNN && total<=CAP){
    for (int i=tid;i<2048;i+=256) hist[i]=0;
    __syncthreads();
    for (int i=tid;i<total;i+=256) atomicAdd(&hist[buf[i]>>21],1);
    __syncthreads();
    find_bin(hist,part,2048,Krem,tid,&sB,&sLob);
    unsigned pre=(unsigned)sB; Krem-=sLob;
    for (int i=tid;i<2048;i+=256) hist[i]=0;
    __syncthreads();
    for (int i=tid;i<total;i+=256){ unsigned k=buf[i]; if ((k>>21)==pre) atomicAdd(&hist[(k>>10)&0x7FFu],1); }
    __syncthreads();
    find_bin(hist,part,2048,Krem,tid,&sB,&sLob);
    pre=(pre<<11)|(unsigned)sB; Krem-=sLob;
    for (int i=tid;i<1024;i+=256) hist[i]=0;
    __syncthreads();
    for (int i=tid;i<total;i+=256){ unsigned k=buf[i]; if ((k>>10)==pre) atomicAdd(&hist[k&0x3FFu],1); }
    __syncthreads();
    find_bin(hist,part,1024,Krem,tid,&sB,&sLob);
    T=(pre<<10)|(unsigned)sB; Krem-=sLob;
    __syncthreads();
    for (int i=tid;i<total;i+=256){ unsigned k=buf[i]; if (k<T) CONTRIB(k); }
  } else {
    // fallback (P ~ 1e-10): exact fp32 full recompute select
    if (tid==0) s_cnt=0;
    for (int i=tid;i<dp;i+=256) qrow[i]=Qm[(size_t)q*dp+i];
    __syncthreads();
    float qq=qn[q];
    auto KEY=[&](int t)->unsigned{
      const float* br=&Tm[(size_t)t*dp];
      float dot=0.f;
      for (int k2=0;k2<dp;k2++) dot+=qrow[k2]*br[k2];
      float d2=fmaxf(qq-2.f*dot+tn[t],0.f);
      return (__float_as_uint(d2)&0xFFFFFFF8u)|(unsigned)labels[t];
    };
    for (int i=tid;i<2048;i+=256) hist[i]=0;
    __syncthreads();
    for (int t=tid;t<NT;t+=256) atomicAdd(&hist[KEY(t)>>21],1);
    __syncthreads();
    find_bin(hist,part,2048,Krem,tid,&sB,&sLob);
    int c=hist[sB]; Krem-=sLob;
    unsigned prefix=(unsigned)sB; int shift=21;
    if (c > CAP){
      __syncthreads();
      for (int i=tid;i<2048;i+=256) hist[i]=0;
      __syncthreads();
      for (int t=tid;t<NT;t+=256){ unsigned k=KEY(t); if ((k>>21)==prefix) atomicAdd(&hist[(k>>10)&0x7FFu],1); }
      __syncthreads();
      find_bin(hist,part,2048,Krem,tid,&sB,&sLob);
      c=hist[sB]; Krem-=sLob; prefix=(prefix<<11)|(unsigned)sB; shift=10;
    }
    if (c > CAP){
      __syncthreads();
      for (int i=tid;i<1024;i+=256) hist[i]=0;
      __syncthreads();
      for (int t=tid;t<NT;t+=256){ unsigned k=KEY(t); if ((k>>10)==prefix) atomicAdd(&hist[k&0x3FFu],1); }
      __syncthreads();
      find_bin(hist,part,1024,Krem,tid,&sB,&sLob);
      c=hist[sB]; Krem-=sLob; prefix=(prefix<<10)|(unsigned)sB; shift=0;
    }
    if (c <= CAP){
      for (int t=tid;t<NT;t+=256){
        unsigned k=KEY(t); unsigned pp=k>>shift;
        if (pp==prefix){ int j=atomicAdd(&s_cnt,1); if (j<CAP) buf[j]=k; }
        else if (pp<prefix){ int j=atomicAdd(&s_low,1); if (j<96) lowbuf[j]=k; }
      }
      __syncthreads();
      int sh=shift;
      while (sh>0){
        int nsh=(sh==21)?10:0;
        int nb=1<<(sh-nsh);
        __syncthreads();
        for (int i=tid;i<nb;i+=256) hist[i]=0;
        __syncthreads();
        int cc=s_cnt;
        for (int i=tid;i<cc;i+=256) atomicAdd(&hist[(buf[i]>>nsh)&(unsigned)(nb-1)],1);
        __syncthreads();
        find_bin(hist,part,nb,Krem,tid,&sB,&sLob);
        Krem-=sLob; prefix=(prefix<<(sh-nsh))|(unsigned)sB; sh=nsh;
      }
      T=prefix;
      __syncthreads();
      int lowc=s_low, cc=s_cnt;
      for (int i=tid;i<lowc;i+=256){ unsigned k=lowbuf[i]; CONTRIB(k); }
      for (int i=tid;i<cc;i+=256){ unsigned k=buf[i]; if (k<T) CONTRIB(k); }
    } else {
      T=prefix;
      for (int t=tid;t<NT;t+=256){ unsigned k=KEY(t); if (k<T) CONTRIB(k); }
    }
  }
  __syncthreads();
  if (tid==0){
    float d2=__uint_as_float(T&0xFFFFFFF8u);
    float w=(d2>0.f)?(1.0f/sqrtf(d2)):0.f;
    s_w[8] += (float)Krem*w;
    s_w[T&7u] += (float)Krem*w;
  }
  __syncthreads();
  if (tid<8){
    float contrib = s_w[8]-s_w[tid];
    size_t o=(size_t)q*NL+tid;
    tot[o] = first ? contrib : tot[o]+contrib;
  }
#undef CONTRIB
}

// ---------------- empirical p-values ------------------------------------------
__global__ void pvalue_k(const float* __restrict__ tot, const float* __restrict__ cali,
                         float* __restrict__ out){
  __shared__ float t8[NL];
  __shared__ int part[4][NL];
  int tid=threadIdx.x, q=blockIdx.x;
  if (tid<NL) t8[tid]=tot[(size_t)q*NL+tid];
  __syncthreads();
  float th[NL];
  #pragma unroll
  for (int c=0;c<NL;c++) th[c]=t8[c];
  int cnt[NL];
  #pragma unroll
  for (int c=0;c<NL;c++) cnt[c]=0;
  for (int i=tid;i<NCALI;i+=256){
    float v=cali[i];
    #pragma unroll
    for (int c=0;c<NL;c++) cnt[c] += (v>=th[c]) ? 1 : 0;
  }
  #pragma unroll
  for (int c=0;c<NL;c++){
    #pragma unroll
    for (int off=32;off>0;off>>=1) cnt[c]+=__shfl_down(cnt[c],off,64);
  }
  if ((tid&63)==0){
    #pragma unroll
    for (int c=0;c<NL;c++) part[tid>>6][c]=cnt[c];
  }
  __syncthreads();
  if (tid<NL){
    int s=part[0][tid]+part[1][tid]+part[2][tid]+part[3][tid];
    out[(size_t)q*NL+tid] = (float)s / 10000.f;
  }
}

// ---------------- one kNN layer (templated on KCH = dp/32) --------------------
template<int KCH>
static void knn_layer(const float* Qm, const float* Bank,
                      const unsigned short* qh, const unsigned short* ql, float* qnl,
                      const unsigned short* bkH, const unsigned short* bkL,
                      int first, const int* lbl, float* tnb,
                      unsigned* skeys, unsigned* sT, unsigned* slab,
                      float* tot, hipStream_t stream){
  constexpr int dp = KCH*32;
  dist_sub_k<KCH><<<16*NSB,256,0,stream>>>(qh,ql,bkH,bkL,qnl,tnb,lbl,skeys);
  sel64_k<<<NB,256,0,stream>>>(skeys,sT);
  dist_mfma_k<KCH><<<8*16*49,256,0,stream>>>(qh,ql,bkH,bkL,qnl,tnb,lbl,sT,slab);
  final_k<<<NB,256,0,stream>>>(slab,Qm,Bank,qnl,tnb,lbl,tot,first,dp);
}

extern "C" void kernel_launch(void* const* d_in, const int* in_sizes, int n_in,
                              void* d_out, int out_size, void* d_ws, size_t ws_size,
                              hipStream_t stream) {
  const float* x   = (const float*)d_in[0];
  const float* txr = (const float*)d_in[1];
  const int*   lbl = (const int*)  d_in[2];
  const float* cal = (const float*)d_in[3];
  const float* W1  = (const float*)d_in[4];
  const float* b1  = (const float*)d_in[5];
  const float* W2  = (const float*)d_in[6];
  const float* b2  = (const float*)d_in[7];
  const float* W3  = (const float*)d_in[8];
  const float* b3  = (const float*)d_in[9];
  const float* W4  = (const float*)d_in[10];
  const float* b4  = (const float*)d_in[11];
  float* out = (float*)d_out;
  float* ws  = (float*)d_ws;

  size_t off=0;
  float* xq0=ws+off; off+=(size_t)NB*96;
  float* xq1=ws+off; off+=(size_t)NB*128;
  float* xq2=ws+off; off+=(size_t)NB*128;
  float* xq3=ws+off; off+=(size_t)NB*128;
  float* xq4=ws+off; off+=(size_t)NB*32;
  float* tbA=ws+off; off+=(size_t)NT*128;
  float* tbB=ws+off; off+=(size_t)NT*128;
  float* tb4=ws+off; off+=(size_t)NT*32;
  float* qnb=ws+off; off+=(size_t)5*NB;
  float* tnb=ws+off; off+=(size_t)NT;
  float* tot=ws+off; off+=(size_t)NB*NL;
  unsigned* sT=(unsigned*)(ws+off); off+=NB;
  // per-layer query splits (hi/lo), strides: L0=96, L1-3=128, L4=32
  unsigned short* qH0=(unsigned short*)(ws+off); off+=(size_t)NB*48;
  unsigned short* qL0=(unsigned short*)(ws+off); off+=(size_t)NB*48;
  unsigned short* qH1=(unsigned short*)(ws+off); off+=(size_t)NB*64;
  unsigned short* qL1=(unsigned short*)(ws+off); off+=(size_t)NB*64;
  unsigned short* qH2=(unsigned short*)(ws+off); off+=(size_t)NB*64;
  unsigned short* qL2=(unsigned short*)(ws+off); off+=(size_t)NB*64;
  unsigned short* qH3=(unsigned short*)(ws+off); off+=(size_t)NB*64;
  unsigned short* qL3=(unsigned short*)(ws+off); off+=(size_t)NB*64;
  unsigned short* qH4=(unsigned short*)(ws+off); off+=(size_t)NB*16;
  unsigned short* qL4=(unsigned short*)(ws+off); off+=(size_t)NB*16;
  // double-buffered bank splits (mlp_mfma reads one pair, writes the other)
  unsigned short* bkAH=(unsigned short*)(ws+off); off+=(size_t)NT_PAD*64;
  unsigned short* bkAL=(unsigned short*)(ws+off); off+=(size_t)NT_PAD*64;
  unsigned short* bkBH=(unsigned short*)(ws+off); off+=(size_t)NT_PAD*64;
  unsigned short* bkBL=(unsigned short*)(ws+off); off+=(size_t)NT_PAD*64;
  unsigned short* wt1H=(unsigned short*)(ws+off); off+=(size_t)128*48;
  unsigned short* wt1L=(unsigned short*)(ws+off); off+=(size_t)128*48;
  unsigned short* wt2H=(unsigned short*)(ws+off); off+=(size_t)128*64;
  unsigned short* wt2L=(unsigned short*)(ws+off); off+=(size_t)128*64;
  unsigned short* wt3H=(unsigned short*)(ws+off); off+=(size_t)128*64;
  unsigned short* wt3L=(unsigned short*)(ws+off); off+=(size_t)128*64;
  off=(off+3)&~(size_t)3;
  unsigned* slab=(unsigned*)(ws+off);   // NB*NTB*SLOTS = 25.6 MB
  unsigned* skeys=(unsigned*)(ws+off);  // NB*NSUB     =  8.4 MB (aliased; skeys
                                        // dead before dist_mfma_k writes slab)
  { size_t slab_sz=(size_t)NB*NTB*SLOTS, skey_sz=(size_t)NB*NSUB;
    off += (slab_sz > skey_sz ? slab_sz : skey_sz); }

  // prologue (1) + fused query MLP incl. per-layer splits (1)
  prep_k<<<PREP_BLOCKS,256,0,stream>>>(x,xq0,txr,tbA,
                                       W1,wt1H,wt1L,W2,wt2H,wt2L,W3,wt3H,wt3L);
  qmlp_k<<<8,256,0,stream>>>(xq0,W1,b1,W2,b2,W3,b3,W4,b4,xq1,xq2,xq3,xq4,
                             qH1,qL1,qH2,qL2,qH3,qL3,qH4,qL4,qnb);
  // layer-0 conv/norm (raw padded features; only remaining conv_norm launch)
  conv_norm_k<<<(NT+NB)/4,256,0,stream>>>(tbA, bkAH, bkAL, tnb, NT,
                                          xq0, qH0, qL0, qnb+0*NB, NB, 96);

  knn_layer<3>(xq0, tbA, qH0,qL0, qnb+0*NB, bkAH,bkAL, 1, lbl, tnb, skeys,sT,slab, tot, stream);
  mlp_mfma_k<3><<<2*NTB,256,0,stream>>>(bkAH,bkAL,wt1H,wt1L,b1,tbB,bkBH,bkBL,tnb,NT);
  knn_layer<4>(xq1, tbB, qH1,qL1, qnb+1*NB, bkBH,bkBL, 0, lbl, tnb, skeys,sT,slab, tot, stream);
  mlp_mfma_k<4><<<2*NTB,256,0,stream>>>(bkBH,bkBL,wt2H,wt2L,b2,tbA,bkAH,bkAL,tnb,NT);
  knn_layer<4>(xq2, tbA, qH2,qL2, qnb+2*NB, bkAH,bkAL, 0, lbl, tnb, skeys,sT,slab, tot, stream);
  mlp_mfma_k<4><<<2*NTB,256,0,stream>>>(bkAH,bkAL,wt3H,wt3L,b3,tbB,bkBH,bkBL,tnb,NT);
  knn_layer<4>(xq3, tbB, qH3,qL3, qnb+3*NB, bkBH,bkBL, 0, lbl, tnb, skeys,sT,slab, tot, stream);
  mlp8sm_k<<<(NT+31)/32,256,0,stream>>>(tbB,W4,b4,tb4,bkAH,bkAL,tnb,NT);
  knn_layer<1>(xq4, tb4, qH4,qL4, qnb+4*NB, bkAH,bkAL, 0, lbl, tnb, skeys,sT,slab, tot, stream);

  pvalue_k<<<NB,256,0,stream>>>(tot,cal,out);
}

// Round 13
// 647.611 us; speedup vs baseline: 2.6201x; 1.1208x over previous
//
#include <hip/hip_runtime.h>
#include <math.h>

#define KNN 75
#define NL 8
#define NB 1024
#define NT 50000
#define NT_PAD 50048  // NTB*TT rows allocated for bf16 banks (pad rows masked)
#define NCALI 10000
#define KC 32
#define TT 128
#define NTB 391       // ceil(NT/TT)
#define SLOTS 16      // per (q, t-block) slab: [count, up to 15 hit keys] = 64B
#define CAP 6144      // candidate buffer per query
#define NSUB 2048     // sampled train points for threshold
#define NSB 16        // NSUB/TT subset t-blocks
#define SSTRIDE 24
#define SOFF 11       // 11 + 24*2047 = 49139 < 50000
#define RSEL 32       // sample rank -> expected |{k < T}| ~ 780, lambda/slab ~ 2
#define MLP8_BQ 1563  // ceil(NT/32) bank blocks in mlp8sm; query blocks follow

// prep_k block ranges
#define PB_Q    384                   // NB*96/256
#define PB_BANK 18750                 // NT*96/256
#define PB_W1   48                    // 128*96/256
#define PB_W23  64                    // 128*128/256
#define PREP_BLOCKS (PB_Q+PB_BANK+PB_W1+2*PB_W23)

typedef __attribute__((ext_vector_type(8))) short bf16x8;
typedef __attribute__((ext_vector_type(4))) float f32x4;

__device__ __forceinline__ int swz(int c){ return c + ((c>>5)<<2); }

__device__ __forceinline__ unsigned short f2bf_rn(float x){
  unsigned u = __float_as_uint(x);
  unsigned r = (u + 0x7FFFu + ((u>>16)&1u)) >> 16;
  return (unsigned short)r;
}
__device__ __forceinline__ float bf2f(unsigned short h){
  return __uint_as_float(((unsigned)h)<<16);
}
__device__ __forceinline__ bf16x8 ld8(const unsigned short* p){
  return *(const bf16x8*)p;
}
// async global->LDS, 16B per lane; LDS dest = wave-uniform base + lane*16
__device__ __forceinline__ void gl_lds16(const unsigned short* g, unsigned short* l){
  __builtin_amdgcn_global_load_lds(
      (const __attribute__((address_space(1))) void*)g,
      (__attribute__((address_space(3))) void*)l, 16, 0, 0);
}

// ---------------- fused prologue: pad copies + weight splits ------------------
__device__ __forceinline__ void pad_one(const float* __restrict__ in,
                                        float* __restrict__ out, int M,
                                        int Din, int Dout, int idx){
  if (idx >= M*Dout) return;
  int r = idx / Dout, c = idx - r*Dout;
  out[idx] = (c < Din) ? in[r*Din + c] : 0.f;
}
__device__ __forceinline__ void wsplit_one(const float* __restrict__ W, int kreal,
                                           int dp, unsigned short* __restrict__ WtH,
                                           unsigned short* __restrict__ WtL, int idx){
  int n = idx / dp, k = idx - n*dp;
  float v = (k < kreal) ? W[(size_t)k*128 + n] : 0.f;
  unsigned short h = f2bf_rn(v);
  WtH[idx] = h;
  WtL[idx] = f2bf_rn(v - bf2f(h));
}
__global__ void prep_k(const float* __restrict__ x, float* __restrict__ xq0,
                       const float* __restrict__ txr, float* __restrict__ tbA,
                       const float* __restrict__ W1, unsigned short* wt1H, unsigned short* wt1L,
                       const float* __restrict__ W2, unsigned short* wt2H, unsigned short* wt2L,
                       const float* __restrict__ W3, unsigned short* wt3H, unsigned short* wt3L){
  int b = blockIdx.x, tid = threadIdx.x;
  if (b < PB_Q){
    pad_one(x, xq0, NB, 83, 96, b*256 + tid);
  } else if (b < PB_Q + PB_BANK){
    pad_one(txr, tbA, NT, 83, 96, (b-PB_Q)*256 + tid);
  } else if (b < PB_Q + PB_BANK + PB_W1){
    wsplit_one(W1, 83, 96,  wt1H, wt1L, (b-PB_Q-PB_BANK)*256 + tid);
  } else if (b < PB_Q + PB_BANK + PB_W1 + PB_W23){
    wsplit_one(W2, 128, 128, wt2H, wt2L, (b-PB_Q-PB_BANK-PB_W1)*256 + tid);
  } else {
    wsplit_one(W3, 128, 128, wt3H, wt3L, (b-PB_Q-PB_BANK-PB_W1-PB_W23)*256 + tid);
  }
}

// ---- bank logits + softmax + split/norm; query rows appended (blocks >= MLP8_BQ)
__global__ void mlp8sm_k(const float* __restrict__ AB, const float* __restrict__ AQ,
                         const float* __restrict__ W4, const float* __restrict__ b4,
                         float* __restrict__ OutB,
                         unsigned short* __restrict__ SBH, unsigned short* __restrict__ SBL,
                         float* __restrict__ nrmB,
                         float* __restrict__ OutQ,
                         unsigned short* __restrict__ SQH, unsigned short* __restrict__ SQL,
                         float* __restrict__ nrmQ){
  __shared__ float Ws[128*8];
  int tid = threadIdx.x;
  for (int i=tid;i<1024;i+=256) Ws[i]=W4[i];
  __syncthreads();
  int b = blockIdx.x;
  bool isq = (b >= MLP8_BQ);
  int r = (isq ? (b-MLP8_BQ) : b)*32 + (tid>>3), c = tid&7;
  int M = isq ? NB : NT;
  if (r >= M) return;
  const float* A = isq ? AQ : AB;
  float* Out = isq ? OutQ : OutB;
  unsigned short* SH = isq ? SQH : SBH;
  unsigned short* SL = isq ? SQL : SBL;
  float* nrm = isq ? nrmQ : nrmB;
  const float* a = &A[(size_t)r*128];
  float acc = b4[c];
  #pragma unroll 16
  for (int k=0;k<128;k++) acc += a[k]*Ws[k*8+c];
  int lane = tid & 63, base = lane & ~7;
  float v[8];
  #pragma unroll
  for (int j=0;j<8;j++) v[j] = __shfl(acc, base+j, 64);
  float m=-1e30f;
  #pragma unroll
  for (int j=0;j<8;j++) m = v[j]>m ? v[j] : m;
  float s=0.f;
  #pragma unroll
  for (int j=0;j<8;j++){ v[j]=__expf(v[j]-m); s+=v[j]; }
  float inv=1.f/s;
  float nn=0.f;
  #pragma unroll
  for (int j=0;j<8;j++){ float pv=v[j]*inv; v[j]=pv; nn+=pv*pv; }
  float* p = &Out[(size_t)r*32];
  float pv = v[c];
  p[c]    = pv;
  p[8+c]  = 0.f;
  p[16+c] = 0.f;
  p[24+c] = 0.f;
  unsigned short h = f2bf_rn(pv);
  SH[(size_t)r*32 + c]    = h;
  SL[(size_t)r*32 + c]    = f2bf_rn(pv - bf2f(h));
  SH[(size_t)r*32 + 8+c]  = 0; SL[(size_t)r*32 + 8+c]  = 0;
  SH[(size_t)r*32 + 16+c] = 0; SL[(size_t)r*32 + 16+c] = 0;
  SH[(size_t)r*32 + 24+c] = 0; SL[(size_t)r*32 + 24+c] = 0;
  if (c==0) nrm[r] = nn;
}

// ---- fp32 -> (hi,lo) bf16 split + row squared-norms (layer 0 only) -----------
__global__ void conv_norm_k(
    const float* __restrict__ XA, unsigned short* __restrict__ HA,
    unsigned short* __restrict__ LA, float* __restrict__ nA, int MA,
    const float* __restrict__ XB, unsigned short* __restrict__ HB,
    unsigned short* __restrict__ LB, float* __restrict__ nB, int MB,
    int dp)
{
  int w = threadIdx.x>>6, lane = threadIdx.x&63;
  int row = blockIdx.x*4 + w;
  const float* src; unsigned short* dh; unsigned short* dl; float* nrm;
  if (row < MA){
    src=&XA[(size_t)row*dp]; dh=&HA[(size_t)row*dp]; dl=&LA[(size_t)row*dp]; nrm=&nA[row];
  } else {
    int r2 = row - MA;
    if (r2 >= MB) return;
    src=&XB[(size_t)r2*dp]; dh=&HB[(size_t)r2*dp]; dl=&LB[(size_t)r2*dp]; nrm=&nB[r2];
  }
  float s=0.f;
  for (int c=lane*2; c<dp; c+=128){
    float2 v = *(const float2*)&src[c];
    s += v.x*v.x + v.y*v.y;
    unsigned short h0 = f2bf_rn(v.x), h1 = f2bf_rn(v.y);
    float r0 = v.x - bf2f(h0), r1 = v.y - bf2f(h1);
    ushort2 hh; hh.x=h0; hh.y=h1;
    ushort2 ll; ll.x=f2bf_rn(r0); ll.y=f2bf_rn(r1);
    *(ushort2*)&dh[c]=hh;
    *(ushort2*)&dl[c]=ll;
  }
  #pragma unroll
  for (int off=32;off>0;off>>=1) s += __shfl_down(s, off, 64);
  if (lane==0) *nrm=s;
}

// ---------------- scan helper: find bin containing rank Krem ------------------
__device__ __forceinline__ void find_bin(int* hist, int* part, int nb, int Krem,
                                         int tid, int* s_B, int* s_lob){
  int ch = nb>>8;
  int base = tid*ch;
  int s=0;
  for (int b=base;b<base+ch;b++) s+=hist[b];
  int lane = tid & 63, wv = tid>>6;
  int v = s;
  #pragma unroll
  for (int off=1; off<64; off<<=1){
    int u = __shfl_up(v, off, 64);
    if (lane >= off) v += u;
  }
  if (lane==63) part[wv] = v;
  __syncthreads();
  int wbase = 0;
  #pragma unroll
  for (int w2=0; w2<4; w2++) wbase += (w2 < wv) ? part[w2] : 0;
  v += wbase;
  int excl = v - s;
  if (v >= Krem && excl < Krem){
    int lob = excl, B = base + ch - 1;
    for (int b=base;b<base+ch;b++){
      if (lob + hist[b] >= Krem){ B=b; break; }
      lob += hist[b];
    }
    *s_B = B; *s_lob = lob;
  }
  if (tid==255 && v < Krem){ *s_B = nb-1; *s_lob = 0; }  // preserve old default
  __syncthreads();
}

// ---------------- per-query threshold: exact RSEL-th smallest sample key ------
__global__ __launch_bounds__(256) void sel64_k(const unsigned* __restrict__ skeys,
                                               unsigned* __restrict__ Tthr){
  __shared__ unsigned buf[NSUB];
  __shared__ int hist[2048];
  __shared__ int part[256];
  __shared__ int sB, sLob;
  int tid=threadIdx.x, q=blockIdx.x;
  for (int i=tid;i<NSUB;i+=256) buf[i]=skeys[(size_t)q*NSUB+i];
  int Krem=RSEL;
  for (int i=tid;i<2048;i+=256) hist[i]=0;
  __syncthreads();
  for (int i=tid;i<NSUB;i+=256) atomicAdd(&hist[buf[i]>>21],1);
  __syncthreads();
  find_bin(hist,part,2048,Krem,tid,&sB,&sLob);
  unsigned pre=(unsigned)sB; Krem-=sLob;
  for (int i=tid;i<2048;i+=256) hist[i]=0;
  __syncthreads();
  for (int i=tid;i<NSUB;i+=256){ unsigned k=buf[i]; if ((k>>21)==pre) atomicAdd(&hist[(k>>10)&0x7FFu],1); }
  __syncthreads();
  find_bin(hist,part,2048,Krem,tid,&sB,&sLob);
  pre=(pre<<11)|(unsigned)sB; Krem-=sLob;
  for (int i=tid;i<1024;i+=256) hist[i]=0;
  __syncthreads();
  for (int i=tid;i<NSUB;i+=256){ unsigned k=buf[i]; if ((k>>10)==pre) atomicAdd(&hist[k&0x3FFu],1); }
  __syncthreads();
  find_bin(hist,part,1024,Krem,tid,&sB,&sLob);
  if (tid==0) Tthr[q]=(pre<<10)|(unsigned)sB;
}

// ====== MFMA section: one 64x128 sub-tile x one K-chunk from LDS ==============
#define MFMA_SEC(BHC, BLC, AH, AL)                                               \
  _Pragma("unroll")                                                              \
  for (int tj=0;tj<8;tj++){                                                      \
    int rowB = tj*16 + col;                                                      \
    int sw = (((quad + (rowB>>1)) & 3) << 3);                                    \
    bf16x8 bh = *(const bf16x8*)&(BHC)[rowB*32 + sw];                            \
    bf16x8 bl = *(const bf16x8*)&(BLC)[rowB*32 + sw];                            \
    acc[tj] = __builtin_amdgcn_mfma_f32_16x16x32_bf16(AH, bh, acc[tj], 0,0,0);   \
    acc[tj] = __builtin_amdgcn_mfma_f32_16x16x32_bf16(AH, bl, acc[tj], 0,0,0);   \
    acc[tj] = __builtin_amdgcn_mfma_f32_16x16x32_bf16(AL, bh, acc[tj], 0,0,0);   \
  }

#define MFMA_KLOOP(ROWMAP)                                                       \
  size_t aoff = (size_t)(qbase + w*16 + col)*dp + quad*8;                        \
  const unsigned short* pAH = QH + aoff;                                         \
  const unsigned short* pAL = QL + aoff;                                         \
  int i0 = tid,      row0 = i0>>2, sg0 = ((i0&3) - (row0>>1)) & 3;               \
  int i1 = tid+256,  row1 = i1>>2, sg1 = ((i1&3) - (row1>>1)) & 3;               \
  size_t g0 = (size_t)(ROWMAP(n0+row0))*dp + (size_t)sg0*8;                      \
  size_t g1 = (size_t)(ROWMAP(n0+row1))*dp + (size_t)sg1*8;                      \
  f32x4 acc[8];                                                                  \
  _Pragma("unroll")                                                              \
  for (int tj=0;tj<8;tj++){ f32x4 z={0.f,0.f,0.f,0.f}; acc[tj]=z; }              \
  gl_lds16(TH + g0, BH0 + i0*8);                                                 \
  gl_lds16(TH + g1, BH0 + i1*8);                                                 \
  gl_lds16(TL + g0, BL0 + i0*8);                                                 \
  gl_lds16(TL + g1, BL0 + i1*8);                                                 \
  bf16x8 xh = ld8(pAH), xl = ld8(pAL);                                           \
  bf16x8 yh = xh, yl = xl;                                                       \
  _Pragma("unroll")                                                              \
  for (int kc=0; kc<kchunks; kc+=2){                                             \
    __syncthreads();                                                             \
    if (kc+1 < kchunks){                                                         \
      size_t ko=(size_t)(kc+1)*32;                                               \
      gl_lds16(TH + g0 + ko, BH1 + i0*8);                                        \
      gl_lds16(TH + g1 + ko, BH1 + i1*8);                                        \
      gl_lds16(TL + g0 + ko, BL1 + i0*8);                                        \
      gl_lds16(TL + g1 + ko, BL1 + i1*8);                                        \
      yh = ld8(pAH + ko); yl = ld8(pAL + ko);                                    \
    }                                                                            \
    MFMA_SEC(BH0, BL0, xh, xl);                                                  \
    if (kc+1 < kchunks){                                                         \
      __syncthreads();                                                           \
      if (kc+2 < kchunks){                                                       \
        size_t ko=(size_t)(kc+2)*32;                                             \
        gl_lds16(TH + g0 + ko, BH0 + i0*8);                                      \
        gl_lds16(TH + g1 + ko, BH0 + i1*8);                                      \
        gl_lds16(TL + g0 + ko, BL0 + i0*8);                                      \
        gl_lds16(TL + g1 + ko, BL0 + i1*8);                                      \
        xh = ld8(pAH + ko); xl = ld8(pAL + ko);                                  \
      }                                                                          \
      MFMA_SEC(BH1, BL1, yh, yl);                                                \
    }                                                                            \
  }

#define ROW_ID(r) (r)
#define ROW_SUB(r) ((r)*SSTRIDE + SOFF)

// ---------------- MFMA split-bf16 distance GEMM vs full bank ------------------
template<int KCH>
__global__ __launch_bounds__(256) void dist_mfma_k(
    const unsigned short* __restrict__ QH, const unsigned short* __restrict__ QL,
    const unsigned short* __restrict__ TH, const unsigned short* __restrict__ TL,
    const float* __restrict__ qn, const float* __restrict__ tn,
    const int* __restrict__ labels, const unsigned* __restrict__ Tthr,
    unsigned* __restrict__ slab)
{
  constexpr int dp = KCH*32;
  __shared__ __align__(16) unsigned short smem[4*4096];   // 32 KB
  unsigned short* BH0 = smem;
  unsigned short* BH1 = smem + 4096;
  unsigned short* BL0 = smem + 8192;
  unsigned short* BL1 = smem + 12288;
  unsigned (*hitbuf)[SLOTS] = (unsigned (*)[SLOTS])smem;  // aliases BH0 (4 KB)
  int* hcnt = (int*)(smem + 4096);                        // aliases BH1 head
  int b = blockIdx.x;
  int xcd = b & 7, s = b >> 3;
  int qb = s & 15, tslot = s >> 4;
  int t_blk = xcd + 8*tslot;
  if (t_blk >= NTB) return;
  int tid = threadIdx.x, w = tid>>6, lane = tid&63;
  int quad = lane>>4, col = lane&15;
  int qbase = qb*64;
  int n0 = t_blk*TT;
  constexpr int kchunks = KCH;

  MFMA_KLOOP(ROW_ID)

  // epilogue: barrier FIRST (K-loop LDS reads must complete before aliasing)
  __syncthreads();
  if (tid<64) hcnt[tid]=0;
  __syncthreads();
  float qnr[4]; unsigned Tq[4]; float thrF[4];
  #pragma unroll
  for (int r=0;r<4;r++){
    int q = qbase + w*16 + quad*4 + r;
    qnr[r]  = qn[q];
    Tq[r]   = Tthr[q];
    thrF[r] = __uint_as_float(Tq[r] | 7u);  // superset boundary
  }
  #pragma unroll
  for (int tj=0;tj<8;tj++){
    int t = n0 + tj*16 + col;
    if (t < NT){
      float tnv = tn[t];
      unsigned lab = (unsigned)labels[t];
      #pragma unroll
      for (int r=0;r<4;r++){
        float d2 = fmaf(-2.f, acc[tj][r], qnr[r] + tnv);
        if (d2 <= thrF[r]){
          float d2c = fmaxf(d2, 0.f);
          unsigned key = (__float_as_uint(d2c)&0xFFFFFFF8u) | lab;
          if (key < Tq[r]){
            int ql = w*16 + quad*4 + r;
            int idx = atomicAdd(&hcnt[ql], 1);
            if (idx < SLOTS-1) hitbuf[ql][1+idx] = key;
          }
        }
      }
    }
  }
  __syncthreads();
  if (tid<64) hitbuf[tid][0]=(unsigned)hcnt[tid];
  __syncthreads();
  // slab[q][t_blk]: final_k reads each query's 391 slabs contiguously
  {
    int q = tid>>2, sub = (tid&3)*4;
    uint4 v = *(uint4*)&hitbuf[q][sub];
    *(uint4*)&slab[((size_t)(qbase+q)*NTB + t_blk)*SLOTS + sub] = v;
  }
}

// ---------------- MFMA split-bf16 distance GEMM vs SAMPLED subset -------------
template<int KCH>
__global__ __launch_bounds__(256) void dist_sub_k(
    const unsigned short* __restrict__ QH, const unsigned short* __restrict__ QL,
    const unsigned short* __restrict__ TH, const unsigned short* __restrict__ TL,
    const float* __restrict__ qn, const float* __restrict__ tn,
    const int* __restrict__ labels, unsigned* __restrict__ keys)
{
  constexpr int dp = KCH*32;
  __shared__ __align__(16) unsigned short smem[4*4096];   // 32 KB
  unsigned short* BH0 = smem;
  unsigned short* BH1 = smem + 4096;
  unsigned short* BL0 = smem + 8192;
  unsigned short* BL1 = smem + 12288;
  int b = blockIdx.x;
  int qb = b & 15, t_blk = b >> 4;           // t_blk in [0, NSB)
  int tid = threadIdx.x, w = tid>>6, lane = tid&63;
  int quad = lane>>4, col = lane&15;
  int qbase = qb*64;
  int n0 = t_blk*TT;                         // subset-space row base
  constexpr int kchunks = KCH;

  MFMA_KLOOP(ROW_SUB)

  // epilogue: write all keys; 16-lane quad -> 64B contiguous store per (tj,r)
  float qnr[4];
  #pragma unroll
  for (int r=0;r<4;r++)
    qnr[r] = qn[qbase + w*16 + quad*4 + r];
  #pragma unroll
  for (int tj=0;tj<8;tj++){
    int sI = n0 + tj*16 + col;
    int g  = sI*SSTRIDE + SOFF;
    float tnv = tn[g];
    unsigned lab = (unsigned)labels[g];
    #pragma unroll
    for (int r=0;r<4;r++){
      float d2 = fmaxf(fmaf(-2.f, acc[tj][r], qnr[r] + tnv), 0.f);
      unsigned key = (__float_as_uint(d2)&0xFFFFFFF8u) | lab;
      int q = qbase + w*16 + quad*4 + r;
      keys[(size_t)q*NSUB + sI] = key;
    }
  }
}

// ---------------- MFMA split-bf16 MLP: Out = relu(A @ Wt^T + b) ---------------
// Bank rows in blocks [0, 2*NTB); QUERY rows appended in blocks [2*NTB, +16)
// (query pointers selected per-block). Emits fp32 out + bf16 hi/lo split +
// row norms straight from registers. Replaces the 76us 8-block serial qmlp_k
// (0.3% occupancy, pure latency) at +2% block count on a full-GPU kernel.
template<int KCH>
__global__ __launch_bounds__(256) void mlp_mfma_k(
    const unsigned short* __restrict__ bkH, const unsigned short* __restrict__ bkL,
    const unsigned short* __restrict__ qh,  const unsigned short* __restrict__ ql,
    const unsigned short* __restrict__ TH, const unsigned short* __restrict__ TL,
    const float* __restrict__ bias,
    float* __restrict__ OutB, unsigned short* __restrict__ SBH,
    unsigned short* __restrict__ SBL, float* __restrict__ nrmB,
    float* __restrict__ OutQ, unsigned short* __restrict__ SQH,
    unsigned short* __restrict__ SQL, float* __restrict__ nrmQ)
{
  constexpr int dp = KCH*32;
  __shared__ __align__(16) unsigned short smem[4*4096];   // 32 KB
  unsigned short* BH0 = smem;
  unsigned short* BH1 = smem + 4096;
  unsigned short* BL0 = smem + 8192;
  unsigned short* BL1 = smem + 12288;
  int b = blockIdx.x;
  bool isq = (b >= 2*NTB);
  const unsigned short* QH = isq ? qh : bkH;
  const unsigned short* QL = isq ? ql : bkL;
  float* Out = isq ? OutQ : OutB;
  unsigned short* SH = isq ? SQH : SBH;
  unsigned short* SL = isq ? SQL : SBL;
  float* nrm = isq ? nrmQ : nrmB;
  int M = isq ? NB : NT;
  int tid = threadIdx.x, w = tid>>6, lane = tid&63;
  int quad = lane>>4, col = lane&15;
  int qbase = (isq ? (b - 2*NTB) : b) * 64;
  int n0 = 0;                                // Wt rows 0..127
  constexpr int kchunks = KCH;

  MFMA_KLOOP(ROW_ID)

  // epilogue: bias + relu + fp32 store + bf16 split + row norm
  float bb[8];
  #pragma unroll
  for (int tj=0;tj<8;tj++) bb[tj] = bias[tj*16 + col];
  #pragma unroll
  for (int r=0;r<4;r++){
    int row = qbase + w*16 + quad*4 + r;
    if (row < M){
      float vv[8]; float s=0.f;
      #pragma unroll
      for (int tj=0;tj<8;tj++){
        float v = acc[tj][r] + bb[tj];
        v = v > 0.f ? v : 0.f;
        vv[tj] = v;
        s += v*v;
        Out[(size_t)row*128 + tj*16 + col] = v;
      }
      // 16-lane (quad) reduce for the row norm
      #pragma unroll
      for (int off=1; off<16; off<<=1) s += __shfl_xor(s, off, 16);
      if (col==0) nrm[row] = s;
      #pragma unroll
      for (int tj=0;tj<8;tj++){
        unsigned short h = f2bf_rn(vv[tj]);
        SH[(size_t)row*128 + tj*16 + col] = h;
        SL[(size_t)row*128 + tj*16 + col] = f2bf_rn(vv[tj] - bf2f(h));
      }
    }
  }
}

// ---------------- gather slabs, exact radix select + class sums ---------------
__global__ __launch_bounds__(256) void final_k(
    const unsigned* __restrict__ slab,
    const float* __restrict__ Qm, const float* __restrict__ Tm,
    const float* __restrict__ qn, const float* __restrict__ tn,
    const int* __restrict__ labels,
    float* __restrict__ tot, int first, int dp)
{
  __shared__ int hist[2048];
  __shared__ int part[256];
  __shared__ unsigned buf[CAP];
  __shared__ unsigned lowbuf[96];
  __shared__ float qrow[128];
  __shared__ int sB,sLob,s_cnt,s_low,s_bad;
  __shared__ float s_w[9];
  int tid=threadIdx.x, q=blockIdx.x;
  if (tid==0){ for (int j=0;j<9;j++) s_w[j]=0.f; s_cnt=0; s_low=0; s_bad=0; }
  __syncthreads();

  // [q][t_blk] layout: query q's slabs are ONE contiguous 25KB run
  const unsigned* sq = slab + (size_t)q*NTB*SLOTS;
  for (int sidx=tid; sidx<NTB; sidx+=256){
    const unsigned* s = sq + (size_t)sidx*SLOTS;
    uint4 a = *(const uint4*)s;
    unsigned cnt = a.x;
    if (cnt > SLOTS-1){ s_bad=1; continue; }
    if (!cnt) continue;
    int base = atomicAdd(&s_cnt, (int)cnt);
    if (base + (int)cnt <= CAP){
      buf[base] = a.y;
      if (cnt>=2) buf[base+1] = a.z;
      if (cnt>=3) buf[base+2] = a.w;
      for (unsigned w=4; w<=cnt; w++) buf[base+w-1] = s[w];
    }
  }
  __syncthreads();
  int total = s_cnt;
  int bad = s_bad;

#define CONTRIB(kk) do{ float d2_=__uint_as_float((kk)&0xFFFFFFF8u); \
    if (d2_>0.f){ float w_=1.0f/sqrtf(d2_); \
      atomicAdd(&s_w[8],w_); atomicAdd(&s_w[(kk)&7u],w_); } }while(0)

  unsigned T; int Krem=KNN;
  if (!bad && total>=KNN && total<=CAP){
    for (int i=tid;i<2048;i+=256) hist[i]=0;
    __syncthreads();
    for (int i=tid;i<total;i+=256) atomicAdd(&hist[buf[i]>>21],1);
    __syncthreads();
    find_bin(hist,part,2048,Krem,tid,&sB,&sLob);
    unsigned pre=(unsigned)sB; Krem-=sLob;
    for (int i=tid;i<2048;i+=256) hist[i]=0;
    __syncthreads();
    for (int i=tid;i<total;i+=256){ unsigned k=buf[i]; if ((k>>21)==pre) atomicAdd(&hist[(k>>10)&0x7FFu],1); }
    __syncthreads();
    find_bin(hist,part,2048,Krem,tid,&sB,&sLob);
    pre=(pre<<11)|(unsigned)sB; Krem-=sLob;
    for (int i=tid;i<1024;i+=256) hist[i]=0;
    __syncthreads();
    for (int i=tid;i<total;i+=256){ unsigned k=buf[i]; if ((k>>10)==pre) atomicAdd(&hist[k&0x3FFu],1); }
    __syncthreads();
    find_bin(hist,part,1024,Krem,tid,&sB,&sLob);
    T=(pre<<10)|(unsigned)sB; Krem-=sLob;
    __syncthreads();
    for (int i=tid;i<total;i+=256){ unsigned k=buf[i]; if (k<T) CONTRIB(k); }
  } else {
    // fallback (P ~ 1e-10): exact fp32 full recompute select
    if (tid==0) s_cnt=0;
    for (int i=tid;i<dp;i+=256) qrow[i]=Qm[(size_t)q*dp+i];
    __syncthreads();
    float qq=qn[q];
    auto KEY=[&](int t)->unsigned{
      const float* br=&Tm[(size_t)t*dp];
      float dot=0.f;
      for (int k2=0;k2<dp;k2++) dot+=qrow[k2]*br[k2];
      float d2=fmaxf(qq-2.f*dot+tn[t],0.f);
      return (__float_as_uint(d2)&0xFFFFFFF8u)|(unsigned)labels[t];
    };
    for (int i=tid;i<2048;i+=256) hist[i]=0;
    __syncthreads();
    for (int t=tid;t<NT;t+=256) atomicAdd(&hist[KEY(t)>>21],1);
    __syncthreads();
    find_bin(hist,part,2048,Krem,tid,&sB,&sLob);
    int c=hist[sB]; Krem-=sLob;
    unsigned prefix=(unsigned)sB; int shift=21;
    if (c > CAP){
      __syncthreads();
      for (int i=tid;i<2048;i+=256) hist[i]=0;
      __syncthreads();
      for (int t=tid;t<NT;t+=256){ unsigned k=KEY(t); if ((k>>21)==prefix) atomicAdd(&hist[(k>>10)&0x7FFu],1); }
      __syncthreads();
      find_bin(hist,part,2048,Krem,tid,&sB,&sLob);
      c=hist[sB]; Krem-=sLob; prefix=(prefix<<11)|(unsigned)sB; shift=10;
    }
    if (c > CAP){
      __syncthreads();
      for (int i=tid;i<1024;i+=256) hist[i]=0;
      __syncthreads();
      for (int t=tid;t<NT;t+=256){ unsigned k=KEY(t); if ((k>>10)==prefix) atomicAdd(&hist[k&0x3FFu],1); }
      __syncthreads();
      find_bin(hist,part,1024,Krem,tid,&sB,&sLob);
      c=hist[sB]; Krem-=sLob; prefix=(prefix<<10)|(unsigned)sB; shift=0;
    }
    if (c <= CAP){
      for (int t=tid;t<NT;t+=256){
        unsigned k=KEY(t); unsigned pp=k>>shift;
        if (pp==prefix){ int j=atomicAdd(&s_cnt,1); if (j<CAP) buf[j]=k; }
        else if (pp<prefix){ int j=atomicAdd(&s_low,1); if (j<96) lowbuf[j]=k; }
      }
      __syncthreads();
      int sh=shift;
      while (sh>0){
        int nsh=(sh==21)?10:0;
        int nb=1<<(sh-nsh);
        __syncthreads();
        for (int i=tid;i<nb;i+=256) hist[i]=0;
        __syncthreads();
        int cc=s_cnt;
        for (int i=tid;i<cc;i+=256) atomicAdd(&hist[(buf[i]>>nsh)&(unsigned)(nb-1)],1);
        __syncthreads();
        find_bin(hist,part,nb,Krem,tid,&sB,&sLob);
        Krem-=sLob; prefix=(prefix<<(sh-nsh))|(unsigned)sB; sh=nsh;
      }
      T=prefix;
      __syncthreads();
      int lowc=s_low, cc=s_cnt;
      for (int i=tid;i<lowc;i+=256){ unsigned k=lowbuf[i]; CONTRIB(k); }
      for (int i=tid;i<cc;i+=256){ unsigned k=buf[i]; if (k<T) CONTRIB(k); }
    } else {
      T=prefix;
      for (int t=tid;t<NT;t+=256){ unsigned k=KEY(t); if (k<T) CONTRIB(k); }
    }
  }
  __syncthreads();
  if (tid==0){
    float d2=__uint_as_float(T&0xFFFFFFF8u);
    float w=(d2>0.f)?(1.0f/sqrtf(d2)):0.f;
    s_w[8] += (float)Krem*w;
    s_w[T&7u] += (float)Krem*w;
  }
  __syncthreads();
  if (tid<8){
    float contrib = s_w[8]-s_w[tid];
    size_t o=(size_t)q*NL+tid;
    tot[o] = first ? contrib : tot[o]+contrib;
  }
#undef CONTRIB
}

// ---------------- empirical p-values ------------------------------------------
__global__ void pvalue_k(const float* __restrict__ tot, const float* __restrict__ cali,
                         float* __restrict__ out){
  __shared__ float t8[NL];
  __shared__ int part[4][NL];
  int tid=threadIdx.x, q=blockIdx.x;
  if (tid<NL) t8[tid]=tot[(size_t)q*NL+tid];
  __syncthreads();
  float th[NL];
  #pragma unroll
  for (int c=0;c<NL;c++) th[c]=t8[c];
  int cnt[NL];
  #pragma unroll
  for (int c=0;c<NL;c++) cnt[c]=0;
  for (int i=tid;i<NCALI;i+=256){
    float v=cali[i];
    #pragma unroll
    for (int c=0;c<NL;c++) cnt[c] += (v>=th[c]) ? 1 : 0;
  }
  #pragma unroll
  for (int c=0;c<NL;c++){
    #pragma unroll
    for (int off=32;off>0;off>>=1) cnt[c]+=__shfl_down(cnt[c],off,64);
  }
  if ((tid&63)==0){
    #pragma unroll
    for (int c=0;c<NL;c++) part[tid>>6][c]=cnt[c];
  }
  __syncthreads();
  if (tid<NL){
    int s=part[0][tid]+part[1][tid]+part[2][tid]+part[3][tid];
    out[(size_t)q*NL+tid] = (float)s / 10000.f;
  }
}

// ---------------- one kNN layer (templated on KCH = dp/32) --------------------
template<int KCH>
static void knn_layer(const float* Qm, const float* Bank,
                      const unsigned short* qh, const unsigned short* ql, float* qnl,
                      const unsigned short* bkH, const unsigned short* bkL,
                      int first, const int* lbl, float* tnb,
                      unsigned* skeys, unsigned* sT, unsigned* slab,
                      float* tot, hipStream_t stream){
  constexpr int dp = KCH*32;
  dist_sub_k<KCH><<<16*NSB,256,0,stream>>>(qh,ql,bkH,bkL,qnl,tnb,lbl,skeys);
  sel64_k<<<NB,256,0,stream>>>(skeys,sT);
  dist_mfma_k<KCH><<<8*16*49,256,0,stream>>>(qh,ql,bkH,bkL,qnl,tnb,lbl,sT,slab);
  final_k<<<NB,256,0,stream>>>(slab,Qm,Bank,qnl,tnb,lbl,tot,first,dp);
}

extern "C" void kernel_launch(void* const* d_in, const int* in_sizes, int n_in,
                              void* d_out, int out_size, void* d_ws, size_t ws_size,
                              hipStream_t stream) {
  const float* x   = (const float*)d_in[0];
  const float* txr = (const float*)d_in[1];
  const int*   lbl = (const int*)  d_in[2];
  const float* cal = (const float*)d_in[3];
  const float* W1  = (const float*)d_in[4];
  const float* b1  = (const float*)d_in[5];
  const float* W2  = (const float*)d_in[6];
  const float* b2  = (const float*)d_in[7];
  const float* W3  = (const float*)d_in[8];
  const float* b3  = (const float*)d_in[9];
  const float* W4  = (const float*)d_in[10];
  const float* b4  = (const float*)d_in[11];
  float* out = (float*)d_out;
  float* ws  = (float*)d_ws;

  size_t off=0;
  float* xq0=ws+off; off+=(size_t)NB*96;
  float* xq1=ws+off; off+=(size_t)NB*128;
  float* xq2=ws+off; off+=(size_t)NB*128;
  float* xq3=ws+off; off+=(size_t)NB*128;
  float* xq4=ws+off; off+=(size_t)NB*32;
  float* tbA=ws+off; off+=(size_t)NT*128;
  float* tbB=ws+off; off+=(size_t)NT*128;
  float* tb4=ws+off; off+=(size_t)NT*32;
  float* qnb=ws+off; off+=(size_t)5*NB;
  float* tnb=ws+off; off+=(size_t)NT;
  float* tot=ws+off; off+=(size_t)NB*NL;
  unsigned* sT=(unsigned*)(ws+off); off+=NB;
  // per-layer query splits (hi/lo), strides: L0=96, L1-3=128, L4=32
  unsigned short* qH0=(unsigned short*)(ws+off); off+=(size_t)NB*48;
  unsigned short* qL0=(unsigned short*)(ws+off); off+=(size_t)NB*48;
  unsigned short* qH1=(unsigned short*)(ws+off); off+=(size_t)NB*64;
  unsigned short* qL1=(unsigned short*)(ws+off); off+=(size_t)NB*64;
  unsigned short* qH2=(unsigned short*)(ws+off); off+=(size_t)NB*64;
  unsigned short* qL2=(unsigned short*)(ws+off); off+=(size_t)NB*64;
  unsigned short* qH3=(unsigned short*)(ws+off); off+=(size_t)NB*64;
  unsigned short* qL3=(unsigned short*)(ws+off); off+=(size_t)NB*64;
  unsigned short* qH4=(unsigned short*)(ws+off); off+=(size_t)NB*16;
  unsigned short* qL4=(unsigned short*)(ws+off); off+=(size_t)NB*16;
  // double-buffered bank splits (mlp_mfma reads one pair, writes the other)
  unsigned short* bkAH=(unsigned short*)(ws+off); off+=(size_t)NT_PAD*64;
  unsigned short* bkAL=(unsigned short*)(ws+off); off+=(size_t)NT_PAD*64;
  unsigned short* bkBH=(unsigned short*)(ws+off); off+=(size_t)NT_PAD*64;
  unsigned short* bkBL=(unsigned short*)(ws+off); off+=(size_t)NT_PAD*64;
  unsigned short* wt1H=(unsigned short*)(ws+off); off+=(size_t)128*48;
  unsigned short* wt1L=(unsigned short*)(ws+off); off+=(size_t)128*48;
  unsigned short* wt2H=(unsigned short*)(ws+off); off+=(size_t)128*64;
  unsigned short* wt2L=(unsigned short*)(ws+off); off+=(size_t)128*64;
  unsigned short* wt3H=(unsigned short*)(ws+off); off+=(size_t)128*64;
  unsigned short* wt3L=(unsigned short*)(ws+off); off+=(size_t)128*64;
  off=(off+3)&~(size_t)3;
  unsigned* slab=(unsigned*)(ws+off);   // NB*NTB*SLOTS = 25.6 MB
  unsigned* skeys=(unsigned*)(ws+off);  // NB*NSUB     =  8.4 MB (aliased; skeys
                                        // dead before dist_mfma_k writes slab)
  { size_t slab_sz=(size_t)NB*NTB*SLOTS, skey_sz=(size_t)NB*NSUB;
    off += (slab_sz > skey_sz ? slab_sz : skey_sz); }

  // prologue (1) + layer-0 conv/norm (1); query MLP rides the bank MLP kernels
  prep_k<<<PREP_BLOCKS,256,0,stream>>>(x,xq0,txr,tbA,
                                       W1,wt1H,wt1L,W2,wt2H,wt2L,W3,wt3H,wt3L);
  conv_norm_k<<<(NT+NB)/4,256,0,stream>>>(tbA, bkAH, bkAL, tnb, NT,
                                          xq0, qH0, qL0, qnb+0*NB, NB, 96);

  knn_layer<3>(xq0, tbA, qH0,qL0, qnb+0*NB, bkAH,bkAL, 1, lbl, tnb, skeys,sT,slab, tot, stream);
  mlp_mfma_k<3><<<2*NTB+16,256,0,stream>>>(bkAH,bkAL, qH0,qL0, wt1H,wt1L, b1,
                                           tbB,bkBH,bkBL,tnb, xq1,qH1,qL1,qnb+1*NB);
  knn_layer<4>(xq1, tbB, qH1,qL1, qnb+1*NB, bkBH,bkBL, 0, lbl, tnb, skeys,sT,slab, tot, stream);
  mlp_mfma_k<4><<<2*NTB+16,256,0,stream>>>(bkBH,bkBL, qH1,qL1, wt2H,wt2L, b2,
                                           tbA,bkAH,bkAL,tnb, xq2,qH2,qL2,qnb+2*NB);
  knn_layer<4>(xq2, tbA, qH2,qL2, qnb+2*NB, bkAH,bkAL, 0, lbl, tnb, skeys,sT,slab, tot, stream);
  mlp_mfma_k<4><<<2*NTB+16,256,0,stream>>>(bkAH,bkAL, qH2,qL2, wt3H,wt3L, b3,
                                           tbB,bkBH,bkBL,tnb, xq3,qH3,qL3,qnb+3*NB);
  knn_layer<4>(xq3, tbB, qH3,qL3, qnb+3*NB, bkBH,bkBL, 0, lbl, tnb, skeys,sT,slab, tot, stream);
  mlp8sm_k<<<MLP8_BQ+32,256,0,stream>>>(tbB, xq3, W4, b4,
                                        tb4,bkAH,bkAL,tnb, xq4,qH4,qL4,qnb+4*NB);
  knn_layer<1>(xq4, tb4, qH4,qL4, qnb+4*NB, bkAH,bkAL, 0, lbl, tnb, skeys,sT,slab, tot, stream);

  pvalue_k<<<NB,256,0,stream>>>(tot,cal,out);
}